// Round 6
// baseline (1049.005 us; speedup 1.0000x reference)
//
#include <hip/hip_runtime.h>
#include <math.h>

// ---------------------------------------------------------------------------
// Model constants
// ---------------------------------------------------------------------------
namespace {
constexpr int B_ = 4, T_ = 12, N_ = 2000, D_ = 16, FF_ = 64, E_ = 4, L_ = 2;
constexpr int EA_ = 3000, H_ = 3, HD_ = EA_ / H_;   // 1000
constexpr int BT_ = B_ * T_;                         // 48 rows per r-group
constexpr int R3_ = 3 * BT_;                         // 144 stacked rows
constexpr long long NN_ = (long long)N_ * N_;        // 4,000,000
constexpr int BTN_ = B_ * T_ * N_;                   // 96,000
constexpr float BETA_ = 0.01f, CW_ = 0.001f;
constexpr int RKS_ = 50;                             // r-GEMM split-K
constexpr int RKC_ = 40;                             // r-GEMM k-chunk (5 groups of 8)

// ---------------------------------------------------------------------------
// Workspace layout (float offsets)
// ---------------------------------------------------------------------------
constexpr size_t OFF_OUT4 = 0;                                   // [B,T,N,D]
constexpr size_t OFF_LOWT = OFF_OUT4 + (size_t)BTN_ * D_;        // lowT^T [N][48]
constexpr size_t OFF_HVT  = OFF_LOWT + BTN_;                     // highV^T [N][48]
constexpr size_t OFF_ALIN = OFF_HVT + BTN_;                      // r^T [N][144]
constexpr size_t OFF_RT   = OFF_ALIN + (size_t)N_ * R3_;         // R^T [EA][144]
constexpr size_t OFF_P    = OFF_RT + (size_t)EA_ * R3_;          // P [144][9000]
constexpr size_t OFF_AOT  = OFF_P + (size_t)R3_ * 3 * EA_;       // Ao^T [EA][144]
constexpr size_t OFF_OT   = OFF_AOT + (size_t)EA_ * R3_;         // O^T  [EA][144]
constexpr size_t OFF_O2P  = OFF_OT + (size_t)EA_ * R3_;          // out2 pre-p2 [B][T*N]
constexpr size_t OFF_OUTP = OFF_O2P + BTN_;                      // outp [B,T,N]
constexpr size_t OFF_O2F  = OFF_OUTP + BTN_;                     // out2 final [B,T,N]
constexpr size_t OFF_G1   = OFF_O2F + BTN_;                      // f1 normalized*10 [8000][12]
constexpr size_t OFF_G2   = OFF_G1 + 96000;                      // f2 normalized [8000][12]
constexpr size_t OFF_LI   = OFF_G2 + 96000;                      // li [8000]
constexpr size_t OFF_S    = OFF_LI + 8000;                       // G row sums [2000]
constexpr size_t OFF_RSL  = OFF_S + 2000;                        // rowsum lowT [48]
constexpr size_t OFF_RSH  = OFF_RSL + 48;                        // rowsum hv [48]
constexpr size_t OFF_STP  = OFF_RSH + 48;                        // stat partials 3*512*2
constexpr size_t OFF_STAT = OFF_STP + 3072;                      // {mu,isd} x3
constexpr size_t OFF_MMP  = OFF_STAT + 8;                        // minmax partials [3][64][2]
constexpr size_t OFF_AB   = OFF_MMP + 384;                       // {alpha,beta} x3
constexpr size_t OFF_CSP  = OFF_AB + 8;                          // colsum partials [16][3000]
constexpr size_t OFF_CS   = OFF_CSP + 48000;                     // lt_w colsums [3000]
constexpr size_t OFF_FEAT = OFF_CS + 3000;                       // feat [B][D]
constexpr size_t OFF_GATE = OFF_FEAT + 64;                       // gates [B][E]
constexpr size_t OFF_BAL  = OFF_GATE + 16;                       // balance scalar
constexpr size_t OFF_PART = ((OFF_BAL + 1 + 255) & ~(size_t)255); // GEMM split-K partials
} // namespace

// ---------------------------------------------------------------------------
// Small helpers
// ---------------------------------------------------------------------------
__device__ __forceinline__ float waveReduceSum(float v) {
  for (int off = 32; off; off >>= 1) v += __shfl_down(v, off);
  return v;
}

// 48 FMAs: acc[0..47] += a4[.] * bv  (fixed order -> bit-identical partials)
__device__ __forceinline__ void fma48(float* __restrict__ acc,
                                      const float4* __restrict__ a4, float bv) {
#pragma unroll
  for (int r4 = 0; r4 < BT_ / 4; ++r4) {
    float4 av = a4[r4];
    acc[r4 * 4 + 0] = fmaf(av.x, bv, acc[r4 * 4 + 0]);
    acc[r4 * 4 + 1] = fmaf(av.y, bv, acc[r4 * 4 + 1]);
    acc[r4 * 4 + 2] = fmaf(av.z, bv, acc[r4 * 4 + 2]);
    acc[r4 * 4 + 3] = fmaf(av.w, bv, acc[r4 * 4 + 3]);
  }
}

// ---------------------------------------------------------------------------
__global__ void k_init(float* ws) {
  if (threadIdx.x == 0) ws[OFF_BAL] = 0.f;
}

// out4[b,t,n,d] = x[b,t,n]*sw[d] + sb[d]
__global__ void k_start(const float* __restrict__ x, const float* __restrict__ sw,
                        const float* __restrict__ sb, float* __restrict__ out4) {
  int i = blockIdx.x * 256 + threadIdx.x;
  if (i >= BTN_ * D_) return;
  int d = i & 15;
  out4[i] = fmaf(x[i >> 4], sw[d], sb[d]);
}

// feat[b,d] = mean over (t,n) of out4
__global__ void k_feat(const float* __restrict__ out4, float* __restrict__ feat) {
  int b = blockIdx.x >> 4, d = blockIdx.x & 15;
  float s = 0.f;
  for (int tn = threadIdx.x; tn < T_ * N_; tn += 256)
    s += out4[((size_t)b * T_ * N_ + tn) * D_ + d];
  __shared__ float red[4];
  s = waveReduceSum(s);
  if ((threadIdx.x & 63) == 0) red[threadIdx.x >> 6] = s;
  __syncthreads();
  if (threadIdx.x == 0)
    feat[blockIdx.x] = (red[0] + red[1] + red[2] + red[3]) * (1.f / (T_ * N_));
}

// logits -> top2 -> gates + balance accumulation (single block)
__global__ void k_gate(const float* __restrict__ feat, const float* __restrict__ gw,
                       float* __restrict__ ws, int l) {
  __shared__ float lg[B_ * E_];
  int tid = threadIdx.x;
  if (tid < B_ * E_) {
    int b = tid >> 2, e = tid & 3;
    float s = 0.f;
    for (int d = 0; d < D_; ++d) s = fmaf(feat[b * D_ + d], gw[(l * D_ + d) * E_ + e], s);
    lg[tid] = s;
  }
  __syncthreads();
  if (tid == 0) {
    float* gates = ws + OFF_GATE;
    float imp[E_] = {0, 0, 0, 0}, load[E_] = {0, 0, 0, 0};
    for (int i = 0; i < B_ * E_; ++i) gates[i] = 0.f;
    for (int b = 0; b < B_; ++b) {
      const float* lb = lg + b * E_;
      int i1 = 0; float v1 = lb[0];
      for (int e = 1; e < E_; ++e) if (lb[e] > v1) { v1 = lb[e]; i1 = e; }
      int i2 = -1; float v2 = -1e30f;
      for (int e = 0; e < E_; ++e) { if (e == i1) continue; if (lb[e] > v2) { v2 = lb[e]; i2 = e; } }
      float e2 = expf(v2 - v1);
      float den = 1.f + e2;
      float g1 = 1.f / den, g2 = e2 / den;
      gates[b * E_ + i1] = g1; gates[b * E_ + i2] = g2;
      imp[i1] += g1; imp[i2] += g2; load[i1] += 1.f; load[i2] += 1.f;
    }
    float bal = 0.f;
    float m = 0.f; for (int e = 0; e < E_; ++e) m += imp[e]; m *= 0.25f;
    float v = 0.f; for (int e = 0; e < E_; ++e) { float d = imp[e] - m; v += d * d; } v *= 0.25f;
    bal += v / (m * m + 1e-10f);
    m = 0.f; for (int e = 0; e < E_; ++e) m += load[e]; m *= 0.25f;
    v = 0.f; for (int e = 0; e < E_; ++e) { float d = load[e] - m; v += d * d; } v *= 0.25f;
    bal += v / (m * m + 1e-10f);
    ws[OFF_BAL] += bal;
  }
}

// MoE expert apply (in-place residual), layer l
__global__ void k_expert(float* __restrict__ out4, const float* __restrict__ w1,
                         const float* __restrict__ b1, const float* __restrict__ w2,
                         const float* __restrict__ b2, const float* __restrict__ ws, int l) {
  int b = blockIdx.y;
  int tn = blockIdx.x * 256 + threadIdx.x;
  if (tn >= T_ * N_) return;
  float* row = out4 + ((size_t)b * T_ * N_ + tn) * D_;
  float r[D_], acc[D_];
#pragma unroll
  for (int d = 0; d < D_; ++d) { r[d] = row[d]; acc[d] = r[d]; }
  const float* gates = ws + OFF_GATE;
  for (int e = 0; e < E_; ++e) {
    float g = gates[b * E_ + e];
    if (g <= 0.f) continue;
    const float* W1 = w1 + (size_t)(l * E_ + e) * D_ * FF_;
    const float* B1 = b1 + (size_t)(l * E_ + e) * FF_;
    const float* W2 = w2 + (size_t)(l * E_ + e) * FF_ * D_;
    const float* B2 = b2 + (size_t)(l * E_ + e) * D_;
#pragma unroll 4
    for (int f = 0; f < FF_; ++f) {
      float p = B1[f];
#pragma unroll
      for (int d = 0; d < D_; ++d) p = fmaf(r[d], W1[d * FF_ + f], p);
      float c = 0.7978845608028654f * (p + 0.044715f * p * p * p);
      float hv = 0.5f * p * (1.f + tanhf(c));
      float gh = g * hv;
#pragma unroll
      for (int d = 0; d < D_; ++d) acc[d] = fmaf(gh, W2[f * D_ + d], acc[d]);
    }
#pragma unroll
    for (int d = 0; d < D_; ++d) acc[d] = fmaf(g, B2[d], acc[d]);
  }
#pragma unroll
  for (int d = 0; d < D_; ++d) row[d] = acc[d];
}

// wavelet split; writes transposed [n][row], row = t*B+b
__global__ void k_wavelet(const float* __restrict__ x, const float* __restrict__ velo,
                          float* __restrict__ lowT, float* __restrict__ hvT) {
  int i = blockIdx.x * 256 + threadIdx.x;
  if (i >= BTN_) return;
  int b = i / (T_ * N_);
  int t = (i / N_) % T_;
  int n = i % N_;
  int ip = b * T_ * N_ + ((t + T_ - 1) % T_) * N_ + n;
  int row = t * B_ + b;
  lowT[(size_t)n * BT_ + row] = 0.5f * (x[i] + x[ip]);
  hvT[(size_t)n * BT_ + row] = 0.5f * (velo[i] - velo[ip]);
}

// row sums of lowT / hvT (96 blocks)
__global__ void k_rowsum(const float* __restrict__ lowT, const float* __restrict__ hvT,
                         float* __restrict__ ws) {
  int which = blockIdx.x / BT_;
  int row = blockIdx.x % BT_;
  const float* M = which ? hvT : lowT;
  float s = 0.f;
  for (int n = threadIdx.x; n < N_; n += 256) s += M[(size_t)n * BT_ + row];
  __shared__ float red[4];
  s = waveReduceSum(s);
  if ((threadIdx.x & 63) == 0) red[threadIdx.x >> 6] = s;
  __syncthreads();
  if (threadIdx.x == 0) ws[(which ? OFF_RSH : OFF_RSL) + row] = red[0] + red[1] + red[2] + red[3];
}

// S[m] = sum_n v0[m]/adj[m,n]
__global__ void k_S(const float* __restrict__ adj, const float* __restrict__ v0,
                    float* __restrict__ S) {
  int m = blockIdx.x;
  float vm = v0[m];
  const float* a = adj + (size_t)m * N_;
  float s = 0.f;
  for (int n = threadIdx.x; n < N_; n += 256) s += vm / a[n];
  __shared__ float red[4];
  s = waveReduceSum(s);
  if ((threadIdx.x & 63) == 0) red[threadIdx.x >> 6] = s;
  __syncthreads();
  if (threadIdx.x == 0) S[m] = red[0] + red[1] + red[2] + red[3];
}

// sum / sumsq of a dense NxN matrix  (512 blocks)
__global__ void k_stats(const float* __restrict__ M, float* __restrict__ part) {
  float s = 0.f, ss = 0.f;
  for (long long i = blockIdx.x * 256 + threadIdx.x; i < NN_; i += 512 * 256) {
    float v = M[i];
    s += v; ss = fmaf(v, v, ss);
  }
  __shared__ float r1[4], r2[4];
  for (int off = 32; off; off >>= 1) { s += __shfl_down(s, off); ss += __shfl_down(ss, off); }
  if ((threadIdx.x & 63) == 0) { r1[threadIdx.x >> 6] = s; r2[threadIdx.x >> 6] = ss; }
  __syncthreads();
  if (threadIdx.x == 0) {
    part[blockIdx.x * 2] = r1[0] + r1[1] + r1[2] + r1[3];
    part[blockIdx.x * 2 + 1] = r2[0] + r2[1] + r2[2] + r2[3];
  }
}

// same but for the on-the-fly NS laplacian
__global__ void k_nsstats(const float* __restrict__ adj, const float* __restrict__ v0,
                          const float* __restrict__ S, float* __restrict__ part) {
  float s = 0.f, ss = 0.f;
  for (long long i = blockIdx.x * 256 + threadIdx.x; i < NN_; i += 512 * 256) {
    int m = (int)(i / N_), n = (int)(i % N_);
    float e = -(v0[m] / adj[i]);
    if (m == n) e += S[m];
    s += e; ss = fmaf(e, e, ss);
  }
  __shared__ float r1[4], r2[4];
  for (int off = 32; off; off >>= 1) { s += __shfl_down(s, off); ss += __shfl_down(ss, off); }
  if ((threadIdx.x & 63) == 0) { r1[threadIdx.x >> 6] = s; r2[threadIdx.x >> 6] = ss; }
  __syncthreads();
  if (threadIdx.x == 0) {
    part[blockIdx.x * 2] = r1[0] + r1[1] + r1[2] + r1[3];
    part[blockIdx.x * 2 + 1] = r2[0] + r2[1] + r2[2] + r2[3];
  }
}

// combine 512 {sum,sumsq} partials -> {mu, 1/std}
__global__ void k_stats2(const float* __restrict__ part, float* __restrict__ stat) {
  float s = 0.f, ss = 0.f;
  for (int i = threadIdx.x; i < 512; i += 256) { s += part[i * 2]; ss += part[i * 2 + 1]; }
  __shared__ float r1[4], r2[4];
  for (int off = 32; off; off >>= 1) { s += __shfl_down(s, off); ss += __shfl_down(ss, off); }
  if ((threadIdx.x & 63) == 0) { r1[threadIdx.x >> 6] = s; r2[threadIdx.x >> 6] = ss; }
  __syncthreads();
  if (threadIdx.x == 0) {
    float su = r1[0] + r1[1] + r1[2] + r1[3];
    float sq = r2[0] + r2[1] + r2[2] + r2[3];
    float mu = su * (1.f / (float)NN_);
    float var = sq * (1.f / (float)NN_) - mu * mu;
    stat[0] = mu;
    stat[1] = 1.f / sqrtf(var);
  }
}

// ---------------------------------------------------------------------------
// Skinny streaming GEMM, 48 accumulator rows per block, software-pipelined
// (groups of 8 K-steps, next group's B prefetched). Row-group g folded into
// blockIdx.x (g = x % gz) so the gz row-groups of one column chunk dispatch
// adjacently and share the B stream in L2.
// part[(ks*rowTot + g*48 + r)*NC + col]
// ---------------------------------------------------------------------------
__global__ __launch_bounds__(256) void k_gemm48(
    const float* __restrict__ AT, int lda, int rowTot,
    const float* __restrict__ Bm, float* __restrict__ part,
    int Kdim, int NC, int kchunk, int gz) {
  int g = blockIdx.x % gz;
  int cb = blockIdx.x / gz;
  int col = cb * 256 + threadIdx.x;
  int m0 = blockIdx.y * kchunk;
  int m1 = min(Kdim, m0 + kchunk);
  float acc[BT_];
#pragma unroll
  for (int r = 0; r < BT_; ++r) acc[r] = 0.f;
  if (col < NC) {
    const float* ap = AT + (size_t)m0 * lda + g * BT_;
    const float* bp = Bm + (size_t)m0 * NC + col;
    int len = m1 - m0;
    int ng = len >> 3;
    float bc[8];
    if (ng > 0) {
#pragma unroll
      for (int u = 0; u < 8; ++u) bc[u] = bp[(size_t)u * NC];
    }
    for (int gi = 0; gi < ng; ++gi) {
      float bn[8];
      bool more = (gi + 1 < ng);
      if (more) {
#pragma unroll
        for (int u = 0; u < 8; ++u) bn[u] = bp[(size_t)(8 + u) * NC];
      }
#pragma unroll
      for (int u = 0; u < 8; ++u)
        fma48(acc, (const float4*)(ap + (size_t)u * lda), bc[u]);
      ap += (size_t)8 * lda;
      bp += (size_t)8 * NC;
      if (more) {
#pragma unroll
        for (int u = 0; u < 8; ++u) bc[u] = bn[u];
      }
    }
    for (int m = m0 + (ng << 3); m < m1; ++m) {
      fma48(acc, (const float4*)ap, *bp);
      ap += lda;
      bp += NC;
    }
    float* pp = part + ((size_t)blockIdx.y * rowTot + g * BT_) * NC + col;
#pragma unroll
    for (int r = 0; r < BT_; ++r) pp[(size_t)r * NC] = acc[r];
  }
}

// NS-laplacian variant: B generated on the fly from adj/v0/S, same pipeline
__global__ __launch_bounds__(256) void k_gemmNS(
    const float* __restrict__ hvT, const float* __restrict__ adj,
    const float* __restrict__ v0, const float* __restrict__ S,
    float* __restrict__ part, int kchunk) {
  int col = blockIdx.x * 256 + threadIdx.x;
  int m0 = blockIdx.y * kchunk;
  int m1 = min(N_, m0 + kchunk);
  float acc[BT_];
#pragma unroll
  for (int r = 0; r < BT_; ++r) acc[r] = 0.f;
  if (col < N_) {
    const float* ap = hvT + (size_t)m0 * BT_;
    const float* jp = adj + (size_t)m0 * N_ + col;
    int len = m1 - m0;
    int ng = len >> 3;
    float jc[8];
    if (ng > 0) {
#pragma unroll
      for (int u = 0; u < 8; ++u) jc[u] = jp[(size_t)u * N_];
    }
    int m = m0;
    for (int gi = 0; gi < ng; ++gi) {
      float jn[8];
      bool more = (gi + 1 < ng);
      if (more) {
#pragma unroll
        for (int u = 0; u < 8; ++u) jn[u] = jp[(size_t)(8 + u) * N_];
      }
#pragma unroll
      for (int u = 0; u < 8; ++u) {
        float bv = -(v0[m + u] / jc[u]);
        if (m + u == col) bv += S[m + u];
        fma48(acc, (const float4*)(ap + (size_t)u * BT_), bv);
      }
      m += 8;
      ap += (size_t)8 * BT_;
      jp += (size_t)8 * N_;
      if (more) {
#pragma unroll
        for (int u = 0; u < 8; ++u) jc[u] = jn[u];
      }
    }
    for (; m < m1; ++m) {
      float bv = -(v0[m] / (*jp));
      if (m == col) bv += S[m];
      fma48(acc, (const float4*)ap, bv);
      ap += BT_;
      jp += N_;
    }
    float* pp = part + (size_t)blockIdx.y * BT_ * N_ + col;
#pragma unroll
    for (int r = 0; r < BT_; ++r) pp[(size_t)r * N_] = acc[r];
  }
}

// epilogue: r matmul + fused std-normalization -> ALIN[n][g*48+row]
__global__ void k_epiR(const float* __restrict__ part, float* __restrict__ ws,
                       int ksplit, int g, int statIdx, size_t rsOff) {
  int n = blockIdx.x * 256 + threadIdx.x;
  int row = blockIdx.y;
  if (n >= N_) return;
  float s = 0.f;
  for (int ks = 0; ks < ksplit; ++ks) s += part[((size_t)(ks * BT_ + row)) * N_ + n];
  float mu = ws[OFF_STAT + statIdx], isd = ws[OFF_STAT + statIdx + 1];
  float val = (s - mu * ws[rsOff + row]) * isd;
  ws[OFF_ALIN + (size_t)n * R3_ + g * BT_ + row] = val;
}

// min/max per r-group
__global__ void k_minmax(const float* __restrict__ alin, float* __restrict__ mmp) {
  int g = blockIdx.y;
  float mn = 3.4e38f, mx = -3.4e38f;
  for (int i = blockIdx.x * 256 + threadIdx.x; i < N_ * BT_; i += 64 * 256) {
    int n = i / BT_, r = i % BT_;
    float v = alin[(size_t)n * R3_ + g * BT_ + r];
    mn = fminf(mn, v); mx = fmaxf(mx, v);
  }
  __shared__ float rn[4], rx[4];
  for (int off = 32; off; off >>= 1) {
    mn = fminf(mn, __shfl_down(mn, off));
    mx = fmaxf(mx, __shfl_down(mx, off));
  }
  if ((threadIdx.x & 63) == 0) { rn[threadIdx.x >> 6] = mn; rx[threadIdx.x >> 6] = mx; }
  __syncthreads();
  if (threadIdx.x == 0) {
    mn = fminf(fminf(rn[0], rn[1]), fminf(rn[2], rn[3]));
    mx = fmaxf(fmaxf(rx[0], rx[1]), fmaxf(rx[2], rx[3]));
    mmp[(size_t)(g * 64 + blockIdx.x) * 2] = mn;
    mmp[(size_t)(g * 64 + blockIdx.x) * 2 + 1] = mx;
  }
}

__global__ void k_minmax2(float* __restrict__ ws) {
  int g = blockIdx.x;
  int i = threadIdx.x;  // 64 threads
  float mn = ws[OFF_MMP + (size_t)(g * 64 + i) * 2];
  float mx = ws[OFF_MMP + (size_t)(g * 64 + i) * 2 + 1];
  for (int off = 32; off; off >>= 1) {
    mn = fminf(mn, __shfl_down(mn, off));
    mx = fmaxf(mx, __shfl_down(mx, off));
  }
  if (i == 0) {
    float denom = fmaxf(mx - mn, 1e-8f);
    float a = 1.f / denom;
    ws[OFF_AB + g * 2] = a;
    ws[OFF_AB + g * 2 + 1] = -mn * a;
  }
}

// lt_w column sums (two stage)
__global__ void k_colsum(const float* __restrict__ ltw, float* __restrict__ csp) {
  int e = blockIdx.x * 256 + threadIdx.x;
  int ks = blockIdx.y;
  if (e >= EA_) return;
  float s = 0.f;
  for (int n = ks * 125; n < (ks + 1) * 125; ++n) s += ltw[(size_t)n * EA_ + e];
  csp[(size_t)ks * EA_ + e] = s;
}
__global__ void k_colsum2(float* __restrict__ ws) {
  int e = blockIdx.x * 256 + threadIdx.x;
  if (e >= EA_) return;
  float s = 0.f;
  for (int ks = 0; ks < 16; ++ks) s += ws[OFF_CSP + (size_t)ks * EA_ + e];
  ws[OFF_CS + e] = s;
}

// lin epilogue: rng01 folded in -> RT[e][row144]
__global__ void k_epiLin(const float* __restrict__ part, const float* __restrict__ ltb,
                         float* __restrict__ ws, int ksplit) {
  int e = blockIdx.x * 256 + threadIdx.x;
  int row = blockIdx.y;
  if (e >= EA_) return;
  float s = 0.f;
  for (int ks = 0; ks < ksplit; ++ks) s += part[((size_t)(ks * R3_ + row)) * EA_ + e];
  int g = row / BT_;
  float a = ws[OFF_AB + g * 2], bb = ws[OFF_AB + g * 2 + 1];
  ws[OFF_RT + (size_t)e * R3_ + row] = fmaf(a, s, fmaf(bb, ws[OFF_CS + e], ltb[e]));
}

// qkv epilogue -> P[row144][9000]
__global__ void k_epiQkv(const float* __restrict__ part, const float* __restrict__ qkvb,
                         float* __restrict__ P, int ksplit) {
  int c = blockIdx.x * 256 + threadIdx.x;
  int row = blockIdx.y;
  if (c >= 3 * EA_) return;
  float s = 0.f;
  for (int ks = 0; ks < ksplit; ++ks) s += part[((size_t)(ks * R3_ + row)) * (3 * EA_) + c];
  P[(size_t)row * (3 * EA_) + c] = s + qkvb[c];
}

// attention core (tiny): one block per (mha, s, b, h)
__global__ void k_attn(const float* __restrict__ P, float* __restrict__ AoT) {
  int mha = blockIdx.y;
  int s_ = blockIdx.x / (B_ * H_);
  int rem = blockIdx.x % (B_ * H_);
  int b = rem / H_, h = rem % H_;
  const int pq[3] = {0, 1, 2}, pk[3] = {1, 2, 0}, pv[3] = {2, 0, 1};
  const float* qrow = P + ((size_t)(pq[mha] * BT_ + s_ * B_ + b)) * (3 * EA_) + h * HD_;
  __shared__ float sc[T_];
  __shared__ float red[4];
  for (int t = 0; t < T_; ++t) {
    const float* krow = P + ((size_t)(pk[mha] * BT_ + t * B_ + b)) * (3 * EA_) + EA_ + h * HD_;
    float p = 0.f;
    for (int d = threadIdx.x; d < HD_; d += 256) p = fmaf(qrow[d], krow[d], p);
    p = waveReduceSum(p);
    if ((threadIdx.x & 63) == 0) red[threadIdx.x >> 6] = p;
    __syncthreads();
    if (threadIdx.x == 0) sc[t] = (red[0] + red[1] + red[2] + red[3]) * 0.031622776601683794f;
    __syncthreads();
  }
  float a[T_];
  float m = sc[0];
#pragma unroll
  for (int t = 1; t < T_; ++t) m = fmaxf(m, sc[t]);
  float sum = 0.f;
#pragma unroll
  for (int t = 0; t < T_; ++t) { a[t] = expf(sc[t] - m); sum += a[t]; }
  float inv = 1.f / sum;
#pragma unroll
  for (int t = 0; t < T_; ++t) a[t] *= inv;
  int orow = mha * BT_ + s_ * B_ + b;
  for (int d = threadIdx.x; d < HD_; d += 256) {
    float o = 0.f;
#pragma unroll
    for (int t = 0; t < T_; ++t)
      o = fmaf(a[t], P[((size_t)(pv[mha] * BT_ + t * B_ + b)) * (3 * EA_) + 2 * EA_ + h * HD_ + d], o);
    AoT[(size_t)(h * HD_ + d) * R3_ + orow] = o;
  }
}

// attn-out epilogue -> OT[c][row144]
__global__ void k_epiAO(const float* __restrict__ part, const float* __restrict__ aob,
                        float* __restrict__ OT, int ksplit) {
  int c = blockIdx.x * 256 + threadIdx.x;
  int row = blockIdx.y;
  if (c >= EA_) return;
  float s = 0.f;
  for (int ks = 0; ks < ksplit; ++ks) s += part[((size_t)(ks * R3_ + row)) * EA_ + c];
  OT[(size_t)c * R3_ + row] = s + aob[c];
}

// ll epilogue: sum three mha branches -> out2_pre[b][t*N+n] (with BETA and 3*bias)
__global__ void k_epiLL(const float* __restrict__ part, const float* __restrict__ llb,
                        float* __restrict__ o2p, int ksplit) {
  int n = blockIdx.x * 256 + threadIdx.x;
  int row = blockIdx.y;  // t*B+b
  if (n >= N_) return;
  float s = 0.f;
  for (int g = 0; g < 3; ++g)
    for (int ks = 0; ks < ksplit; ++ks)
      s += part[((size_t)(ks * R3_ + g * BT_ + row)) * N_ + n];
  int t = row / B_, b = row % B_;
  o2p[(size_t)b * (T_ * N_) + t * N_ + n] = BETA_ * (s + 3.f * llb[n]);
}

// trunk projection outp[b,t,n]
__global__ void k_proj(const float* __restrict__ out4, const float* __restrict__ pw,
                       const float* __restrict__ pb, float* __restrict__ outp) {
  int i = blockIdx.x * 256 + threadIdx.x;
  if (i >= BTN_) return;
  int b = i / (T_ * N_);
  int t = (i / N_) % T_;
  int n = i % N_;
  float acc = pb[t];
  for (int t2 = 0; t2 < T_; ++t2) {
    const float* o = out4 + ((size_t)(b * T_ + t2) * N_ + n) * D_;
#pragma unroll
    for (int d = 0; d < D_; ++d) acc = fmaf(o[d], pw[(t2 * D_ + d) * T_ + t], acc);
  }
  outp[i] = acc;
}

// p2 (replicates the reshape(-1,T) quirk exactly)
__global__ void k_p2(const float* __restrict__ o2p, const float* __restrict__ p2w,
                     const float* __restrict__ p2b, float* __restrict__ o2f) {
  int i = blockIdx.x * 256 + threadIdx.x;
  if (i >= BTN_) return;
  int b = i / (T_ * N_);
  int t = (i / N_) % T_;
  int n = i % N_;
  float acc = p2b[t];
  const float* src = o2p + (size_t)b * (T_ * N_) + (size_t)n * T_;
#pragma unroll
  for (int c = 0; c < T_; ++c) acc = fmaf(src[c], p2w[c * T_ + t], acc);
  o2f[i] = acc;
}

__global__ void k_out3(const float* __restrict__ outp, const float* __restrict__ o2f,
                       float* __restrict__ dout) {
  int i = blockIdx.x * 256 + threadIdx.x;
  if (i < BTN_) dout[i] = outp[i] + o2f[i];
}

// row-normalize f1 (x10 for /0.1) and f2
__global__ void k_fnorm(const float* __restrict__ outp, const float* __restrict__ o2f,
                        float* __restrict__ g1, float* __restrict__ g2) {
  int r = blockIdx.x * 256 + threadIdx.x;
  if (r >= B_ * N_) return;
  int b = r / N_, n = r % N_;
  float v1[T_], v2[T_];
  float s1 = 0.f, s2 = 0.f;
#pragma unroll
  for (int t = 0; t < T_; ++t) {
    v1[t] = outp[(size_t)b * T_ * N_ + t * N_ + n];
    v2[t] = o2f[(size_t)b * T_ * N_ + t * N_ + n];
    s1 = fmaf(v1[t], v1[t], s1);
    s2 = fmaf(v2[t], v2[t], s2);
  }
  float n1 = fmaxf(sqrtf(s1), 1e-12f), n2 = fmaxf(sqrtf(s2), 1e-12f);
  float i1 = 10.f / n1, i2 = 1.f / n2;
#pragma unroll
  for (int t = 0; t < T_; ++t) {
    g1[(size_t)r * T_ + t] = v1[t] * i1;
    g2[(size_t)r * T_ + t] = v2[t] * i2;
  }
}

// per-row logsumexp + diagonal of sim.
// 16 rows per block x 16 threads per row; one accumulator per thread (no spill).
__global__ __launch_bounds__(256) void k_lse(const float* __restrict__ g1,
                                             const float* __restrict__ g2,
                                             float* __restrict__ li) {
  int r = threadIdx.x >> 4;   // 0..15 row within block
  int k = threadIdx.x & 15;   // 0..15 j-phase
  int row = blockIdx.x * 16 + r;
  const float4* qp = (const float4*)(g1 + (size_t)row * T_);
  float4 qa = qp[0], qb = qp[1], qc = qp[2];
  float sm = 0.f, sd = 0.f;
  for (int j = k; j < B_ * N_; j += 16) {
    const float4* p = (const float4*)(g2 + (size_t)j * T_);
    float4 A = p[0], Bv = p[1], C = p[2];
    float s = qa.x * A.x;
    s = fmaf(qa.y, A.y, s);  s = fmaf(qa.z, A.z, s);  s = fmaf(qa.w, A.w, s);
    s = fmaf(qb.x, Bv.x, s); s = fmaf(qb.y, Bv.y, s); s = fmaf(qb.z, Bv.z, s);
    s = fmaf(qb.w, Bv.w, s); s = fmaf(qc.x, C.x, s);  s = fmaf(qc.y, C.y, s);
    s = fmaf(qc.z, C.z, s);  s = fmaf(qc.w, C.w, s);
    sm += __expf(s);
    if (j == row) sd = s;
  }
#pragma unroll
  for (int off = 8; off; off >>= 1) {
    sm += __shfl_xor(sm, off);
    sd += __shfl_xor(sd, off);
  }
  if (k == 0) li[row] = sd - logf(sm);
}

__global__ void k_final(const float* __restrict__ li, const float* __restrict__ ws,
                        float* __restrict__ dout) {
  float s = 0.f;
  for (int i = threadIdx.x; i < B_ * N_; i += 256) s += li[i];
  __shared__ float red[4];
  s = waveReduceSum(s);
  if ((threadIdx.x & 63) == 0) red[threadIdx.x >> 6] = s;
  __syncthreads();
  if (threadIdx.x == 0) {
    float closs = -(red[0] + red[1] + red[2] + red[3]) * (1.f / (B_ * N_));
    dout[BTN_] = ws[OFF_BAL];
    dout[BTN_ + 1] = CW_ * closs;
  }
}

// ---------------------------------------------------------------------------
extern "C" void kernel_launch(void* const* d_in, const int* in_sizes, int n_in,
                              void* d_out, int out_size, void* d_ws, size_t ws_size,
                              hipStream_t stream) {
  const float* x    = (const float*)d_in[0];
  const float* velo = (const float*)d_in[1];
  const float* adj  = (const float*)d_in[2];
  const float* lapd = (const float*)d_in[3];
  const float* laph = (const float*)d_in[4];
  const float* sw   = (const float*)d_in[5];
  const float* sb   = (const float*)d_in[6];
  const float* gw   = (const float*)d_in[7];
  const float* ew1  = (const float*)d_in[8];
  const float* eb1  = (const float*)d_in[9];
  const float* ew2  = (const float*)d_in[10];
  const float* eb2  = (const float*)d_in[11];
  const float* pw   = (const float*)d_in[12];
  const float* pb   = (const float*)d_in[13];
  const float* ltw  = (const float*)d_in[14];
  const float* ltb  = (const float*)d_in[15];
  const float* qkvw = (const float*)d_in[16];
  const float* qkvb = (const float*)d_in[17];
  const float* aow  = (const float*)d_in[18];
  const float* aob  = (const float*)d_in[19];
  const float* llw  = (const float*)d_in[20];
  const float* llb  = (const float*)d_in[21];
  const float* p2w  = (const float*)d_in[22];
  const float* p2b  = (const float*)d_in[23];
  float* ws = (float*)d_ws;
  float* dout = (float*)d_out;
  const float* v0 = velo;  // velo[0,0,:]
  float* part = ws + OFF_PART;
  dim3 b256(256);

  // adaptive split-K selection against workspace size
  size_t availF = (ws_size / 4 > OFF_PART) ? (ws_size / 4 - OFF_PART) : 0;
  auto pick = [&](const int* c, int n, size_t perSplit, int fb) {
    for (int i = 0; i < n; ++i)
      if ((size_t)c[i] * perSplit <= availF) return c[i];
    return fb;
  };
  const int cQ[] = {25, 12, 8, 4};
  const int cL[] = {25, 16};
  int qkvS = pick(cQ, 4, (size_t)R3_ * 3 * EA_, 4);
  int linS = pick(cL, 2, (size_t)R3_ * EA_, 16);
  int aoS  = linS;
  int llS  = pick(cL, 2, (size_t)R3_ * N_, 16);
  int qkvC = (EA_ + qkvS - 1) / qkvS;
  int linC = (N_ + linS - 1) / linS;
  int aoC  = (EA_ + aoS - 1) / aoS;
  int llC  = (EA_ + llS - 1) / llS;

  k_init<<<dim3(1), dim3(64), 0, stream>>>(ws);
  k_start<<<dim3((BTN_ * D_ + 255) / 256), b256, 0, stream>>>(x, sw, sb, ws + OFF_OUT4);

  for (int l = 0; l < L_; ++l) {
    k_feat<<<dim3(B_ * D_), b256, 0, stream>>>(ws + OFF_OUT4, ws + OFF_FEAT);
    k_gate<<<dim3(1), dim3(64), 0, stream>>>(ws + OFF_FEAT, gw, ws, l);
    k_expert<<<dim3((T_ * N_ + 255) / 256, B_), b256, 0, stream>>>(ws + OFF_OUT4, ew1, eb1, ew2, eb2, ws, l);
  }

  k_wavelet<<<dim3((BTN_ + 255) / 256), b256, 0, stream>>>(x, velo, ws + OFF_LOWT, ws + OFF_HVT);
  k_rowsum<<<dim3(2 * BT_), b256, 0, stream>>>(ws + OFF_LOWT, ws + OFF_HVT, ws);
  k_S<<<dim3(N_), b256, 0, stream>>>(adj, v0, ws + OFF_S);
  k_stats<<<dim3(512), b256, 0, stream>>>(lapd, ws + OFF_STP);
  k_stats2<<<dim3(1), b256, 0, stream>>>(ws + OFF_STP, ws + OFF_STAT);
  k_stats<<<dim3(512), b256, 0, stream>>>(laph, ws + OFF_STP + 1024);
  k_stats2<<<dim3(1), b256, 0, stream>>>(ws + OFF_STP + 1024, ws + OFF_STAT + 2);
  k_nsstats<<<dim3(512), b256, 0, stream>>>(adj, v0, ws + OFF_S, ws + OFF_STP + 2048);
  k_stats2<<<dim3(1), b256, 0, stream>>>(ws + OFF_STP + 2048, ws + OFF_STAT + 4);

  // r1 / r2 / r3 with fused normalization (split-K 50, kchunk 40 = 5 groups of 8)
  k_gemm48<<<dim3(8, RKS_), b256, 0, stream>>>(ws + OFF_LOWT, BT_, BT_, lapd, part, N_, N_, RKC_, 1);
  k_epiR<<<dim3(8, 48), b256, 0, stream>>>(part, ws, RKS_, 0, 0, OFF_RSL);
  k_gemmNS<<<dim3(8, RKS_), b256, 0, stream>>>(ws + OFF_HVT, adj, v0, ws + OFF_S, part, RKC_);
  k_epiR<<<dim3(8, 48), b256, 0, stream>>>(part, ws, RKS_, 1, 4, OFF_RSH);
  k_gemm48<<<dim3(8, RKS_), b256, 0, stream>>>(ws + OFF_LOWT, BT_, BT_, laph, part, N_, N_, RKC_, 1);
  k_epiR<<<dim3(8, 48), b256, 0, stream>>>(part, ws, RKS_, 2, 2, OFF_RSL);

  k_minmax<<<dim3(64, 3), b256, 0, stream>>>(ws + OFF_ALIN, ws + OFF_MMP);
  k_minmax2<<<dim3(3), dim3(64), 0, stream>>>(ws);
  k_colsum<<<dim3(12, 16), b256, 0, stream>>>(ltw, ws + OFF_CSP);
  k_colsum2<<<dim3(12), b256, 0, stream>>>(ws);

  // lin: [144,2000] @ lt_w  (3 row-groups folded into grid.x)
  k_gemm48<<<dim3(12 * 3, linS), b256, 0, stream>>>(ws + OFF_ALIN, R3_, R3_, ltw, part, N_, EA_, linC, 3);
  k_epiLin<<<dim3(12, 144), b256, 0, stream>>>(part, ltb, ws, linS);

  // qkv: [144,3000] @ qkv_w[3000,9000]
  k_gemm48<<<dim3(36 * 3, qkvS), b256, 0, stream>>>(ws + OFF_RT, R3_, R3_, qkvw, part, EA_, 3 * EA_, qkvC, 3);
  k_epiQkv<<<dim3(36, 144), b256, 0, stream>>>(part, qkvb, ws + OFF_P, qkvS);

  // attention (3 mha in grid.y)
  k_attn<<<dim3(T_ * B_ * H_, 3), b256, 0, stream>>>(ws + OFF_P, ws + OFF_AOT);

  // attn out projection
  k_gemm48<<<dim3(12 * 3, aoS), b256, 0, stream>>>(ws + OFF_AOT, R3_, R3_, aow, part, EA_, EA_, aoC, 3);
  k_epiAO<<<dim3(12, 144), b256, 0, stream>>>(part, aob, ws + OFF_OT, aoS);

  // ll (back) projection + branch sum
  k_gemm48<<<dim3(8 * 3, llS), b256, 0, stream>>>(ws + OFF_OT, R3_, R3_, llw, part, EA_, N_, llC, 3);
  k_epiLL<<<dim3(8, 48), b256, 0, stream>>>(part, llb, ws + OFF_O2P, llS);

  k_proj<<<dim3((BTN_ + 255) / 256), b256, 0, stream>>>(ws + OFF_OUT4, pw, pb, ws + OFF_OUTP);
  k_p2<<<dim3((BTN_ + 255) / 256), b256, 0, stream>>>(ws + OFF_O2P, p2w, p2b, ws + OFF_O2F);
  k_out3<<<dim3((BTN_ + 255) / 256), b256, 0, stream>>>(ws + OFF_OUTP, ws + OFF_O2F, dout);

  k_fnorm<<<dim3((B_ * N_ + 255) / 256), b256, 0, stream>>>(ws + OFF_OUTP, ws + OFF_O2F, ws + OFF_G1, ws + OFF_G2);
  k_lse<<<dim3(B_ * N_ / 16), b256, 0, stream>>>(ws + OFF_G1, ws + OFF_G2, ws + OFF_LI);
  k_final<<<dim3(1), b256, 0, stream>>>(ws + OFF_LI, ws, dout);
}

// Round 7
// 943.997 us; speedup vs baseline: 1.1112x; 1.1112x over previous
//
#include <hip/hip_runtime.h>
#include <math.h>

// ---------------------------------------------------------------------------
// Model constants
// ---------------------------------------------------------------------------
namespace {
constexpr int B_ = 4, T_ = 12, N_ = 2000, D_ = 16, FF_ = 64, E_ = 4, L_ = 2;
constexpr int EA_ = 3000, H_ = 3, HD_ = EA_ / H_;   // 1000
constexpr int BT_ = B_ * T_;                         // 48
constexpr int R3_ = 3 * BT_;                         // 144
constexpr long long NN_ = (long long)N_ * N_;        // 4,000,000
constexpr int BTN_ = B_ * T_ * N_;                   // 96,000
constexpr float BETA_ = 0.01f, CW_ = 0.001f;
constexpr int RKS_ = 50;                             // r-GEMM split-K
constexpr int RKC_ = 40;                             // r-GEMM k-chunk
constexpr int KP3 = 3008;                            // K=3000 padded to 32
constexpr int KP2 = 2016;                            // K=2000 padded to 32

// ---------------------------------------------------------------------------
// Workspace layout (float offsets)
// ---------------------------------------------------------------------------
constexpr size_t OFF_OUT4 = 0;                                   // [B,T,N,D]
constexpr size_t OFF_LOWT = OFF_OUT4 + (size_t)BTN_ * D_;        // lowT^T [N][48]
constexpr size_t OFF_HVT  = OFF_LOWT + BTN_;                     // highV^T [N][48]
constexpr size_t OFF_ALIN = OFF_HVT + BTN_;                      // r^T [N][144]
constexpr size_t OFF_RT   = OFF_ALIN + (size_t)N_ * R3_;         // (unused, kept)
constexpr size_t OFF_P    = OFF_RT + (size_t)EA_ * R3_;          // P [144][9000]
constexpr size_t OFF_AOT  = OFF_P + (size_t)R3_ * 3 * EA_;       // (unused, kept)
constexpr size_t OFF_OT   = OFF_AOT + (size_t)EA_ * R3_;         // (unused, kept)
constexpr size_t OFF_O2P  = OFF_OT + (size_t)EA_ * R3_;          // out2 pre-p2 [B][T*N]
constexpr size_t OFF_OUTP = OFF_O2P + BTN_;                      // outp [B,T,N]
constexpr size_t OFF_O2F  = OFF_OUTP + BTN_;                     // out2 final [B,T,N]
constexpr size_t OFF_G1   = OFF_O2F + BTN_;                      // f1*10 [8000][12]
constexpr size_t OFF_G2   = OFF_G1 + 96000;                      // f2 [8000][12]
constexpr size_t OFF_LI   = OFF_G2 + 96000;                      // li [8000]
constexpr size_t OFF_S    = OFF_LI + 8000;                       // G row sums [2000]
constexpr size_t OFF_RSL  = OFF_S + 2000;
constexpr size_t OFF_RSH  = OFF_RSL + 48;
constexpr size_t OFF_STP  = OFF_RSH + 48;
constexpr size_t OFF_STAT = OFF_STP + 3072;
constexpr size_t OFF_MMP  = OFF_STAT + 8;
constexpr size_t OFF_AB   = OFF_MMP + 384;
constexpr size_t OFF_CSP  = OFF_AB + 8;
constexpr size_t OFF_CS   = OFF_CSP + 48000;
constexpr size_t OFF_FEAT = OFF_CS + 3000;
constexpr size_t OFF_GATE = OFF_FEAT + 64;
constexpr size_t OFF_BAL  = OFF_GATE + 16;
constexpr size_t OFF_PART = ((OFF_BAL + 1 + 255) & ~(size_t)255); // split-K partials
constexpr size_t PARTCAP  = 6000000;                              // cap (floats)
// bf16 regions (sizes in floats = ushorts/2)
constexpr size_t OFF_BT_Q  = OFF_PART + PARTCAP;                  // qkvw^T  [9000][KP3]
constexpr size_t OFF_BT_A  = OFF_BT_Q + (size_t)9000 * KP3 / 2;   // aow^T   [3000][KP3]
constexpr size_t OFF_BT_L  = OFF_BT_A + (size_t)3000 * KP3 / 2;   // llw^T   [2000][KP3]
constexpr size_t OFF_BT_W  = OFF_BT_L + (size_t)2000 * KP3 / 2;   // ltw^T   [3000][KP2]
constexpr size_t OFF_AT_LIN= OFF_BT_W + (size_t)3000 * KP2 / 2;   // ALIN^T  [144][KP2]
constexpr size_t OFF_AT_Q  = OFF_AT_LIN + (size_t)R3_ * KP2 / 2;  // RT^T    [144][KP3]
constexpr size_t OFF_AT_AO = OFF_AT_Q + (size_t)R3_ * KP3 / 2;    // Ao      [144][KP3]
constexpr size_t OFF_AT_LL = OFF_AT_AO + (size_t)R3_ * KP3 / 2;   // O       [144][KP3]
} // namespace

typedef __attribute__((ext_vector_type(8))) short short8;
typedef __attribute__((ext_vector_type(4))) float f32x4;

// ---------------------------------------------------------------------------
// Helpers
// ---------------------------------------------------------------------------
__device__ __forceinline__ float waveReduceSum(float v) {
  for (int off = 32; off; off >>= 1) v += __shfl_down(v, off);
  return v;
}

__device__ __forceinline__ unsigned short f2bf(float x) {  // RNE fp32->bf16
  unsigned int u = __float_as_uint(x);
  unsigned int r = (u + 0x7FFFu + ((u >> 16) & 1u)) >> 16;
  return (unsigned short)r;
}

__device__ __forceinline__ void fma48(float* __restrict__ acc,
                                      const float4* __restrict__ a4, float bv) {
#pragma unroll
  for (int r4 = 0; r4 < BT_ / 4; ++r4) {
    float4 av = a4[r4];
    acc[r4 * 4 + 0] = fmaf(av.x, bv, acc[r4 * 4 + 0]);
    acc[r4 * 4 + 1] = fmaf(av.y, bv, acc[r4 * 4 + 1]);
    acc[r4 * 4 + 2] = fmaf(av.z, bv, acc[r4 * 4 + 2]);
    acc[r4 * 4 + 3] = fmaf(av.w, bv, acc[r4 * 4 + 3]);
  }
}

// ---------------------------------------------------------------------------
__global__ void k_init(float* ws) {
  if (threadIdx.x == 0) ws[OFF_BAL] = 0.f;
}

__global__ void k_start(const float* __restrict__ x, const float* __restrict__ sw,
                        const float* __restrict__ sb, float* __restrict__ out4) {
  int i = blockIdx.x * 256 + threadIdx.x;
  if (i >= BTN_ * D_) return;
  int d = i & 15;
  out4[i] = fmaf(x[i >> 4], sw[d], sb[d]);
}

__global__ void k_feat(const float* __restrict__ out4, float* __restrict__ feat) {
  int b = blockIdx.x >> 4, d = blockIdx.x & 15;
  float s = 0.f;
  for (int tn = threadIdx.x; tn < T_ * N_; tn += 256)
    s += out4[((size_t)b * T_ * N_ + tn) * D_ + d];
  __shared__ float red[4];
  s = waveReduceSum(s);
  if ((threadIdx.x & 63) == 0) red[threadIdx.x >> 6] = s;
  __syncthreads();
  if (threadIdx.x == 0)
    feat[blockIdx.x] = (red[0] + red[1] + red[2] + red[3]) * (1.f / (T_ * N_));
}

__global__ void k_gate(const float* __restrict__ feat, const float* __restrict__ gw,
                       float* __restrict__ ws, int l) {
  __shared__ float lg[B_ * E_];
  int tid = threadIdx.x;
  if (tid < B_ * E_) {
    int b = tid >> 2, e = tid & 3;
    float s = 0.f;
    for (int d = 0; d < D_; ++d) s = fmaf(feat[b * D_ + d], gw[(l * D_ + d) * E_ + e], s);
    lg[tid] = s;
  }
  __syncthreads();
  if (tid == 0) {
    float* gates = ws + OFF_GATE;
    float imp[E_] = {0, 0, 0, 0}, load[E_] = {0, 0, 0, 0};
    for (int i = 0; i < B_ * E_; ++i) gates[i] = 0.f;
    for (int b = 0; b < B_; ++b) {
      const float* lb = lg + b * E_;
      int i1 = 0; float v1 = lb[0];
      for (int e = 1; e < E_; ++e) if (lb[e] > v1) { v1 = lb[e]; i1 = e; }
      int i2 = -1; float v2 = -1e30f;
      for (int e = 0; e < E_; ++e) { if (e == i1) continue; if (lb[e] > v2) { v2 = lb[e]; i2 = e; } }
      float e2 = expf(v2 - v1);
      float den = 1.f + e2;
      float g1 = 1.f / den, g2 = e2 / den;
      gates[b * E_ + i1] = g1; gates[b * E_ + i2] = g2;
      imp[i1] += g1; imp[i2] += g2; load[i1] += 1.f; load[i2] += 1.f;
    }
    float bal = 0.f;
    float m = 0.f; for (int e = 0; e < E_; ++e) m += imp[e]; m *= 0.25f;
    float v = 0.f; for (int e = 0; e < E_; ++e) { float d = imp[e] - m; v += d * d; } v *= 0.25f;
    bal += v / (m * m + 1e-10f);
    m = 0.f; for (int e = 0; e < E_; ++e) m += load[e]; m *= 0.25f;
    v = 0.f; for (int e = 0; e < E_; ++e) { float d = load[e] - m; v += d * d; } v *= 0.25f;
    bal += v / (m * m + 1e-10f);
    ws[OFF_BAL] += bal;
  }
}

__global__ void k_expert(float* __restrict__ out4, const float* __restrict__ w1,
                         const float* __restrict__ b1, const float* __restrict__ w2,
                         const float* __restrict__ b2, const float* __restrict__ ws, int l) {
  int b = blockIdx.y;
  int tn = blockIdx.x * 256 + threadIdx.x;
  if (tn >= T_ * N_) return;
  float* row = out4 + ((size_t)b * T_ * N_ + tn) * D_;
  float r[D_], acc[D_];
#pragma unroll
  for (int d = 0; d < D_; ++d) { r[d] = row[d]; acc[d] = r[d]; }
  const float* gates = ws + OFF_GATE;
  for (int e = 0; e < E_; ++e) {
    float g = gates[b * E_ + e];
    if (g <= 0.f) continue;
    const float* W1 = w1 + (size_t)(l * E_ + e) * D_ * FF_;
    const float* B1 = b1 + (size_t)(l * E_ + e) * FF_;
    const float* W2 = w2 + (size_t)(l * E_ + e) * FF_ * D_;
    const float* B2 = b2 + (size_t)(l * E_ + e) * D_;
#pragma unroll 4
    for (int f = 0; f < FF_; ++f) {
      float p = B1[f];
#pragma unroll
      for (int d = 0; d < D_; ++d) p = fmaf(r[d], W1[d * FF_ + f], p);
      float c = 0.7978845608028654f * (p + 0.044715f * p * p * p);
      float hv = 0.5f * p * (1.f + tanhf(c));
      float gh = g * hv;
#pragma unroll
      for (int d = 0; d < D_; ++d) acc[d] = fmaf(gh, W2[f * D_ + d], acc[d]);
    }
#pragma unroll
    for (int d = 0; d < D_; ++d) acc[d] = fmaf(g, B2[d], acc[d]);
  }
#pragma unroll
  for (int d = 0; d < D_; ++d) row[d] = acc[d];
}

__global__ void k_wavelet(const float* __restrict__ x, const float* __restrict__ velo,
                          float* __restrict__ lowT, float* __restrict__ hvT) {
  int i = blockIdx.x * 256 + threadIdx.x;
  if (i >= BTN_) return;
  int b = i / (T_ * N_);
  int t = (i / N_) % T_;
  int n = i % N_;
  int ip = b * T_ * N_ + ((t + T_ - 1) % T_) * N_ + n;
  int row = t * B_ + b;
  lowT[(size_t)n * BT_ + row] = 0.5f * (x[i] + x[ip]);
  hvT[(size_t)n * BT_ + row] = 0.5f * (velo[i] - velo[ip]);
}

__global__ void k_rowsum(const float* __restrict__ lowT, const float* __restrict__ hvT,
                         float* __restrict__ ws) {
  int which = blockIdx.x / BT_;
  int row = blockIdx.x % BT_;
  const float* M = which ? hvT : lowT;
  float s = 0.f;
  for (int n = threadIdx.x; n < N_; n += 256) s += M[(size_t)n * BT_ + row];
  __shared__ float red[4];
  s = waveReduceSum(s);
  if ((threadIdx.x & 63) == 0) red[threadIdx.x >> 6] = s;
  __syncthreads();
  if (threadIdx.x == 0) ws[(which ? OFF_RSH : OFF_RSL) + row] = red[0] + red[1] + red[2] + red[3];
}

__global__ void k_S(const float* __restrict__ adj, const float* __restrict__ v0,
                    float* __restrict__ S) {
  int m = blockIdx.x;
  float vm = v0[m];
  const float* a = adj + (size_t)m * N_;
  float s = 0.f;
  for (int n = threadIdx.x; n < N_; n += 256) s += vm / a[n];
  __shared__ float red[4];
  s = waveReduceSum(s);
  if ((threadIdx.x & 63) == 0) red[threadIdx.x >> 6] = s;
  __syncthreads();
  if (threadIdx.x == 0) S[m] = red[0] + red[1] + red[2] + red[3];
}

__global__ void k_stats(const float* __restrict__ M, float* __restrict__ part) {
  float s = 0.f, ss = 0.f;
  for (long long i = blockIdx.x * 256 + threadIdx.x; i < NN_; i += 512 * 256) {
    float v = M[i];
    s += v; ss = fmaf(v, v, ss);
  }
  __shared__ float r1[4], r2[4];
  for (int off = 32; off; off >>= 1) { s += __shfl_down(s, off); ss += __shfl_down(ss, off); }
  if ((threadIdx.x & 63) == 0) { r1[threadIdx.x >> 6] = s; r2[threadIdx.x >> 6] = ss; }
  __syncthreads();
  if (threadIdx.x == 0) {
    part[blockIdx.x * 2] = r1[0] + r1[1] + r1[2] + r1[3];
    part[blockIdx.x * 2 + 1] = r2[0] + r2[1] + r2[2] + r2[3];
  }
}

__global__ void k_nsstats(const float* __restrict__ adj, const float* __restrict__ v0,
                          const float* __restrict__ S, float* __restrict__ part) {
  float s = 0.f, ss = 0.f;
  for (long long i = blockIdx.x * 256 + threadIdx.x; i < NN_; i += 512 * 256) {
    int m = (int)(i / N_), n = (int)(i % N_);
    float e = -(v0[m] / adj[i]);
    if (m == n) e += S[m];
    s += e; ss = fmaf(e, e, ss);
  }
  __shared__ float r1[4], r2[4];
  for (int off = 32; off; off >>= 1) { s += __shfl_down(s, off); ss += __shfl_down(ss, off); }
  if ((threadIdx.x & 63) == 0) { r1[threadIdx.x >> 6] = s; r2[threadIdx.x >> 6] = ss; }
  __syncthreads();
  if (threadIdx.x == 0) {
    part[blockIdx.x * 2] = r1[0] + r1[1] + r1[2] + r1[3];
    part[blockIdx.x * 2 + 1] = r2[0] + r2[1] + r2[2] + r2[3];
  }
}

__global__ void k_stats2(const float* __restrict__ part, float* __restrict__ stat) {
  float s = 0.f, ss = 0.f;
  for (int i = threadIdx.x; i < 512; i += 256) { s += part[i * 2]; ss += part[i * 2 + 1]; }
  __shared__ float r1[4], r2[4];
  for (int off = 32; off; off >>= 1) { s += __shfl_down(s, off); ss += __shfl_down(ss, off); }
  if ((threadIdx.x & 63) == 0) { r1[threadIdx.x >> 6] = s; r2[threadIdx.x >> 6] = ss; }
  __syncthreads();
  if (threadIdx.x == 0) {
    float su = r1[0] + r1[1] + r1[2] + r1[3];
    float sq = r2[0] + r2[1] + r2[2] + r2[3];
    float mu = su * (1.f / (float)NN_);
    float var = sq * (1.f / (float)NN_) - mu * mu;
    stat[0] = mu;
    stat[1] = 1.f / sqrtf(var);
  }
}

// ---------------------------------------------------------------------------
// fp32 streaming GEMM (used for r1/r3 and NS only), 8-deep B prefetch
// ---------------------------------------------------------------------------
__global__ __launch_bounds__(256) void k_gemm48(
    const float* __restrict__ AT, int lda, int rowTot,
    const float* __restrict__ Bm, float* __restrict__ part,
    int Kdim, int NC, int kchunk) {
  int col = blockIdx.x * 256 + threadIdx.x;
  int m0 = blockIdx.y * kchunk;
  int m1 = min(Kdim, m0 + kchunk);
  float acc[BT_];
#pragma unroll
  for (int r = 0; r < BT_; ++r) acc[r] = 0.f;
  if (col < NC) {
    const float* ap = AT + (size_t)m0 * lda;
    const float* bp = Bm + (size_t)m0 * NC + col;
    int len = m1 - m0;
    int ng = len >> 3;
    float bc[8];
    if (ng > 0) {
#pragma unroll
      for (int u = 0; u < 8; ++u) bc[u] = bp[(size_t)u * NC];
    }
    for (int gi = 0; gi < ng; ++gi) {
      float bn[8];
      bool more = (gi + 1 < ng);
      if (more) {
#pragma unroll
        for (int u = 0; u < 8; ++u) bn[u] = bp[(size_t)(8 + u) * NC];
      }
#pragma unroll
      for (int u = 0; u < 8; ++u)
        fma48(acc, (const float4*)(ap + (size_t)u * lda), bc[u]);
      ap += (size_t)8 * lda;
      bp += (size_t)8 * NC;
      if (more) {
#pragma unroll
        for (int u = 0; u < 8; ++u) bc[u] = bn[u];
      }
    }
    for (int m = m0 + (ng << 3); m < m1; ++m) {
      fma48(acc, (const float4*)ap, *bp);
      ap += lda;
      bp += NC;
    }
    float* pp = part + (size_t)blockIdx.y * rowTot * NC + col;
#pragma unroll
    for (int r = 0; r < BT_; ++r) pp[(size_t)r * NC] = acc[r];
  }
}

__global__ __launch_bounds__(256) void k_gemmNS(
    const float* __restrict__ hvT, const float* __restrict__ adj,
    const float* __restrict__ v0, const float* __restrict__ S,
    float* __restrict__ part, int kchunk) {
  int col = blockIdx.x * 256 + threadIdx.x;
  int m0 = blockIdx.y * kchunk;
  int m1 = min(N_, m0 + kchunk);
  float acc[BT_];
#pragma unroll
  for (int r = 0; r < BT_; ++r) acc[r] = 0.f;
  if (col < N_) {
    const float* ap = hvT + (size_t)m0 * BT_;
    const float* jp = adj + (size_t)m0 * N_ + col;
    int len = m1 - m0;
    int ng = len >> 3;
    float jc[8];
    if (ng > 0) {
#pragma unroll
      for (int u = 0; u < 8; ++u) jc[u] = jp[(size_t)u * N_];
    }
    int m = m0;
    for (int gi = 0; gi < ng; ++gi) {
      float jn[8];
      bool more = (gi + 1 < ng);
      if (more) {
#pragma unroll
        for (int u = 0; u < 8; ++u) jn[u] = jp[(size_t)(8 + u) * N_];
      }
#pragma unroll
      for (int u = 0; u < 8; ++u) {
        float bv = -(v0[m + u] / jc[u]);
        if (m + u == col) bv += S[m + u];
        fma48(acc, (const float4*)(ap + (size_t)u * BT_), bv);
      }
      m += 8;
      ap += (size_t)8 * BT_;
      jp += (size_t)8 * N_;
      if (more) {
#pragma unroll
        for (int u = 0; u < 8; ++u) jc[u] = jn[u];
      }
    }
    for (; m < m1; ++m) {
      float bv = -(v0[m] / (*jp));
      if (m == col) bv += S[m];
      fma48(acc, (const float4*)ap, bv);
      ap += BT_;
      jp += N_;
    }
    float* pp = part + (size_t)blockIdx.y * BT_ * N_ + col;
#pragma unroll
    for (int r = 0; r < BT_; ++r) pp[(size_t)r * N_] = acc[r];
  }
}

// ---------------------------------------------------------------------------
// fp32 [K][Nc] -> bf16 transposed [Nc][Kp] (zero-padded K), LDS 32x32 tiles
// ---------------------------------------------------------------------------
__global__ __launch_bounds__(256) void k_wtrans(const float* __restrict__ W,
                                                unsigned short* __restrict__ Wt,
                                                int K, int Nc, int Kp) {
  __shared__ unsigned short t[32][33];
  int k0 = blockIdx.y * 32, n0 = blockIdx.x * 32;
  int tx = threadIdx.x & 31, ty = threadIdx.x >> 5;  // 32 x 8
#pragma unroll
  for (int i = 0; i < 4; ++i) {
    int k = k0 + ty + i * 8, n = n0 + tx;
    float v = (k < K && n < Nc) ? W[(size_t)k * Nc + n] : 0.f;
    t[ty + i * 8][tx] = f2bf(v);
  }
  __syncthreads();
#pragma unroll
  for (int i = 0; i < 4; ++i) {
    int n = n0 + ty + i * 8, k = k0 + tx;
    if (n < Nc && k < Kp) Wt[(size_t)n * Kp + k] = t[tx][ty + i * 8];
  }
}

// ---------------------------------------------------------------------------
// MFMA GEMM: part[ks][144][Nc] = At(bf16 [144][Kp])^ @ Bt(bf16 [Nc][Kp])^T
// wave = 16 cols x all 144 rows (9 A-frags, L2-resident A; B streamed once)
// ---------------------------------------------------------------------------
__global__ __launch_bounds__(256, 4) void k_mfma(
    const unsigned short* __restrict__ At, const unsigned short* __restrict__ Bt,
    float* __restrict__ part, int Nc, int Kp, int stepsTot, int stepChunk) {
  int lane = threadIdx.x & 63;
  int w = threadIdx.x >> 6;
  int lr = lane & 15, lo = lane >> 4;
  int gcol = blockIdx.x * 64 + w * 16 + lr;
  int bcol = min(gcol, Nc - 1);
  int s0 = blockIdx.y * stepChunk;
  int s1 = min(stepsTot, s0 + stepChunk);
  f32x4 acc[9];
#pragma unroll
  for (int mt = 0; mt < 9; ++mt) {
    acc[mt][0] = 0.f; acc[mt][1] = 0.f; acc[mt][2] = 0.f; acc[mt][3] = 0.f;
  }
  const unsigned short* bp = Bt + (size_t)bcol * Kp + (size_t)s0 * 32 + lo * 8;
  const unsigned short* ap = At + (size_t)lr * Kp + (size_t)s0 * 32 + lo * 8;
  for (int s = s0; s < s1; ++s) {
    short8 b = *(const short8*)bp;
#pragma unroll
    for (int mt = 0; mt < 9; ++mt) {
      short8 a = *(const short8*)(ap + (size_t)mt * 16 * Kp);
      acc[mt] = __builtin_amdgcn_mfma_f32_16x16x32_bf16(a, b, acc[mt], 0, 0, 0);
    }
    bp += 32;
    ap += 32;
  }
  if (gcol < Nc) {
#pragma unroll
    for (int mt = 0; mt < 9; ++mt) {
      int row = mt * 16 + lo * 4;
      float* pp = part + ((size_t)blockIdx.y * R3_ + row) * Nc + gcol;
      pp[0] = acc[mt][0];
      pp[(size_t)Nc] = acc[mt][1];
      pp[2 * (size_t)Nc] = acc[mt][2];
      pp[3 * (size_t)Nc] = acc[mt][3];
    }
  }
}

// ---------------------------------------------------------------------------
// Epilogues
// ---------------------------------------------------------------------------
// r matmul + std-normalization -> ALIN fp32 + At_lin bf16 [144][KP2]
__global__ void k_epiR(const float* __restrict__ part, float* __restrict__ ws,
                       unsigned short* __restrict__ atl,
                       int ksplit, int g, int statIdx, size_t rsOff) {
  int n = blockIdx.x * 256 + threadIdx.x;
  int row = blockIdx.y;
  if (n >= KP2) return;
  int arow = g * BT_ + row;
  if (n >= N_) { atl[(size_t)arow * KP2 + n] = 0; return; }
  float s = 0.f;
  for (int ks = 0; ks < ksplit; ++ks) s += part[((size_t)(ks * BT_ + row)) * N_ + n];
  float mu = ws[OFF_STAT + statIdx], isd = ws[OFF_STAT + statIdx + 1];
  float val = (s - mu * ws[rsOff + row]) * isd;
  ws[OFF_ALIN + (size_t)n * R3_ + arow] = val;
  atl[(size_t)arow * KP2 + n] = f2bf(val);
}

__global__ void k_minmax(const float* __restrict__ alin, float* __restrict__ mmp) {
  int g = blockIdx.y;
  float mn = 3.4e38f, mx = -3.4e38f;
  for (int i = blockIdx.x * 256 + threadIdx.x; i < N_ * BT_; i += 64 * 256) {
    int n = i / BT_, r = i % BT_;
    float v = alin[(size_t)n * R3_ + g * BT_ + r];
    mn = fminf(mn, v); mx = fmaxf(mx, v);
  }
  __shared__ float rn[4], rx[4];
  for (int off = 32; off; off >>= 1) {
    mn = fminf(mn, __shfl_down(mn, off));
    mx = fmaxf(mx, __shfl_down(mx, off));
  }
  if ((threadIdx.x & 63) == 0) { rn[threadIdx.x >> 6] = mn; rx[threadIdx.x >> 6] = mx; }
  __syncthreads();
  if (threadIdx.x == 0) {
    mn = fminf(fminf(rn[0], rn[1]), fminf(rn[2], rn[3]));
    mx = fmaxf(fmaxf(rx[0], rx[1]), fmaxf(rx[2], rx[3]));
    mmp[(size_t)(g * 64 + blockIdx.x) * 2] = mn;
    mmp[(size_t)(g * 64 + blockIdx.x) * 2 + 1] = mx;
  }
}

__global__ void k_minmax2(float* __restrict__ ws) {
  int g = blockIdx.x;
  int i = threadIdx.x;
  float mn = ws[OFF_MMP + (size_t)(g * 64 + i) * 2];
  float mx = ws[OFF_MMP + (size_t)(g * 64 + i) * 2 + 1];
  for (int off = 32; off; off >>= 1) {
    mn = fminf(mn, __shfl_down(mn, off));
    mx = fmaxf(mx, __shfl_down(mx, off));
  }
  if (i == 0) {
    float denom = fmaxf(mx - mn, 1e-8f);
    float a = 1.f / denom;
    ws[OFF_AB + g * 2] = a;
    ws[OFF_AB + g * 2 + 1] = -mn * a;
  }
}

__global__ void k_colsum(const float* __restrict__ ltw, float* __restrict__ csp) {
  int e = blockIdx.x * 256 + threadIdx.x;
  int ks = blockIdx.y;
  if (e >= EA_) return;
  float s = 0.f;
  for (int n = ks * 125; n < (ks + 1) * 125; ++n) s += ltw[(size_t)n * EA_ + e];
  csp[(size_t)ks * EA_ + e] = s;
}
__global__ void k_colsum2(float* __restrict__ ws) {
  int e = blockIdx.x * 256 + threadIdx.x;
  if (e >= EA_) return;
  float s = 0.f;
  for (int ks = 0; ks < 16; ++ks) s += ws[OFF_CSP + (size_t)ks * EA_ + e];
  ws[OFF_CS + e] = s;
}

// lin epilogue -> At_q bf16 [144][KP3] (rng01 folded)
__global__ void k_epiLin(const float* __restrict__ part, const float* __restrict__ ltb,
                         float* __restrict__ ws, unsigned short* __restrict__ atq,
                         int ksplit) {
  int e = blockIdx.x * 256 + threadIdx.x;
  int row = blockIdx.y;
  if (e >= KP3) return;
  if (e >= EA_) { atq[(size_t)row * KP3 + e] = 0; return; }
  float s = 0.f;
  for (int ks = 0; ks < ksplit; ++ks) s += part[((size_t)(ks * R3_ + row)) * EA_ + e];
  int g = row / BT_;
  float a = ws[OFF_AB + g * 2], bb = ws[OFF_AB + g * 2 + 1];
  float val = fmaf(a, s, fmaf(bb, ws[OFF_CS + e], ltb[e]));
  atq[(size_t)row * KP3 + e] = f2bf(val);
}

// qkv epilogue -> P fp32 [144][9000]
__global__ void k_epiQkv(const float* __restrict__ part, const float* __restrict__ qkvb,
                         float* __restrict__ P, int ksplit) {
  int c = blockIdx.x * 256 + threadIdx.x;
  int row = blockIdx.y;
  if (c >= 3 * EA_) return;
  float s = 0.f;
  for (int ks = 0; ks < ksplit; ++ks) s += part[((size_t)(ks * R3_ + row)) * (3 * EA_) + c];
  P[(size_t)row * (3 * EA_) + c] = s + qkvb[c];
}

// attention -> At_ao bf16 [144][KP3]
__global__ void k_attn(const float* __restrict__ P, unsigned short* __restrict__ atao) {
  int mha = blockIdx.y;
  int s_ = blockIdx.x / (B_ * H_);
  int rem = blockIdx.x % (B_ * H_);
  int b = rem / H_, h = rem % H_;
  const int pq[3] = {0, 1, 2}, pk[3] = {1, 2, 0}, pv[3] = {2, 0, 1};
  const float* qrow = P + ((size_t)(pq[mha] * BT_ + s_ * B_ + b)) * (3 * EA_) + h * HD_;
  __shared__ float sc[T_];
  __shared__ float red[4];
  for (int t = 0; t < T_; ++t) {
    const float* krow = P + ((size_t)(pk[mha] * BT_ + t * B_ + b)) * (3 * EA_) + EA_ + h * HD_;
    float p = 0.f;
    for (int d = threadIdx.x; d < HD_; d += 256) p = fmaf(qrow[d], krow[d], p);
    p = waveReduceSum(p);
    if ((threadIdx.x & 63) == 0) red[threadIdx.x >> 6] = p;
    __syncthreads();
    if (threadIdx.x == 0) sc[t] = (red[0] + red[1] + red[2] + red[3]) * 0.031622776601683794f;
    __syncthreads();
  }
  float a[T_];
  float m = sc[0];
#pragma unroll
  for (int t = 1; t < T_; ++t) m = fmaxf(m, sc[t]);
  float sum = 0.f;
#pragma unroll
  for (int t = 0; t < T_; ++t) { a[t] = expf(sc[t] - m); sum += a[t]; }
  float inv = 1.f / sum;
#pragma unroll
  for (int t = 0; t < T_; ++t) a[t] *= inv;
  int orow = mha * BT_ + s_ * B_ + b;
  for (int d = threadIdx.x; d < HD_; d += 256) {
    float o = 0.f;
#pragma unroll
    for (int t = 0; t < T_; ++t)
      o = fmaf(a[t], P[((size_t)(pv[mha] * BT_ + t * B_ + b)) * (3 * EA_) + 2 * EA_ + h * HD_ + d], o);
    atao[(size_t)orow * KP3 + h * HD_ + d] = f2bf(o);
  }
  if (h == 0 && threadIdx.x < 8) atao[(size_t)orow * KP3 + EA_ + threadIdx.x] = 0;
}

// attn-out epilogue -> At_ll bf16 [144][KP3]
__global__ void k_epiAO(const float* __restrict__ part, const float* __restrict__ aob,
                        unsigned short* __restrict__ atll, int ksplit) {
  int c = blockIdx.x * 256 + threadIdx.x;
  int row = blockIdx.y;
  if (c >= KP3) return;
  if (c >= EA_) { atll[(size_t)row * KP3 + c] = 0; return; }
  float s = 0.f;
  for (int ks = 0; ks < ksplit; ++ks) s += part[((size_t)(ks * R3_ + row)) * EA_ + c];
  atll[(size_t)row * KP3 + c] = f2bf(s + aob[c]);
}

// ll epilogue: sum three mha branches -> out2_pre
__global__ void k_epiLL(const float* __restrict__ part, const float* __restrict__ llb,
                        float* __restrict__ o2p, int ksplit) {
  int n = blockIdx.x * 256 + threadIdx.x;
  int row = blockIdx.y;  // t*B+b
  if (n >= N_) return;
  float s = 0.f;
  for (int g = 0; g < 3; ++g)
    for (int ks = 0; ks < ksplit; ++ks)
      s += part[((size_t)(ks * R3_ + g * BT_ + row)) * N_ + n];
  int t = row / B_, b = row % B_;
  o2p[(size_t)b * (T_ * N_) + t * N_ + n] = BETA_ * (s + 3.f * llb[n]);
}

__global__ void k_proj(const float* __restrict__ out4, const float* __restrict__ pw,
                       const float* __restrict__ pb, float* __restrict__ outp) {
  int i = blockIdx.x * 256 + threadIdx.x;
  if (i >= BTN_) return;
  int b = i / (T_ * N_);
  int t = (i / N_) % T_;
  int n = i % N_;
  float acc = pb[t];
  for (int t2 = 0; t2 < T_; ++t2) {
    const float* o = out4 + ((size_t)(b * T_ + t2) * N_ + n) * D_;
#pragma unroll
    for (int d = 0; d < D_; ++d) acc = fmaf(o[d], pw[(t2 * D_ + d) * T_ + t], acc);
  }
  outp[i] = acc;
}

__global__ void k_p2(const float* __restrict__ o2p, const float* __restrict__ p2w,
                     const float* __restrict__ p2b, float* __restrict__ o2f) {
  int i = blockIdx.x * 256 + threadIdx.x;
  if (i >= BTN_) return;
  int b = i / (T_ * N_);
  int t = (i / N_) % T_;
  int n = i % N_;
  float acc = p2b[t];
  const float* src = o2p + (size_t)b * (T_ * N_) + (size_t)n * T_;
#pragma unroll
  for (int c = 0; c < T_; ++c) acc = fmaf(src[c], p2w[c * T_ + t], acc);
  o2f[i] = acc;
}

__global__ void k_out3(const float* __restrict__ outp, const float* __restrict__ o2f,
                       float* __restrict__ dout) {
  int i = blockIdx.x * 256 + threadIdx.x;
  if (i < BTN_) dout[i] = outp[i] + o2f[i];
}

__global__ void k_fnorm(const float* __restrict__ outp, const float* __restrict__ o2f,
                        float* __restrict__ g1, float* __restrict__ g2) {
  int r = blockIdx.x * 256 + threadIdx.x;
  if (r >= B_ * N_) return;
  int b = r / N_, n = r % N_;
  float v1[T_], v2[T_];
  float s1 = 0.f, s2 = 0.f;
#pragma unroll
  for (int t = 0; t < T_; ++t) {
    v1[t] = outp[(size_t)b * T_ * N_ + t * N_ + n];
    v2[t] = o2f[(size_t)b * T_ * N_ + t * N_ + n];
    s1 = fmaf(v1[t], v1[t], s1);
    s2 = fmaf(v2[t], v2[t], s2);
  }
  float n1 = fmaxf(sqrtf(s1), 1e-12f), n2 = fmaxf(sqrtf(s2), 1e-12f);
  float i1 = 10.f / n1, i2 = 1.f / n2;
#pragma unroll
  for (int t = 0; t < T_; ++t) {
    g1[(size_t)r * T_ + t] = v1[t] * i1;
    g2[(size_t)r * T_ + t] = v2[t] * i2;
  }
}

__global__ __launch_bounds__(256) void k_lse(const float* __restrict__ g1,
                                             const float* __restrict__ g2,
                                             float* __restrict__ li) {
  int r = threadIdx.x >> 4;
  int k = threadIdx.x & 15;
  int row = blockIdx.x * 16 + r;
  const float4* qp = (const float4*)(g1 + (size_t)row * T_);
  float4 qa = qp[0], qb = qp[1], qc = qp[2];
  float sm = 0.f, sd = 0.f;
  for (int j = k; j < B_ * N_; j += 16) {
    const float4* p = (const float4*)(g2 + (size_t)j * T_);
    float4 A = p[0], Bv = p[1], C = p[2];
    float s = qa.x * A.x;
    s = fmaf(qa.y, A.y, s);  s = fmaf(qa.z, A.z, s);  s = fmaf(qa.w, A.w, s);
    s = fmaf(qb.x, Bv.x, s); s = fmaf(qb.y, Bv.y, s); s = fmaf(qb.z, Bv.z, s);
    s = fmaf(qb.w, Bv.w, s); s = fmaf(qc.x, C.x, s);  s = fmaf(qc.y, C.y, s);
    s = fmaf(qc.z, C.z, s);  s = fmaf(qc.w, C.w, s);
    sm += __expf(s);
    if (j == row) sd = s;
  }
#pragma unroll
  for (int off = 8; off; off >>= 1) {
    sm += __shfl_xor(sm, off);
    sd += __shfl_xor(sd, off);
  }
  if (k == 0) li[row] = sd - logf(sm);
}

__global__ void k_final(const float* __restrict__ li, const float* __restrict__ ws,
                        float* __restrict__ dout) {
  float s = 0.f;
  for (int i = threadIdx.x; i < B_ * N_; i += 256) s += li[i];
  __shared__ float red[4];
  s = waveReduceSum(s);
  if ((threadIdx.x & 63) == 0) red[threadIdx.x >> 6] = s;
  __syncthreads();
  if (threadIdx.x == 0) {
    float closs = -(red[0] + red[1] + red[2] + red[3]) * (1.f / (B_ * N_));
    dout[BTN_] = ws[OFF_BAL];
    dout[BTN_ + 1] = CW_ * closs;
  }
}

// ---------------------------------------------------------------------------
extern "C" void kernel_launch(void* const* d_in, const int* in_sizes, int n_in,
                              void* d_out, int out_size, void* d_ws, size_t ws_size,
                              hipStream_t stream) {
  const float* x    = (const float*)d_in[0];
  const float* velo = (const float*)d_in[1];
  const float* adj  = (const float*)d_in[2];
  const float* lapd = (const float*)d_in[3];
  const float* laph = (const float*)d_in[4];
  const float* sw   = (const float*)d_in[5];
  const float* sb   = (const float*)d_in[6];
  const float* gw   = (const float*)d_in[7];
  const float* ew1  = (const float*)d_in[8];
  const float* eb1  = (const float*)d_in[9];
  const float* ew2  = (const float*)d_in[10];
  const float* eb2  = (const float*)d_in[11];
  const float* pw   = (const float*)d_in[12];
  const float* pb   = (const float*)d_in[13];
  const float* ltw  = (const float*)d_in[14];
  const float* ltb  = (const float*)d_in[15];
  const float* qkvw = (const float*)d_in[16];
  const float* qkvb = (const float*)d_in[17];
  const float* aow  = (const float*)d_in[18];
  const float* aob  = (const float*)d_in[19];
  const float* llw  = (const float*)d_in[20];
  const float* llb  = (const float*)d_in[21];
  const float* p2w  = (const float*)d_in[22];
  const float* p2b  = (const float*)d_in[23];
  float* ws = (float*)d_ws;
  float* dout = (float*)d_out;
  const float* v0 = velo;  // velo[0,0,:]
  float* part = ws + OFF_PART;
  unsigned short* btQ  = (unsigned short*)(ws + OFF_BT_Q);
  unsigned short* btA  = (unsigned short*)(ws + OFF_BT_A);
  unsigned short* btL  = (unsigned short*)(ws + OFF_BT_L);
  unsigned short* btW  = (unsigned short*)(ws + OFF_BT_W);
  unsigned short* atLin = (unsigned short*)(ws + OFF_AT_LIN);
  unsigned short* atQ   = (unsigned short*)(ws + OFF_AT_Q);
  unsigned short* atAO  = (unsigned short*)(ws + OFF_AT_AO);
  unsigned short* atLL  = (unsigned short*)(ws + OFF_AT_LL);
  dim3 b256(256);

  k_init<<<dim3(1), dim3(64), 0, stream>>>(ws);

  // weight transposes to bf16 (depend only on inputs)
  k_wtrans<<<dim3(282, 94), b256, 0, stream>>>(qkvw, btQ, EA_, 3 * EA_, KP3);
  k_wtrans<<<dim3(94, 94), b256, 0, stream>>>(aow, btA, EA_, EA_, KP3);
  k_wtrans<<<dim3(63, 94), b256, 0, stream>>>(llw, btL, EA_, N_, KP3);
  k_wtrans<<<dim3(94, 63), b256, 0, stream>>>(ltw, btW, N_, EA_, KP2);

  k_start<<<dim3((BTN_ * D_ + 255) / 256), b256, 0, stream>>>(x, sw, sb, ws + OFF_OUT4);

  for (int l = 0; l < L_; ++l) {
    k_feat<<<dim3(B_ * D_), b256, 0, stream>>>(ws + OFF_OUT4, ws + OFF_FEAT);
    k_gate<<<dim3(1), dim3(64), 0, stream>>>(ws + OFF_FEAT, gw, ws, l);
    k_expert<<<dim3((T_ * N_ + 255) / 256, B_), b256, 0, stream>>>(ws + OFF_OUT4, ew1, eb1, ew2, eb2, ws, l);
  }

  k_wavelet<<<dim3((BTN_ + 255) / 256), b256, 0, stream>>>(x, velo, ws + OFF_LOWT, ws + OFF_HVT);
  k_rowsum<<<dim3(2 * BT_), b256, 0, stream>>>(ws + OFF_LOWT, ws + OFF_HVT, ws);
  k_S<<<dim3(N_), b256, 0, stream>>>(adj, v0, ws + OFF_S);
  k_stats<<<dim3(512), b256, 0, stream>>>(lapd, ws + OFF_STP);
  k_stats2<<<dim3(1), b256, 0, stream>>>(ws + OFF_STP, ws + OFF_STAT);
  k_stats<<<dim3(512), b256, 0, stream>>>(laph, ws + OFF_STP + 1024);
  k_stats2<<<dim3(1), b256, 0, stream>>>(ws + OFF_STP + 1024, ws + OFF_STAT + 2);
  k_nsstats<<<dim3(512), b256, 0, stream>>>(adj, v0, ws + OFF_S, ws + OFF_STP + 2048);
  k_stats2<<<dim3(1), b256, 0, stream>>>(ws + OFF_STP + 2048, ws + OFF_STAT + 4);

  // r1 / r2 / r3 (fp32, split-K 50)
  k_gemm48<<<dim3(8, RKS_), b256, 0, stream>>>(ws + OFF_LOWT, BT_, BT_, lapd, part, N_, N_, RKC_);
  k_epiR<<<dim3(8, 48), b256, 0, stream>>>(part, ws, atLin, RKS_, 0, 0, OFF_RSL);
  k_gemmNS<<<dim3(8, RKS_), b256, 0, stream>>>(ws + OFF_HVT, adj, v0, ws + OFF_S, part, RKC_);
  k_epiR<<<dim3(8, 48), b256, 0, stream>>>(part, ws, atLin, RKS_, 1, 4, OFF_RSH);
  k_gemm48<<<dim3(8, RKS_), b256, 0, stream>>>(ws + OFF_LOWT, BT_, BT_, laph, part, N_, N_, RKC_);
  k_epiR<<<dim3(8, 48), b256, 0, stream>>>(part, ws, atLin, RKS_, 2, 2, OFF_RSL);

  k_minmax<<<dim3(64, 3), b256, 0, stream>>>(ws + OFF_ALIN, ws + OFF_MMP);
  k_minmax2<<<dim3(3), dim3(64), 0, stream>>>(ws);
  k_colsum<<<dim3(12, 16), b256, 0, stream>>>(ltw, ws + OFF_CSP);
  k_colsum2<<<dim3(12), b256, 0, stream>>>(ws);

  // lin (MFMA): [144,2000]bf16 @ ltw^T  -> 9 splits x 7 steps (K=2016)
  k_mfma<<<dim3(47, 9), b256, 0, stream>>>(atLin, btW, part, EA_, KP2, KP2 / 32, 7);
  k_epiLin<<<dim3(12, 144), b256, 0, stream>>>(part, ltb, ws, atQ, 9);

  // qkv (MFMA): 4 splits x 24 steps (K=3008)
  k_mfma<<<dim3(141, 4), b256, 0, stream>>>(atQ, btQ, part, 3 * EA_, KP3, KP3 / 32, 24);
  k_epiQkv<<<dim3(36, 144), b256, 0, stream>>>(part, qkvb, ws + OFF_P, 4);

  // attention (3 mha in grid.y) -> At_ao bf16
  k_attn<<<dim3(T_ * B_ * H_, 3), b256, 0, stream>>>(ws + OFF_P, atAO);

  // attn-out (MFMA): 12 splits x 8 steps
  k_mfma<<<dim3(47, 12), b256, 0, stream>>>(atAO, btA, part, EA_, KP3, KP3 / 32, 8);
  k_epiAO<<<dim3(12, 144), b256, 0, stream>>>(part, aob, atLL, 12);

  // ll (MFMA): 12 splits x 8 steps
  k_mfma<<<dim3(32, 12), b256, 0, stream>>>(atLL, btL, part, N_, KP3, KP3 / 32, 8);
  k_epiLL<<<dim3(8, 48), b256, 0, stream>>>(part, llb, ws + OFF_O2P, 12);

  k_proj<<<dim3((BTN_ + 255) / 256), b256, 0, stream>>>(ws + OFF_OUT4, pw, pb, ws + OFF_OUTP);
  k_p2<<<dim3((BTN_ + 255) / 256), b256, 0, stream>>>(ws + OFF_O2P, p2w, p2b, ws + OFF_O2F);
  k_out3<<<dim3((BTN_ + 255) / 256), b256, 0, stream>>>(ws + OFF_OUTP, ws + OFF_O2F, dout);

  k_fnorm<<<dim3((B_ * N_ + 255) / 256), b256, 0, stream>>>(ws + OFF_OUTP, ws + OFF_O2F, ws + OFF_G1, ws + OFF_G2);
  k_lse<<<dim3(B_ * N_ / 16), b256, 0, stream>>>(ws + OFF_G1, ws + OFF_G2, ws + OFF_LI);
  k_final<<<dim3(1), b256, 0, stream>>>(ws + OFF_LI, ws, dout);
}

// Round 8
// 892.279 us; speedup vs baseline: 1.1756x; 1.0580x over previous
//
#include <hip/hip_runtime.h>
#include <math.h>

// ---------------------------------------------------------------------------
// Model constants
// ---------------------------------------------------------------------------
namespace {
constexpr int B_ = 4, T_ = 12, N_ = 2000, D_ = 16, FF_ = 64, E_ = 4, L_ = 2;
constexpr int EA_ = 3000, H_ = 3, HD_ = EA_ / H_;   // 1000
constexpr int BT_ = B_ * T_;                         // 48
constexpr int R3_ = 3 * BT_;                         // 144
constexpr long long NN_ = (long long)N_ * N_;        // 4,000,000
constexpr int BTN_ = B_ * T_ * N_;                   // 96,000
constexpr float BETA_ = 0.01f, CW_ = 0.001f;
constexpr int RKS_ = 50;                             // r-GEMM split-K
constexpr int RKC_ = 40;                             // r-GEMM k-chunk
constexpr int KP3 = 3008;                            // K=3000 padded to 32
constexpr int KP2 = 2016;                            // K=2000 padded to 32
constexpr int LSE_JS = 4;                            // k_lse j-splits
constexpr int LSE_JCH = 8000 / LSE_JS;               // 2000

// ---------------------------------------------------------------------------
// Workspace layout (float offsets)
// ---------------------------------------------------------------------------
constexpr size_t OFF_OUT4 = 0;                                   // [B,T,N,D]
constexpr size_t OFF_LOWT = OFF_OUT4 + (size_t)BTN_ * D_;        // lowT^T [N][48]
constexpr size_t OFF_HVT  = OFF_LOWT + BTN_;                     // highV^T [N][48]
constexpr size_t OFF_ALIN = OFF_HVT + BTN_;                      // r^T [N][144]
constexpr size_t OFF_RT   = OFF_ALIN + (size_t)N_ * R3_;         // (unused, kept)
constexpr size_t OFF_P    = OFF_RT + (size_t)EA_ * R3_;          // P [144][9000]
constexpr size_t OFF_AOT  = OFF_P + (size_t)R3_ * 3 * EA_;       // (unused, kept)
constexpr size_t OFF_OT   = OFF_AOT + (size_t)EA_ * R3_;         // (unused, kept)
constexpr size_t OFF_O2P  = OFF_OT + (size_t)EA_ * R3_;          // out2 pre-p2 [B][T*N]
constexpr size_t OFF_OUTP = OFF_O2P + BTN_;                      // outp [B,T,N]
constexpr size_t OFF_O2F  = OFF_OUTP + BTN_;                     // out2 final [B,T,N]
constexpr size_t OFF_G1   = OFF_O2F + BTN_;                      // f1*10 [8000][12]
constexpr size_t OFF_G2   = OFF_G1 + 96000;                      // f2 [8000][12]
constexpr size_t OFF_LI   = OFF_G2 + 96000;                      // li [8000]
constexpr size_t OFF_S    = OFF_LI + 8000;                       // G row sums [2000]
constexpr size_t OFF_RSL  = OFF_S + 2000;
constexpr size_t OFF_RSH  = OFF_RSL + 48;
constexpr size_t OFF_STP  = OFF_RSH + 48;
constexpr size_t OFF_STAT = OFF_STP + 3072;
constexpr size_t OFF_MMP  = OFF_STAT + 8;
constexpr size_t OFF_AB   = OFF_MMP + 384;
constexpr size_t OFF_CSP  = OFF_AB + 8;
constexpr size_t OFF_CS   = OFF_CSP + 48000;
constexpr size_t OFF_FEAT = OFF_CS + 3000;
constexpr size_t OFF_GATE = OFF_FEAT + 64;
constexpr size_t OFF_BAL  = OFF_GATE + 16;
constexpr size_t OFF_PART = ((OFF_BAL + 1 + 255) & ~(size_t)255); // split-K partials
constexpr size_t PARTCAP  = 6000000;                              // cap (floats)
// bf16 regions (sizes in floats = ushorts/2)
constexpr size_t OFF_BT_Q  = OFF_PART + PARTCAP;                  // qkvw^T  [9000][KP3]
constexpr size_t OFF_BT_A  = OFF_BT_Q + (size_t)9000 * KP3 / 2;   // aow^T   [3000][KP3]
constexpr size_t OFF_BT_L  = OFF_BT_A + (size_t)3000 * KP3 / 2;   // llw^T   [2000][KP3]
constexpr size_t OFF_BT_W  = OFF_BT_L + (size_t)2000 * KP3 / 2;   // ltw^T   [3000][KP2]
constexpr size_t OFF_AT_LIN= OFF_BT_W + (size_t)3000 * KP2 / 2;   // ALIN^T  [144][KP2]
constexpr size_t OFF_AT_Q  = OFF_AT_LIN + (size_t)R3_ * KP2 / 2;  // RT^T    [144][KP3]
constexpr size_t OFF_AT_AO = OFF_AT_Q + (size_t)R3_ * KP3 / 2;    // Ao      [144][KP3]
constexpr size_t OFF_AT_LL = OFF_AT_AO + (size_t)R3_ * KP3 / 2;   // O       [144][KP3]
} // namespace

typedef __attribute__((ext_vector_type(8))) short short8;
typedef __attribute__((ext_vector_type(4))) float f32x4;

// ---------------------------------------------------------------------------
// Helpers
// ---------------------------------------------------------------------------
__device__ __forceinline__ float waveReduceSum(float v) {
  for (int off = 32; off; off >>= 1) v += __shfl_down(v, off);
  return v;
}

__device__ __forceinline__ unsigned short f2bf(float x) {  // RNE fp32->bf16
  unsigned int u = __float_as_uint(x);
  unsigned int r = (u + 0x7FFFu + ((u >> 16) & 1u)) >> 16;
  return (unsigned short)r;
}

__device__ __forceinline__ void fma48(float* __restrict__ acc,
                                      const float4* __restrict__ a4, float bv) {
#pragma unroll
  for (int r4 = 0; r4 < BT_ / 4; ++r4) {
    float4 av = a4[r4];
    acc[r4 * 4 + 0] = fmaf(av.x, bv, acc[r4 * 4 + 0]);
    acc[r4 * 4 + 1] = fmaf(av.y, bv, acc[r4 * 4 + 1]);
    acc[r4 * 4 + 2] = fmaf(av.z, bv, acc[r4 * 4 + 2]);
    acc[r4 * 4 + 3] = fmaf(av.w, bv, acc[r4 * 4 + 3]);
  }
}

// ---------------------------------------------------------------------------
__global__ void k_init(float* ws) {
  if (threadIdx.x == 0) ws[OFF_BAL] = 0.f;
}

__global__ void k_start(const float* __restrict__ x, const float* __restrict__ sw,
                        const float* __restrict__ sb, float* __restrict__ out4) {
  int i = blockIdx.x * 256 + threadIdx.x;
  if (i >= BTN_ * D_) return;
  int d = i & 15;
  out4[i] = fmaf(x[i >> 4], sw[d], sb[d]);
}

__global__ void k_feat(const float* __restrict__ out4, float* __restrict__ feat) {
  int b = blockIdx.x >> 4, d = blockIdx.x & 15;
  float s = 0.f;
  for (int tn = threadIdx.x; tn < T_ * N_; tn += 256)
    s += out4[((size_t)b * T_ * N_ + tn) * D_ + d];
  __shared__ float red[4];
  s = waveReduceSum(s);
  if ((threadIdx.x & 63) == 0) red[threadIdx.x >> 6] = s;
  __syncthreads();
  if (threadIdx.x == 0)
    feat[blockIdx.x] = (red[0] + red[1] + red[2] + red[3]) * (1.f / (T_ * N_));
}

__global__ void k_gate(const float* __restrict__ feat, const float* __restrict__ gw,
                       float* __restrict__ ws, int l) {
  __shared__ float lg[B_ * E_];
  int tid = threadIdx.x;
  if (tid < B_ * E_) {
    int b = tid >> 2, e = tid & 3;
    float s = 0.f;
    for (int d = 0; d < D_; ++d) s = fmaf(feat[b * D_ + d], gw[(l * D_ + d) * E_ + e], s);
    lg[tid] = s;
  }
  __syncthreads();
  if (tid == 0) {
    float* gates = ws + OFF_GATE;
    float imp[E_] = {0, 0, 0, 0}, load[E_] = {0, 0, 0, 0};
    for (int i = 0; i < B_ * E_; ++i) gates[i] = 0.f;
    for (int b = 0; b < B_; ++b) {
      const float* lb = lg + b * E_;
      int i1 = 0; float v1 = lb[0];
      for (int e = 1; e < E_; ++e) if (lb[e] > v1) { v1 = lb[e]; i1 = e; }
      int i2 = -1; float v2 = -1e30f;
      for (int e = 0; e < E_; ++e) { if (e == i1) continue; if (lb[e] > v2) { v2 = lb[e]; i2 = e; } }
      float e2 = expf(v2 - v1);
      float den = 1.f + e2;
      float g1 = 1.f / den, g2 = e2 / den;
      gates[b * E_ + i1] = g1; gates[b * E_ + i2] = g2;
      imp[i1] += g1; imp[i2] += g2; load[i1] += 1.f; load[i2] += 1.f;
    }
    float bal = 0.f;
    float m = 0.f; for (int e = 0; e < E_; ++e) m += imp[e]; m *= 0.25f;
    float v = 0.f; for (int e = 0; e < E_; ++e) { float d = imp[e] - m; v += d * d; } v *= 0.25f;
    bal += v / (m * m + 1e-10f);
    m = 0.f; for (int e = 0; e < E_; ++e) m += load[e]; m *= 0.25f;
    v = 0.f; for (int e = 0; e < E_; ++e) { float d = load[e] - m; v += d * d; } v *= 0.25f;
    bal += v / (m * m + 1e-10f);
    ws[OFF_BAL] += bal;
  }
}

__global__ void k_expert(float* __restrict__ out4, const float* __restrict__ w1,
                         const float* __restrict__ b1, const float* __restrict__ w2,
                         const float* __restrict__ b2, const float* __restrict__ ws, int l) {
  int b = blockIdx.y;
  int tn = blockIdx.x * 256 + threadIdx.x;
  if (tn >= T_ * N_) return;
  float* row = out4 + ((size_t)b * T_ * N_ + tn) * D_;
  float r[D_], acc[D_];
#pragma unroll
  for (int d = 0; d < D_; ++d) { r[d] = row[d]; acc[d] = r[d]; }
  const float* gates = ws + OFF_GATE;
  for (int e = 0; e < E_; ++e) {
    float g = gates[b * E_ + e];
    if (g <= 0.f) continue;
    const float* W1 = w1 + (size_t)(l * E_ + e) * D_ * FF_;
    const float* B1 = b1 + (size_t)(l * E_ + e) * FF_;
    const float* W2 = w2 + (size_t)(l * E_ + e) * FF_ * D_;
    const float* B2 = b2 + (size_t)(l * E_ + e) * D_;
#pragma unroll 4
    for (int f = 0; f < FF_; ++f) {
      float p = B1[f];
#pragma unroll
      for (int d = 0; d < D_; ++d) p = fmaf(r[d], W1[d * FF_ + f], p);
      float c = 0.7978845608028654f * (p + 0.044715f * p * p * p);
      float hv = 0.5f * p * (1.f + tanhf(c));
      float gh = g * hv;
#pragma unroll
      for (int d = 0; d < D_; ++d) acc[d] = fmaf(gh, W2[f * D_ + d], acc[d]);
    }
#pragma unroll
    for (int d = 0; d < D_; ++d) acc[d] = fmaf(g, B2[d], acc[d]);
  }
#pragma unroll
  for (int d = 0; d < D_; ++d) row[d] = acc[d];
}

__global__ void k_wavelet(const float* __restrict__ x, const float* __restrict__ velo,
                          float* __restrict__ lowT, float* __restrict__ hvT) {
  int i = blockIdx.x * 256 + threadIdx.x;
  if (i >= BTN_) return;
  int b = i / (T_ * N_);
  int t = (i / N_) % T_;
  int n = i % N_;
  int ip = b * T_ * N_ + ((t + T_ - 1) % T_) * N_ + n;
  int row = t * B_ + b;
  lowT[(size_t)n * BT_ + row] = 0.5f * (x[i] + x[ip]);
  hvT[(size_t)n * BT_ + row] = 0.5f * (velo[i] - velo[ip]);
}

__global__ void k_rowsum(const float* __restrict__ lowT, const float* __restrict__ hvT,
                         float* __restrict__ ws) {
  int which = blockIdx.x / BT_;
  int row = blockIdx.x % BT_;
  const float* M = which ? hvT : lowT;
  float s = 0.f;
  for (int n = threadIdx.x; n < N_; n += 256) s += M[(size_t)n * BT_ + row];
  __shared__ float red[4];
  s = waveReduceSum(s);
  if ((threadIdx.x & 63) == 0) red[threadIdx.x >> 6] = s;
  __syncthreads();
  if (threadIdx.x == 0) ws[(which ? OFF_RSH : OFF_RSL) + row] = red[0] + red[1] + red[2] + red[3];
}

__global__ void k_S(const float* __restrict__ adj, const float* __restrict__ v0,
                    float* __restrict__ S) {
  int m = blockIdx.x;
  float vm = v0[m];
  const float* a = adj + (size_t)m * N_;
  float s = 0.f;
  for (int n = threadIdx.x; n < N_; n += 256) s += vm / a[n];
  __shared__ float red[4];
  s = waveReduceSum(s);
  if ((threadIdx.x & 63) == 0) red[threadIdx.x >> 6] = s;
  __syncthreads();
  if (threadIdx.x == 0) S[m] = red[0] + red[1] + red[2] + red[3];
}

__global__ void k_stats(const float* __restrict__ M, float* __restrict__ part) {
  float s = 0.f, ss = 0.f;
  for (long long i = blockIdx.x * 256 + threadIdx.x; i < NN_; i += 512 * 256) {
    float v = M[i];
    s += v; ss = fmaf(v, v, ss);
  }
  __shared__ float r1[4], r2[4];
  for (int off = 32; off; off >>= 1) { s += __shfl_down(s, off); ss += __shfl_down(ss, off); }
  if ((threadIdx.x & 63) == 0) { r1[threadIdx.x >> 6] = s; r2[threadIdx.x >> 6] = ss; }
  __syncthreads();
  if (threadIdx.x == 0) {
    part[blockIdx.x * 2] = r1[0] + r1[1] + r1[2] + r1[3];
    part[blockIdx.x * 2 + 1] = r2[0] + r2[1] + r2[2] + r2[3];
  }
}

__global__ void k_nsstats(const float* __restrict__ adj, const float* __restrict__ v0,
                          const float* __restrict__ S, float* __restrict__ part) {
  float s = 0.f, ss = 0.f;
  for (long long i = blockIdx.x * 256 + threadIdx.x; i < NN_; i += 512 * 256) {
    int m = (int)(i / N_), n = (int)(i % N_);
    float e = -(v0[m] / adj[i]);
    if (m == n) e += S[m];
    s += e; ss = fmaf(e, e, ss);
  }
  __shared__ float r1[4], r2[4];
  for (int off = 32; off; off >>= 1) { s += __shfl_down(s, off); ss += __shfl_down(ss, off); }
  if ((threadIdx.x & 63) == 0) { r1[threadIdx.x >> 6] = s; r2[threadIdx.x >> 6] = ss; }
  __syncthreads();
  if (threadIdx.x == 0) {
    part[blockIdx.x * 2] = r1[0] + r1[1] + r1[2] + r1[3];
    part[blockIdx.x * 2 + 1] = r2[0] + r2[1] + r2[2] + r2[3];
  }
}

__global__ void k_stats2(const float* __restrict__ part, float* __restrict__ stat) {
  float s = 0.f, ss = 0.f;
  for (int i = threadIdx.x; i < 512; i += 256) { s += part[i * 2]; ss += part[i * 2 + 1]; }
  __shared__ float r1[4], r2[4];
  for (int off = 32; off; off >>= 1) { s += __shfl_down(s, off); ss += __shfl_down(ss, off); }
  if ((threadIdx.x & 63) == 0) { r1[threadIdx.x >> 6] = s; r2[threadIdx.x >> 6] = ss; }
  __syncthreads();
  if (threadIdx.x == 0) {
    float su = r1[0] + r1[1] + r1[2] + r1[3];
    float sq = r2[0] + r2[1] + r2[2] + r2[3];
    float mu = su * (1.f / (float)NN_);
    float var = sq * (1.f / (float)NN_) - mu * mu;
    stat[0] = mu;
    stat[1] = 1.f / sqrtf(var);
  }
}

// ---------------------------------------------------------------------------
// fp32 streaming GEMM (r1/r3, NS), 8-deep B prefetch
// ---------------------------------------------------------------------------
__global__ __launch_bounds__(256) void k_gemm48(
    const float* __restrict__ AT, int lda, int rowTot,
    const float* __restrict__ Bm, float* __restrict__ part,
    int Kdim, int NC, int kchunk) {
  int col = blockIdx.x * 256 + threadIdx.x;
  int m0 = blockIdx.y * kchunk;
  int m1 = min(Kdim, m0 + kchunk);
  float acc[BT_];
#pragma unroll
  for (int r = 0; r < BT_; ++r) acc[r] = 0.f;
  if (col < NC) {
    const float* ap = AT + (size_t)m0 * lda;
    const float* bp = Bm + (size_t)m0 * NC + col;
    int len = m1 - m0;
    int ng = len >> 3;
    float bc[8];
    if (ng > 0) {
#pragma unroll
      for (int u = 0; u < 8; ++u) bc[u] = bp[(size_t)u * NC];
    }
    for (int gi = 0; gi < ng; ++gi) {
      float bn[8];
      bool more = (gi + 1 < ng);
      if (more) {
#pragma unroll
        for (int u = 0; u < 8; ++u) bn[u] = bp[(size_t)(8 + u) * NC];
      }
#pragma unroll
      for (int u = 0; u < 8; ++u)
        fma48(acc, (const float4*)(ap + (size_t)u * lda), bc[u]);
      ap += (size_t)8 * lda;
      bp += (size_t)8 * NC;
      if (more) {
#pragma unroll
        for (int u = 0; u < 8; ++u) bc[u] = bn[u];
      }
    }
    for (int m = m0 + (ng << 3); m < m1; ++m) {
      fma48(acc, (const float4*)ap, *bp);
      ap += lda;
      bp += NC;
    }
    float* pp = part + (size_t)blockIdx.y * rowTot * NC + col;
#pragma unroll
    for (int r = 0; r < BT_; ++r) pp[(size_t)r * NC] = acc[r];
  }
}

__global__ __launch_bounds__(256) void k_gemmNS(
    const float* __restrict__ hvT, const float* __restrict__ adj,
    const float* __restrict__ v0, const float* __restrict__ S,
    float* __restrict__ part, int kchunk) {
  int col = blockIdx.x * 256 + threadIdx.x;
  int m0 = blockIdx.y * kchunk;
  int m1 = min(N_, m0 + kchunk);
  float acc[BT_];
#pragma unroll
  for (int r = 0; r < BT_; ++r) acc[r] = 0.f;
  if (col < N_) {
    const float* ap = hvT + (size_t)m0 * BT_;
    const float* jp = adj + (size_t)m0 * N_ + col;
    int len = m1 - m0;
    int ng = len >> 3;
    float jc[8];
    if (ng > 0) {
#pragma unroll
      for (int u = 0; u < 8; ++u) jc[u] = jp[(size_t)u * N_];
    }
    int m = m0;
    for (int gi = 0; gi < ng; ++gi) {
      float jn[8];
      bool more = (gi + 1 < ng);
      if (more) {
#pragma unroll
        for (int u = 0; u < 8; ++u) jn[u] = jp[(size_t)(8 + u) * N_];
      }
#pragma unroll
      for (int u = 0; u < 8; ++u) {
        float bv = -(v0[m + u] / jc[u]);
        if (m + u == col) bv += S[m + u];
        fma48(acc, (const float4*)(ap + (size_t)u * BT_), bv);
      }
      m += 8;
      ap += (size_t)8 * BT_;
      jp += (size_t)8 * N_;
      if (more) {
#pragma unroll
        for (int u = 0; u < 8; ++u) jc[u] = jn[u];
      }
    }
    for (; m < m1; ++m) {
      float bv = -(v0[m] / (*jp));
      if (m == col) bv += S[m];
      fma48(acc, (const float4*)ap, bv);
      ap += BT_;
      jp += N_;
    }
    float* pp = part + (size_t)blockIdx.y * BT_ * N_ + col;
#pragma unroll
    for (int r = 0; r < BT_; ++r) pp[(size_t)r * N_] = acc[r];
  }
}

// ---------------------------------------------------------------------------
// fp32 [K][Nc] -> bf16 transposed [Nc][Kp] (zero-padded K), LDS 32x32 tiles
// ---------------------------------------------------------------------------
__global__ __launch_bounds__(256) void k_wtrans(const float* __restrict__ W,
                                                unsigned short* __restrict__ Wt,
                                                int K, int Nc, int Kp) {
  __shared__ unsigned short t[32][33];
  int k0 = blockIdx.y * 32, n0 = blockIdx.x * 32;
  int tx = threadIdx.x & 31, ty = threadIdx.x >> 5;  // 32 x 8
#pragma unroll
  for (int i = 0; i < 4; ++i) {
    int k = k0 + ty + i * 8, n = n0 + tx;
    float v = (k < K && n < Nc) ? W[(size_t)k * Nc + n] : 0.f;
    t[ty + i * 8][tx] = f2bf(v);
  }
  __syncthreads();
#pragma unroll
  for (int i = 0; i < 4; ++i) {
    int n = n0 + ty + i * 8, k = k0 + tx;
    if (n < Nc && k < Kp) Wt[(size_t)n * Kp + k] = t[tx][ty + i * 8];
  }
}

// ---------------------------------------------------------------------------
// MFMA GEMM: part[ks][144][Nc] = At(bf16 [144][Kp]) @ Bt(bf16 [Nc][Kp])^T
// ---------------------------------------------------------------------------
__global__ __launch_bounds__(256, 4) void k_mfma(
    const unsigned short* __restrict__ At, const unsigned short* __restrict__ Bt,
    float* __restrict__ part, int Nc, int Kp, int stepsTot, int stepChunk) {
  int lane = threadIdx.x & 63;
  int w = threadIdx.x >> 6;
  int lr = lane & 15, lo = lane >> 4;
  int gcol = blockIdx.x * 64 + w * 16 + lr;
  int bcol = min(gcol, Nc - 1);
  int s0 = blockIdx.y * stepChunk;
  int s1 = min(stepsTot, s0 + stepChunk);
  f32x4 acc[9];
#pragma unroll
  for (int mt = 0; mt < 9; ++mt) {
    acc[mt][0] = 0.f; acc[mt][1] = 0.f; acc[mt][2] = 0.f; acc[mt][3] = 0.f;
  }
  const unsigned short* bp = Bt + (size_t)bcol * Kp + (size_t)s0 * 32 + lo * 8;
  const unsigned short* ap = At + (size_t)lr * Kp + (size_t)s0 * 32 + lo * 8;
  for (int s = s0; s < s1; ++s) {
    short8 b = *(const short8*)bp;
#pragma unroll
    for (int mt = 0; mt < 9; ++mt) {
      short8 a = *(const short8*)(ap + (size_t)mt * 16 * Kp);
      acc[mt] = __builtin_amdgcn_mfma_f32_16x16x32_bf16(a, b, acc[mt], 0, 0, 0);
    }
    bp += 32;
    ap += 32;
  }
  if (gcol < Nc) {
#pragma unroll
    for (int mt = 0; mt < 9; ++mt) {
      int row = mt * 16 + lo * 4;
      float* pp = part + ((size_t)blockIdx.y * R3_ + row) * Nc + gcol;
      pp[0] = acc[mt][0];
      pp[(size_t)Nc] = acc[mt][1];
      pp[2 * (size_t)Nc] = acc[mt][2];
      pp[3 * (size_t)Nc] = acc[mt][3];
    }
  }
}

// ---------------------------------------------------------------------------
// Epilogues
// ---------------------------------------------------------------------------
__global__ void k_epiR(const float* __restrict__ part, float* __restrict__ ws,
                       unsigned short* __restrict__ atl,
                       int ksplit, int g, int statIdx, size_t rsOff) {
  int n = blockIdx.x * 256 + threadIdx.x;
  int row = blockIdx.y;
  if (n >= KP2) return;
  int arow = g * BT_ + row;
  if (n >= N_) { atl[(size_t)arow * KP2 + n] = 0; return; }
  float s = 0.f;
  for (int ks = 0; ks < ksplit; ++ks) s += part[((size_t)(ks * BT_ + row)) * N_ + n];
  float mu = ws[OFF_STAT + statIdx], isd = ws[OFF_STAT + statIdx + 1];
  float val = (s - mu * ws[rsOff + row]) * isd;
  ws[OFF_ALIN + (size_t)n * R3_ + arow] = val;
  atl[(size_t)arow * KP2 + n] = f2bf(val);
}

__global__ void k_minmax(const float* __restrict__ alin, float* __restrict__ mmp) {
  int g = blockIdx.y;
  float mn = 3.4e38f, mx = -3.4e38f;
  for (int i = blockIdx.x * 256 + threadIdx.x; i < N_ * BT_; i += 64 * 256) {
    int n = i / BT_, r = i % BT_;
    float v = alin[(size_t)n * R3_ + g * BT_ + r];
    mn = fminf(mn, v); mx = fmaxf(mx, v);
  }
  __shared__ float rn[4], rx[4];
  for (int off = 32; off; off >>= 1) {
    mn = fminf(mn, __shfl_down(mn, off));
    mx = fmaxf(mx, __shfl_down(mx, off));
  }
  if ((threadIdx.x & 63) == 0) { rn[threadIdx.x >> 6] = mn; rx[threadIdx.x >> 6] = mx; }
  __syncthreads();
  if (threadIdx.x == 0) {
    mn = fminf(fminf(rn[0], rn[1]), fminf(rn[2], rn[3]));
    mx = fmaxf(fmaxf(rx[0], rx[1]), fmaxf(rx[2], rx[3]));
    mmp[(size_t)(g * 64 + blockIdx.x) * 2] = mn;
    mmp[(size_t)(g * 64 + blockIdx.x) * 2 + 1] = mx;
  }
}

__global__ void k_minmax2(float* __restrict__ ws) {
  int g = blockIdx.x;
  int i = threadIdx.x;
  float mn = ws[OFF_MMP + (size_t)(g * 64 + i) * 2];
  float mx = ws[OFF_MMP + (size_t)(g * 64 + i) * 2 + 1];
  for (int off = 32; off; off >>= 1) {
    mn = fminf(mn, __shfl_down(mn, off));
    mx = fmaxf(mx, __shfl_down(mx, off));
  }
  if (i == 0) {
    float denom = fmaxf(mx - mn, 1e-8f);
    float a = 1.f / denom;
    ws[OFF_AB + g * 2] = a;
    ws[OFF_AB + g * 2 + 1] = -mn * a;
  }
}

__global__ void k_colsum(const float* __restrict__ ltw, float* __restrict__ csp) {
  int e = blockIdx.x * 256 + threadIdx.x;
  int ks = blockIdx.y;
  if (e >= EA_) return;
  float s = 0.f;
  for (int n = ks * 125; n < (ks + 1) * 125; ++n) s += ltw[(size_t)n * EA_ + e];
  csp[(size_t)ks * EA_ + e] = s;
}
__global__ void k_colsum2(float* __restrict__ ws) {
  int e = blockIdx.x * 256 + threadIdx.x;
  if (e >= EA_) return;
  float s = 0.f;
  for (int ks = 0; ks < 16; ++ks) s += ws[OFF_CSP + (size_t)ks * EA_ + e];
  ws[OFF_CS + e] = s;
}

__global__ void k_epiLin(const float* __restrict__ part, const float* __restrict__ ltb,
                         float* __restrict__ ws, unsigned short* __restrict__ atq,
                         int ksplit) {
  int e = blockIdx.x * 256 + threadIdx.x;
  int row = blockIdx.y;
  if (e >= KP3) return;
  if (e >= EA_) { atq[(size_t)row * KP3 + e] = 0; return; }
  float s = 0.f;
  for (int ks = 0; ks < ksplit; ++ks) s += part[((size_t)(ks * R3_ + row)) * EA_ + e];
  int g = row / BT_;
  float a = ws[OFF_AB + g * 2], bb = ws[OFF_AB + g * 2 + 1];
  float val = fmaf(a, s, fmaf(bb, ws[OFF_CS + e], ltb[e]));
  atq[(size_t)row * KP3 + e] = f2bf(val);
}

__global__ void k_epiQkv(const float* __restrict__ part, const float* __restrict__ qkvb,
                         float* __restrict__ P, int ksplit) {
  int c = blockIdx.x * 256 + threadIdx.x;
  int row = blockIdx.y;
  if (c >= 3 * EA_) return;
  float s = 0.f;
  for (int ks = 0; ks < ksplit; ++ks) s += part[((size_t)(ks * R3_ + row)) * (3 * EA_) + c];
  P[(size_t)row * (3 * EA_) + c] = s + qkvb[c];
}

__global__ void k_attn(const float* __restrict__ P, unsigned short* __restrict__ atao) {
  int mha = blockIdx.y;
  int s_ = blockIdx.x / (B_ * H_);
  int rem = blockIdx.x % (B_ * H_);
  int b = rem / H_, h = rem % H_;
  const int pq[3] = {0, 1, 2}, pk[3] = {1, 2, 0}, pv[3] = {2, 0, 1};
  const float* qrow = P + ((size_t)(pq[mha] * BT_ + s_ * B_ + b)) * (3 * EA_) + h * HD_;
  __shared__ float sc[T_];
  __shared__ float red[4];
  for (int t = 0; t < T_; ++t) {
    const float* krow = P + ((size_t)(pk[mha] * BT_ + t * B_ + b)) * (3 * EA_) + EA_ + h * HD_;
    float p = 0.f;
    for (int d = threadIdx.x; d < HD_; d += 256) p = fmaf(qrow[d], krow[d], p);
    p = waveReduceSum(p);
    if ((threadIdx.x & 63) == 0) red[threadIdx.x >> 6] = p;
    __syncthreads();
    if (threadIdx.x == 0) sc[t] = (red[0] + red[1] + red[2] + red[3]) * 0.031622776601683794f;
    __syncthreads();
  }
  float a[T_];
  float m = sc[0];
#pragma unroll
  for (int t = 1; t < T_; ++t) m = fmaxf(m, sc[t]);
  float sum = 0.f;
#pragma unroll
  for (int t = 0; t < T_; ++t) { a[t] = expf(sc[t] - m); sum += a[t]; }
  float inv = 1.f / sum;
#pragma unroll
  for (int t = 0; t < T_; ++t) a[t] *= inv;
  int orow = mha * BT_ + s_ * B_ + b;
  for (int d = threadIdx.x; d < HD_; d += 256) {
    float o = 0.f;
#pragma unroll
    for (int t = 0; t < T_; ++t)
      o = fmaf(a[t], P[((size_t)(pv[mha] * BT_ + t * B_ + b)) * (3 * EA_) + 2 * EA_ + h * HD_ + d], o);
    atao[(size_t)orow * KP3 + h * HD_ + d] = f2bf(o);
  }
  if (h == 0 && threadIdx.x < 8) atao[(size_t)orow * KP3 + EA_ + threadIdx.x] = 0;
}

__global__ void k_epiAO(const float* __restrict__ part, const float* __restrict__ aob,
                        unsigned short* __restrict__ atll, int ksplit) {
  int c = blockIdx.x * 256 + threadIdx.x;
  int row = blockIdx.y;
  if (c >= KP3) return;
  if (c >= EA_) { atll[(size_t)row * KP3 + c] = 0; return; }
  float s = 0.f;
  for (int ks = 0; ks < ksplit; ++ks) s += part[((size_t)(ks * R3_ + row)) * EA_ + c];
  atll[(size_t)row * KP3 + c] = f2bf(s + aob[c]);
}

__global__ void k_epiLL(const float* __restrict__ part, const float* __restrict__ llb,
                        float* __restrict__ o2p, int ksplit) {
  int n = blockIdx.x * 256 + threadIdx.x;
  int row = blockIdx.y;  // t*B+b
  if (n >= N_) return;
  float s = 0.f;
  for (int g = 0; g < 3; ++g)
    for (int ks = 0; ks < ksplit; ++ks)
      s += part[((size_t)(ks * R3_ + g * BT_ + row)) * N_ + n];
  int t = row / B_, b = row % B_;
  o2p[(size_t)b * (T_ * N_) + t * N_ + n] = BETA_ * (s + 3.f * llb[n]);
}

__global__ void k_proj(const float* __restrict__ out4, const float* __restrict__ pw,
                       const float* __restrict__ pb, float* __restrict__ outp) {
  int i = blockIdx.x * 256 + threadIdx.x;
  if (i >= BTN_) return;
  int b = i / (T_ * N_);
  int t = (i / N_) % T_;
  int n = i % N_;
  float acc = pb[t];
  for (int t2 = 0; t2 < T_; ++t2) {
    const float* o = out4 + ((size_t)(b * T_ + t2) * N_ + n) * D_;
#pragma unroll
    for (int d = 0; d < D_; ++d) acc = fmaf(o[d], pw[(t2 * D_ + d) * T_ + t], acc);
  }
  outp[i] = acc;
}

__global__ void k_p2(const float* __restrict__ o2p, const float* __restrict__ p2w,
                     const float* __restrict__ p2b, float* __restrict__ o2f) {
  int i = blockIdx.x * 256 + threadIdx.x;
  if (i >= BTN_) return;
  int b = i / (T_ * N_);
  int t = (i / N_) % T_;
  int n = i % N_;
  float acc = p2b[t];
  const float* src = o2p + (size_t)b * (T_ * N_) + (size_t)n * T_;
#pragma unroll
  for (int c = 0; c < T_; ++c) acc = fmaf(src[c], p2w[c * T_ + t], acc);
  o2f[i] = acc;
}

__global__ void k_out3(const float* __restrict__ outp, const float* __restrict__ o2f,
                       float* __restrict__ dout) {
  int i = blockIdx.x * 256 + threadIdx.x;
  if (i < BTN_) dout[i] = outp[i] + o2f[i];
}

__global__ void k_fnorm(const float* __restrict__ outp, const float* __restrict__ o2f,
                        float* __restrict__ g1, float* __restrict__ g2) {
  int r = blockIdx.x * 256 + threadIdx.x;
  if (r >= B_ * N_) return;
  int b = r / N_, n = r % N_;
  float v1[T_], v2[T_];
  float s1 = 0.f, s2 = 0.f;
#pragma unroll
  for (int t = 0; t < T_; ++t) {
    v1[t] = outp[(size_t)b * T_ * N_ + t * N_ + n];
    v2[t] = o2f[(size_t)b * T_ * N_ + t * N_ + n];
    s1 = fmaf(v1[t], v1[t], s1);
    s2 = fmaf(v2[t], v2[t], s2);
  }
  float n1 = fmaxf(sqrtf(s1), 1e-12f), n2 = fmaxf(sqrtf(s2), 1e-12f);
  float i1 = 10.f / n1, i2 = 1.f / n2;
#pragma unroll
  for (int t = 0; t < T_; ++t) {
    g1[(size_t)r * T_ + t] = v1[t] * i1;
    g2[(size_t)r * T_ + t] = v2[t] * i2;
  }
}

// per-row logsumexp, j-split 4-way for occupancy; partial exp-sums + diag
__global__ __launch_bounds__(256) void k_lse(const float* __restrict__ g1,
                                             const float* __restrict__ g2,
                                             float* __restrict__ psm,
                                             float* __restrict__ psd) {
  int r = threadIdx.x >> 4;   // row within block
  int k = threadIdx.x & 15;   // j-phase
  int row = blockIdx.x * 16 + r;
  int js = blockIdx.y;
  const float4* qp = (const float4*)(g1 + (size_t)row * T_);
  float4 qa = qp[0], qb = qp[1], qc = qp[2];
  float sm = 0.f, sd = 0.f;
  int j0 = js * LSE_JCH;
  for (int j = j0 + k; j < j0 + LSE_JCH; j += 16) {
    const float4* p = (const float4*)(g2 + (size_t)j * T_);
    float4 A = p[0], Bv = p[1], C = p[2];
    // 3 independent 4-FMA chains (halves dependent latency)
    float s0 = qa.x * A.x;
    s0 = fmaf(qa.y, A.y, s0); s0 = fmaf(qa.z, A.z, s0); s0 = fmaf(qa.w, A.w, s0);
    float s1 = qb.x * Bv.x;
    s1 = fmaf(qb.y, Bv.y, s1); s1 = fmaf(qb.z, Bv.z, s1); s1 = fmaf(qb.w, Bv.w, s1);
    float s2 = qc.x * C.x;
    s2 = fmaf(qc.y, C.y, s2); s2 = fmaf(qc.z, C.z, s2); s2 = fmaf(qc.w, C.w, s2);
    float s = (s0 + s1) + s2;
    sm += __expf(s);
    if (j == row) sd = s;
  }
#pragma unroll
  for (int off = 8; off; off >>= 1) {
    sm += __shfl_xor(sm, off);
    sd += __shfl_xor(sd, off);
  }
  if (k == 0) {
    psm[(size_t)js * 8000 + row] = sm;
    psd[(size_t)js * 8000 + row] = sd;
  }
}

// combine j-splits -> li[row]
__global__ void k_lse2(const float* __restrict__ psm, const float* __restrict__ psd,
                       float* __restrict__ li) {
  int row = blockIdx.x * 256 + threadIdx.x;
  if (row >= B_ * N_) return;
  float sm = 0.f, sd = 0.f;
#pragma unroll
  for (int js = 0; js < LSE_JS; ++js) {
    sm += psm[(size_t)js * 8000 + row];
    sd += psd[(size_t)js * 8000 + row];
  }
  li[row] = sd - logf(sm);
}

__global__ void k_final(const float* __restrict__ li, const float* __restrict__ ws,
                        float* __restrict__ dout) {
  float s = 0.f;
  for (int i = threadIdx.x; i < B_ * N_; i += 256) s += li[i];
  __shared__ float red[4];
  s = waveReduceSum(s);
  if ((threadIdx.x & 63) == 0) red[threadIdx.x >> 6] = s;
  __syncthreads();
  if (threadIdx.x == 0) {
    float closs = -(red[0] + red[1] + red[2] + red[3]) * (1.f / (B_ * N_));
    dout[BTN_] = ws[OFF_BAL];
    dout[BTN_ + 1] = CW_ * closs;
  }
}

// ---------------------------------------------------------------------------
extern "C" void kernel_launch(void* const* d_in, const int* in_sizes, int n_in,
                              void* d_out, int out_size, void* d_ws, size_t ws_size,
                              hipStream_t stream) {
  const float* x    = (const float*)d_in[0];
  const float* velo = (const float*)d_in[1];
  const float* adj  = (const float*)d_in[2];
  const float* lapd = (const float*)d_in[3];
  const float* laph = (const float*)d_in[4];
  const float* sw   = (const float*)d_in[5];
  const float* sb   = (const float*)d_in[6];
  const float* gw   = (const float*)d_in[7];
  const float* ew1  = (const float*)d_in[8];
  const float* eb1  = (const float*)d_in[9];
  const float* ew2  = (const float*)d_in[10];
  const float* eb2  = (const float*)d_in[11];
  const float* pw   = (const float*)d_in[12];
  const float* pb   = (const float*)d_in[13];
  const float* ltw  = (const float*)d_in[14];
  const float* ltb  = (const float*)d_in[15];
  const float* qkvw = (const float*)d_in[16];
  const float* qkvb = (const float*)d_in[17];
  const float* aow  = (const float*)d_in[18];
  const float* aob  = (const float*)d_in[19];
  const float* llw  = (const float*)d_in[20];
  const float* llb  = (const float*)d_in[21];
  const float* p2w  = (const float*)d_in[22];
  const float* p2b  = (const float*)d_in[23];
  float* ws = (float*)d_ws;
  float* dout = (float*)d_out;
  const float* v0 = velo;  // velo[0,0,:]
  float* part = ws + OFF_PART;
  unsigned short* btQ  = (unsigned short*)(ws + OFF_BT_Q);
  unsigned short* btA  = (unsigned short*)(ws + OFF_BT_A);
  unsigned short* btL  = (unsigned short*)(ws + OFF_BT_L);
  unsigned short* btW  = (unsigned short*)(ws + OFF_BT_W);
  unsigned short* atLin = (unsigned short*)(ws + OFF_AT_LIN);
  unsigned short* atQ   = (unsigned short*)(ws + OFF_AT_Q);
  unsigned short* atAO  = (unsigned short*)(ws + OFF_AT_AO);
  unsigned short* atLL  = (unsigned short*)(ws + OFF_AT_LL);
  dim3 b256(256);

  k_init<<<dim3(1), dim3(64), 0, stream>>>(ws);

  // weight transposes to bf16 (depend only on inputs)
  k_wtrans<<<dim3(282, 94), b256, 0, stream>>>(qkvw, btQ, EA_, 3 * EA_, KP3);
  k_wtrans<<<dim3(94, 94), b256, 0, stream>>>(aow, btA, EA_, EA_, KP3);
  k_wtrans<<<dim3(63, 94), b256, 0, stream>>>(llw, btL, EA_, N_, KP3);
  k_wtrans<<<dim3(94, 63), b256, 0, stream>>>(ltw, btW, N_, EA_, KP2);

  k_start<<<dim3((BTN_ * D_ + 255) / 256), b256, 0, stream>>>(x, sw, sb, ws + OFF_OUT4);

  for (int l = 0; l < L_; ++l) {
    k_feat<<<dim3(B_ * D_), b256, 0, stream>>>(ws + OFF_OUT4, ws + OFF_FEAT);
    k_gate<<<dim3(1), dim3(64), 0, stream>>>(ws + OFF_FEAT, gw, ws, l);
    k_expert<<<dim3((T_ * N_ + 255) / 256, B_), b256, 0, stream>>>(ws + OFF_OUT4, ew1, eb1, ew2, eb2, ws, l);
  }

  k_wavelet<<<dim3((BTN_ + 255) / 256), b256, 0, stream>>>(x, velo, ws + OFF_LOWT, ws + OFF_HVT);
  k_rowsum<<<dim3(2 * BT_), b256, 0, stream>>>(ws + OFF_LOWT, ws + OFF_HVT, ws);
  k_S<<<dim3(N_), b256, 0, stream>>>(adj, v0, ws + OFF_S);
  k_stats<<<dim3(512), b256, 0, stream>>>(lapd, ws + OFF_STP);
  k_stats2<<<dim3(1), b256, 0, stream>>>(ws + OFF_STP, ws + OFF_STAT);
  k_stats<<<dim3(512), b256, 0, stream>>>(laph, ws + OFF_STP + 1024);
  k_stats2<<<dim3(1), b256, 0, stream>>>(ws + OFF_STP + 1024, ws + OFF_STAT + 2);
  k_nsstats<<<dim3(512), b256, 0, stream>>>(adj, v0, ws + OFF_S, ws + OFF_STP + 2048);
  k_stats2<<<dim3(1), b256, 0, stream>>>(ws + OFF_STP + 2048, ws + OFF_STAT + 4);

  // r1 / r2 / r3 (fp32, split-K 50)
  k_gemm48<<<dim3(8, RKS_), b256, 0, stream>>>(ws + OFF_LOWT, BT_, BT_, lapd, part, N_, N_, RKC_);
  k_epiR<<<dim3(8, 48), b256, 0, stream>>>(part, ws, atLin, RKS_, 0, 0, OFF_RSL);
  k_gemmNS<<<dim3(8, RKS_), b256, 0, stream>>>(ws + OFF_HVT, adj, v0, ws + OFF_S, part, RKC_);
  k_epiR<<<dim3(8, 48), b256, 0, stream>>>(part, ws, atLin, RKS_, 1, 4, OFF_RSH);
  k_gemm48<<<dim3(8, RKS_), b256, 0, stream>>>(ws + OFF_LOWT, BT_, BT_, laph, part, N_, N_, RKC_);
  k_epiR<<<dim3(8, 48), b256, 0, stream>>>(part, ws, atLin, RKS_, 2, 2, OFF_RSL);

  k_minmax<<<dim3(64, 3), b256, 0, stream>>>(ws + OFF_ALIN, ws + OFF_MMP);
  k_minmax2<<<dim3(3), dim3(64), 0, stream>>>(ws);
  k_colsum<<<dim3(12, 16), b256, 0, stream>>>(ltw, ws + OFF_CSP);
  k_colsum2<<<dim3(12), b256, 0, stream>>>(ws);

  // lin (MFMA)
  k_mfma<<<dim3(47, 9), b256, 0, stream>>>(atLin, btW, part, EA_, KP2, KP2 / 32, 7);
  k_epiLin<<<dim3(12, 144), b256, 0, stream>>>(part, ltb, ws, atQ, 9);

  // qkv (MFMA)
  k_mfma<<<dim3(141, 4), b256, 0, stream>>>(atQ, btQ, part, 3 * EA_, KP3, KP3 / 32, 24);
  k_epiQkv<<<dim3(36, 144), b256, 0, stream>>>(part, qkvb, ws + OFF_P, 4);

  // attention
  k_attn<<<dim3(T_ * B_ * H_, 3), b256, 0, stream>>>(ws + OFF_P, atAO);

  // attn-out (MFMA)
  k_mfma<<<dim3(47, 12), b256, 0, stream>>>(atAO, btA, part, EA_, KP3, KP3 / 32, 8);
  k_epiAO<<<dim3(12, 144), b256, 0, stream>>>(part, aob, atLL, 12);

  // ll (MFMA)
  k_mfma<<<dim3(32, 12), b256, 0, stream>>>(atLL, btL, part, N_, KP3, KP3 / 32, 8);
  k_epiLL<<<dim3(8, 48), b256, 0, stream>>>(part, llb, ws + OFF_O2P, 12);

  k_proj<<<dim3((BTN_ + 255) / 256), b256, 0, stream>>>(ws + OFF_OUT4, pw, pb, ws + OFF_OUTP);
  k_p2<<<dim3((BTN_ + 255) / 256), b256, 0, stream>>>(ws + OFF_O2P, p2w, p2b, ws + OFF_O2F);
  k_out3<<<dim3((BTN_ + 255) / 256), b256, 0, stream>>>(ws + OFF_OUTP, ws + OFF_O2F, dout);

  k_fnorm<<<dim3((B_ * N_ + 255) / 256), b256, 0, stream>>>(ws + OFF_OUTP, ws + OFF_O2F, ws + OFF_G1, ws + OFF_G2);
  // psm/psd partials live in `part` (free after the last GEMM epilogue)
  k_lse<<<dim3(B_ * N_ / 16, LSE_JS), b256, 0, stream>>>(ws + OFF_G1, ws + OFF_G2, part, part + (size_t)LSE_JS * 8000);
  k_lse2<<<dim3((B_ * N_ + 255) / 256), b256, 0, stream>>>(part, part + (size_t)LSE_JS * 8000, ws + OFF_LI);
  k_final<<<dim3(1), b256, 0, stream>>>(ws + OFF_LI, ws, dout);
}

// Round 9
// 810.255 us; speedup vs baseline: 1.2947x; 1.1012x over previous
//
#include <hip/hip_runtime.h>
#include <math.h>

// ---------------------------------------------------------------------------
// Model constants
// ---------------------------------------------------------------------------
namespace {
constexpr int B_ = 4, T_ = 12, N_ = 2000, D_ = 16, FF_ = 64, E_ = 4, L_ = 2;
constexpr int EA_ = 3000, H_ = 3, HD_ = EA_ / H_;   // 1000
constexpr int BT_ = B_ * T_;                         // 48
constexpr int R3_ = 3 * BT_;                         // 144
constexpr long long NN_ = (long long)N_ * N_;        // 4,000,000
constexpr int BTN_ = B_ * T_ * N_;                   // 96,000
constexpr float BETA_ = 0.01f, CW_ = 0.001f;
constexpr int RKS_ = 50;                             // r-GEMM split-K
constexpr int RKC_ = 40;                             // r-GEMM k-chunk
constexpr int KP3 = 3008;                            // K=3000 padded to 32
constexpr int KP2 = 2016;                            // K=2000 padded to 32

// ---------------------------------------------------------------------------
// Workspace layout (float offsets)
// ---------------------------------------------------------------------------
constexpr size_t OFF_OUT4 = 0;                                   // [B,T,N,D]
constexpr size_t OFF_LOWT = OFF_OUT4 + (size_t)BTN_ * D_;        // lowT^T [N][48]
constexpr size_t OFF_HVT  = OFF_LOWT + BTN_;                     // highV^T [N][48]
constexpr size_t OFF_ALIN = OFF_HVT + BTN_;                      // r^T [N][144]
constexpr size_t OFF_RT   = OFF_ALIN + (size_t)N_ * R3_;         // (unused, kept)
constexpr size_t OFF_P    = OFF_RT + (size_t)EA_ * R3_;          // P [144][9000]
constexpr size_t OFF_AOT  = OFF_P + (size_t)R3_ * 3 * EA_;       // (unused, kept)
constexpr size_t OFF_OT   = OFF_AOT + (size_t)EA_ * R3_;         // (unused, kept)
constexpr size_t OFF_O2P  = OFF_OT + (size_t)EA_ * R3_;          // out2 pre-p2 [B][T*N]
constexpr size_t OFF_OUTP = OFF_O2P + BTN_;                      // outp [B,T,N]
constexpr size_t OFF_O2F  = OFF_OUTP + BTN_;                     // out2 final [B,T,N]
constexpr size_t OFF_LI   = OFF_O2F + BTN_;                      // (spare)
constexpr size_t OFF_S    = OFF_LI + 8000;                       // G row sums [2000]
constexpr size_t OFF_RSL  = OFF_S + 2000;
constexpr size_t OFF_RSH  = OFF_RSL + 48;
constexpr size_t OFF_STP  = OFF_RSH + 48;
constexpr size_t OFF_STAT = OFF_STP + 3072;
constexpr size_t OFF_MMP  = OFF_STAT + 8;
constexpr size_t OFF_AB   = OFF_MMP + 384;
constexpr size_t OFF_CSP  = OFF_AB + 8;
constexpr size_t OFF_CS   = OFF_CSP + 48000;
constexpr size_t OFF_FEAT = OFF_CS + 3000;
constexpr size_t OFF_GATE = OFF_FEAT + 64;
constexpr size_t OFF_BAL  = OFF_GATE + 16;
constexpr size_t OFF_PART = ((OFF_BAL + 1 + 255) & ~(size_t)255); // split-K partials
constexpr size_t PARTCAP  = 6000000;                              // cap (floats)
// bf16 regions (sizes in floats = ushorts/2)
constexpr size_t OFF_BT_Q  = OFF_PART + PARTCAP;                  // qkvw^T  [9000][KP3]
constexpr size_t OFF_BT_A  = OFF_BT_Q + (size_t)9000 * KP3 / 2;   // aow^T   [3000][KP3]
constexpr size_t OFF_BT_L  = OFF_BT_A + (size_t)3000 * KP3 / 2;   // llw^T   [2000][KP3]
constexpr size_t OFF_BT_W  = OFF_BT_L + (size_t)2000 * KP3 / 2;   // ltw^T   [3000][KP2]
constexpr size_t OFF_AT_LIN= OFF_BT_W + (size_t)3000 * KP2 / 2;   // ALIN^T  [144][KP2]
constexpr size_t OFF_AT_Q  = OFF_AT_LIN + (size_t)R3_ * KP2 / 2;  // RT^T    [144][KP3]
constexpr size_t OFF_AT_AO = OFF_AT_Q + (size_t)R3_ * KP3 / 2;    // Ao      [144][KP3]
constexpr size_t OFF_AT_LL = OFF_AT_AO + (size_t)R3_ * KP3 / 2;   // O       [144][KP3]
constexpr size_t OFF_G1B   = OFF_AT_LL + (size_t)R3_ * KP3 / 2;   // f1 bf16 [8000][32]
constexpr size_t OFF_G2B   = OFF_G1B + 128000;                    // f2 bf16 [8000][32]
} // namespace

typedef __attribute__((ext_vector_type(8))) short short8;
typedef __attribute__((ext_vector_type(4))) float f32x4;

// ---------------------------------------------------------------------------
// Helpers
// ---------------------------------------------------------------------------
__device__ __forceinline__ float waveReduceSum(float v) {
  for (int off = 32; off; off >>= 1) v += __shfl_down(v, off);
  return v;
}

__device__ __forceinline__ unsigned short f2bf(float x) {  // RNE fp32->bf16
  unsigned int u = __float_as_uint(x);
  unsigned int r = (u + 0x7FFFu + ((u >> 16) & 1u)) >> 16;
  return (unsigned short)r;
}

__device__ __forceinline__ void fma48(float* __restrict__ acc,
                                      const float4* __restrict__ a4, float bv) {
#pragma unroll
  for (int r4 = 0; r4 < BT_ / 4; ++r4) {
    float4 av = a4[r4];
    acc[r4 * 4 + 0] = fmaf(av.x, bv, acc[r4 * 4 + 0]);
    acc[r4 * 4 + 1] = fmaf(av.y, bv, acc[r4 * 4 + 1]);
    acc[r4 * 4 + 2] = fmaf(av.z, bv, acc[r4 * 4 + 2]);
    acc[r4 * 4 + 3] = fmaf(av.w, bv, acc[r4 * 4 + 3]);
  }
}

// ---------------------------------------------------------------------------
__global__ void k_init(float* ws) {
  if (threadIdx.x == 0) ws[OFF_BAL] = 0.f;
}

__global__ void k_start(const float* __restrict__ x, const float* __restrict__ sw,
                        const float* __restrict__ sb, float* __restrict__ out4) {
  int i = blockIdx.x * 256 + threadIdx.x;
  if (i >= BTN_ * D_) return;
  int d = i & 15;
  out4[i] = fmaf(x[i >> 4], sw[d], sb[d]);
}

__global__ void k_feat(const float* __restrict__ out4, float* __restrict__ feat) {
  int b = blockIdx.x >> 4, d = blockIdx.x & 15;
  float s = 0.f;
  for (int tn = threadIdx.x; tn < T_ * N_; tn += 256)
    s += out4[((size_t)b * T_ * N_ + tn) * D_ + d];
  __shared__ float red[4];
  s = waveReduceSum(s);
  if ((threadIdx.x & 63) == 0) red[threadIdx.x >> 6] = s;
  __syncthreads();
  if (threadIdx.x == 0)
    feat[blockIdx.x] = (red[0] + red[1] + red[2] + red[3]) * (1.f / (T_ * N_));
}

__global__ void k_gate(const float* __restrict__ feat, const float* __restrict__ gw,
                       float* __restrict__ ws, int l) {
  __shared__ float lg[B_ * E_];
  int tid = threadIdx.x;
  if (tid < B_ * E_) {
    int b = tid >> 2, e = tid & 3;
    float s = 0.f;
    for (int d = 0; d < D_; ++d) s = fmaf(feat[b * D_ + d], gw[(l * D_ + d) * E_ + e], s);
    lg[tid] = s;
  }
  __syncthreads();
  if (tid == 0) {
    float* gates = ws + OFF_GATE;
    float imp[E_] = {0, 0, 0, 0}, load[E_] = {0, 0, 0, 0};
    for (int i = 0; i < B_ * E_; ++i) gates[i] = 0.f;
    for (int b = 0; b < B_; ++b) {
      const float* lb = lg + b * E_;
      int i1 = 0; float v1 = lb[0];
      for (int e = 1; e < E_; ++e) if (lb[e] > v1) { v1 = lb[e]; i1 = e; }
      int i2 = -1; float v2 = -1e30f;
      for (int e = 0; e < E_; ++e) { if (e == i1) continue; if (lb[e] > v2) { v2 = lb[e]; i2 = e; } }
      float e2 = expf(v2 - v1);
      float den = 1.f + e2;
      float g1 = 1.f / den, g2 = e2 / den;
      gates[b * E_ + i1] = g1; gates[b * E_ + i2] = g2;
      imp[i1] += g1; imp[i2] += g2; load[i1] += 1.f; load[i2] += 1.f;
    }
    float bal = 0.f;
    float m = 0.f; for (int e = 0; e < E_; ++e) m += imp[e]; m *= 0.25f;
    float v = 0.f; for (int e = 0; e < E_; ++e) { float d = imp[e] - m; v += d * d; } v *= 0.25f;
    bal += v / (m * m + 1e-10f);
    m = 0.f; for (int e = 0; e < E_; ++e) m += load[e]; m *= 0.25f;
    v = 0.f; for (int e = 0; e < E_; ++e) { float d = load[e] - m; v += d * d; } v *= 0.25f;
    bal += v / (m * m + 1e-10f);
    ws[OFF_BAL] += bal;
  }
}

__global__ void k_expert(float* __restrict__ out4, const float* __restrict__ w1,
                         const float* __restrict__ b1, const float* __restrict__ w2,
                         const float* __restrict__ b2, const float* __restrict__ ws, int l) {
  int b = blockIdx.y;
  int tn = blockIdx.x * 256 + threadIdx.x;
  if (tn >= T_ * N_) return;
  float* row = out4 + ((size_t)b * T_ * N_ + tn) * D_;
  float r[D_], acc[D_];
#pragma unroll
  for (int d = 0; d < D_; ++d) { r[d] = row[d]; acc[d] = r[d]; }
  const float* gates = ws + OFF_GATE;
  for (int e = 0; e < E_; ++e) {
    float g = gates[b * E_ + e];
    if (g <= 0.f) continue;
    const float* W1 = w1 + (size_t)(l * E_ + e) * D_ * FF_;
    const float* B1 = b1 + (size_t)(l * E_ + e) * FF_;
    const float* W2 = w2 + (size_t)(l * E_ + e) * FF_ * D_;
    const float* B2 = b2 + (size_t)(l * E_ + e) * D_;
#pragma unroll 4
    for (int f = 0; f < FF_; ++f) {
      float p = B1[f];
#pragma unroll
      for (int d = 0; d < D_; ++d) p = fmaf(r[d], W1[d * FF_ + f], p);
      float c = 0.7978845608028654f * (p + 0.044715f * p * p * p);
      float hv = 0.5f * p * (1.f + tanhf(c));
      float gh = g * hv;
#pragma unroll
      for (int d = 0; d < D_; ++d) acc[d] = fmaf(gh, W2[f * D_ + d], acc[d]);
    }
#pragma unroll
    for (int d = 0; d < D_; ++d) acc[d] = fmaf(g, B2[d], acc[d]);
  }
#pragma unroll
  for (int d = 0; d < D_; ++d) row[d] = acc[d];
}

__global__ void k_wavelet(const float* __restrict__ x, const float* __restrict__ velo,
                          float* __restrict__ lowT, float* __restrict__ hvT) {
  int i = blockIdx.x * 256 + threadIdx.x;
  if (i >= BTN_) return;
  int b = i / (T_ * N_);
  int t = (i / N_) % T_;
  int n = i % N_;
  int ip = b * T_ * N_ + ((t + T_ - 1) % T_) * N_ + n;
  int row = t * B_ + b;
  lowT[(size_t)n * BT_ + row] = 0.5f * (x[i] + x[ip]);
  hvT[(size_t)n * BT_ + row] = 0.5f * (velo[i] - velo[ip]);
}

__global__ void k_rowsum(const float* __restrict__ lowT, const float* __restrict__ hvT,
                         float* __restrict__ ws) {
  int which = blockIdx.x / BT_;
  int row = blockIdx.x % BT_;
  const float* M = which ? hvT : lowT;
  float s = 0.f;
  for (int n = threadIdx.x; n < N_; n += 256) s += M[(size_t)n * BT_ + row];
  __shared__ float red[4];
  s = waveReduceSum(s);
  if ((threadIdx.x & 63) == 0) red[threadIdx.x >> 6] = s;
  __syncthreads();
  if (threadIdx.x == 0) ws[(which ? OFF_RSH : OFF_RSL) + row] = red[0] + red[1] + red[2] + red[3];
}

__global__ void k_S(const float* __restrict__ adj, const float* __restrict__ v0,
                    float* __restrict__ S) {
  int m = blockIdx.x;
  float vm = v0[m];
  const float* a = adj + (size_t)m * N_;
  float s = 0.f;
  for (int n = threadIdx.x; n < N_; n += 256) s += vm / a[n];
  __shared__ float red[4];
  s = waveReduceSum(s);
  if ((threadIdx.x & 63) == 0) red[threadIdx.x >> 6] = s;
  __syncthreads();
  if (threadIdx.x == 0) S[m] = red[0] + red[1] + red[2] + red[3];
}

__global__ void k_stats(const float* __restrict__ M, float* __restrict__ part) {
  float s = 0.f, ss = 0.f;
  for (long long i = blockIdx.x * 256 + threadIdx.x; i < NN_; i += 512 * 256) {
    float v = M[i];
    s += v; ss = fmaf(v, v, ss);
  }
  __shared__ float r1[4], r2[4];
  for (int off = 32; off; off >>= 1) { s += __shfl_down(s, off); ss += __shfl_down(ss, off); }
  if ((threadIdx.x & 63) == 0) { r1[threadIdx.x >> 6] = s; r2[threadIdx.x >> 6] = ss; }
  __syncthreads();
  if (threadIdx.x == 0) {
    part[blockIdx.x * 2] = r1[0] + r1[1] + r1[2] + r1[3];
    part[blockIdx.x * 2 + 1] = r2[0] + r2[1] + r2[2] + r2[3];
  }
}

__global__ void k_nsstats(const float* __restrict__ adj, const float* __restrict__ v0,
                          const float* __restrict__ S, float* __restrict__ part) {
  float s = 0.f, ss = 0.f;
  for (long long i = blockIdx.x * 256 + threadIdx.x; i < NN_; i += 512 * 256) {
    int m = (int)(i / N_), n = (int)(i % N_);
    float e = -(v0[m] / adj[i]);
    if (m == n) e += S[m];
    s += e; ss = fmaf(e, e, ss);
  }
  __shared__ float r1[4], r2[4];
  for (int off = 32; off; off >>= 1) { s += __shfl_down(s, off); ss += __shfl_down(ss, off); }
  if ((threadIdx.x & 63) == 0) { r1[threadIdx.x >> 6] = s; r2[threadIdx.x >> 6] = ss; }
  __syncthreads();
  if (threadIdx.x == 0) {
    part[blockIdx.x * 2] = r1[0] + r1[1] + r1[2] + r1[3];
    part[blockIdx.x * 2 + 1] = r2[0] + r2[1] + r2[2] + r2[3];
  }
}

__global__ void k_stats2(const float* __restrict__ part, float* __restrict__ stat) {
  float s = 0.f, ss = 0.f;
  for (int i = threadIdx.x; i < 512; i += 256) { s += part[i * 2]; ss += part[i * 2 + 1]; }
  __shared__ float r1[4], r2[4];
  for (int off = 32; off; off >>= 1) { s += __shfl_down(s, off); ss += __shfl_down(ss, off); }
  if ((threadIdx.x & 63) == 0) { r1[threadIdx.x >> 6] = s; r2[threadIdx.x >> 6] = ss; }
  __syncthreads();
  if (threadIdx.x == 0) {
    float su = r1[0] + r1[1] + r1[2] + r1[3];
    float sq = r2[0] + r2[1] + r2[2] + r2[3];
    float mu = su * (1.f / (float)NN_);
    float var = sq * (1.f / (float)NN_) - mu * mu;
    stat[0] = mu;
    stat[1] = 1.f / sqrtf(var);
  }
}

// ---------------------------------------------------------------------------
// fp32 streaming GEMM (r1/r3, NS), 8-deep B prefetch
// ---------------------------------------------------------------------------
__global__ __launch_bounds__(256) void k_gemm48(
    const float* __restrict__ AT, int lda, int rowTot,
    const float* __restrict__ Bm, float* __restrict__ part,
    int Kdim, int NC, int kchunk) {
  int col = blockIdx.x * 256 + threadIdx.x;
  int m0 = blockIdx.y * kchunk;
  int m1 = min(Kdim, m0 + kchunk);
  float acc[BT_];
#pragma unroll
  for (int r = 0; r < BT_; ++r) acc[r] = 0.f;
  if (col < NC) {
    const float* ap = AT + (size_t)m0 * lda;
    const float* bp = Bm + (size_t)m0 * NC + col;
    int len = m1 - m0;
    int ng = len >> 3;
    float bc[8];
    if (ng > 0) {
#pragma unroll
      for (int u = 0; u < 8; ++u) bc[u] = bp[(size_t)u * NC];
    }
    for (int gi = 0; gi < ng; ++gi) {
      float bn[8];
      bool more = (gi + 1 < ng);
      if (more) {
#pragma unroll
        for (int u = 0; u < 8; ++u) bn[u] = bp[(size_t)(8 + u) * NC];
      }
#pragma unroll
      for (int u = 0; u < 8; ++u)
        fma48(acc, (const float4*)(ap + (size_t)u * lda), bc[u]);
      ap += (size_t)8 * lda;
      bp += (size_t)8 * NC;
      if (more) {
#pragma unroll
        for (int u = 0; u < 8; ++u) bc[u] = bn[u];
      }
    }
    for (int m = m0 + (ng << 3); m < m1; ++m) {
      fma48(acc, (const float4*)ap, *bp);
      ap += lda;
      bp += NC;
    }
    float* pp = part + (size_t)blockIdx.y * rowTot * NC + col;
#pragma unroll
    for (int r = 0; r < BT_; ++r) pp[(size_t)r * NC] = acc[r];
  }
}

__global__ __launch_bounds__(256) void k_gemmNS(
    const float* __restrict__ hvT, const float* __restrict__ adj,
    const float* __restrict__ v0, const float* __restrict__ S,
    float* __restrict__ part, int kchunk) {
  int col = blockIdx.x * 256 + threadIdx.x;
  int m0 = blockIdx.y * kchunk;
  int m1 = min(N_, m0 + kchunk);
  float acc[BT_];
#pragma unroll
  for (int r = 0; r < BT_; ++r) acc[r] = 0.f;
  if (col < N_) {
    const float* ap = hvT + (size_t)m0 * BT_;
    const float* jp = adj + (size_t)m0 * N_ + col;
    int len = m1 - m0;
    int ng = len >> 3;
    float jc[8];
    if (ng > 0) {
#pragma unroll
      for (int u = 0; u < 8; ++u) jc[u] = jp[(size_t)u * N_];
    }
    int m = m0;
    for (int gi = 0; gi < ng; ++gi) {
      float jn[8];
      bool more = (gi + 1 < ng);
      if (more) {
#pragma unroll
        for (int u = 0; u < 8; ++u) jn[u] = jp[(size_t)(8 + u) * N_];
      }
#pragma unroll
      for (int u = 0; u < 8; ++u) {
        float bv = -(v0[m + u] / jc[u]);
        if (m + u == col) bv += S[m + u];
        fma48(acc, (const float4*)(ap + (size_t)u * BT_), bv);
      }
      m += 8;
      ap += (size_t)8 * BT_;
      jp += (size_t)8 * N_;
      if (more) {
#pragma unroll
        for (int u = 0; u < 8; ++u) jc[u] = jn[u];
      }
    }
    for (; m < m1; ++m) {
      float bv = -(v0[m] / (*jp));
      if (m == col) bv += S[m];
      fma48(acc, (const float4*)ap, bv);
      ap += BT_;
      jp += N_;
    }
    float* pp = part + (size_t)blockIdx.y * BT_ * N_ + col;
#pragma unroll
    for (int r = 0; r < BT_; ++r) pp[(size_t)r * N_] = acc[r];
  }
}

// ---------------------------------------------------------------------------
// Fused 4-way weight transpose: fp32 [K][Nc] -> bf16 [Nc][Kp], grid.z selects
// ---------------------------------------------------------------------------
__global__ __launch_bounds__(256) void k_wtrans4(
    const float* __restrict__ W0, const float* __restrict__ W1,
    const float* __restrict__ W2, const float* __restrict__ W3,
    unsigned short* __restrict__ T0, unsigned short* __restrict__ T1,
    unsigned short* __restrict__ T2, unsigned short* __restrict__ T3) {
  int z = blockIdx.z;
  const float* W; unsigned short* Wt; int K, Nc, Kp;
  if (z == 0)      { W = W0; Wt = T0; K = EA_; Nc = 3 * EA_; Kp = KP3; }
  else if (z == 1) { W = W1; Wt = T1; K = EA_; Nc = EA_;     Kp = KP3; }
  else if (z == 2) { W = W2; Wt = T2; K = EA_; Nc = N_;      Kp = KP3; }
  else             { W = W3; Wt = T3; K = N_;  Nc = EA_;     Kp = KP2; }
  int k0 = blockIdx.y * 32, n0 = blockIdx.x * 32;
  if (n0 >= Nc || k0 >= Kp) return;
  __shared__ unsigned short t[32][33];
  int tx = threadIdx.x & 31, ty = threadIdx.x >> 5;  // 32 x 8
#pragma unroll
  for (int i = 0; i < 4; ++i) {
    int k = k0 + ty + i * 8, n = n0 + tx;
    float v = (k < K && n < Nc) ? W[(size_t)k * Nc + n] : 0.f;
    t[ty + i * 8][tx] = f2bf(v);
  }
  __syncthreads();
#pragma unroll
  for (int i = 0; i < 4; ++i) {
    int n = n0 + ty + i * 8, k = k0 + tx;
    if (n < Nc && k < Kp) Wt[(size_t)n * Kp + k] = t[tx][ty + i * 8];
  }
}

// ---------------------------------------------------------------------------
// MFMA GEMM: part[ks][144][Nc] = At(bf16 [144][Kp]) @ Bt(bf16 [Nc][Kp])^T
// ---------------------------------------------------------------------------
__global__ __launch_bounds__(256, 4) void k_mfma(
    const unsigned short* __restrict__ At, const unsigned short* __restrict__ Bt,
    float* __restrict__ part, int Nc, int Kp, int stepsTot, int stepChunk) {
  int lane = threadIdx.x & 63;
  int w = threadIdx.x >> 6;
  int lr = lane & 15, lo = lane >> 4;
  int gcol = blockIdx.x * 64 + w * 16 + lr;
  int bcol = min(gcol, Nc - 1);
  int s0 = blockIdx.y * stepChunk;
  int s1 = min(stepsTot, s0 + stepChunk);
  f32x4 acc[9];
#pragma unroll
  for (int mt = 0; mt < 9; ++mt) {
    acc[mt][0] = 0.f; acc[mt][1] = 0.f; acc[mt][2] = 0.f; acc[mt][3] = 0.f;
  }
  const unsigned short* bp = Bt + (size_t)bcol * Kp + (size_t)s0 * 32 + lo * 8;
  const unsigned short* ap = At + (size_t)lr * Kp + (size_t)s0 * 32 + lo * 8;
  for (int s = s0; s < s1; ++s) {
    short8 b = *(const short8*)bp;
#pragma unroll
    for (int mt = 0; mt < 9; ++mt) {
      short8 a = *(const short8*)(ap + (size_t)mt * 16 * Kp);
      acc[mt] = __builtin_amdgcn_mfma_f32_16x16x32_bf16(a, b, acc[mt], 0, 0, 0);
    }
    bp += 32;
    ap += 32;
  }
  if (gcol < Nc) {
#pragma unroll
    for (int mt = 0; mt < 9; ++mt) {
      int row = mt * 16 + lo * 4;
      float* pp = part + ((size_t)blockIdx.y * R3_ + row) * Nc + gcol;
      pp[0] = acc[mt][0];
      pp[(size_t)Nc] = acc[mt][1];
      pp[2 * (size_t)Nc] = acc[mt][2];
      pp[3 * (size_t)Nc] = acc[mt][3];
    }
  }
}

// ---------------------------------------------------------------------------
// Epilogues
// ---------------------------------------------------------------------------
__global__ void k_epiR(const float* __restrict__ part, float* __restrict__ ws,
                       unsigned short* __restrict__ atl,
                       int ksplit, int g, int statIdx, size_t rsOff) {
  int n = blockIdx.x * 256 + threadIdx.x;
  int row = blockIdx.y;
  if (n >= KP2) return;
  int arow = g * BT_ + row;
  if (n >= N_) { atl[(size_t)arow * KP2 + n] = 0; return; }
  float s = 0.f;
  for (int ks = 0; ks < ksplit; ++ks) s += part[((size_t)(ks * BT_ + row)) * N_ + n];
  float mu = ws[OFF_STAT + statIdx], isd = ws[OFF_STAT + statIdx + 1];
  float val = (s - mu * ws[rsOff + row]) * isd;
  ws[OFF_ALIN + (size_t)n * R3_ + arow] = val;
  atl[(size_t)arow * KP2 + n] = f2bf(val);
}

__global__ void k_minmax(const float* __restrict__ alin, float* __restrict__ mmp) {
  int g = blockIdx.y;
  float mn = 3.4e38f, mx = -3.4e38f;
  for (int i = blockIdx.x * 256 + threadIdx.x; i < N_ * BT_; i += 64 * 256) {
    int n = i / BT_, r = i % BT_;
    float v = alin[(size_t)n * R3_ + g * BT_ + r];
    mn = fminf(mn, v); mx = fmaxf(mx, v);
  }
  __shared__ float rn[4], rx[4];
  for (int off = 32; off; off >>= 1) {
    mn = fminf(mn, __shfl_down(mn, off));
    mx = fmaxf(mx, __shfl_down(mx, off));
  }
  if ((threadIdx.x & 63) == 0) { rn[threadIdx.x >> 6] = mn; rx[threadIdx.x >> 6] = mx; }
  __syncthreads();
  if (threadIdx.x == 0) {
    mn = fminf(fminf(rn[0], rn[1]), fminf(rn[2], rn[3]));
    mx = fmaxf(fmaxf(rx[0], rx[1]), fmaxf(rx[2], rx[3]));
    mmp[(size_t)(g * 64 + blockIdx.x) * 2] = mn;
    mmp[(size_t)(g * 64 + blockIdx.x) * 2 + 1] = mx;
  }
}

__global__ void k_minmax2(float* __restrict__ ws) {
  int g = blockIdx.x;
  int i = threadIdx.x;
  float mn = ws[OFF_MMP + (size_t)(g * 64 + i) * 2];
  float mx = ws[OFF_MMP + (size_t)(g * 64 + i) * 2 + 1];
  for (int off = 32; off; off >>= 1) {
    mn = fminf(mn, __shfl_down(mn, off));
    mx = fmaxf(mx, __shfl_down(mx, off));
  }
  if (i == 0) {
    float denom = fmaxf(mx - mn, 1e-8f);
    float a = 1.f / denom;
    ws[OFF_AB + g * 2] = a;
    ws[OFF_AB + g * 2 + 1] = -mn * a;
  }
}

__global__ void k_colsum(const float* __restrict__ ltw, float* __restrict__ csp) {
  int e = blockIdx.x * 256 + threadIdx.x;
  int ks = blockIdx.y;
  if (e >= EA_) return;
  float s = 0.f;
  for (int n = ks * 125; n < (ks + 1) * 125; ++n) s += ltw[(size_t)n * EA_ + e];
  csp[(size_t)ks * EA_ + e] = s;
}
__global__ void k_colsum2(float* __restrict__ ws) {
  int e = blockIdx.x * 256 + threadIdx.x;
  if (e >= EA_) return;
  float s = 0.f;
  for (int ks = 0; ks < 16; ++ks) s += ws[OFF_CSP + (size_t)ks * EA_ + e];
  ws[OFF_CS + e] = s;
}

__global__ void k_epiLin(const float* __restrict__ part, const float* __restrict__ ltb,
                         float* __restrict__ ws, unsigned short* __restrict__ atq,
                         int ksplit) {
  int e = blockIdx.x * 256 + threadIdx.x;
  int row = blockIdx.y;
  if (e >= KP3) return;
  if (e >= EA_) { atq[(size_t)row * KP3 + e] = 0; return; }
  float s = 0.f;
  for (int ks = 0; ks < ksplit; ++ks) s += part[((size_t)(ks * R3_ + row)) * EA_ + e];
  int g = row / BT_;
  float a = ws[OFF_AB + g * 2], bb = ws[OFF_AB + g * 2 + 1];
  float val = fmaf(a, s, fmaf(bb, ws[OFF_CS + e], ltb[e]));
  atq[(size_t)row * KP3 + e] = f2bf(val);
}

__global__ void k_epiQkv(const float* __restrict__ part, const float* __restrict__ qkvb,
                         float* __restrict__ P, int ksplit) {
  int c = blockIdx.x * 256 + threadIdx.x;
  int row = blockIdx.y;
  if (c >= 3 * EA_) return;
  float s = 0.f;
  for (int ks = 0; ks < ksplit; ++ks) s += part[((size_t)(ks * R3_ + row)) * (3 * EA_) + c];
  P[(size_t)row * (3 * EA_) + c] = s + qkvb[c];
}

__global__ void k_attn(const float* __restrict__ P, unsigned short* __restrict__ atao) {
  int mha = blockIdx.y;
  int s_ = blockIdx.x / (B_ * H_);
  int rem = blockIdx.x % (B_ * H_);
  int b = rem / H_, h = rem % H_;
  const int pq[3] = {0, 1, 2}, pk[3] = {1, 2, 0}, pv[3] = {2, 0, 1};
  const float* qrow = P + ((size_t)(pq[mha] * BT_ + s_ * B_ + b)) * (3 * EA_) + h * HD_;
  __shared__ float sc[T_];
  __shared__ float red[4];
  for (int t = 0; t < T_; ++t) {
    const float* krow = P + ((size_t)(pk[mha] * BT_ + t * B_ + b)) * (3 * EA_) + EA_ + h * HD_;
    float p = 0.f;
    for (int d = threadIdx.x; d < HD_; d += 256) p = fmaf(qrow[d], krow[d], p);
    p = waveReduceSum(p);
    if ((threadIdx.x & 63) == 0) red[threadIdx.x >> 6] = p;
    __syncthreads();
    if (threadIdx.x == 0) sc[t] = (red[0] + red[1] + red[2] + red[3]) * 0.031622776601683794f;
    __syncthreads();
  }
  float a[T_];
  float m = sc[0];
#pragma unroll
  for (int t = 1; t < T_; ++t) m = fmaxf(m, sc[t]);
  float sum = 0.f;
#pragma unroll
  for (int t = 0; t < T_; ++t) { a[t] = expf(sc[t] - m); sum += a[t]; }
  float inv = 1.f / sum;
#pragma unroll
  for (int t = 0; t < T_; ++t) a[t] *= inv;
  int orow = mha * BT_ + s_ * B_ + b;
  for (int d = threadIdx.x; d < HD_; d += 256) {
    float o = 0.f;
#pragma unroll
    for (int t = 0; t < T_; ++t)
      o = fmaf(a[t], P[((size_t)(pv[mha] * BT_ + t * B_ + b)) * (3 * EA_) + 2 * EA_ + h * HD_ + d], o);
    atao[(size_t)orow * KP3 + h * HD_ + d] = f2bf(o);
  }
  if (h == 0 && threadIdx.x < 8) atao[(size_t)orow * KP3 + EA_ + threadIdx.x] = 0;
}

__global__ void k_epiAO(const float* __restrict__ part, const float* __restrict__ aob,
                        unsigned short* __restrict__ atll, int ksplit) {
  int c = blockIdx.x * 256 + threadIdx.x;
  int row = blockIdx.y;
  if (c >= KP3) return;
  if (c >= EA_) { atll[(size_t)row * KP3 + c] = 0; return; }
  float s = 0.f;
  for (int ks = 0; ks < ksplit; ++ks) s += part[((size_t)(ks * R3_ + row)) * EA_ + c];
  atll[(size_t)row * KP3 + c] = f2bf(s + aob[c]);
}

__global__ void k_epiLL(const float* __restrict__ part, const float* __restrict__ llb,
                        float* __restrict__ o2p, int ksplit) {
  int n = blockIdx.x * 256 + threadIdx.x;
  int row = blockIdx.y;  // t*B+b
  if (n >= N_) return;
  float s = 0.f;
  for (int g = 0; g < 3; ++g)
    for (int ks = 0; ks < ksplit; ++ks)
      s += part[((size_t)(ks * R3_ + g * BT_ + row)) * N_ + n];
  int t = row / B_, b = row % B_;
  o2p[(size_t)b * (T_ * N_) + t * N_ + n] = BETA_ * (s + 3.f * llb[n]);
}

__global__ void k_proj(const float* __restrict__ out4, const float* __restrict__ pw,
                       const float* __restrict__ pb, float* __restrict__ outp) {
  int i = blockIdx.x * 256 + threadIdx.x;
  if (i >= BTN_) return;
  int b = i / (T_ * N_);
  int t = (i / N_) % T_;
  int n = i % N_;
  float acc = pb[t];
  for (int t2 = 0; t2 < T_; ++t2) {
    const float* o = out4 + ((size_t)(b * T_ + t2) * N_ + n) * D_;
#pragma unroll
    for (int d = 0; d < D_; ++d) acc = fmaf(o[d], pw[(t2 * D_ + d) * T_ + t], acc);
  }
  outp[i] = acc;
}

__global__ void k_p2(const float* __restrict__ o2p, const float* __restrict__ p2w,
                     const float* __restrict__ p2b, float* __restrict__ o2f) {
  int i = blockIdx.x * 256 + threadIdx.x;
  if (i >= BTN_) return;
  int b = i / (T_ * N_);
  int t = (i / N_) % T_;
  int n = i % N_;
  float acc = p2b[t];
  const float* src = o2p + (size_t)b * (T_ * N_) + (size_t)n * T_;
#pragma unroll
  for (int c = 0; c < T_; ++c) acc = fmaf(src[c], p2w[c * T_ + t], acc);
  o2f[i] = acc;
}

// fused: out3 write + f-normalization -> bf16 padded rows g1b/g2b [8000][32]
__global__ void k_fng(const float* __restrict__ outp, const float* __restrict__ o2f,
                      float* __restrict__ dout, unsigned short* __restrict__ g1b,
                      unsigned short* __restrict__ g2b) {
  int r = blockIdx.x * 256 + threadIdx.x;
  if (r >= B_ * N_) return;
  int b = r / N_, n = r % N_;
  float v1[T_], v2[T_];
  float s1 = 0.f, s2 = 0.f;
#pragma unroll
  for (int t = 0; t < T_; ++t) {
    size_t idx = (size_t)b * T_ * N_ + (size_t)t * N_ + n;
    v1[t] = outp[idx];
    v2[t] = o2f[idx];
    dout[idx] = v1[t] + v2[t];
    s1 = fmaf(v1[t], v1[t], s1);
    s2 = fmaf(v2[t], v2[t], s2);
  }
  float n1 = fmaxf(sqrtf(s1), 1e-12f), n2 = fmaxf(sqrtf(s2), 1e-12f);
  float i1 = 10.f / n1, i2 = 1.f / n2;
  unsigned short q[32], z[32];
#pragma unroll
  for (int t = 0; t < T_; ++t) { q[t] = f2bf(v1[t] * i1); z[t] = f2bf(v2[t] * i2); }
#pragma unroll
  for (int t = T_; t < 32; ++t) { q[t] = 0; z[t] = 0; }
  short8* qd = (short8*)(g1b + (size_t)r * 32);
  short8* zd = (short8*)(g2b + (size_t)r * 32);
#pragma unroll
  for (int c = 0; c < 4; ++c) {
    short8 pv, pz;
#pragma unroll
    for (int e = 0; e < 8; ++e) { pv[e] = (short)q[c * 8 + e]; pz[e] = (short)z[c * 8 + e]; }
    qd[c] = pv;
    zd[c] = pz;
  }
}

// MFMA logsumexp: per block 16 q-rows; 16 j-slices (4 waves x grid.y=4)
__global__ __launch_bounds__(256) void k_lsemf(const unsigned short* __restrict__ g1b,
                                               const unsigned short* __restrict__ g2b,
                                               float* __restrict__ psm,
                                               float* __restrict__ psd) {
  int lane = threadIdx.x & 63, w = threadIdx.x >> 6;
  int lr = lane & 15, lo = lane >> 4;
  int i0 = blockIdx.x * 16;
  int slice = blockIdx.y * 4 + w;     // 0..15
  short8 a = *(const short8*)(g1b + (size_t)(i0 + lr) * 32 + lo * 8);
  float sm[4] = {0.f, 0.f, 0.f, 0.f};
  float sd[4] = {0.f, 0.f, 0.f, 0.f};
  for (int t = slice; t < 500; t += 16) {
    int j0 = t * 16;
    short8 b = *(const short8*)(g2b + (size_t)(j0 + lr) * 32 + lo * 8);
    f32x4 acc = {0.f, 0.f, 0.f, 0.f};
    acc = __builtin_amdgcn_mfma_f32_16x16x32_bf16(a, b, acc, 0, 0, 0);
#pragma unroll
    for (int rg = 0; rg < 4; ++rg) {
      float s = acc[rg];                      // row=i0+lo*4+rg, col=j0+lr
      sm[rg] += __expf(s);
      if (j0 + lr == i0 + lo * 4 + rg) sd[rg] = s;
    }
  }
#pragma unroll
  for (int off = 1; off < 16; off <<= 1) {
#pragma unroll
    for (int rg = 0; rg < 4; ++rg) {
      sm[rg] += __shfl_xor(sm[rg], off);
      sd[rg] += __shfl_xor(sd[rg], off);
    }
  }
  __shared__ float lsm[4][16], lsd[4][16];
  if (lr == 0) {
#pragma unroll
    for (int rg = 0; rg < 4; ++rg) {
      lsm[w][lo * 4 + rg] = sm[rg];
      lsd[w][lo * 4 + rg] = sd[rg];
    }
  }
  __syncthreads();
  if (threadIdx.x < 16) {
    float m = lsm[0][threadIdx.x] + lsm[1][threadIdx.x] + lsm[2][threadIdx.x] + lsm[3][threadIdx.x];
    float d = lsd[0][threadIdx.x] + lsd[1][threadIdx.x] + lsd[2][threadIdx.x] + lsd[3][threadIdx.x];
    psm[(size_t)blockIdx.y * 8000 + i0 + threadIdx.x] = m;
    psd[(size_t)blockIdx.y * 8000 + i0 + threadIdx.x] = d;
  }
}

// fused: combine j-splits + mean + final scalars
__global__ __launch_bounds__(1024) void k_lsefin(const float* __restrict__ psm,
                                                 const float* __restrict__ psd,
                                                 const float* __restrict__ ws,
                                                 float* __restrict__ dout) {
  float acc = 0.f;
  for (int r = threadIdx.x; r < B_ * N_; r += 1024) {
    float sm = psm[r] + psm[8000 + r] + psm[16000 + r] + psm[24000 + r];
    float sd = psd[r] + psd[8000 + r] + psd[16000 + r] + psd[24000 + r];
    acc += sd - logf(sm);
  }
  __shared__ float red[16];
  acc = waveReduceSum(acc);
  if ((threadIdx.x & 63) == 0) red[threadIdx.x >> 6] = acc;
  __syncthreads();
  if (threadIdx.x == 0) {
    float s = 0.f;
    for (int i = 0; i < 16; ++i) s += red[i];
    float closs = -s * (1.f / (B_ * N_));
    dout[BTN_] = ws[OFF_BAL];
    dout[BTN_ + 1] = CW_ * closs;
  }
}

// ---------------------------------------------------------------------------
extern "C" void kernel_launch(void* const* d_in, const int* in_sizes, int n_in,
                              void* d_out, int out_size, void* d_ws, size_t ws_size,
                              hipStream_t stream) {
  const float* x    = (const float*)d_in[0];
  const float* velo = (const float*)d_in[1];
  const float* adj  = (const float*)d_in[2];
  const float* lapd = (const float*)d_in[3];
  const float* laph = (const float*)d_in[4];
  const float* sw   = (const float*)d_in[5];
  const float* sb   = (const float*)d_in[6];
  const float* gw   = (const float*)d_in[7];
  const float* ew1  = (const float*)d_in[8];
  const float* eb1  = (const float*)d_in[9];
  const float* ew2  = (const float*)d_in[10];
  const float* eb2  = (const float*)d_in[11];
  const float* pw   = (const float*)d_in[12];
  const float* pb   = (const float*)d_in[13];
  const float* ltw  = (const float*)d_in[14];
  const float* ltb  = (const float*)d_in[15];
  const float* qkvw = (const float*)d_in[16];
  const float* qkvb = (const float*)d_in[17];
  const float* aow  = (const float*)d_in[18];
  const float* aob  = (const float*)d_in[19];
  const float* llw  = (const float*)d_in[20];
  const float* llb  = (const float*)d_in[21];
  const float* p2w  = (const float*)d_in[22];
  const float* p2b  = (const float*)d_in[23];
  float* ws = (float*)d_ws;
  float* dout = (float*)d_out;
  const float* v0 = velo;  // velo[0,0,:]
  float* part = ws + OFF_PART;
  unsigned short* btQ  = (unsigned short*)(ws + OFF_BT_Q);
  unsigned short* btA  = (unsigned short*)(ws + OFF_BT_A);
  unsigned short* btL  = (unsigned short*)(ws + OFF_BT_L);
  unsigned short* btW  = (unsigned short*)(ws + OFF_BT_W);
  unsigned short* atLin = (unsigned short*)(ws + OFF_AT_LIN);
  unsigned short* atQ   = (unsigned short*)(ws + OFF_AT_Q);
  unsigned short* atAO  = (unsigned short*)(ws + OFF_AT_AO);
  unsigned short* atLL  = (unsigned short*)(ws + OFF_AT_LL);
  unsigned short* g1b   = (unsigned short*)(ws + OFF_G1B);
  unsigned short* g2b   = (unsigned short*)(ws + OFF_G2B);
  dim3 b256(256);

  k_init<<<dim3(1), dim3(64), 0, stream>>>(ws);

  // fused weight transposes to bf16
  k_wtrans4<<<dim3(282, 94, 4), b256, 0, stream>>>(qkvw, aow, llw, ltw, btQ, btA, btL, btW);

  k_start<<<dim3((BTN_ * D_ + 255) / 256), b256, 0, stream>>>(x, sw, sb, ws + OFF_OUT4);

  for (int l = 0; l < L_; ++l) {
    k_feat<<<dim3(B_ * D_), b256, 0, stream>>>(ws + OFF_OUT4, ws + OFF_FEAT);
    k_gate<<<dim3(1), dim3(64), 0, stream>>>(ws + OFF_FEAT, gw, ws, l);
    k_expert<<<dim3((T_ * N_ + 255) / 256, B_), b256, 0, stream>>>(ws + OFF_OUT4, ew1, eb1, ew2, eb2, ws, l);
  }

  k_wavelet<<<dim3((BTN_ + 255) / 256), b256, 0, stream>>>(x, velo, ws + OFF_LOWT, ws + OFF_HVT);
  k_rowsum<<<dim3(2 * BT_), b256, 0, stream>>>(ws + OFF_LOWT, ws + OFF_HVT, ws);
  k_S<<<dim3(N_), b256, 0, stream>>>(adj, v0, ws + OFF_S);
  k_stats<<<dim3(512), b256, 0, stream>>>(lapd, ws + OFF_STP);
  k_stats2<<<dim3(1), b256, 0, stream>>>(ws + OFF_STP, ws + OFF_STAT);
  k_stats<<<dim3(512), b256, 0, stream>>>(laph, ws + OFF_STP + 1024);
  k_stats2<<<dim3(1), b256, 0, stream>>>(ws + OFF_STP + 1024, ws + OFF_STAT + 2);
  k_nsstats<<<dim3(512), b256, 0, stream>>>(adj, v0, ws + OFF_S, ws + OFF_STP + 2048);
  k_stats2<<<dim3(1), b256, 0, stream>>>(ws + OFF_STP + 2048, ws + OFF_STAT + 4);

  // r1 / r2 / r3 (fp32, split-K 50)
  k_gemm48<<<dim3(8, RKS_), b256, 0, stream>>>(ws + OFF_LOWT, BT_, BT_, lapd, part, N_, N_, RKC_);
  k_epiR<<<dim3(8, 48), b256, 0, stream>>>(part, ws, atLin, RKS_, 0, 0, OFF_RSL);
  k_gemmNS<<<dim3(8, RKS_), b256, 0, stream>>>(ws + OFF_HVT, adj, v0, ws + OFF_S, part, RKC_);
  k_epiR<<<dim3(8, 48), b256, 0, stream>>>(part, ws, atLin, RKS_, 1, 4, OFF_RSH);
  k_gemm48<<<dim3(8, RKS_), b256, 0, stream>>>(ws + OFF_LOWT, BT_, BT_, laph, part, N_, N_, RKC_);
  k_epiR<<<dim3(8, 48), b256, 0, stream>>>(part, ws, atLin, RKS_, 2, 2, OFF_RSL);

  k_minmax<<<dim3(64, 3), b256, 0, stream>>>(ws + OFF_ALIN, ws + OFF_MMP);
  k_minmax2<<<dim3(3), dim3(64), 0, stream>>>(ws);
  k_colsum<<<dim3(12, 16), b256, 0, stream>>>(ltw, ws + OFF_CSP);
  k_colsum2<<<dim3(12), b256, 0, stream>>>(ws);

  // lin (MFMA)
  k_mfma<<<dim3(47, 9), b256, 0, stream>>>(atLin, btW, part, EA_, KP2, KP2 / 32, 7);
  k_epiLin<<<dim3(12, 144), b256, 0, stream>>>(part, ltb, ws, atQ, 9);

  // qkv (MFMA)
  k_mfma<<<dim3(141, 4), b256, 0, stream>>>(atQ, btQ, part, 3 * EA_, KP3, KP3 / 32, 24);
  k_epiQkv<<<dim3(36, 144), b256, 0, stream>>>(part, qkvb, ws + OFF_P, 4);

  // attention
  k_attn<<<dim3(T_ * B_ * H_, 3), b256, 0, stream>>>(ws + OFF_P, atAO);

  // attn-out (MFMA)
  k_mfma<<<dim3(47, 12), b256, 0, stream>>>(atAO, btA, part, EA_, KP3, KP3 / 32, 8);
  k_epiAO<<<dim3(12, 144), b256, 0, stream>>>(part, aob, atLL, 12);

  // ll (MFMA)
  k_mfma<<<dim3(32, 12), b256, 0, stream>>>(atLL, btL, part, N_, KP3, KP3 / 32, 8);
  k_epiLL<<<dim3(8, 48), b256, 0, stream>>>(part, llb, ws + OFF_O2P, 12);

  k_proj<<<dim3((BTN_ + 255) / 256), b256, 0, stream>>>(ws + OFF_OUT4, pw, pb, ws + OFF_OUTP);
  k_p2<<<dim3((BTN_ + 255) / 256), b256, 0, stream>>>(ws + OFF_O2P, p2w, p2b, ws + OFF_O2F);

  // fused out3 + fnorm (writes dout body + bf16 g1b/g2b)
  k_fng<<<dim3((B_ * N_ + 255) / 256), b256, 0, stream>>>(ws + OFF_OUTP, ws + OFF_O2F, dout, g1b, g2b);

  // MFMA logsumexp; psm/psd partials live in `part`
  k_lsemf<<<dim3(500, 4), b256, 0, stream>>>(g1b, g2b, part, part + 32000);
  k_lsefin<<<dim3(1), dim3(1024), 0, stream>>>(part, part + 32000, ws, dout);
}

// Round 10
// 797.894 us; speedup vs baseline: 1.3147x; 1.0155x over previous
//
#include <hip/hip_runtime.h>
#include <math.h>

// ---------------------------------------------------------------------------
// Model constants
// ---------------------------------------------------------------------------
namespace {
constexpr int B_ = 4, T_ = 12, N_ = 2000, D_ = 16, FF_ = 64, E_ = 4, L_ = 2;
constexpr int EA_ = 3000, H_ = 3, HD_ = EA_ / H_;   // 1000
constexpr int BT_ = B_ * T_;                         // 48
constexpr int R3_ = 3 * BT_;                         // 144
constexpr long long NN_ = (long long)N_ * N_;        // 4,000,000
constexpr int BTN_ = B_ * T_ * N_;                   // 96,000
constexpr float BETA_ = 0.01f, CW_ = 0.001f;
constexpr int RKS_ = 50;                             // r-GEMM split-K
constexpr int RKC_ = 40;                             // r-GEMM k-chunk
constexpr int KP3 = 3008;                            // K=3000 padded to 32
constexpr int KP2 = 2016;                            // K=2000 padded to 32

// transpose grid (64K x 32N tiles), linearized exact block counts
constexpr int WT_Q = 282 * 47;            // qkvw: Nc=9000, Kp=3008
constexpr int WT_A = 94 * 47;             // aow : Nc=3000, Kp=3008
constexpr int WT_L = 63 * 47;             // llw : Nc=2000, Kp=3008
constexpr int WT_W = 94 * 32;             // ltw : Nc=3000, Kp=2016
constexpr int WT_C0 = WT_Q;               // 13254
constexpr int WT_C1 = WT_C0 + WT_A;       // 17672
constexpr int WT_C2 = WT_C1 + WT_L;       // 20633
constexpr int WT_TOT = WT_C2 + WT_W;      // 23641

// ---------------------------------------------------------------------------
// Workspace layout (float offsets)
// ---------------------------------------------------------------------------
constexpr size_t OFF_OUT4 = 0;                                   // [B,T,N,D]
constexpr size_t OFF_LOWT = OFF_OUT4 + (size_t)BTN_ * D_;        // lowT^T [N][48]
constexpr size_t OFF_HVT  = OFF_LOWT + BTN_;                     // highV^T [N][48]
constexpr size_t OFF_ALIN = OFF_HVT + BTN_;                      // r^T [N][144]
constexpr size_t OFF_RT   = OFF_ALIN + (size_t)N_ * R3_;         // (unused, kept)
constexpr size_t OFF_P    = OFF_RT + (size_t)EA_ * R3_;          // P [144][9000]
constexpr size_t OFF_AOT  = OFF_P + (size_t)R3_ * 3 * EA_;       // (unused, kept)
constexpr size_t OFF_OT   = OFF_AOT + (size_t)EA_ * R3_;         // (unused, kept)
constexpr size_t OFF_O2P  = OFF_OT + (size_t)EA_ * R3_;          // out2 pre-p2 [B][T*N]
constexpr size_t OFF_OUTP = OFF_O2P + BTN_;                      // outp [B,T,N]
constexpr size_t OFF_O2F  = OFF_OUTP + BTN_;                     // out2 final [B,T,N]
constexpr size_t OFF_LI   = OFF_O2F + BTN_;                      // (spare)
constexpr size_t OFF_S    = OFF_LI + 8000;                       // G row sums [2000]
constexpr size_t OFF_RSL  = OFF_S + 2000;
constexpr size_t OFF_RSH  = OFF_RSL + 48;
constexpr size_t OFF_STP  = OFF_RSH + 48;
constexpr size_t OFF_STAT = OFF_STP + 3072;
constexpr size_t OFF_MMP  = OFF_STAT + 8;
constexpr size_t OFF_AB   = OFF_MMP + 384;
constexpr size_t OFF_CSP  = OFF_AB + 8;
constexpr size_t OFF_CS   = OFF_CSP + 48000;
constexpr size_t OFF_FEAT = OFF_CS + 3000;
constexpr size_t OFF_GATE = OFF_FEAT + 64;
constexpr size_t OFF_BAL  = OFF_GATE + 16;
constexpr size_t OFF_PART = ((OFF_BAL + 1 + 255) & ~(size_t)255); // split-K partials
constexpr size_t PARTCAP  = 6000000;                              // cap (floats)
// bf16 regions (sizes in floats = ushorts/2)
constexpr size_t OFF_BT_Q  = OFF_PART + PARTCAP;                  // qkvw^T  [9000][KP3]
constexpr size_t OFF_BT_A  = OFF_BT_Q + (size_t)9000 * KP3 / 2;   // aow^T   [3000][KP3]
constexpr size_t OFF_BT_L  = OFF_BT_A + (size_t)3000 * KP3 / 2;   // llw^T   [2000][KP3]
constexpr size_t OFF_BT_W  = OFF_BT_L + (size_t)2000 * KP3 / 2;   // ltw^T   [3000][KP2]
constexpr size_t OFF_AT_LIN= OFF_BT_W + (size_t)3000 * KP2 / 2;   // ALIN^T  [144][KP2]
constexpr size_t OFF_AT_Q  = OFF_AT_LIN + (size_t)R3_ * KP2 / 2;  // RT^T    [144][KP3]
constexpr size_t OFF_AT_AO = OFF_AT_Q + (size_t)R3_ * KP3 / 2;    // Ao      [144][KP3]
constexpr size_t OFF_AT_LL = OFF_AT_AO + (size_t)R3_ * KP3 / 2;   // O       [144][KP3]
constexpr size_t OFF_G1B   = OFF_AT_LL + (size_t)R3_ * KP3 / 2;   // f1 bf16 [8000][32]
constexpr size_t OFF_G2B   = OFF_G1B + 128000;                    // f2 bf16 [8000][32]
} // namespace

typedef __attribute__((ext_vector_type(8))) short short8;
typedef __attribute__((ext_vector_type(4))) float f32x4;

// ---------------------------------------------------------------------------
// Helpers
// ---------------------------------------------------------------------------
__device__ __forceinline__ float waveReduceSum(float v) {
  for (int off = 32; off; off >>= 1) v += __shfl_down(v, off);
  return v;
}

__device__ __forceinline__ unsigned short f2bf(float x) {  // RNE fp32->bf16
  unsigned int u = __float_as_uint(x);
  unsigned int r = (u + 0x7FFFu + ((u >> 16) & 1u)) >> 16;
  return (unsigned short)r;
}

__device__ __forceinline__ void fma48(float* __restrict__ acc,
                                      const float4* __restrict__ a4, float bv) {
#pragma unroll
  for (int r4 = 0; r4 < BT_ / 4; ++r4) {
    float4 av = a4[r4];
    acc[r4 * 4 + 0] = fmaf(av.x, bv, acc[r4 * 4 + 0]);
    acc[r4 * 4 + 1] = fmaf(av.y, bv, acc[r4 * 4 + 1]);
    acc[r4 * 4 + 2] = fmaf(av.z, bv, acc[r4 * 4 + 2]);
    acc[r4 * 4 + 3] = fmaf(av.w, bv, acc[r4 * 4 + 3]);
  }
}

// ---------------------------------------------------------------------------
__global__ void k_init(float* ws) {
  if (threadIdx.x == 0) ws[OFF_BAL] = 0.f;
}

__global__ void k_start(const float* __restrict__ x, const float* __restrict__ sw,
                        const float* __restrict__ sb, float* __restrict__ out4) {
  int i = blockIdx.x * 256 + threadIdx.x;
  if (i >= BTN_ * D_) return;
  int d = i & 15;
  out4[i] = fmaf(x[i >> 4], sw[d], sb[d]);
}

__global__ void k_feat(const float* __restrict__ out4, float* __restrict__ feat) {
  int b = blockIdx.x >> 4, d = blockIdx.x & 15;
  float s = 0.f;
  for (int tn = threadIdx.x; tn < T_ * N_; tn += 256)
    s += out4[((size_t)b * T_ * N_ + tn) * D_ + d];
  __shared__ float red[4];
  s = waveReduceSum(s);
  if ((threadIdx.x & 63) == 0) red[threadIdx.x >> 6] = s;
  __syncthreads();
  if (threadIdx.x == 0)
    feat[blockIdx.x] = (red[0] + red[1] + red[2] + red[3]) * (1.f / (T_ * N_));
}

__global__ void k_gate(const float* __restrict__ feat, const float* __restrict__ gw,
                       float* __restrict__ ws, int l) {
  __shared__ float lg[B_ * E_];
  int tid = threadIdx.x;
  if (tid < B_ * E_) {
    int b = tid >> 2, e = tid & 3;
    float s = 0.f;
    for (int d = 0; d < D_; ++d) s = fmaf(feat[b * D_ + d], gw[(l * D_ + d) * E_ + e], s);
    lg[tid] = s;
  }
  __syncthreads();
  if (tid == 0) {
    float* gates = ws + OFF_GATE;
    float imp[E_] = {0, 0, 0, 0}, load[E_] = {0, 0, 0, 0};
    for (int i = 0; i < B_ * E_; ++i) gates[i] = 0.f;
    for (int b = 0; b < B_; ++b) {
      const float* lb = lg + b * E_;
      int i1 = 0; float v1 = lb[0];
      for (int e = 1; e < E_; ++e) if (lb[e] > v1) { v1 = lb[e]; i1 = e; }
      int i2 = -1; float v2 = -1e30f;
      for (int e = 0; e < E_; ++e) { if (e == i1) continue; if (lb[e] > v2) { v2 = lb[e]; i2 = e; } }
      float e2 = expf(v2 - v1);
      float den = 1.f + e2;
      float g1 = 1.f / den, g2 = e2 / den;
      gates[b * E_ + i1] = g1; gates[b * E_ + i2] = g2;
      imp[i1] += g1; imp[i2] += g2; load[i1] += 1.f; load[i2] += 1.f;
    }
    float bal = 0.f;
    float m = 0.f; for (int e = 0; e < E_; ++e) m += imp[e]; m *= 0.25f;
    float v = 0.f; for (int e = 0; e < E_; ++e) { float d = imp[e] - m; v += d * d; } v *= 0.25f;
    bal += v / (m * m + 1e-10f);
    m = 0.f; for (int e = 0; e < E_; ++e) m += load[e]; m *= 0.25f;
    v = 0.f; for (int e = 0; e < E_; ++e) { float d = load[e] - m; v += d * d; } v *= 0.25f;
    bal += v / (m * m + 1e-10f);
    ws[OFF_BAL] += bal;
  }
}

__global__ void k_expert(float* __restrict__ out4, const float* __restrict__ w1,
                         const float* __restrict__ b1, const float* __restrict__ w2,
                         const float* __restrict__ b2, const float* __restrict__ ws, int l) {
  int b = blockIdx.y;
  int tn = blockIdx.x * 256 + threadIdx.x;
  if (tn >= T_ * N_) return;
  float* row = out4 + ((size_t)b * T_ * N_ + tn) * D_;
  float r[D_], acc[D_];
#pragma unroll
  for (int d = 0; d < D_; ++d) { r[d] = row[d]; acc[d] = r[d]; }
  const float* gates = ws + OFF_GATE;
  for (int e = 0; e < E_; ++e) {
    float g = gates[b * E_ + e];
    if (g <= 0.f) continue;
    const float* W1 = w1 + (size_t)(l * E_ + e) * D_ * FF_;
    const float* B1 = b1 + (size_t)(l * E_ + e) * FF_;
    const float* W2 = w2 + (size_t)(l * E_ + e) * FF_ * D_;
    const float* B2 = b2 + (size_t)(l * E_ + e) * D_;
#pragma unroll 4
    for (int f = 0; f < FF_; ++f) {
      float p = B1[f];
#pragma unroll
      for (int d = 0; d < D_; ++d) p = fmaf(r[d], W1[d * FF_ + f], p);
      float c = 0.7978845608028654f * (p + 0.044715f * p * p * p);
      float hv = 0.5f * p * (1.f + tanhf(c));
      float gh = g * hv;
#pragma unroll
      for (int d = 0; d < D_; ++d) acc[d] = fmaf(gh, W2[f * D_ + d], acc[d]);
    }
#pragma unroll
    for (int d = 0; d < D_; ++d) acc[d] = fmaf(g, B2[d], acc[d]);
  }
#pragma unroll
  for (int d = 0; d < D_; ++d) row[d] = acc[d];
}

__global__ void k_wavelet(const float* __restrict__ x, const float* __restrict__ velo,
                          float* __restrict__ lowT, float* __restrict__ hvT) {
  int i = blockIdx.x * 256 + threadIdx.x;
  if (i >= BTN_) return;
  int b = i / (T_ * N_);
  int t = (i / N_) % T_;
  int n = i % N_;
  int ip = b * T_ * N_ + ((t + T_ - 1) % T_) * N_ + n;
  int row = t * B_ + b;
  lowT[(size_t)n * BT_ + row] = 0.5f * (x[i] + x[ip]);
  hvT[(size_t)n * BT_ + row] = 0.5f * (velo[i] - velo[ip]);
}

__global__ void k_rowsum(const float* __restrict__ lowT, const float* __restrict__ hvT,
                         float* __restrict__ ws) {
  int which = blockIdx.x / BT_;
  int row = blockIdx.x % BT_;
  const float* M = which ? hvT : lowT;
  float s = 0.f;
  for (int n = threadIdx.x; n < N_; n += 256) s += M[(size_t)n * BT_ + row];
  __shared__ float red[4];
  s = waveReduceSum(s);
  if ((threadIdx.x & 63) == 0) red[threadIdx.x >> 6] = s;
  __syncthreads();
  if (threadIdx.x == 0) ws[(which ? OFF_RSH : OFF_RSL) + row] = red[0] + red[1] + red[2] + red[3];
}

__global__ void k_S(const float* __restrict__ adj, const float* __restrict__ v0,
                    float* __restrict__ S) {
  int m = blockIdx.x;
  float vm = v0[m];
  const float* a = adj + (size_t)m * N_;
  float s = 0.f;
  for (int n = threadIdx.x; n < N_; n += 256) s += vm / a[n];
  __shared__ float red[4];
  s = waveReduceSum(s);
  if ((threadIdx.x & 63) == 0) red[threadIdx.x >> 6] = s;
  __syncthreads();
  if (threadIdx.x == 0) S[m] = red[0] + red[1] + red[2] + red[3];
}

__global__ void k_stats(const float* __restrict__ M, float* __restrict__ part) {
  float s = 0.f, ss = 0.f;
  for (long long i = blockIdx.x * 256 + threadIdx.x; i < NN_; i += 512 * 256) {
    float v = M[i];
    s += v; ss = fmaf(v, v, ss);
  }
  __shared__ float r1[4], r2[4];
  for (int off = 32; off; off >>= 1) { s += __shfl_down(s, off); ss += __shfl_down(ss, off); }
  if ((threadIdx.x & 63) == 0) { r1[threadIdx.x >> 6] = s; r2[threadIdx.x >> 6] = ss; }
  __syncthreads();
  if (threadIdx.x == 0) {
    part[blockIdx.x * 2] = r1[0] + r1[1] + r1[2] + r1[3];
    part[blockIdx.x * 2 + 1] = r2[0] + r2[1] + r2[2] + r2[3];
  }
}

__global__ void k_nsstats(const float* __restrict__ adj, const float* __restrict__ v0,
                          const float* __restrict__ S, float* __restrict__ part) {
  float s = 0.f, ss = 0.f;
  for (long long i = blockIdx.x * 256 + threadIdx.x; i < NN_; i += 512 * 256) {
    int m = (int)(i / N_), n = (int)(i % N_);
    float e = -(v0[m] / adj[i]);
    if (m == n) e += S[m];
    s += e; ss = fmaf(e, e, ss);
  }
  __shared__ float r1[4], r2[4];
  for (int off = 32; off; off >>= 1) { s += __shfl_down(s, off); ss += __shfl_down(ss, off); }
  if ((threadIdx.x & 63) == 0) { r1[threadIdx.x >> 6] = s; r2[threadIdx.x >> 6] = ss; }
  __syncthreads();
  if (threadIdx.x == 0) {
    part[blockIdx.x * 2] = r1[0] + r1[1] + r1[2] + r1[3];
    part[blockIdx.x * 2 + 1] = r2[0] + r2[1] + r2[2] + r2[3];
  }
}

__global__ void k_stats2(const float* __restrict__ part, float* __restrict__ stat) {
  float s = 0.f, ss = 0.f;
  for (int i = threadIdx.x; i < 512; i += 256) { s += part[i * 2]; ss += part[i * 2 + 1]; }
  __shared__ float r1[4], r2[4];
  for (int off = 32; off; off >>= 1) { s += __shfl_down(s, off); ss += __shfl_down(ss, off); }
  if ((threadIdx.x & 63) == 0) { r1[threadIdx.x >> 6] = s; r2[threadIdx.x >> 6] = ss; }
  __syncthreads();
  if (threadIdx.x == 0) {
    float su = r1[0] + r1[1] + r1[2] + r1[3];
    float sq = r2[0] + r2[1] + r2[2] + r2[3];
    float mu = su * (1.f / (float)NN_);
    float var = sq * (1.f / (float)NN_) - mu * mu;
    stat[0] = mu;
    stat[1] = 1.f / sqrtf(var);
  }
}

// ---------------------------------------------------------------------------
// fp32 streaming GEMM (r1/r3, NS), 8-deep B prefetch
// ---------------------------------------------------------------------------
__global__ __launch_bounds__(256) void k_gemm48(
    const float* __restrict__ AT, int lda, int rowTot,
    const float* __restrict__ Bm, float* __restrict__ part,
    int Kdim, int NC, int kchunk) {
  int col = blockIdx.x * 256 + threadIdx.x;
  int m0 = blockIdx.y * kchunk;
  int m1 = min(Kdim, m0 + kchunk);
  float acc[BT_];
#pragma unroll
  for (int r = 0; r < BT_; ++r) acc[r] = 0.f;
  if (col < NC) {
    const float* ap = AT + (size_t)m0 * lda;
    const float* bp = Bm + (size_t)m0 * NC + col;
    int len = m1 - m0;
    int ng = len >> 3;
    float bc[8];
    if (ng > 0) {
#pragma unroll
      for (int u = 0; u < 8; ++u) bc[u] = bp[(size_t)u * NC];
    }
    for (int gi = 0; gi < ng; ++gi) {
      float bn[8];
      bool more = (gi + 1 < ng);
      if (more) {
#pragma unroll
        for (int u = 0; u < 8; ++u) bn[u] = bp[(size_t)(8 + u) * NC];
      }
#pragma unroll
      for (int u = 0; u < 8; ++u)
        fma48(acc, (const float4*)(ap + (size_t)u * lda), bc[u]);
      ap += (size_t)8 * lda;
      bp += (size_t)8 * NC;
      if (more) {
#pragma unroll
        for (int u = 0; u < 8; ++u) bc[u] = bn[u];
      }
    }
    for (int m = m0 + (ng << 3); m < m1; ++m) {
      fma48(acc, (const float4*)ap, *bp);
      ap += lda;
      bp += NC;
    }
    float* pp = part + (size_t)blockIdx.y * rowTot * NC + col;
#pragma unroll
    for (int r = 0; r < BT_; ++r) pp[(size_t)r * NC] = acc[r];
  }
}

__global__ __launch_bounds__(256) void k_gemmNS(
    const float* __restrict__ hvT, const float* __restrict__ adj,
    const float* __restrict__ v0, const float* __restrict__ S,
    float* __restrict__ part, int kchunk) {
  int col = blockIdx.x * 256 + threadIdx.x;
  int m0 = blockIdx.y * kchunk;
  int m1 = min(N_, m0 + kchunk);
  float acc[BT_];
#pragma unroll
  for (int r = 0; r < BT_; ++r) acc[r] = 0.f;
  if (col < N_) {
    const float* ap = hvT + (size_t)m0 * BT_;
    const float* jp = adj + (size_t)m0 * N_ + col;
    int len = m1 - m0;
    int ng = len >> 3;
    float jc[8];
    if (ng > 0) {
#pragma unroll
      for (int u = 0; u < 8; ++u) jc[u] = jp[(size_t)u * N_];
    }
    int m = m0;
    for (int gi = 0; gi < ng; ++gi) {
      float jn[8];
      bool more = (gi + 1 < ng);
      if (more) {
#pragma unroll
        for (int u = 0; u < 8; ++u) jn[u] = jp[(size_t)(8 + u) * N_];
      }
#pragma unroll
      for (int u = 0; u < 8; ++u) {
        float bv = -(v0[m + u] / jc[u]);
        if (m + u == col) bv += S[m + u];
        fma48(acc, (const float4*)(ap + (size_t)u * BT_), bv);
      }
      m += 8;
      ap += (size_t)8 * BT_;
      jp += (size_t)8 * N_;
      if (more) {
#pragma unroll
        for (int u = 0; u < 8; ++u) jc[u] = jn[u];
      }
    }
    for (; m < m1; ++m) {
      float bv = -(v0[m] / (*jp));
      if (m == col) bv += S[m];
      fma48(acc, (const float4*)ap, bv);
      ap += BT_;
      jp += N_;
    }
    float* pp = part + (size_t)blockIdx.y * BT_ * N_ + col;
#pragma unroll
    for (int r = 0; r < BT_; ++r) pp[(size_t)r * N_] = acc[r];
  }
}

// ---------------------------------------------------------------------------
// Fused weight transpose: fp32 [K][Nc] -> bf16 [Nc][Kp]; 64K x 32N tiles,
// fp32 LDS staging (odd-dword stride), packed 4B bf16x2 writes.
// ---------------------------------------------------------------------------
__global__ __launch_bounds__(256) void k_wtrans4(
    const float* __restrict__ W0, const float* __restrict__ W1,
    const float* __restrict__ W2, const float* __restrict__ W3,
    unsigned short* __restrict__ T0, unsigned short* __restrict__ T1,
    unsigned short* __restrict__ T2, unsigned short* __restrict__ T3) {
  int bid = blockIdx.x;
  const float* W; unsigned short* Wt; int K, Nc, Kp, rel, KT;
  if (bid < WT_C0)      { W = W0; Wt = T0; K = EA_; Nc = 3 * EA_; Kp = KP3; rel = bid;          KT = 47; }
  else if (bid < WT_C1) { W = W1; Wt = T1; K = EA_; Nc = EA_;     Kp = KP3; rel = bid - WT_C0;  KT = 47; }
  else if (bid < WT_C2) { W = W2; Wt = T2; K = EA_; Nc = N_;      Kp = KP3; rel = bid - WT_C1;  KT = 47; }
  else                  { W = W3; Wt = T3; K = N_;  Nc = EA_;     Kp = KP2; rel = bid - WT_C2;  KT = 32; }
  int nTile = rel / KT, kTile = rel % KT;
  int k0 = kTile * 64, n0 = nTile * 32;
  __shared__ float t[64][33];
  int tx = threadIdx.x & 31, ty = threadIdx.x >> 5;  // 32 x 8
#pragma unroll
  for (int i = 0; i < 8; ++i) {
    int kl = ty + i * 8;
    int k = k0 + kl, n = n0 + tx;
    t[kl][tx] = (k < K && n < Nc) ? W[(size_t)k * Nc + n] : 0.f;
  }
  __syncthreads();
  // write: lane tx handles k-pair 2*tx; ty covers 8 n per pass
  int k = k0 + 2 * tx;
#pragma unroll
  for (int i = 0; i < 4; ++i) {
    int nl = ty + i * 8;
    int n = n0 + nl;
    if (n < Nc && k < Kp) {
      unsigned int lo = f2bf(t[2 * tx][nl]);
      unsigned int hi = f2bf(t[2 * tx + 1][nl]);
      *(unsigned int*)(Wt + (size_t)n * Kp + k) = (hi << 16) | lo;
    }
  }
}

// ---------------------------------------------------------------------------
// MFMA GEMM: part[ks][144][Nc] = At(bf16 [144][Kp]) @ Bt(bf16 [Nc][Kp])^T
// ---------------------------------------------------------------------------
__global__ __launch_bounds__(256, 4) void k_mfma(
    const unsigned short* __restrict__ At, const unsigned short* __restrict__ Bt,
    float* __restrict__ part, int Nc, int Kp, int stepsTot, int stepChunk) {
  int lane = threadIdx.x & 63;
  int w = threadIdx.x >> 6;
  int lr = lane & 15, lo = lane >> 4;
  int gcol = blockIdx.x * 64 + w * 16 + lr;
  int bcol = min(gcol, Nc - 1);
  int s0 = blockIdx.y * stepChunk;
  int s1 = min(stepsTot, s0 + stepChunk);
  f32x4 acc[9];
#pragma unroll
  for (int mt = 0; mt < 9; ++mt) {
    acc[mt][0] = 0.f; acc[mt][1] = 0.f; acc[mt][2] = 0.f; acc[mt][3] = 0.f;
  }
  const unsigned short* bp = Bt + (size_t)bcol * Kp + (size_t)s0 * 32 + lo * 8;
  const unsigned short* ap = At + (size_t)lr * Kp + (size_t)s0 * 32 + lo * 8;
  for (int s = s0; s < s1; ++s) {
    short8 b = *(const short8*)bp;
#pragma unroll
    for (int mt = 0; mt < 9; ++mt) {
      short8 a = *(const short8*)(ap + (size_t)mt * 16 * Kp);
      acc[mt] = __builtin_amdgcn_mfma_f32_16x16x32_bf16(a, b, acc[mt], 0, 0, 0);
    }
    bp += 32;
    ap += 32;
  }
  if (gcol < Nc) {
#pragma unroll
    for (int mt = 0; mt < 9; ++mt) {
      int row = mt * 16 + lo * 4;
      float* pp = part + ((size_t)blockIdx.y * R3_ + row) * Nc + gcol;
      pp[0] = acc[mt][0];
      pp[(size_t)Nc] = acc[mt][1];
      pp[2 * (size_t)Nc] = acc[mt][2];
      pp[3 * (size_t)Nc] = acc[mt][3];
    }
  }
}

// ---------------------------------------------------------------------------
// Epilogues
// ---------------------------------------------------------------------------
__global__ void k_epiR(const float* __restrict__ part, float* __restrict__ ws,
                       unsigned short* __restrict__ atl,
                       int ksplit, int g, int statIdx, size_t rsOff) {
  int n = blockIdx.x * 256 + threadIdx.x;
  int row = blockIdx.y;
  if (n >= KP2) return;
  int arow = g * BT_ + row;
  if (n >= N_) { atl[(size_t)arow * KP2 + n] = 0; return; }
  float s = 0.f;
  for (int ks = 0; ks < ksplit; ++ks) s += part[((size_t)(ks * BT_ + row)) * N_ + n];
  float mu = ws[OFF_STAT + statIdx], isd = ws[OFF_STAT + statIdx + 1];
  float val = (s - mu * ws[rsOff + row]) * isd;
  ws[OFF_ALIN + (size_t)n * R3_ + arow] = val;
  atl[(size_t)arow * KP2 + n] = f2bf(val);
}

__global__ void k_minmax(const float* __restrict__ alin, float* __restrict__ mmp) {
  int g = blockIdx.y;
  float mn = 3.4e38f, mx = -3.4e38f;
  for (int i = blockIdx.x * 256 + threadIdx.x; i < N_ * BT_; i += 64 * 256) {
    int n = i / BT_, r = i % BT_;
    float v = alin[(size_t)n * R3_ + g * BT_ + r];
    mn = fminf(mn, v); mx = fmaxf(mx, v);
  }
  __shared__ float rn[4], rx[4];
  for (int off = 32; off; off >>= 1) {
    mn = fminf(mn, __shfl_down(mn, off));
    mx = fmaxf(mx, __shfl_down(mx, off));
  }
  if ((threadIdx.x & 63) == 0) { rn[threadIdx.x >> 6] = mn; rx[threadIdx.x >> 6] = mx; }
  __syncthreads();
  if (threadIdx.x == 0) {
    mn = fminf(fminf(rn[0], rn[1]), fminf(rn[2], rn[3]));
    mx = fmaxf(fmaxf(rx[0], rx[1]), fmaxf(rx[2], rx[3]));
    mmp[(size_t)(g * 64 + blockIdx.x) * 2] = mn;
    mmp[(size_t)(g * 64 + blockIdx.x) * 2 + 1] = mx;
  }
}

__global__ void k_minmax2(float* __restrict__ ws) {
  int g = blockIdx.x;
  int i = threadIdx.x;
  float mn = ws[OFF_MMP + (size_t)(g * 64 + i) * 2];
  float mx = ws[OFF_MMP + (size_t)(g * 64 + i) * 2 + 1];
  for (int off = 32; off; off >>= 1) {
    mn = fminf(mn, __shfl_down(mn, off));
    mx = fmaxf(mx, __shfl_down(mx, off));
  }
  if (i == 0) {
    float denom = fmaxf(mx - mn, 1e-8f);
    float a = 1.f / denom;
    ws[OFF_AB + g * 2] = a;
    ws[OFF_AB + g * 2 + 1] = -mn * a;
  }
}

__global__ void k_colsum(const float* __restrict__ ltw, float* __restrict__ csp) {
  int e = blockIdx.x * 256 + threadIdx.x;
  int ks = blockIdx.y;
  if (e >= EA_) return;
  float s = 0.f;
  for (int n = ks * 125; n < (ks + 1) * 125; ++n) s += ltw[(size_t)n * EA_ + e];
  csp[(size_t)ks * EA_ + e] = s;
}
__global__ void k_colsum2(float* __restrict__ ws) {
  int e = blockIdx.x * 256 + threadIdx.x;
  if (e >= EA_) return;
  float s = 0.f;
  for (int ks = 0; ks < 16; ++ks) s += ws[OFF_CSP + (size_t)ks * EA_ + e];
  ws[OFF_CS + e] = s;
}

__global__ void k_epiLin(const float* __restrict__ part, const float* __restrict__ ltb,
                         float* __restrict__ ws, unsigned short* __restrict__ atq,
                         int ksplit) {
  int e = blockIdx.x * 256 + threadIdx.x;
  int row = blockIdx.y;
  if (e >= KP3) return;
  if (e >= EA_) { atq[(size_t)row * KP3 + e] = 0; return; }
  float s = 0.f;
  for (int ks = 0; ks < ksplit; ++ks) s += part[((size_t)(ks * R3_ + row)) * EA_ + e];
  int g = row / BT_;
  float a = ws[OFF_AB + g * 2], bb = ws[OFF_AB + g * 2 + 1];
  float val = fmaf(a, s, fmaf(bb, ws[OFF_CS + e], ltb[e]));
  atq[(size_t)row * KP3 + e] = f2bf(val);
}

__global__ void k_epiQkv(const float* __restrict__ part, const float* __restrict__ qkvb,
                         float* __restrict__ P, int ksplit) {
  int c = blockIdx.x * 256 + threadIdx.x;
  int row = blockIdx.y;
  if (c >= 3 * EA_) return;
  float s = 0.f;
  for (int ks = 0; ks < ksplit; ++ks) s += part[((size_t)(ks * R3_ + row)) * (3 * EA_) + c];
  P[(size_t)row * (3 * EA_) + c] = s + qkvb[c];
}

__global__ void k_attn(const float* __restrict__ P, unsigned short* __restrict__ atao) {
  int mha = blockIdx.y;
  int s_ = blockIdx.x / (B_ * H_);
  int rem = blockIdx.x % (B_ * H_);
  int b = rem / H_, h = rem % H_;
  const int pq[3] = {0, 1, 2}, pk[3] = {1, 2, 0}, pv[3] = {2, 0, 1};
  const float* qrow = P + ((size_t)(pq[mha] * BT_ + s_ * B_ + b)) * (3 * EA_) + h * HD_;
  __shared__ float sc[T_];
  __shared__ float red[4];
  for (int t = 0; t < T_; ++t) {
    const float* krow = P + ((size_t)(pk[mha] * BT_ + t * B_ + b)) * (3 * EA_) + EA_ + h * HD_;
    float p = 0.f;
    for (int d = threadIdx.x; d < HD_; d += 256) p = fmaf(qrow[d], krow[d], p);
    p = waveReduceSum(p);
    if ((threadIdx.x & 63) == 0) red[threadIdx.x >> 6] = p;
    __syncthreads();
    if (threadIdx.x == 0) sc[t] = (red[0] + red[1] + red[2] + red[3]) * 0.031622776601683794f;
    __syncthreads();
  }
  float a[T_];
  float m = sc[0];
#pragma unroll
  for (int t = 1; t < T_; ++t) m = fmaxf(m, sc[t]);
  float sum = 0.f;
#pragma unroll
  for (int t = 0; t < T_; ++t) { a[t] = expf(sc[t] - m); sum += a[t]; }
  float inv = 1.f / sum;
#pragma unroll
  for (int t = 0; t < T_; ++t) a[t] *= inv;
  int orow = mha * BT_ + s_ * B_ + b;
  for (int d = threadIdx.x; d < HD_; d += 256) {
    float o = 0.f;
#pragma unroll
    for (int t = 0; t < T_; ++t)
      o = fmaf(a[t], P[((size_t)(pv[mha] * BT_ + t * B_ + b)) * (3 * EA_) + 2 * EA_ + h * HD_ + d], o);
    atao[(size_t)orow * KP3 + h * HD_ + d] = f2bf(o);
  }
  if (h == 0 && threadIdx.x < 8) atao[(size_t)orow * KP3 + EA_ + threadIdx.x] = 0;
}

__global__ void k_epiAO(const float* __restrict__ part, const float* __restrict__ aob,
                        unsigned short* __restrict__ atll, int ksplit) {
  int c = blockIdx.x * 256 + threadIdx.x;
  int row = blockIdx.y;
  if (c >= KP3) return;
  if (c >= EA_) { atll[(size_t)row * KP3 + c] = 0; return; }
  float s = 0.f;
  for (int ks = 0; ks < ksplit; ++ks) s += part[((size_t)(ks * R3_ + row)) * EA_ + c];
  atll[(size_t)row * KP3 + c] = f2bf(s + aob[c]);
}

__global__ void k_epiLL(const float* __restrict__ part, const float* __restrict__ llb,
                        float* __restrict__ o2p, int ksplit) {
  int n = blockIdx.x * 256 + threadIdx.x;
  int row = blockIdx.y;  // t*B+b
  if (n >= N_) return;
  float s = 0.f;
  for (int g = 0; g < 3; ++g)
    for (int ks = 0; ks < ksplit; ++ks)
      s += part[((size_t)(ks * R3_ + g * BT_ + row)) * N_ + n];
  int t = row / B_, b = row % B_;
  o2p[(size_t)b * (T_ * N_) + t * N_ + n] = BETA_ * (s + 3.f * llb[n]);
}

__global__ void k_proj(const float* __restrict__ out4, const float* __restrict__ pw,
                       const float* __restrict__ pb, float* __restrict__ outp) {
  int i = blockIdx.x * 256 + threadIdx.x;
  if (i >= BTN_) return;
  int b = i / (T_ * N_);
  int t = (i / N_) % T_;
  int n = i % N_;
  float acc = pb[t];
  for (int t2 = 0; t2 < T_; ++t2) {
    const float* o = out4 + ((size_t)(b * T_ + t2) * N_ + n) * D_;
#pragma unroll
    for (int d = 0; d < D_; ++d) acc = fmaf(o[d], pw[(t2 * D_ + d) * T_ + t], acc);
  }
  outp[i] = acc;
}

__global__ void k_p2(const float* __restrict__ o2p, const float* __restrict__ p2w,
                     const float* __restrict__ p2b, float* __restrict__ o2f) {
  int i = blockIdx.x * 256 + threadIdx.x;
  if (i >= BTN_) return;
  int b = i / (T_ * N_);
  int t = (i / N_) % T_;
  int n = i % N_;
  float acc = p2b[t];
  const float* src = o2p + (size_t)b * (T_ * N_) + (size_t)n * T_;
#pragma unroll
  for (int c = 0; c < T_; ++c) acc = fmaf(src[c], p2w[c * T_ + t], acc);
  o2f[i] = acc;
}

// fused: out3 write + f-normalization -> bf16 padded rows g1b/g2b [8000][32]
__global__ void k_fng(const float* __restrict__ outp, const float* __restrict__ o2f,
                      float* __restrict__ dout, unsigned short* __restrict__ g1b,
                      unsigned short* __restrict__ g2b) {
  int r = blockIdx.x * 256 + threadIdx.x;
  if (r >= B_ * N_) return;
  int b = r / N_, n = r % N_;
  float v1[T_], v2[T_];
  float s1 = 0.f, s2 = 0.f;
#pragma unroll
  for (int t = 0; t < T_; ++t) {
    size_t idx = (size_t)b * T_ * N_ + (size_t)t * N_ + n;
    v1[t] = outp[idx];
    v2[t] = o2f[idx];
    dout[idx] = v1[t] + v2[t];
    s1 = fmaf(v1[t], v1[t], s1);
    s2 = fmaf(v2[t], v2[t], s2);
  }
  float n1 = fmaxf(sqrtf(s1), 1e-12f), n2 = fmaxf(sqrtf(s2), 1e-12f);
  float i1 = 10.f / n1, i2 = 1.f / n2;
  unsigned short q[32], z[32];
#pragma unroll
  for (int t = 0; t < T_; ++t) { q[t] = f2bf(v1[t] * i1); z[t] = f2bf(v2[t] * i2); }
#pragma unroll
  for (int t = T_; t < 32; ++t) { q[t] = 0; z[t] = 0; }
  short8* qd = (short8*)(g1b + (size_t)r * 32);
  short8* zd = (short8*)(g2b + (size_t)r * 32);
#pragma unroll
  for (int c = 0; c < 4; ++c) {
    short8 pv, pz;
#pragma unroll
    for (int e = 0; e < 8; ++e) { pv[e] = (short)q[c * 8 + e]; pz[e] = (short)z[c * 8 + e]; }
    qd[c] = pv;
    zd[c] = pz;
  }
}

// MFMA logsumexp: per block 16 q-rows; 16 j-slices (4 waves x grid.y=4)
__global__ __launch_bounds__(256) void k_lsemf(const unsigned short* __restrict__ g1b,
                                               const unsigned short* __restrict__ g2b,
                                               float* __restrict__ psm,
                                               float* __restrict__ psd) {
  int lane = threadIdx.x & 63, w = threadIdx.x >> 6;
  int lr = lane & 15, lo = lane >> 4;
  int i0 = blockIdx.x * 16;
  int slice = blockIdx.y * 4 + w;     // 0..15
  short8 a = *(const short8*)(g1b + (size_t)(i0 + lr) * 32 + lo * 8);
  float sm[4] = {0.f, 0.f, 0.f, 0.f};
  float sd[4] = {0.f, 0.f, 0.f, 0.f};
  for (int t = slice; t < 500; t += 16) {
    int j0 = t * 16;
    short8 b = *(const short8*)(g2b + (size_t)(j0 + lr) * 32 + lo * 8);
    f32x4 acc = {0.f, 0.f, 0.f, 0.f};
    acc = __builtin_amdgcn_mfma_f32_16x16x32_bf16(a, b, acc, 0, 0, 0);
#pragma unroll
    for (int rg = 0; rg < 4; ++rg) {
      float s = acc[rg];                      // row=i0+lo*4+rg, col=j0+lr
      sm[rg] += __expf(s);
      if (j0 + lr == i0 + lo * 4 + rg) sd[rg] = s;
    }
  }
#pragma unroll
  for (int off = 1; off < 16; off <<= 1) {
#pragma unroll
    for (int rg = 0; rg < 4; ++rg) {
      sm[rg] += __shfl_xor(sm[rg], off);
      sd[rg] += __shfl_xor(sd[rg], off);
    }
  }
  __shared__ float lsm[4][16], lsd[4][16];
  if (lr == 0) {
#pragma unroll
    for (int rg = 0; rg < 4; ++rg) {
      lsm[w][lo * 4 + rg] = sm[rg];
      lsd[w][lo * 4 + rg] = sd[rg];
    }
  }
  __syncthreads();
  if (threadIdx.x < 16) {
    float m = lsm[0][threadIdx.x] + lsm[1][threadIdx.x] + lsm[2][threadIdx.x] + lsm[3][threadIdx.x];
    float d = lsd[0][threadIdx.x] + lsd[1][threadIdx.x] + lsd[2][threadIdx.x] + lsd[3][threadIdx.x];
    psm[(size_t)blockIdx.y * 8000 + i0 + threadIdx.x] = m;
    psd[(size_t)blockIdx.y * 8000 + i0 + threadIdx.x] = d;
  }
}

// fused: combine j-splits + mean + final scalars
__global__ __launch_bounds__(1024) void k_lsefin(const float* __restrict__ psm,
                                                 const float* __restrict__ psd,
                                                 const float* __restrict__ ws,
                                                 float* __restrict__ dout) {
  float acc = 0.f;
  for (int r = threadIdx.x; r < B_ * N_; r += 1024) {
    float sm = psm[r] + psm[8000 + r] + psm[16000 + r] + psm[24000 + r];
    float sd = psd[r] + psd[8000 + r] + psd[16000 + r] + psd[24000 + r];
    acc += sd - logf(sm);
  }
  __shared__ float red[16];
  acc = waveReduceSum(acc);
  if ((threadIdx.x & 63) == 0) red[threadIdx.x >> 6] = acc;
  __syncthreads();
  if (threadIdx.x == 0) {
    float s = 0.f;
    for (int i = 0; i < 16; ++i) s += red[i];
    float closs = -s * (1.f / (B_ * N_));
    dout[BTN_] = ws[OFF_BAL];
    dout[BTN_ + 1] = CW_ * closs;
  }
}

// ---------------------------------------------------------------------------
extern "C" void kernel_launch(void* const* d_in, const int* in_sizes, int n_in,
                              void* d_out, int out_size, void* d_ws, size_t ws_size,
                              hipStream_t stream) {
  const float* x    = (const float*)d_in[0];
  const float* velo = (const float*)d_in[1];
  const float* adj  = (const float*)d_in[2];
  const float* lapd = (const float*)d_in[3];
  const float* laph = (const float*)d_in[4];
  const float* sw   = (const float*)d_in[5];
  const float* sb   = (const float*)d_in[6];
  const float* gw   = (const float*)d_in[7];
  const float* ew1  = (const float*)d_in[8];
  const float* eb1  = (const float*)d_in[9];
  const float* ew2  = (const float*)d_in[10];
  const float* eb2  = (const float*)d_in[11];
  const float* pw   = (const float*)d_in[12];
  const float* pb   = (const float*)d_in[13];
  const float* ltw  = (const float*)d_in[14];
  const float* ltb  = (const float*)d_in[15];
  const float* qkvw = (const float*)d_in[16];
  const float* qkvb = (const float*)d_in[17];
  const float* aow  = (const float*)d_in[18];
  const float* aob  = (const float*)d_in[19];
  const float* llw  = (const float*)d_in[20];
  const float* llb  = (const float*)d_in[21];
  const float* p2w  = (const float*)d_in[22];
  const float* p2b  = (const float*)d_in[23];
  float* ws = (float*)d_ws;
  float* dout = (float*)d_out;
  const float* v0 = velo;  // velo[0,0,:]
  float* part = ws + OFF_PART;
  unsigned short* btQ  = (unsigned short*)(ws + OFF_BT_Q);
  unsigned short* btA  = (unsigned short*)(ws + OFF_BT_A);
  unsigned short* btL  = (unsigned short*)(ws + OFF_BT_L);
  unsigned short* btW  = (unsigned short*)(ws + OFF_BT_W);
  unsigned short* atLin = (unsigned short*)(ws + OFF_AT_LIN);
  unsigned short* atQ   = (unsigned short*)(ws + OFF_AT_Q);
  unsigned short* atAO  = (unsigned short*)(ws + OFF_AT_AO);
  unsigned short* atLL  = (unsigned short*)(ws + OFF_AT_LL);
  unsigned short* g1b   = (unsigned short*)(ws + OFF_G1B);
  unsigned short* g2b   = (unsigned short*)(ws + OFF_G2B);
  dim3 b256(256);

  k_init<<<dim3(1), dim3(64), 0, stream>>>(ws);

  // fused weight transposes to bf16 (exact linearized grid)
  k_wtrans4<<<dim3(WT_TOT), b256, 0, stream>>>(qkvw, aow, llw, ltw, btQ, btA, btL, btW);

  k_start<<<dim3((BTN_ * D_ + 255) / 256), b256, 0, stream>>>(x, sw, sb, ws + OFF_OUT4);

  for (int l = 0; l < L_; ++l) {
    k_feat<<<dim3(B_ * D_), b256, 0, stream>>>(ws + OFF_OUT4, ws + OFF_FEAT);
    k_gate<<<dim3(1), dim3(64), 0, stream>>>(ws + OFF_FEAT, gw, ws, l);
    k_expert<<<dim3((T_ * N_ + 255) / 256, B_), b256, 0, stream>>>(ws + OFF_OUT4, ew1, eb1, ew2, eb2, ws, l);
  }

  k_wavelet<<<dim3((BTN_ + 255) / 256), b256, 0, stream>>>(x, velo, ws + OFF_LOWT, ws + OFF_HVT);
  k_rowsum<<<dim3(2 * BT_), b256, 0, stream>>>(ws + OFF_LOWT, ws + OFF_HVT, ws);
  k_S<<<dim3(N_), b256, 0, stream>>>(adj, v0, ws + OFF_S);
  k_stats<<<dim3(512), b256, 0, stream>>>(lapd, ws + OFF_STP);
  k_stats2<<<dim3(1), b256, 0, stream>>>(ws + OFF_STP, ws + OFF_STAT);
  k_stats<<<dim3(512), b256, 0, stream>>>(laph, ws + OFF_STP + 1024);
  k_stats2<<<dim3(1), b256, 0, stream>>>(ws + OFF_STP + 1024, ws + OFF_STAT + 2);
  k_nsstats<<<dim3(512), b256, 0, stream>>>(adj, v0, ws + OFF_S, ws + OFF_STP + 2048);
  k_stats2<<<dim3(1), b256, 0, stream>>>(ws + OFF_STP + 2048, ws + OFF_STAT + 4);

  // r1 / r2 / r3 (fp32, split-K 50)
  k_gemm48<<<dim3(8, RKS_), b256, 0, stream>>>(ws + OFF_LOWT, BT_, BT_, lapd, part, N_, N_, RKC_);
  k_epiR<<<dim3(8, 48), b256, 0, stream>>>(part, ws, atLin, RKS_, 0, 0, OFF_RSL);
  k_gemmNS<<<dim3(8, RKS_), b256, 0, stream>>>(ws + OFF_HVT, adj, v0, ws + OFF_S, part, RKC_);
  k_epiR<<<dim3(8, 48), b256, 0, stream>>>(part, ws, atLin, RKS_, 1, 4, OFF_RSH);
  k_gemm48<<<dim3(8, RKS_), b256, 0, stream>>>(ws + OFF_LOWT, BT_, BT_, laph, part, N_, N_, RKC_);
  k_epiR<<<dim3(8, 48), b256, 0, stream>>>(part, ws, atLin, RKS_, 2, 2, OFF_RSL);

  k_minmax<<<dim3(64, 3), b256, 0, stream>>>(ws + OFF_ALIN, ws + OFF_MMP);
  k_minmax2<<<dim3(3), dim3(64), 0, stream>>>(ws);
  k_colsum<<<dim3(12, 16), b256, 0, stream>>>(ltw, ws + OFF_CSP);
  k_colsum2<<<dim3(12), b256, 0, stream>>>(ws);

  // lin (MFMA)
  k_mfma<<<dim3(47, 9), b256, 0, stream>>>(atLin, btW, part, EA_, KP2, KP2 / 32, 7);
  k_epiLin<<<dim3(12, 144), b256, 0, stream>>>(part, ltb, ws, atQ, 9);

  // qkv (MFMA)
  k_mfma<<<dim3(141, 4), b256, 0, stream>>>(atQ, btQ, part, 3 * EA_, KP3, KP3 / 32, 24);
  k_epiQkv<<<dim3(36, 144), b256, 0, stream>>>(part, qkvb, ws + OFF_P, 4);

  // attention
  k_attn<<<dim3(T_ * B_ * H_, 3), b256, 0, stream>>>(ws + OFF_P, atAO);

  // attn-out (MFMA)
  k_mfma<<<dim3(47, 12), b256, 0, stream>>>(atAO, btA, part, EA_, KP3, KP3 / 32, 8);
  k_epiAO<<<dim3(12, 144), b256, 0, stream>>>(part, aob, atLL, 12);

  // ll (MFMA)
  k_mfma<<<dim3(32, 12), b256, 0, stream>>>(atLL, btL, part, N_, KP3, KP3 / 32, 8);
  k_epiLL<<<dim3(8, 48), b256, 0, stream>>>(part, llb, ws + OFF_O2P, 12);

  k_proj<<<dim3((BTN_ + 255) / 256), b256, 0, stream>>>(ws + OFF_OUT4, pw, pb, ws + OFF_OUTP);
  k_p2<<<dim3((BTN_ + 255) / 256), b256, 0, stream>>>(ws + OFF_O2P, p2w, p2b, ws + OFF_O2F);

  // fused out3 + fnorm (writes dout body + bf16 g1b/g2b)
  k_fng<<<dim3((B_ * N_ + 255) / 256), b256, 0, stream>>>(ws + OFF_OUTP, ws + OFF_O2F, dout, g1b, g2b);

  // MFMA logsumexp; psm/psd partials live in `part`
  k_lsemf<<<dim3(500, 4), b256, 0, stream>>>(g1b, g2b, part, part + 32000);
  k_lsefin<<<dim3(1), dim3(1024), 0, stream>>>(part, part + 32000, ws, dout);
}

// Round 11
// 718.413 us; speedup vs baseline: 1.4602x; 1.1106x over previous
//
#include <hip/hip_runtime.h>
#include <math.h>

// ---------------------------------------------------------------------------
// Model constants
// ---------------------------------------------------------------------------
namespace {
constexpr int B_ = 4, T_ = 12, N_ = 2000, D_ = 16, FF_ = 64, E_ = 4, L_ = 2;
constexpr int EA_ = 3000, H_ = 3, HD_ = EA_ / H_;   // 1000
constexpr int BT_ = B_ * T_;                         // 48
constexpr int R3_ = 3 * BT_;                         // 144
constexpr long long NN_ = (long long)N_ * N_;        // 4,000,000
constexpr int BTN_ = B_ * T_ * N_;                   // 96,000
constexpr float BETA_ = 0.01f, CW_ = 0.001f;
constexpr int RKS_ = 50;                             // r-GEMM split-K
constexpr int RKC_ = 40;                             // r-GEMM k-chunk
constexpr int KP3 = 3008;                            // K=3000 padded to 32
constexpr int KP2 = 2016;                            // K=2000 padded to 32

// transpose grid v3: 64K x 64N tiles, nTile fastest (page-friendly reads)
constexpr int W2_QN = 141, W2_QK = 47;    // qkvw: Nc=9000, Kp=3008
constexpr int W2_AN = 47,  W2_AK = 47;    // aow : Nc=3000, Kp=3008
constexpr int W2_LN = 32,  W2_LK = 47;    // llw : Nc=2000, Kp=3008
constexpr int W2_WN = 47,  W2_WK = 32;    // ltw : Nc=3000, Kp=2016
constexpr int W2_C0 = W2_QN * W2_QK;              // 6627
constexpr int W2_C1 = W2_C0 + W2_AN * W2_AK;      // 8836
constexpr int W2_C2 = W2_C1 + W2_LN * W2_LK;      // 10340
constexpr int W2_TOT = W2_C2 + W2_WN * W2_WK;     // 11844

// ---------------------------------------------------------------------------
// Workspace layout (float offsets)
// ---------------------------------------------------------------------------
constexpr size_t OFF_OUT4 = 0;                                   // [B,T,N,D]
constexpr size_t OFF_LOWT = OFF_OUT4 + (size_t)BTN_ * D_;        // lowT^T [N][48]
constexpr size_t OFF_HVT  = OFF_LOWT + BTN_;                     // highV^T [N][48]
constexpr size_t OFF_ALIN = OFF_HVT + BTN_;                      // r^T [N][144]
constexpr size_t OFF_RT   = OFF_ALIN + (size_t)N_ * R3_;         // (unused, kept)
constexpr size_t OFF_P    = OFF_RT + (size_t)EA_ * R3_;          // P [144][9000]
constexpr size_t OFF_AOT  = OFF_P + (size_t)R3_ * 3 * EA_;       // (unused, kept)
constexpr size_t OFF_OT   = OFF_AOT + (size_t)EA_ * R3_;         // (unused, kept)
constexpr size_t OFF_O2P  = OFF_OT + (size_t)EA_ * R3_;          // out2 pre-p2 [B][T*N]
constexpr size_t OFF_OUTP = OFF_O2P + BTN_;                      // outp [B,T,N]
constexpr size_t OFF_O2F  = OFF_OUTP + BTN_;                     // out2 final [B,T,N]
constexpr size_t OFF_LI   = OFF_O2F + BTN_;                      // (spare)
constexpr size_t OFF_S    = OFF_LI + 8000;                       // G row sums [2000]
constexpr size_t OFF_RSL  = OFF_S + 2000;
constexpr size_t OFF_RSH  = OFF_RSL + 48;
constexpr size_t OFF_STP  = OFF_RSH + 48;
constexpr size_t OFF_STAT = OFF_STP + 3072;
constexpr size_t OFF_MMP  = OFF_STAT + 8;
constexpr size_t OFF_AB   = OFF_MMP + 384;
constexpr size_t OFF_CSP  = OFF_AB + 8;
constexpr size_t OFF_CS   = OFF_CSP + 48000;
constexpr size_t OFF_FEAT = OFF_CS + 3000;
constexpr size_t OFF_GATE = OFF_FEAT + 64;
constexpr size_t OFF_BAL  = OFF_GATE + 16;
constexpr size_t OFF_PART = ((OFF_BAL + 1 + 255) & ~(size_t)255); // split-K partials
constexpr size_t PARTCAP  = 6000000;                              // cap (floats)
// bf16 regions (sizes in floats = ushorts/2)
constexpr size_t OFF_BT_Q  = OFF_PART + PARTCAP;                  // qkvw^T  [9000][KP3]
constexpr size_t OFF_BT_A  = OFF_BT_Q + (size_t)9000 * KP3 / 2;   // aow^T   [3000][KP3]
constexpr size_t OFF_BT_L  = OFF_BT_A + (size_t)3000 * KP3 / 2;   // llw^T   [2000][KP3]
constexpr size_t OFF_BT_W  = OFF_BT_L + (size_t)2000 * KP3 / 2;   // ltw^T   [3000][KP2]
constexpr size_t OFF_AT_LIN= OFF_BT_W + (size_t)3000 * KP2 / 2;   // ALIN^T  [144][KP2]
constexpr size_t OFF_AT_Q  = OFF_AT_LIN + (size_t)R3_ * KP2 / 2;  // RT^T    [144][KP3]
constexpr size_t OFF_AT_AO = OFF_AT_Q + (size_t)R3_ * KP3 / 2;    // Ao      [144][KP3]
constexpr size_t OFF_AT_LL = OFF_AT_AO + (size_t)R3_ * KP3 / 2;   // O       [144][KP3]
constexpr size_t OFF_G1B   = OFF_AT_LL + (size_t)R3_ * KP3 / 2;   // f1 bf16 [8000][32]
constexpr size_t OFF_G2B   = OFF_G1B + 128000;                    // f2 bf16 [8000][32]
} // namespace

typedef __attribute__((ext_vector_type(8))) short short8;
typedef __attribute__((ext_vector_type(4))) float f32x4;

// ---------------------------------------------------------------------------
// Helpers
// ---------------------------------------------------------------------------
__device__ __forceinline__ float waveReduceSum(float v) {
  for (int off = 32; off; off >>= 1) v += __shfl_down(v, off);
  return v;
}

__device__ __forceinline__ unsigned short f2bf(float x) {  // RNE fp32->bf16
  unsigned int u = __float_as_uint(x);
  unsigned int r = (u + 0x7FFFu + ((u >> 16) & 1u)) >> 16;
  return (unsigned short)r;
}

__device__ __forceinline__ void fma48(float* __restrict__ acc,
                                      const float4* __restrict__ a4, float bv) {
#pragma unroll
  for (int r4 = 0; r4 < BT_ / 4; ++r4) {
    float4 av = a4[r4];
    acc[r4 * 4 + 0] = fmaf(av.x, bv, acc[r4 * 4 + 0]);
    acc[r4 * 4 + 1] = fmaf(av.y, bv, acc[r4 * 4 + 1]);
    acc[r4 * 4 + 2] = fmaf(av.z, bv, acc[r4 * 4 + 2]);
    acc[r4 * 4 + 3] = fmaf(av.w, bv, acc[r4 * 4 + 3]);
  }
}

// ---------------------------------------------------------------------------
__global__ void k_init(float* ws) {
  if (threadIdx.x == 0) ws[OFF_BAL] = 0.f;
}

__global__ void k_start(const float* __restrict__ x, const float* __restrict__ sw,
                        const float* __restrict__ sb, float* __restrict__ out4) {
  int i = blockIdx.x * 256 + threadIdx.x;
  if (i >= BTN_ * D_) return;
  int d = i & 15;
  out4[i] = fmaf(x[i >> 4], sw[d], sb[d]);
}

__global__ void k_feat(const float* __restrict__ out4, float* __restrict__ feat) {
  int b = blockIdx.x >> 4, d = blockIdx.x & 15;
  float s = 0.f;
  for (int tn = threadIdx.x; tn < T_ * N_; tn += 256)
    s += out4[((size_t)b * T_ * N_ + tn) * D_ + d];
  __shared__ float red[4];
  s = waveReduceSum(s);
  if ((threadIdx.x & 63) == 0) red[threadIdx.x >> 6] = s;
  __syncthreads();
  if (threadIdx.x == 0)
    feat[blockIdx.x] = (red[0] + red[1] + red[2] + red[3]) * (1.f / (T_ * N_));
}

__global__ void k_gate(const float* __restrict__ feat, const float* __restrict__ gw,
                       float* __restrict__ ws, int l) {
  __shared__ float lg[B_ * E_];
  int tid = threadIdx.x;
  if (tid < B_ * E_) {
    int b = tid >> 2, e = tid & 3;
    float s = 0.f;
    for (int d = 0; d < D_; ++d) s = fmaf(feat[b * D_ + d], gw[(l * D_ + d) * E_ + e], s);
    lg[tid] = s;
  }
  __syncthreads();
  if (tid == 0) {
    float* gates = ws + OFF_GATE;
    float imp[E_] = {0, 0, 0, 0}, load[E_] = {0, 0, 0, 0};
    for (int i = 0; i < B_ * E_; ++i) gates[i] = 0.f;
    for (int b = 0; b < B_; ++b) {
      const float* lb = lg + b * E_;
      int i1 = 0; float v1 = lb[0];
      for (int e = 1; e < E_; ++e) if (lb[e] > v1) { v1 = lb[e]; i1 = e; }
      int i2 = -1; float v2 = -1e30f;
      for (int e = 0; e < E_; ++e) { if (e == i1) continue; if (lb[e] > v2) { v2 = lb[e]; i2 = e; } }
      float e2 = expf(v2 - v1);
      float den = 1.f + e2;
      float g1 = 1.f / den, g2 = e2 / den;
      gates[b * E_ + i1] = g1; gates[b * E_ + i2] = g2;
      imp[i1] += g1; imp[i2] += g2; load[i1] += 1.f; load[i2] += 1.f;
    }
    float bal = 0.f;
    float m = 0.f; for (int e = 0; e < E_; ++e) m += imp[e]; m *= 0.25f;
    float v = 0.f; for (int e = 0; e < E_; ++e) { float d = imp[e] - m; v += d * d; } v *= 0.25f;
    bal += v / (m * m + 1e-10f);
    m = 0.f; for (int e = 0; e < E_; ++e) m += load[e]; m *= 0.25f;
    v = 0.f; for (int e = 0; e < E_; ++e) { float d = load[e] - m; v += d * d; } v *= 0.25f;
    bal += v / (m * m + 1e-10f);
    ws[OFF_BAL] += bal;
  }
}

// MoE expert apply; gelu via sigmoid identity: 0.5*p*(1+tanh(c)) = p*sigm(2c)
__global__ void k_expert(float* __restrict__ out4, const float* __restrict__ w1,
                         const float* __restrict__ b1, const float* __restrict__ w2,
                         const float* __restrict__ b2, const float* __restrict__ ws, int l) {
  int b = blockIdx.y;
  int tn = blockIdx.x * 256 + threadIdx.x;
  if (tn >= T_ * N_) return;
  float* row = out4 + ((size_t)b * T_ * N_ + tn) * D_;
  float r[D_], acc[D_];
#pragma unroll
  for (int d = 0; d < D_; ++d) { r[d] = row[d]; acc[d] = r[d]; }
  const float* gates = ws + OFF_GATE;
  for (int e = 0; e < E_; ++e) {
    float g = gates[b * E_ + e];
    if (g <= 0.f) continue;
    const float* W1 = w1 + (size_t)(l * E_ + e) * D_ * FF_;
    const float* B1 = b1 + (size_t)(l * E_ + e) * FF_;
    const float* W2 = w2 + (size_t)(l * E_ + e) * FF_ * D_;
    const float* B2 = b2 + (size_t)(l * E_ + e) * D_;
#pragma unroll 4
    for (int f = 0; f < FF_; ++f) {
      float p = B1[f];
#pragma unroll
      for (int d = 0; d < D_; ++d) p = fmaf(r[d], W1[d * FF_ + f], p);
      // gelu(p) = p * sigmoid(2*0.7978845608*(p + 0.044715 p^3))
      float c2 = 1.5957691216057308f * (p + 0.044715f * p * p * p);
      float e1 = __expf(-c2);
      float hv = p * __builtin_amdgcn_rcpf(1.f + e1);
      float gh = g * hv;
#pragma unroll
      for (int d = 0; d < D_; ++d) acc[d] = fmaf(gh, W2[f * D_ + d], acc[d]);
    }
#pragma unroll
    for (int d = 0; d < D_; ++d) acc[d] = fmaf(g, B2[d], acc[d]);
  }
#pragma unroll
  for (int d = 0; d < D_; ++d) row[d] = acc[d];
}

__global__ void k_wavelet(const float* __restrict__ x, const float* __restrict__ velo,
                          float* __restrict__ lowT, float* __restrict__ hvT) {
  int i = blockIdx.x * 256 + threadIdx.x;
  if (i >= BTN_) return;
  int b = i / (T_ * N_);
  int t = (i / N_) % T_;
  int n = i % N_;
  int ip = b * T_ * N_ + ((t + T_ - 1) % T_) * N_ + n;
  int row = t * B_ + b;
  lowT[(size_t)n * BT_ + row] = 0.5f * (x[i] + x[ip]);
  hvT[(size_t)n * BT_ + row] = 0.5f * (velo[i] - velo[ip]);
}

__global__ void k_rowsum(const float* __restrict__ lowT, const float* __restrict__ hvT,
                         float* __restrict__ ws) {
  int which = blockIdx.x / BT_;
  int row = blockIdx.x % BT_;
  const float* M = which ? hvT : lowT;
  float s = 0.f;
  for (int n = threadIdx.x; n < N_; n += 256) s += M[(size_t)n * BT_ + row];
  __shared__ float red[4];
  s = waveReduceSum(s);
  if ((threadIdx.x & 63) == 0) red[threadIdx.x >> 6] = s;
  __syncthreads();
  if (threadIdx.x == 0) ws[(which ? OFF_RSH : OFF_RSL) + row] = red[0] + red[1] + red[2] + red[3];
}

__global__ void k_S(const float* __restrict__ adj, const float* __restrict__ v0,
                    float* __restrict__ S) {
  int m = blockIdx.x;
  float vm = v0[m];
  const float* a = adj + (size_t)m * N_;
  float s = 0.f;
  for (int n = threadIdx.x; n < N_; n += 256) s += vm / a[n];
  __shared__ float red[4];
  s = waveReduceSum(s);
  if ((threadIdx.x & 63) == 0) red[threadIdx.x >> 6] = s;
  __syncthreads();
  if (threadIdx.x == 0) S[m] = red[0] + red[1] + red[2] + red[3];
}

__global__ void k_stats(const float* __restrict__ M, float* __restrict__ part) {
  float s = 0.f, ss = 0.f;
  for (long long i = blockIdx.x * 256 + threadIdx.x; i < NN_; i += 512 * 256) {
    float v = M[i];
    s += v; ss = fmaf(v, v, ss);
  }
  __shared__ float r1[4], r2[4];
  for (int off = 32; off; off >>= 1) { s += __shfl_down(s, off); ss += __shfl_down(ss, off); }
  if ((threadIdx.x & 63) == 0) { r1[threadIdx.x >> 6] = s; r2[threadIdx.x >> 6] = ss; }
  __syncthreads();
  if (threadIdx.x == 0) {
    part[blockIdx.x * 2] = r1[0] + r1[1] + r1[2] + r1[3];
    part[blockIdx.x * 2 + 1] = r2[0] + r2[1] + r2[2] + r2[3];
  }
}

__global__ void k_nsstats(const float* __restrict__ adj, const float* __restrict__ v0,
                          const float* __restrict__ S, float* __restrict__ part) {
  float s = 0.f, ss = 0.f;
  for (long long i = blockIdx.x * 256 + threadIdx.x; i < NN_; i += 512 * 256) {
    int m = (int)(i / N_), n = (int)(i % N_);
    float e = -(v0[m] / adj[i]);
    if (m == n) e += S[m];
    s += e; ss = fmaf(e, e, ss);
  }
  __shared__ float r1[4], r2[4];
  for (int off = 32; off; off >>= 1) { s += __shfl_down(s, off); ss += __shfl_down(ss, off); }
  if ((threadIdx.x & 63) == 0) { r1[threadIdx.x >> 6] = s; r2[threadIdx.x >> 6] = ss; }
  __syncthreads();
  if (threadIdx.x == 0) {
    part[blockIdx.x * 2] = r1[0] + r1[1] + r1[2] + r1[3];
    part[blockIdx.x * 2 + 1] = r2[0] + r2[1] + r2[2] + r2[3];
  }
}

__global__ void k_stats2(const float* __restrict__ part, float* __restrict__ stat) {
  float s = 0.f, ss = 0.f;
  for (int i = threadIdx.x; i < 512; i += 256) { s += part[i * 2]; ss += part[i * 2 + 1]; }
  __shared__ float r1[4], r2[4];
  for (int off = 32; off; off >>= 1) { s += __shfl_down(s, off); ss += __shfl_down(ss, off); }
  if ((threadIdx.x & 63) == 0) { r1[threadIdx.x >> 6] = s; r2[threadIdx.x >> 6] = ss; }
  __syncthreads();
  if (threadIdx.x == 0) {
    float su = r1[0] + r1[1] + r1[2] + r1[3];
    float sq = r2[0] + r2[1] + r2[2] + r2[3];
    float mu = su * (1.f / (float)NN_);
    float var = sq * (1.f / (float)NN_) - mu * mu;
    stat[0] = mu;
    stat[1] = 1.f / sqrtf(var);
  }
}

// ---------------------------------------------------------------------------
// fp32 streaming GEMM (r1/r3, NS), 8-deep B prefetch
// ---------------------------------------------------------------------------
__global__ __launch_bounds__(256) void k_gemm48(
    const float* __restrict__ AT, int lda, int rowTot,
    const float* __restrict__ Bm, float* __restrict__ part,
    int Kdim, int NC, int kchunk) {
  int col = blockIdx.x * 256 + threadIdx.x;
  int m0 = blockIdx.y * kchunk;
  int m1 = min(Kdim, m0 + kchunk);
  float acc[BT_];
#pragma unroll
  for (int r = 0; r < BT_; ++r) acc[r] = 0.f;
  if (col < NC) {
    const float* ap = AT + (size_t)m0 * lda;
    const float* bp = Bm + (size_t)m0 * NC + col;
    int len = m1 - m0;
    int ng = len >> 3;
    float bc[8];
    if (ng > 0) {
#pragma unroll
      for (int u = 0; u < 8; ++u) bc[u] = bp[(size_t)u * NC];
    }
    for (int gi = 0; gi < ng; ++gi) {
      float bn[8];
      bool more = (gi + 1 < ng);
      if (more) {
#pragma unroll
        for (int u = 0; u < 8; ++u) bn[u] = bp[(size_t)(8 + u) * NC];
      }
#pragma unroll
      for (int u = 0; u < 8; ++u)
        fma48(acc, (const float4*)(ap + (size_t)u * lda), bc[u]);
      ap += (size_t)8 * lda;
      bp += (size_t)8 * NC;
      if (more) {
#pragma unroll
        for (int u = 0; u < 8; ++u) bc[u] = bn[u];
      }
    }
    for (int m = m0 + (ng << 3); m < m1; ++m) {
      fma48(acc, (const float4*)ap, *bp);
      ap += lda;
      bp += NC;
    }
    float* pp = part + (size_t)blockIdx.y * rowTot * NC + col;
#pragma unroll
    for (int r = 0; r < BT_; ++r) pp[(size_t)r * NC] = acc[r];
  }
}

__global__ __launch_bounds__(256) void k_gemmNS(
    const float* __restrict__ hvT, const float* __restrict__ adj,
    const float* __restrict__ v0, const float* __restrict__ S,
    float* __restrict__ part, int kchunk) {
  int col = blockIdx.x * 256 + threadIdx.x;
  int m0 = blockIdx.y * kchunk;
  int m1 = min(N_, m0 + kchunk);
  float acc[BT_];
#pragma unroll
  for (int r = 0; r < BT_; ++r) acc[r] = 0.f;
  if (col < N_) {
    const float* ap = hvT + (size_t)m0 * BT_;
    const float* jp = adj + (size_t)m0 * N_ + col;
    int len = m1 - m0;
    int ng = len >> 3;
    float jc[8];
    if (ng > 0) {
#pragma unroll
      for (int u = 0; u < 8; ++u) jc[u] = jp[(size_t)u * N_];
    }
    int m = m0;
    for (int gi = 0; gi < ng; ++gi) {
      float jn[8];
      bool more = (gi + 1 < ng);
      if (more) {
#pragma unroll
        for (int u = 0; u < 8; ++u) jn[u] = jp[(size_t)(8 + u) * N_];
      }
#pragma unroll
      for (int u = 0; u < 8; ++u) {
        float bv = -(v0[m + u] / jc[u]);
        if (m + u == col) bv += S[m + u];
        fma48(acc, (const float4*)(ap + (size_t)u * BT_), bv);
      }
      m += 8;
      ap += (size_t)8 * BT_;
      jp += (size_t)8 * N_;
      if (more) {
#pragma unroll
        for (int u = 0; u < 8; ++u) jc[u] = jn[u];
      }
    }
    for (; m < m1; ++m) {
      float bv = -(v0[m] / (*jp));
      if (m == col) bv += S[m];
      fma48(acc, (const float4*)ap, bv);
      ap += BT_;
      jp += N_;
    }
    float* pp = part + (size_t)blockIdx.y * BT_ * N_ + col;
#pragma unroll
    for (int r = 0; r < BT_; ++r) pp[(size_t)r * N_] = acc[r];
  }
}

// ---------------------------------------------------------------------------
// Weight transpose v3: fp32 [K][Nc] -> bf16 [Nc][Kp].
// 64K x 64N tiles, nTile fastest (concurrent blocks sweep full W rows);
// LDS staged transposed t[n][k] (conflict-free both phases); 4B packed writes.
// ---------------------------------------------------------------------------
__global__ __launch_bounds__(256) void k_wtrans4(
    const float* __restrict__ W0, const float* __restrict__ W1,
    const float* __restrict__ W2, const float* __restrict__ W3,
    unsigned short* __restrict__ T0, unsigned short* __restrict__ T1,
    unsigned short* __restrict__ T2, unsigned short* __restrict__ T3) {
  int bid = blockIdx.x;
  const float* W; unsigned short* Wt; int K, Nc, Kp, rel, NT;
  if (bid < W2_C0)      { W = W0; Wt = T0; K = EA_; Nc = 3 * EA_; Kp = KP3; rel = bid;         NT = W2_QN; }
  else if (bid < W2_C1) { W = W1; Wt = T1; K = EA_; Nc = EA_;     Kp = KP3; rel = bid - W2_C0; NT = W2_AN; }
  else if (bid < W2_C2) { W = W2; Wt = T2; K = EA_; Nc = N_;      Kp = KP3; rel = bid - W2_C1; NT = W2_LN; }
  else                  { W = W3; Wt = T3; K = N_;  Nc = EA_;     Kp = KP2; rel = bid - W2_C2; NT = W2_WN; }
  int kTile = rel / NT, nTile = rel % NT;   // nTile fastest
  int k0 = kTile * 64, n0 = nTile * 64;
  __shared__ float t[64][65];               // t[n_local][k_local]
  int tx = threadIdx.x & 63, ty = threadIdx.x >> 6;  // 64 x 4
#pragma unroll
  for (int i = 0; i < 16; ++i) {
    int kl = ty + i * 4;
    int k = k0 + kl, n = n0 + tx;
    t[tx][kl] = (k < K && n < Nc) ? W[(size_t)k * Nc + n] : 0.f;
  }
  __syncthreads();
  // store: lane (tid&31) handles k-pair; (tid>>5)+i*8 covers 64 n rows
  int kp = threadIdx.x & 31;
  int k = k0 + 2 * kp;
#pragma unroll
  for (int i = 0; i < 8; ++i) {
    int nl = (threadIdx.x >> 5) + i * 8;
    int n = n0 + nl;
    if (n < Nc && k < Kp) {
      unsigned int lo = f2bf(t[nl][2 * kp]);
      unsigned int hi = f2bf(t[nl][2 * kp + 1]);
      *(unsigned int*)(Wt + (size_t)n * Kp + k) = (hi << 16) | lo;
    }
  }
}

// ---------------------------------------------------------------------------
// MFMA GEMM: part[ks][144][Nc] = At(bf16 [144][Kp]) @ Bt(bf16 [Nc][Kp])^T
// ---------------------------------------------------------------------------
__global__ __launch_bounds__(256, 4) void k_mfma(
    const unsigned short* __restrict__ At, const unsigned short* __restrict__ Bt,
    float* __restrict__ part, int Nc, int Kp, int stepsTot, int stepChunk) {
  int lane = threadIdx.x & 63;
  int w = threadIdx.x >> 6;
  int lr = lane & 15, lo = lane >> 4;
  int gcol = blockIdx.x * 64 + w * 16 + lr;
  int bcol = min(gcol, Nc - 1);
  int s0 = blockIdx.y * stepChunk;
  int s1 = min(stepsTot, s0 + stepChunk);
  f32x4 acc[9];
#pragma unroll
  for (int mt = 0; mt < 9; ++mt) {
    acc[mt][0] = 0.f; acc[mt][1] = 0.f; acc[mt][2] = 0.f; acc[mt][3] = 0.f;
  }
  const unsigned short* bp = Bt + (size_t)bcol * Kp + (size_t)s0 * 32 + lo * 8;
  const unsigned short* ap = At + (size_t)lr * Kp + (size_t)s0 * 32 + lo * 8;
  for (int s = s0; s < s1; ++s) {
    short8 b = *(const short8*)bp;
#pragma unroll
    for (int mt = 0; mt < 9; ++mt) {
      short8 a = *(const short8*)(ap + (size_t)mt * 16 * Kp);
      acc[mt] = __builtin_amdgcn_mfma_f32_16x16x32_bf16(a, b, acc[mt], 0, 0, 0);
    }
    bp += 32;
    ap += 32;
  }
  if (gcol < Nc) {
#pragma unroll
    for (int mt = 0; mt < 9; ++mt) {
      int row = mt * 16 + lo * 4;
      float* pp = part + ((size_t)blockIdx.y * R3_ + row) * Nc + gcol;
      pp[0] = acc[mt][0];
      pp[(size_t)Nc] = acc[mt][1];
      pp[2 * (size_t)Nc] = acc[mt][2];
      pp[3 * (size_t)Nc] = acc[mt][3];
    }
  }
}

// ---------------------------------------------------------------------------
// Epilogues
// ---------------------------------------------------------------------------
__global__ void k_epiR(const float* __restrict__ part, float* __restrict__ ws,
                       unsigned short* __restrict__ atl,
                       int ksplit, int g, int statIdx, size_t rsOff) {
  int n = blockIdx.x * 256 + threadIdx.x;
  int row = blockIdx.y;
  if (n >= KP2) return;
  int arow = g * BT_ + row;
  if (n >= N_) { atl[(size_t)arow * KP2 + n] = 0; return; }
  float s = 0.f;
  for (int ks = 0; ks < ksplit; ++ks) s += part[((size_t)(ks * BT_ + row)) * N_ + n];
  float mu = ws[OFF_STAT + statIdx], isd = ws[OFF_STAT + statIdx + 1];
  float val = (s - mu * ws[rsOff + row]) * isd;
  ws[OFF_ALIN + (size_t)n * R3_ + arow] = val;
  atl[(size_t)arow * KP2 + n] = f2bf(val);
}

__global__ void k_minmax(const float* __restrict__ alin, float* __restrict__ mmp) {
  int g = blockIdx.y;
  float mn = 3.4e38f, mx = -3.4e38f;
  for (int i = blockIdx.x * 256 + threadIdx.x; i < N_ * BT_; i += 64 * 256) {
    int n = i / BT_, r = i % BT_;
    float v = alin[(size_t)n * R3_ + g * BT_ + r];
    mn = fminf(mn, v); mx = fmaxf(mx, v);
  }
  __shared__ float rn[4], rx[4];
  for (int off = 32; off; off >>= 1) {
    mn = fminf(mn, __shfl_down(mn, off));
    mx = fmaxf(mx, __shfl_down(mx, off));
  }
  if ((threadIdx.x & 63) == 0) { rn[threadIdx.x >> 6] = mn; rx[threadIdx.x >> 6] = mx; }
  __syncthreads();
  if (threadIdx.x == 0) {
    mn = fminf(fminf(rn[0], rn[1]), fminf(rn[2], rn[3]));
    mx = fmaxf(fmaxf(rx[0], rx[1]), fmaxf(rx[2], rx[3]));
    mmp[(size_t)(g * 64 + blockIdx.x) * 2] = mn;
    mmp[(size_t)(g * 64 + blockIdx.x) * 2 + 1] = mx;
  }
}

__global__ void k_minmax2(float* __restrict__ ws) {
  int g = blockIdx.x;
  int i = threadIdx.x;
  float mn = ws[OFF_MMP + (size_t)(g * 64 + i) * 2];
  float mx = ws[OFF_MMP + (size_t)(g * 64 + i) * 2 + 1];
  for (int off = 32; off; off >>= 1) {
    mn = fminf(mn, __shfl_down(mn, off));
    mx = fmaxf(mx, __shfl_down(mx, off));
  }
  if (i == 0) {
    float denom = fmaxf(mx - mn, 1e-8f);
    float a = 1.f / denom;
    ws[OFF_AB + g * 2] = a;
    ws[OFF_AB + g * 2 + 1] = -mn * a;
  }
}

__global__ void k_colsum(const float* __restrict__ ltw, float* __restrict__ csp) {
  int e = blockIdx.x * 256 + threadIdx.x;
  int ks = blockIdx.y;
  if (e >= EA_) return;
  float s = 0.f;
  for (int n = ks * 125; n < (ks + 1) * 125; ++n) s += ltw[(size_t)n * EA_ + e];
  csp[(size_t)ks * EA_ + e] = s;
}
__global__ void k_colsum2(float* __restrict__ ws) {
  int e = blockIdx.x * 256 + threadIdx.x;
  if (e >= EA_) return;
  float s = 0.f;
  for (int ks = 0; ks < 16; ++ks) s += ws[OFF_CSP + (size_t)ks * EA_ + e];
  ws[OFF_CS + e] = s;
}

__global__ void k_epiLin(const float* __restrict__ part, const float* __restrict__ ltb,
                         float* __restrict__ ws, unsigned short* __restrict__ atq,
                         int ksplit) {
  int e = blockIdx.x * 256 + threadIdx.x;
  int row = blockIdx.y;
  if (e >= KP3) return;
  if (e >= EA_) { atq[(size_t)row * KP3 + e] = 0; return; }
  float s = 0.f;
  for (int ks = 0; ks < ksplit; ++ks) s += part[((size_t)(ks * R3_ + row)) * EA_ + e];
  int g = row / BT_;
  float a = ws[OFF_AB + g * 2], bb = ws[OFF_AB + g * 2 + 1];
  float val = fmaf(a, s, fmaf(bb, ws[OFF_CS + e], ltb[e]));
  atq[(size_t)row * KP3 + e] = f2bf(val);
}

__global__ void k_epiQkv(const float* __restrict__ part, const float* __restrict__ qkvb,
                         float* __restrict__ P, int ksplit) {
  int c = blockIdx.x * 256 + threadIdx.x;
  int row = blockIdx.y;
  if (c >= 3 * EA_) return;
  float s = 0.f;
  for (int ks = 0; ks < ksplit; ++ks) s += part[((size_t)(ks * R3_ + row)) * (3 * EA_) + c];
  P[(size_t)row * (3 * EA_) + c] = s + qkvb[c];
}

// attention: waves cover t in parallel (wave-local reductions, one barrier)
__global__ void k_attn(const float* __restrict__ P, unsigned short* __restrict__ atao) {
  int mha = blockIdx.y;
  int s_ = blockIdx.x / (B_ * H_);
  int rem = blockIdx.x % (B_ * H_);
  int b = rem / H_, h = rem % H_;
  const int pq[3] = {0, 1, 2}, pk[3] = {1, 2, 0}, pv[3] = {2, 0, 1};
  const float* qrow = P + ((size_t)(pq[mha] * BT_ + s_ * B_ + b)) * (3 * EA_) + h * HD_;
  __shared__ float sc[T_];
  int w = threadIdx.x >> 6, lane = threadIdx.x & 63;
  for (int t = w; t < T_; t += 4) {
    const float* krow = P + ((size_t)(pk[mha] * BT_ + t * B_ + b)) * (3 * EA_) + EA_ + h * HD_;
    float p = 0.f;
    for (int d = lane; d < HD_; d += 64) p = fmaf(qrow[d], krow[d], p);
    p = waveReduceSum(p);
    if (lane == 0) sc[t] = p * 0.031622776601683794f;
  }
  __syncthreads();
  float a[T_];
  float m = sc[0];
#pragma unroll
  for (int t = 1; t < T_; ++t) m = fmaxf(m, sc[t]);
  float sum = 0.f;
#pragma unroll
  for (int t = 0; t < T_; ++t) { a[t] = expf(sc[t] - m); sum += a[t]; }
  float inv = 1.f / sum;
#pragma unroll
  for (int t = 0; t < T_; ++t) a[t] *= inv;
  int orow = mha * BT_ + s_ * B_ + b;
  for (int d = threadIdx.x; d < HD_; d += 256) {
    float o = 0.f;
#pragma unroll
    for (int t = 0; t < T_; ++t)
      o = fmaf(a[t], P[((size_t)(pv[mha] * BT_ + t * B_ + b)) * (3 * EA_) + 2 * EA_ + h * HD_ + d], o);
    atao[(size_t)orow * KP3 + h * HD_ + d] = f2bf(o);
  }
  if (h == 0 && threadIdx.x < 8) atao[(size_t)orow * KP3 + EA_ + threadIdx.x] = 0;
}

__global__ void k_epiAO(const float* __restrict__ part, const float* __restrict__ aob,
                        unsigned short* __restrict__ atll, int ksplit) {
  int c = blockIdx.x * 256 + threadIdx.x;
  int row = blockIdx.y;
  if (c >= KP3) return;
  if (c >= EA_) { atll[(size_t)row * KP3 + c] = 0; return; }
  float s = 0.f;
  for (int ks = 0; ks < ksplit; ++ks) s += part[((size_t)(ks * R3_ + row)) * EA_ + c];
  atll[(size_t)row * KP3 + c] = f2bf(s + aob[c]);
}

__global__ void k_epiLL(const float* __restrict__ part, const float* __restrict__ llb,
                        float* __restrict__ o2p, int ksplit) {
  int n = blockIdx.x * 256 + threadIdx.x;
  int row = blockIdx.y;  // t*B+b
  if (n >= N_) return;
  float s = 0.f;
  for (int g = 0; g < 3; ++g)
    for (int ks = 0; ks < ksplit; ++ks)
      s += part[((size_t)(ks * R3_ + g * BT_ + row)) * N_ + n];
  int t = row / B_, b = row % B_;
  o2p[(size_t)b * (T_ * N_) + t * N_ + n] = BETA_ * (s + 3.f * llb[n]);
}

__global__ void k_proj(const float* __restrict__ out4, const float* __restrict__ pw,
                       const float* __restrict__ pb, float* __restrict__ outp) {
  int i = blockIdx.x * 256 + threadIdx.x;
  if (i >= BTN_) return;
  int b = i / (T_ * N_);
  int t = (i / N_) % T_;
  int n = i % N_;
  float acc = pb[t];
  for (int t2 = 0; t2 < T_; ++t2) {
    const float* o = out4 + ((size_t)(b * T_ + t2) * N_ + n) * D_;
#pragma unroll
    for (int d = 0; d < D_; ++d) acc = fmaf(o[d], pw[(t2 * D_ + d) * T_ + t], acc);
  }
  outp[i] = acc;
}

__global__ void k_p2(const float* __restrict__ o2p, const float* __restrict__ p2w,
                     const float* __restrict__ p2b, float* __restrict__ o2f) {
  int i = blockIdx.x * 256 + threadIdx.x;
  if (i >= BTN_) return;
  int b = i / (T_ * N_);
  int t = (i / N_) % T_;
  int n = i % N_;
  float acc = p2b[t];
  const float* src = o2p + (size_t)b * (T_ * N_) + (size_t)n * T_;
#pragma unroll
  for (int c = 0; c < T_; ++c) acc = fmaf(src[c], p2w[c * T_ + t], acc);
  o2f[i] = acc;
}

// fused: out3 write + f-normalization -> bf16 padded rows g1b/g2b [8000][32]
__global__ void k_fng(const float* __restrict__ outp, const float* __restrict__ o2f,
                      float* __restrict__ dout, unsigned short* __restrict__ g1b,
                      unsigned short* __restrict__ g2b) {
  int r = blockIdx.x * 256 + threadIdx.x;
  if (r >= B_ * N_) return;
  int b = r / N_, n = r % N_;
  float v1[T_], v2[T_];
  float s1 = 0.f, s2 = 0.f;
#pragma unroll
  for (int t = 0; t < T_; ++t) {
    size_t idx = (size_t)b * T_ * N_ + (size_t)t * N_ + n;
    v1[t] = outp[idx];
    v2[t] = o2f[idx];
    dout[idx] = v1[t] + v2[t];
    s1 = fmaf(v1[t], v1[t], s1);
    s2 = fmaf(v2[t], v2[t], s2);
  }
  float n1 = fmaxf(sqrtf(s1), 1e-12f), n2 = fmaxf(sqrtf(s2), 1e-12f);
  float i1 = 10.f / n1, i2 = 1.f / n2;
  unsigned short q[32], z[32];
#pragma unroll
  for (int t = 0; t < T_; ++t) { q[t] = f2bf(v1[t] * i1); z[t] = f2bf(v2[t] * i2); }
#pragma unroll
  for (int t = T_; t < 32; ++t) { q[t] = 0; z[t] = 0; }
  short8* qd = (short8*)(g1b + (size_t)r * 32);
  short8* zd = (short8*)(g2b + (size_t)r * 32);
#pragma unroll
  for (int c = 0; c < 4; ++c) {
    short8 pv, pz;
#pragma unroll
    for (int e = 0; e < 8; ++e) { pv[e] = (short)q[c * 8 + e]; pz[e] = (short)z[c * 8 + e]; }
    qd[c] = pv;
    zd[c] = pz;
  }
}

// MFMA logsumexp: per block 16 q-rows; 16 j-slices (4 waves x grid.y=4)
__global__ __launch_bounds__(256) void k_lsemf(const unsigned short* __restrict__ g1b,
                                               const unsigned short* __restrict__ g2b,
                                               float* __restrict__ psm,
                                               float* __restrict__ psd) {
  int lane = threadIdx.x & 63, w = threadIdx.x >> 6;
  int lr = lane & 15, lo = lane >> 4;
  int i0 = blockIdx.x * 16;
  int slice = blockIdx.y * 4 + w;     // 0..15
  short8 a = *(const short8*)(g1b + (size_t)(i0 + lr) * 32 + lo * 8);
  float sm[4] = {0.f, 0.f, 0.f, 0.f};
  float sd[4] = {0.f, 0.f, 0.f, 0.f};
  for (int t = slice; t < 500; t += 16) {
    int j0 = t * 16;
    short8 b = *(const short8*)(g2b + (size_t)(j0 + lr) * 32 + lo * 8);
    f32x4 acc = {0.f, 0.f, 0.f, 0.f};
    acc = __builtin_amdgcn_mfma_f32_16x16x32_bf16(a, b, acc, 0, 0, 0);
#pragma unroll
    for (int rg = 0; rg < 4; ++rg) {
      float s = acc[rg];                      // row=i0+lo*4+rg, col=j0+lr
      sm[rg] += __expf(s);
      if (j0 + lr == i0 + lo * 4 + rg) sd[rg] = s;
    }
  }
#pragma unroll
  for (int off = 1; off < 16; off <<= 1) {
#pragma unroll
    for (int rg = 0; rg < 4; ++rg) {
      sm[rg] += __shfl_xor(sm[rg], off);
      sd[rg] += __shfl_xor(sd[rg], off);
    }
  }
  __shared__ float lsm[4][16], lsd[4][16];
  if (lr == 0) {
#pragma unroll
    for (int rg = 0; rg < 4; ++rg) {
      lsm[w][lo * 4 + rg] = sm[rg];
      lsd[w][lo * 4 + rg] = sd[rg];
    }
  }
  __syncthreads();
  if (threadIdx.x < 16) {
    float m = lsm[0][threadIdx.x] + lsm[1][threadIdx.x] + lsm[2][threadIdx.x] + lsm[3][threadIdx.x];
    float d = lsd[0][threadIdx.x] + lsd[1][threadIdx.x] + lsd[2][threadIdx.x] + lsd[3][threadIdx.x];
    psm[(size_t)blockIdx.y * 8000 + i0 + threadIdx.x] = m;
    psd[(size_t)blockIdx.y * 8000 + i0 + threadIdx.x] = d;
  }
}

// fused: combine j-splits + mean + final scalars
__global__ __launch_bounds__(1024) void k_lsefin(const float* __restrict__ psm,
                                                 const float* __restrict__ psd,
                                                 const float* __restrict__ ws,
                                                 float* __restrict__ dout) {
  float acc = 0.f;
  for (int r = threadIdx.x; r < B_ * N_; r += 1024) {
    float sm = psm[r] + psm[8000 + r] + psm[16000 + r] + psm[24000 + r];
    float sd = psd[r] + psd[8000 + r] + psd[16000 + r] + psd[24000 + r];
    acc += sd - logf(sm);
  }
  __shared__ float red[16];
  acc = waveReduceSum(acc);
  if ((threadIdx.x & 63) == 0) red[threadIdx.x >> 6] = acc;
  __syncthreads();
  if (threadIdx.x == 0) {
    float s = 0.f;
    for (int i = 0; i < 16; ++i) s += red[i];
    float closs = -s * (1.f / (B_ * N_));
    dout[BTN_] = ws[OFF_BAL];
    dout[BTN_ + 1] = CW_ * closs;
  }
}

// ---------------------------------------------------------------------------
extern "C" void kernel_launch(void* const* d_in, const int* in_sizes, int n_in,
                              void* d_out, int out_size, void* d_ws, size_t ws_size,
                              hipStream_t stream) {
  const float* x    = (const float*)d_in[0];
  const float* velo = (const float*)d_in[1];
  const float* adj  = (const float*)d_in[2];
  const float* lapd = (const float*)d_in[3];
  const float* laph = (const float*)d_in[4];
  const float* sw   = (const float*)d_in[5];
  const float* sb   = (const float*)d_in[6];
  const float* gw   = (const float*)d_in[7];
  const float* ew1  = (const float*)d_in[8];
  const float* eb1  = (const float*)d_in[9];
  const float* ew2  = (const float*)d_in[10];
  const float* eb2  = (const float*)d_in[11];
  const float* pw   = (const float*)d_in[12];
  const float* pb   = (const float*)d_in[13];
  const float* ltw  = (const float*)d_in[14];
  const float* ltb  = (const float*)d_in[15];
  const float* qkvw = (const float*)d_in[16];
  const float* qkvb = (const float*)d_in[17];
  const float* aow  = (const float*)d_in[18];
  const float* aob  = (const float*)d_in[19];
  const float* llw  = (const float*)d_in[20];
  const float* llb  = (const float*)d_in[21];
  const float* p2w  = (const float*)d_in[22];
  const float* p2b  = (const float*)d_in[23];
  float* ws = (float*)d_ws;
  float* dout = (float*)d_out;
  const float* v0 = velo;  // velo[0,0,:]
  float* part = ws + OFF_PART;
  unsigned short* btQ  = (unsigned short*)(ws + OFF_BT_Q);
  unsigned short* btA  = (unsigned short*)(ws + OFF_BT_A);
  unsigned short* btL  = (unsigned short*)(ws + OFF_BT_L);
  unsigned short* btW  = (unsigned short*)(ws + OFF_BT_W);
  unsigned short* atLin = (unsigned short*)(ws + OFF_AT_LIN);
  unsigned short* atQ   = (unsigned short*)(ws + OFF_AT_Q);
  unsigned short* atAO  = (unsigned short*)(ws + OFF_AT_AO);
  unsigned short* atLL  = (unsigned short*)(ws + OFF_AT_LL);
  unsigned short* g1b   = (unsigned short*)(ws + OFF_G1B);
  unsigned short* g2b   = (unsigned short*)(ws + OFF_G2B);
  dim3 b256(256);

  k_init<<<dim3(1), dim3(64), 0, stream>>>(ws);

  // fused weight transposes to bf16 (64x64 tiles, page-friendly order)
  k_wtrans4<<<dim3(W2_TOT), b256, 0, stream>>>(qkvw, aow, llw, ltw, btQ, btA, btL, btW);

  k_start<<<dim3((BTN_ * D_ + 255) / 256), b256, 0, stream>>>(x, sw, sb, ws + OFF_OUT4);

  for (int l = 0; l < L_; ++l) {
    k_feat<<<dim3(B_ * D_), b256, 0, stream>>>(ws + OFF_OUT4, ws + OFF_FEAT);
    k_gate<<<dim3(1), dim3(64), 0, stream>>>(ws + OFF_FEAT, gw, ws, l);
    k_expert<<<dim3((T_ * N_ + 255) / 256, B_), b256, 0, stream>>>(ws + OFF_OUT4, ew1, eb1, ew2, eb2, ws, l);
  }

  k_wavelet<<<dim3((BTN_ + 255) / 256), b256, 0, stream>>>(x, velo, ws + OFF_LOWT, ws + OFF_HVT);
  k_rowsum<<<dim3(2 * BT_), b256, 0, stream>>>(ws + OFF_LOWT, ws + OFF_HVT, ws);
  k_S<<<dim3(N_), b256, 0, stream>>>(adj, v0, ws + OFF_S);
  k_stats<<<dim3(512), b256, 0, stream>>>(lapd, ws + OFF_STP);
  k_stats2<<<dim3(1), b256, 0, stream>>>(ws + OFF_STP, ws + OFF_STAT);
  k_stats<<<dim3(512), b256, 0, stream>>>(laph, ws + OFF_STP + 1024);
  k_stats2<<<dim3(1), b256, 0, stream>>>(ws + OFF_STP + 1024, ws + OFF_STAT + 2);
  k_nsstats<<<dim3(512), b256, 0, stream>>>(adj, v0, ws + OFF_S, ws + OFF_STP + 2048);
  k_stats2<<<dim3(1), b256, 0, stream>>>(ws + OFF_STP + 2048, ws + OFF_STAT + 4);

  // r1 / r2 / r3 (fp32, split-K 50)
  k_gemm48<<<dim3(8, RKS_), b256, 0, stream>>>(ws + OFF_LOWT, BT_, BT_, lapd, part, N_, N_, RKC_);
  k_epiR<<<dim3(8, 48), b256, 0, stream>>>(part, ws, atLin, RKS_, 0, 0, OFF_RSL);
  k_gemmNS<<<dim3(8, RKS_), b256, 0, stream>>>(ws + OFF_HVT, adj, v0, ws + OFF_S, part, RKC_);
  k_epiR<<<dim3(8, 48), b256, 0, stream>>>(part, ws, atLin, RKS_, 1, 4, OFF_RSH);
  k_gemm48<<<dim3(8, RKS_), b256, 0, stream>>>(ws + OFF_LOWT, BT_, BT_, laph, part, N_, N_, RKC_);
  k_epiR<<<dim3(8, 48), b256, 0, stream>>>(part, ws, atLin, RKS_, 2, 2, OFF_RSL);

  k_minmax<<<dim3(64, 3), b256, 0, stream>>>(ws + OFF_ALIN, ws + OFF_MMP);
  k_minmax2<<<dim3(3), dim3(64), 0, stream>>>(ws);
  k_colsum<<<dim3(12, 16), b256, 0, stream>>>(ltw, ws + OFF_CSP);
  k_colsum2<<<dim3(12), b256, 0, stream>>>(ws);

  // lin (MFMA)
  k_mfma<<<dim3(47, 9), b256, 0, stream>>>(atLin, btW, part, EA_, KP2, KP2 / 32, 7);
  k_epiLin<<<dim3(12, 144), b256, 0, stream>>>(part, ltb, ws, atQ, 9);

  // qkv (MFMA)
  k_mfma<<<dim3(141, 4), b256, 0, stream>>>(atQ, btQ, part, 3 * EA_, KP3, KP3 / 32, 24);
  k_epiQkv<<<dim3(36, 144), b256, 0, stream>>>(part, qkvb, ws + OFF_P, 4);

  // attention
  k_attn<<<dim3(T_ * B_ * H_, 3), b256, 0, stream>>>(ws + OFF_P, atAO);

  // attn-out (MFMA)
  k_mfma<<<dim3(47, 12), b256, 0, stream>>>(atAO, btA, part, EA_, KP3, KP3 / 32, 8);
  k_epiAO<<<dim3(12, 144), b256, 0, stream>>>(part, aob, atLL, 12);

  // ll (MFMA)
  k_mfma<<<dim3(32, 12), b256, 0, stream>>>(atLL, btL, part, N_, KP3, KP3 / 32, 8);
  k_epiLL<<<dim3(8, 48), b256, 0, stream>>>(part, llb, ws + OFF_O2P, 12);

  k_proj<<<dim3((BTN_ + 255) / 256), b256, 0, stream>>>(ws + OFF_OUT4, pw, pb, ws + OFF_OUTP);
  k_p2<<<dim3((BTN_ + 255) / 256), b256, 0, stream>>>(ws + OFF_O2P, p2w, p2b, ws + OFF_O2F);

  // fused out3 + fnorm (writes dout body + bf16 g1b/g2b)
  k_fng<<<dim3((B_ * N_ + 255) / 256), b256, 0, stream>>>(ws + OFF_OUTP, ws + OFF_O2F, dout, g1b, g2b);

  // MFMA logsumexp; psm/psd partials live in `part`
  k_lsemf<<<dim3(500, 4), b256, 0, stream>>>(g1b, g2b, part, part + 32000);
  k_lsefin<<<dim3(1), dim3(1024), 0, stream>>>(part, part + 32000, ws, dout);
}

// Round 12
// 657.706 us; speedup vs baseline: 1.5949x; 1.0923x over previous
//
#include <hip/hip_runtime.h>
#include <math.h>

// ---------------------------------------------------------------------------
// Model constants
// ---------------------------------------------------------------------------
namespace {
constexpr int B_ = 4, T_ = 12, N_ = 2000, D_ = 16, FF_ = 64, E_ = 4, L_ = 2;
constexpr int EA_ = 3000, H_ = 3, HD_ = EA_ / H_;   // 1000
constexpr int BT_ = B_ * T_;                         // 48
constexpr int R3_ = 3 * BT_;                         // 144
constexpr long long NN_ = (long long)N_ * N_;        // 4,000,000
constexpr int BTN_ = B_ * T_ * N_;                   // 96,000
constexpr float BETA_ = 0.01f, CW_ = 0.001f;
constexpr int RKS_ = 16;                             // r-GEMM split-K (fused x3)
constexpr int RKC_ = 125;                            // r-GEMM k-chunk
constexpr int KP3 = 3008;                            // K=3000 padded to 32
constexpr int KP2 = 2016;                            // K=2000 padded to 32

// transpose grid: 64K x 64N tiles, nTile fastest (page-friendly reads)
constexpr int W2_QN = 141, W2_QK = 47;    // qkvw: Nc=9000, Kp=3008
constexpr int W2_AN = 47,  W2_AK = 47;    // aow : Nc=3000, Kp=3008
constexpr int W2_LN = 32,  W2_LK = 47;    // llw : Nc=2000, Kp=3008
constexpr int W2_WN = 47,  W2_WK = 32;    // ltw : Nc=3000, Kp=2016
constexpr int W2_C0 = W2_QN * W2_QK;
constexpr int W2_C1 = W2_C0 + W2_AN * W2_AK;
constexpr int W2_C2 = W2_C1 + W2_LN * W2_LK;
constexpr int W2_TOT = W2_C2 + W2_WN * W2_WK;

// ---------------------------------------------------------------------------
// Workspace layout (float offsets)
// ---------------------------------------------------------------------------
constexpr size_t OFF_OUT4 = 0;                                   // [B,T,N,D]
constexpr size_t OFF_LOWT = OFF_OUT4 + (size_t)BTN_ * D_;        // lowT^T [N][48]
constexpr size_t OFF_HVT  = OFF_LOWT + BTN_;                     // highV^T [N][48]
constexpr size_t OFF_ALIN = OFF_HVT + BTN_;                      // r^T [N][144]
constexpr size_t OFF_RT   = OFF_ALIN + (size_t)N_ * R3_;         // (unused, kept)
constexpr size_t OFF_P    = OFF_RT + (size_t)EA_ * R3_;          // P [144][9000]
constexpr size_t OFF_AOT  = OFF_P + (size_t)R3_ * 3 * EA_;       // (unused, kept)
constexpr size_t OFF_OT   = OFF_AOT + (size_t)EA_ * R3_;         // (unused, kept)
constexpr size_t OFF_O2P  = OFF_OT + (size_t)EA_ * R3_;          // out2 pre-p2 [B][T*N]
constexpr size_t OFF_OUTP = OFF_O2P + BTN_;                      // outp [B,T,N]
constexpr size_t OFF_O2F  = OFF_OUTP + BTN_;                     // out2 final [B,T,N]
constexpr size_t OFF_LI   = OFF_O2F + BTN_;                      // (spare)
constexpr size_t OFF_S    = OFF_LI + 8000;                       // G row sums [2000]
constexpr size_t OFF_RSL  = OFF_S + 2000;
constexpr size_t OFF_RSH  = OFF_RSL + 48;
constexpr size_t OFF_STP  = OFF_RSH + 48;
constexpr size_t OFF_STAT = OFF_STP + 3072;
constexpr size_t OFF_MMP  = OFF_STAT + 8;
constexpr size_t OFF_AB   = OFF_MMP + 384;
constexpr size_t OFF_CSP  = OFF_AB + 8;
constexpr size_t OFF_CS   = OFF_CSP + 48000;
constexpr size_t OFF_FEAT = OFF_CS + 3000;
constexpr size_t OFF_GATE = OFF_FEAT + 64;
constexpr size_t OFF_BAL  = OFF_GATE + 16;
constexpr size_t OFF_PART = ((OFF_BAL + 1 + 255) & ~(size_t)255); // split-K partials
constexpr size_t PARTCAP  = 6000000;                              // cap (floats)
// bf16 regions (sizes in floats = ushorts/2)
constexpr size_t OFF_BT_Q  = OFF_PART + PARTCAP;                  // qkvw^T  [9000][KP3]
constexpr size_t OFF_BT_A  = OFF_BT_Q + (size_t)9000 * KP3 / 2;   // aow^T   [3000][KP3]
constexpr size_t OFF_BT_L  = OFF_BT_A + (size_t)3000 * KP3 / 2;   // llw^T   [2000][KP3]
constexpr size_t OFF_BT_W  = OFF_BT_L + (size_t)2000 * KP3 / 2;   // ltw^T   [3000][KP2]
constexpr size_t OFF_AT_LIN= OFF_BT_W + (size_t)3000 * KP2 / 2;   // ALIN^T  [144][KP2]
constexpr size_t OFF_AT_Q  = OFF_AT_LIN + (size_t)R3_ * KP2 / 2;  // RT^T    [144][KP3]
constexpr size_t OFF_AT_AO = OFF_AT_Q + (size_t)R3_ * KP3 / 2;    // Ao      [144][KP3]
constexpr size_t OFF_AT_LL = OFF_AT_AO + (size_t)R3_ * KP3 / 2;   // O       [144][KP3]
constexpr size_t OFF_G1B   = OFF_AT_LL + (size_t)R3_ * KP3 / 2;   // f1 bf16 [8000][32]
constexpr size_t OFF_G2B   = OFF_G1B + 128000;                    // f2 bf16 [8000][32]
} // namespace

typedef __attribute__((ext_vector_type(8))) short short8;
typedef __attribute__((ext_vector_type(4))) float f32x4;

// ---------------------------------------------------------------------------
// Helpers
// ---------------------------------------------------------------------------
__device__ __forceinline__ float waveReduceSum(float v) {
  for (int off = 32; off; off >>= 1) v += __shfl_down(v, off);
  return v;
}

__device__ __forceinline__ unsigned short f2bf(float x) {  // RNE fp32->bf16
  unsigned int u = __float_as_uint(x);
  unsigned int r = (u + 0x7FFFu + ((u >> 16) & 1u)) >> 16;
  return (unsigned short)r;
}

__device__ __forceinline__ void fma48(float* __restrict__ acc,
                                      const float4* __restrict__ a4, float bv) {
#pragma unroll
  for (int r4 = 0; r4 < BT_ / 4; ++r4) {
    float4 av = a4[r4];
    acc[r4 * 4 + 0] = fmaf(av.x, bv, acc[r4 * 4 + 0]);
    acc[r4 * 4 + 1] = fmaf(av.y, bv, acc[r4 * 4 + 1]);
    acc[r4 * 4 + 2] = fmaf(av.z, bv, acc[r4 * 4 + 2]);
    acc[r4 * 4 + 3] = fmaf(av.w, bv, acc[r4 * 4 + 3]);
  }
}

// ---------------------------------------------------------------------------
__global__ void k_init(float* ws) {
  if (threadIdx.x == 0) ws[OFF_BAL] = 0.f;
}

__global__ void k_start(const float* __restrict__ x, const float* __restrict__ sw,
                        const float* __restrict__ sb, float* __restrict__ out4) {
  int i = blockIdx.x * 256 + threadIdx.x;
  if (i >= BTN_ * D_) return;
  int d = i & 15;
  out4[i] = fmaf(x[i >> 4], sw[d], sb[d]);
}

__global__ void k_feat(const float* __restrict__ out4, float* __restrict__ feat) {
  int b = blockIdx.x >> 4, d = blockIdx.x & 15;
  float s = 0.f;
  for (int tn = threadIdx.x; tn < T_ * N_; tn += 256)
    s += out4[((size_t)b * T_ * N_ + tn) * D_ + d];
  __shared__ float red[4];
  s = waveReduceSum(s);
  if ((threadIdx.x & 63) == 0) red[threadIdx.x >> 6] = s;
  __syncthreads();
  if (threadIdx.x == 0)
    feat[blockIdx.x] = (red[0] + red[1] + red[2] + red[3]) * (1.f / (T_ * N_));
}

__global__ void k_gate(const float* __restrict__ feat, const float* __restrict__ gw,
                       float* __restrict__ ws, int l) {
  __shared__ float lg[B_ * E_];
  int tid = threadIdx.x;
  if (tid < B_ * E_) {
    int b = tid >> 2, e = tid & 3;
    float s = 0.f;
    for (int d = 0; d < D_; ++d) s = fmaf(feat[b * D_ + d], gw[(l * D_ + d) * E_ + e], s);
    lg[tid] = s;
  }
  __syncthreads();
  if (tid == 0) {
    float* gates = ws + OFF_GATE;
    float imp[E_] = {0, 0, 0, 0}, load[E_] = {0, 0, 0, 0};
    for (int i = 0; i < B_ * E_; ++i) gates[i] = 0.f;
    for (int b = 0; b < B_; ++b) {
      const float* lb = lg + b * E_;
      int i1 = 0; float v1 = lb[0];
      for (int e = 1; e < E_; ++e) if (lb[e] > v1) { v1 = lb[e]; i1 = e; }
      int i2 = -1; float v2 = -1e30f;
      for (int e = 0; e < E_; ++e) { if (e == i1) continue; if (lb[e] > v2) { v2 = lb[e]; i2 = e; } }
      float e2 = expf(v2 - v1);
      float den = 1.f + e2;
      float g1 = 1.f / den, g2 = e2 / den;
      gates[b * E_ + i1] = g1; gates[b * E_ + i2] = g2;
      imp[i1] += g1; imp[i2] += g2; load[i1] += 1.f; load[i2] += 1.f;
    }
    float bal = 0.f;
    float m = 0.f; for (int e = 0; e < E_; ++e) m += imp[e]; m *= 0.25f;
    float v = 0.f; for (int e = 0; e < E_; ++e) { float d = imp[e] - m; v += d * d; } v *= 0.25f;
    bal += v / (m * m + 1e-10f);
    m = 0.f; for (int e = 0; e < E_; ++e) m += load[e]; m *= 0.25f;
    v = 0.f; for (int e = 0; e < E_; ++e) { float d = load[e] - m; v += d * d; } v *= 0.25f;
    bal += v / (m * m + 1e-10f);
    ws[OFF_BAL] += bal;
  }
}

// MoE expert apply; gelu via sigmoid identity
__global__ void k_expert(float* __restrict__ out4, const float* __restrict__ w1,
                         const float* __restrict__ b1, const float* __restrict__ w2,
                         const float* __restrict__ b2, const float* __restrict__ ws, int l) {
  int b = blockIdx.y;
  int tn = blockIdx.x * 256 + threadIdx.x;
  if (tn >= T_ * N_) return;
  float* row = out4 + ((size_t)b * T_ * N_ + tn) * D_;
  float r[D_], acc[D_];
#pragma unroll
  for (int d = 0; d < D_; ++d) { r[d] = row[d]; acc[d] = r[d]; }
  const float* gates = ws + OFF_GATE;
  for (int e = 0; e < E_; ++e) {
    float g = gates[b * E_ + e];
    if (g <= 0.f) continue;
    const float* W1 = w1 + (size_t)(l * E_ + e) * D_ * FF_;
    const float* B1 = b1 + (size_t)(l * E_ + e) * FF_;
    const float* W2 = w2 + (size_t)(l * E_ + e) * FF_ * D_;
    const float* B2 = b2 + (size_t)(l * E_ + e) * D_;
#pragma unroll 4
    for (int f = 0; f < FF_; ++f) {
      float p = B1[f];
#pragma unroll
      for (int d = 0; d < D_; ++d) p = fmaf(r[d], W1[d * FF_ + f], p);
      float c2 = 1.5957691216057308f * (p + 0.044715f * p * p * p);
      float e1 = __expf(-c2);
      float hv = p * __builtin_amdgcn_rcpf(1.f + e1);
      float gh = g * hv;
#pragma unroll
      for (int d = 0; d < D_; ++d) acc[d] = fmaf(gh, W2[f * D_ + d], acc[d]);
    }
#pragma unroll
    for (int d = 0; d < D_; ++d) acc[d] = fmaf(g, B2[d], acc[d]);
  }
#pragma unroll
  for (int d = 0; d < D_; ++d) row[d] = acc[d];
}

__global__ void k_wavelet(const float* __restrict__ x, const float* __restrict__ velo,
                          float* __restrict__ lowT, float* __restrict__ hvT) {
  int i = blockIdx.x * 256 + threadIdx.x;
  if (i >= BTN_) return;
  int b = i / (T_ * N_);
  int t = (i / N_) % T_;
  int n = i % N_;
  int ip = b * T_ * N_ + ((t + T_ - 1) % T_) * N_ + n;
  int row = t * B_ + b;
  lowT[(size_t)n * BT_ + row] = 0.5f * (x[i] + x[ip]);
  hvT[(size_t)n * BT_ + row] = 0.5f * (velo[i] - velo[ip]);
}

__global__ void k_rowsum(const float* __restrict__ lowT, const float* __restrict__ hvT,
                         float* __restrict__ ws) {
  int which = blockIdx.x / BT_;
  int row = blockIdx.x % BT_;
  const float* M = which ? hvT : lowT;
  float s = 0.f;
  for (int n = threadIdx.x; n < N_; n += 256) s += M[(size_t)n * BT_ + row];
  __shared__ float red[4];
  s = waveReduceSum(s);
  if ((threadIdx.x & 63) == 0) red[threadIdx.x >> 6] = s;
  __syncthreads();
  if (threadIdx.x == 0) ws[(which ? OFF_RSH : OFF_RSL) + row] = red[0] + red[1] + red[2] + red[3];
}

__global__ void k_S(const float* __restrict__ adj, const float* __restrict__ v0,
                    float* __restrict__ S) {
  int m = blockIdx.x;
  float vm = v0[m];
  const float* a = adj + (size_t)m * N_;
  float s = 0.f;
  for (int n = threadIdx.x; n < N_; n += 256) s += vm / a[n];
  __shared__ float red[4];
  s = waveReduceSum(s);
  if ((threadIdx.x & 63) == 0) red[threadIdx.x >> 6] = s;
  __syncthreads();
  if (threadIdx.x == 0) S[m] = red[0] + red[1] + red[2] + red[3];
}

// fused: sum/sumsq of lapd (z=0), laph (z=1), NS laplacian (z=2)
__global__ void k_stats3(const float* __restrict__ lapd, const float* __restrict__ laph,
                         const float* __restrict__ adj, const float* __restrict__ v0,
                         const float* __restrict__ S, float* __restrict__ stp) {
  int z = blockIdx.z;
  float s = 0.f, ss = 0.f;
  if (z < 2) {
    const float* M = z ? laph : lapd;
    for (long long i = blockIdx.x * 256 + threadIdx.x; i < NN_; i += 512 * 256) {
      float v = M[i];
      s += v; ss = fmaf(v, v, ss);
    }
  } else {
    for (long long i = blockIdx.x * 256 + threadIdx.x; i < NN_; i += 512 * 256) {
      int m = (int)(i / N_), n = (int)(i % N_);
      float e = -(v0[m] / adj[i]);
      if (m == n) e += S[m];
      s += e; ss = fmaf(e, e, ss);
    }
  }
  __shared__ float r1[4], r2[4];
  for (int off = 32; off; off >>= 1) { s += __shfl_down(s, off); ss += __shfl_down(ss, off); }
  if ((threadIdx.x & 63) == 0) { r1[threadIdx.x >> 6] = s; r2[threadIdx.x >> 6] = ss; }
  __syncthreads();
  if (threadIdx.x == 0) {
    float* p = stp + (size_t)z * 1024;
    p[blockIdx.x * 2] = r1[0] + r1[1] + r1[2] + r1[3];
    p[blockIdx.x * 2 + 1] = r2[0] + r2[1] + r2[2] + r2[3];
  }
}

// combine partials -> {mu, 1/std}; z=blockIdx.x maps z0->stat0, z1->stat2, z2->stat4
__global__ void k_stats2(const float* __restrict__ stp, float* __restrict__ stat) {
  int z = blockIdx.x;
  const float* part = stp + (size_t)z * 1024;
  float s = 0.f, ss = 0.f;
  for (int i = threadIdx.x; i < 512; i += 256) { s += part[i * 2]; ss += part[i * 2 + 1]; }
  __shared__ float r1[4], r2[4];
  for (int off = 32; off; off >>= 1) { s += __shfl_down(s, off); ss += __shfl_down(ss, off); }
  if ((threadIdx.x & 63) == 0) { r1[threadIdx.x >> 6] = s; r2[threadIdx.x >> 6] = ss; }
  __syncthreads();
  if (threadIdx.x == 0) {
    float su = r1[0] + r1[1] + r1[2] + r1[3];
    float sq = r2[0] + r2[1] + r2[2] + r2[3];
    float mu = su * (1.f / (float)NN_);
    float var = sq * (1.f / (float)NN_) - mu * mu;
    stat[2 * z] = mu;
    stat[2 * z + 1] = 1.f / sqrtf(var);
  }
}

// ---------------------------------------------------------------------------
// Fused r-GEMMs: z=0 lowT@lapd, z=1 hvT@NS(on the fly), z=2 lowT@laph.
// 48-row accumulators, 8-deep B prefetch; split-K 16, kchunk 125.
// part[z][ks][48][N]
// ---------------------------------------------------------------------------
__global__ __launch_bounds__(256) void k_rgemm3(
    const float* __restrict__ lowT, const float* __restrict__ hvT,
    const float* __restrict__ lapd, const float* __restrict__ laph,
    const float* __restrict__ adj, const float* __restrict__ v0,
    const float* __restrict__ S, float* __restrict__ part) {
  int z = blockIdx.z;
  int col = blockIdx.x * 256 + threadIdx.x;
  int m0 = blockIdx.y * RKC_;
  int m1 = min(N_, m0 + RKC_);
  float acc[BT_];
#pragma unroll
  for (int r = 0; r < BT_; ++r) acc[r] = 0.f;
  if (col < N_) {
    if (z != 1) {
      const float* Bm = z ? laph : lapd;
      const float* ap = lowT + (size_t)m0 * BT_;
      const float* bp = Bm + (size_t)m0 * N_ + col;
      int len = m1 - m0;
      int ng = len >> 3;
      float bc[8];
      if (ng > 0) {
#pragma unroll
        for (int u = 0; u < 8; ++u) bc[u] = bp[(size_t)u * N_];
      }
      for (int gi = 0; gi < ng; ++gi) {
        float bn[8];
        bool more = (gi + 1 < ng);
        if (more) {
#pragma unroll
          for (int u = 0; u < 8; ++u) bn[u] = bp[(size_t)(8 + u) * N_];
        }
#pragma unroll
        for (int u = 0; u < 8; ++u)
          fma48(acc, (const float4*)(ap + (size_t)u * BT_), bc[u]);
        ap += (size_t)8 * BT_;
        bp += (size_t)8 * N_;
        if (more) {
#pragma unroll
          for (int u = 0; u < 8; ++u) bc[u] = bn[u];
        }
      }
      for (int m = m0 + (ng << 3); m < m1; ++m) {
        fma48(acc, (const float4*)ap, *bp);
        ap += BT_;
        bp += N_;
      }
    } else {
      const float* ap = hvT + (size_t)m0 * BT_;
      const float* jp = adj + (size_t)m0 * N_ + col;
      int len = m1 - m0;
      int ng = len >> 3;
      float jc[8];
      if (ng > 0) {
#pragma unroll
        for (int u = 0; u < 8; ++u) jc[u] = jp[(size_t)u * N_];
      }
      int m = m0;
      for (int gi = 0; gi < ng; ++gi) {
        float jn[8];
        bool more = (gi + 1 < ng);
        if (more) {
#pragma unroll
          for (int u = 0; u < 8; ++u) jn[u] = jp[(size_t)(8 + u) * N_];
        }
#pragma unroll
        for (int u = 0; u < 8; ++u) {
          float bv = -(v0[m + u] / jc[u]);
          if (m + u == col) bv += S[m + u];
          fma48(acc, (const float4*)(ap + (size_t)u * BT_), bv);
        }
        m += 8;
        ap += (size_t)8 * BT_;
        jp += (size_t)8 * N_;
        if (more) {
#pragma unroll
          for (int u = 0; u < 8; ++u) jc[u] = jn[u];
        }
      }
      for (; m < m1; ++m) {
        float bv = -(v0[m] / (*jp));
        if (m == col) bv += S[m];
        fma48(acc, (const float4*)ap, bv);
        ap += BT_;
        jp += N_;
      }
    }
    float* pp = part + ((size_t)z * RKS_ + blockIdx.y) * BT_ * N_ + col;
#pragma unroll
    for (int r = 0; r < BT_; ++r) pp[(size_t)r * N_] = acc[r];
  }
}

// fused r epilogue: z selects group / stats / rowsum; -> ALIN + At_lin bf16
__global__ void k_epiR3(const float* __restrict__ part, float* __restrict__ ws,
                        unsigned short* __restrict__ atl) {
  int z = blockIdx.z;
  int n = blockIdx.x * 256 + threadIdx.x;
  int row = blockIdx.y;
  if (n >= KP2) return;
  int arow = z * BT_ + row;
  if (n >= N_) { atl[(size_t)arow * KP2 + n] = 0; return; }
  const float* base = part + (size_t)z * RKS_ * BT_ * N_;
  float s = 0.f;
  for (int ks = 0; ks < RKS_; ++ks) s += base[((size_t)(ks * BT_ + row)) * N_ + n];
  int statIdx = (z == 0) ? 0 : (z == 1 ? 4 : 2);
  size_t rsOff = (z == 1) ? OFF_RSH : OFF_RSL;
  float mu = ws[OFF_STAT + statIdx], isd = ws[OFF_STAT + statIdx + 1];
  float val = (s - mu * ws[rsOff + row]) * isd;
  ws[OFF_ALIN + (size_t)n * R3_ + arow] = val;
  atl[(size_t)arow * KP2 + n] = f2bf(val);
}

// ---------------------------------------------------------------------------
// Weight transpose v4: fp32 [K][Nc] -> bf16 [Nc][Kp].
// 64K x 64N tiles, nTile fastest; float4 global reads (1KB/wave),
// uint2 packed-bf16 writes (512B/wave); <=2-way LDS aliasing both phases.
// ---------------------------------------------------------------------------
__global__ __launch_bounds__(256) void k_wtrans4(
    const float* __restrict__ W0, const float* __restrict__ W1,
    const float* __restrict__ W2, const float* __restrict__ W3,
    unsigned short* __restrict__ T0, unsigned short* __restrict__ T1,
    unsigned short* __restrict__ T2, unsigned short* __restrict__ T3) {
  int bid = blockIdx.x;
  const float* W; unsigned short* Wt; int K, Nc, Kp, rel, NT;
  if (bid < W2_C0)      { W = W0; Wt = T0; K = EA_; Nc = 3 * EA_; Kp = KP3; rel = bid;         NT = W2_QN; }
  else if (bid < W2_C1) { W = W1; Wt = T1; K = EA_; Nc = EA_;     Kp = KP3; rel = bid - W2_C0; NT = W2_AN; }
  else if (bid < W2_C2) { W = W2; Wt = T2; K = EA_; Nc = N_;      Kp = KP3; rel = bid - W2_C1; NT = W2_LN; }
  else                  { W = W3; Wt = T3; K = N_;  Nc = EA_;     Kp = KP2; rel = bid - W2_C2; NT = W2_WN; }
  int kTile = rel / NT, nTile = rel % NT;   // nTile fastest
  int k0 = kTile * 64, n0 = nTile * 64;
  __shared__ float t[64][65];               // t[n_local][k_local]
  int nx = threadIdx.x & 15;                // n-group of 4
  int kk = threadIdx.x >> 4;                // k row base (16)
  bool fullN = (n0 + 64 <= Nc);
#pragma unroll
  for (int i = 0; i < 4; ++i) {
    int kl = kk + 16 * i;
    int k = k0 + kl;
    int n = n0 + 4 * nx;
    float4 v = {0.f, 0.f, 0.f, 0.f};
    if (k < K) {
      if (fullN) {
        v = *(const float4*)(W + (size_t)k * Nc + n);
      } else {
        if (n + 3 < Nc)      v = *(const float4*)(W + (size_t)k * Nc + n);
        else {
          if (n     < Nc) v.x = W[(size_t)k * Nc + n];
          if (n + 1 < Nc) v.y = W[(size_t)k * Nc + n + 1];
          if (n + 2 < Nc) v.z = W[(size_t)k * Nc + n + 2];
          if (n + 3 < Nc) v.w = W[(size_t)k * Nc + n + 3];
        }
      }
    }
    t[4 * nx + 0][kl] = v.x;
    t[4 * nx + 1][kl] = v.y;
    t[4 * nx + 2][kl] = v.z;
    t[4 * nx + 3][kl] = v.w;
  }
  __syncthreads();
  int kq = threadIdx.x & 15;                // k-quad
  int ny = threadIdx.x >> 4;                // n row base (16)
  int k = k0 + 4 * kq;
#pragma unroll
  for (int i = 0; i < 4; ++i) {
    int nl = ny + 16 * i;
    int n = n0 + nl;
    if (n < Nc && k + 3 < Kp) {
      unsigned int w0 = ((unsigned int)f2bf(t[nl][4 * kq + 1]) << 16) | f2bf(t[nl][4 * kq + 0]);
      unsigned int w1 = ((unsigned int)f2bf(t[nl][4 * kq + 3]) << 16) | f2bf(t[nl][4 * kq + 2]);
      uint2 u; u.x = w0; u.y = w1;
      *(uint2*)(Wt + (size_t)n * Kp + k) = u;
    }
  }
}

// ---------------------------------------------------------------------------
// MFMA GEMM: part[ks][144][Nc] = At(bf16 [144][Kp]) @ Bt(bf16 [Nc][Kp])^T
// ---------------------------------------------------------------------------
__global__ __launch_bounds__(256, 4) void k_mfma(
    const unsigned short* __restrict__ At, const unsigned short* __restrict__ Bt,
    float* __restrict__ part, int Nc, int Kp, int stepsTot, int stepChunk) {
  int lane = threadIdx.x & 63;
  int w = threadIdx.x >> 6;
  int lr = lane & 15, lo = lane >> 4;
  int gcol = blockIdx.x * 64 + w * 16 + lr;
  int bcol = min(gcol, Nc - 1);
  int s0 = blockIdx.y * stepChunk;
  int s1 = min(stepsTot, s0 + stepChunk);
  f32x4 acc[9];
#pragma unroll
  for (int mt = 0; mt < 9; ++mt) {
    acc[mt][0] = 0.f; acc[mt][1] = 0.f; acc[mt][2] = 0.f; acc[mt][3] = 0.f;
  }
  const unsigned short* bp = Bt + (size_t)bcol * Kp + (size_t)s0 * 32 + lo * 8;
  const unsigned short* ap = At + (size_t)lr * Kp + (size_t)s0 * 32 + lo * 8;
  for (int s = s0; s < s1; ++s) {
    short8 b = *(const short8*)bp;
#pragma unroll
    for (int mt = 0; mt < 9; ++mt) {
      short8 a = *(const short8*)(ap + (size_t)mt * 16 * Kp);
      acc[mt] = __builtin_amdgcn_mfma_f32_16x16x32_bf16(a, b, acc[mt], 0, 0, 0);
    }
    bp += 32;
    ap += 32;
  }
  if (gcol < Nc) {
#pragma unroll
    for (int mt = 0; mt < 9; ++mt) {
      int row = mt * 16 + lo * 4;
      float* pp = part + ((size_t)blockIdx.y * R3_ + row) * Nc + gcol;
      pp[0] = acc[mt][0];
      pp[(size_t)Nc] = acc[mt][1];
      pp[2 * (size_t)Nc] = acc[mt][2];
      pp[3 * (size_t)Nc] = acc[mt][3];
    }
  }
}

// ---------------------------------------------------------------------------
// Epilogues
// ---------------------------------------------------------------------------
__global__ void k_minmax(const float* __restrict__ alin, float* __restrict__ mmp) {
  int g = blockIdx.y;
  float mn = 3.4e38f, mx = -3.4e38f;
  for (int i = blockIdx.x * 256 + threadIdx.x; i < N_ * BT_; i += 64 * 256) {
    int n = i / BT_, r = i % BT_;
    float v = alin[(size_t)n * R3_ + g * BT_ + r];
    mn = fminf(mn, v); mx = fmaxf(mx, v);
  }
  __shared__ float rn[4], rx[4];
  for (int off = 32; off; off >>= 1) {
    mn = fminf(mn, __shfl_down(mn, off));
    mx = fmaxf(mx, __shfl_down(mx, off));
  }
  if ((threadIdx.x & 63) == 0) { rn[threadIdx.x >> 6] = mn; rx[threadIdx.x >> 6] = mx; }
  __syncthreads();
  if (threadIdx.x == 0) {
    mn = fminf(fminf(rn[0], rn[1]), fminf(rn[2], rn[3]));
    mx = fmaxf(fmaxf(rx[0], rx[1]), fmaxf(rx[2], rx[3]));
    mmp[(size_t)(g * 64 + blockIdx.x) * 2] = mn;
    mmp[(size_t)(g * 64 + blockIdx.x) * 2 + 1] = mx;
  }
}

__global__ void k_minmax2(float* __restrict__ ws) {
  int g = blockIdx.x;
  int i = threadIdx.x;
  float mn = ws[OFF_MMP + (size_t)(g * 64 + i) * 2];
  float mx = ws[OFF_MMP + (size_t)(g * 64 + i) * 2 + 1];
  for (int off = 32; off; off >>= 1) {
    mn = fminf(mn, __shfl_down(mn, off));
    mx = fmaxf(mx, __shfl_down(mx, off));
  }
  if (i == 0) {
    float denom = fmaxf(mx - mn, 1e-8f);
    float a = 1.f / denom;
    ws[OFF_AB + g * 2] = a;
    ws[OFF_AB + g * 2 + 1] = -mn * a;
  }
}

__global__ void k_colsum(const float* __restrict__ ltw, float* __restrict__ csp) {
  int e = blockIdx.x * 256 + threadIdx.x;
  int ks = blockIdx.y;
  if (e >= EA_) return;
  float s = 0.f;
  for (int n = ks * 125; n < (ks + 1) * 125; ++n) s += ltw[(size_t)n * EA_ + e];
  csp[(size_t)ks * EA_ + e] = s;
}
__global__ void k_colsum2(float* __restrict__ ws) {
  int e = blockIdx.x * 256 + threadIdx.x;
  if (e >= EA_) return;
  float s = 0.f;
  for (int ks = 0; ks < 16; ++ks) s += ws[OFF_CSP + (size_t)ks * EA_ + e];
  ws[OFF_CS + e] = s;
}

__global__ void k_epiLin(const float* __restrict__ part, const float* __restrict__ ltb,
                         float* __restrict__ ws, unsigned short* __restrict__ atq,
                         int ksplit) {
  int e = blockIdx.x * 256 + threadIdx.x;
  int row = blockIdx.y;
  if (e >= KP3) return;
  if (e >= EA_) { atq[(size_t)row * KP3 + e] = 0; return; }
  float s = 0.f;
  for (int ks = 0; ks < ksplit; ++ks) s += part[((size_t)(ks * R3_ + row)) * EA_ + e];
  int g = row / BT_;
  float a = ws[OFF_AB + g * 2], bb = ws[OFF_AB + g * 2 + 1];
  float val = fmaf(a, s, fmaf(bb, ws[OFF_CS + e], ltb[e]));
  atq[(size_t)row * KP3 + e] = f2bf(val);
}

__global__ void k_epiQkv(const float* __restrict__ part, const float* __restrict__ qkvb,
                         float* __restrict__ P, int ksplit) {
  int c = blockIdx.x * 256 + threadIdx.x;
  int row = blockIdx.y;
  if (c >= 3 * EA_) return;
  float s = 0.f;
  for (int ks = 0; ks < ksplit; ++ks) s += part[((size_t)(ks * R3_ + row)) * (3 * EA_) + c];
  P[(size_t)row * (3 * EA_) + c] = s + qkvb[c];
}

// attention: waves cover t in parallel (wave-local reductions, one barrier)
__global__ void k_attn(const float* __restrict__ P, unsigned short* __restrict__ atao) {
  int mha = blockIdx.y;
  int s_ = blockIdx.x / (B_ * H_);
  int rem = blockIdx.x % (B_ * H_);
  int b = rem / H_, h = rem % H_;
  const int pq[3] = {0, 1, 2}, pk[3] = {1, 2, 0}, pv[3] = {2, 0, 1};
  const float* qrow = P + ((size_t)(pq[mha] * BT_ + s_ * B_ + b)) * (3 * EA_) + h * HD_;
  __shared__ float sc[T_];
  int w = threadIdx.x >> 6, lane = threadIdx.x & 63;
  for (int t = w; t < T_; t += 4) {
    const float* krow = P + ((size_t)(pk[mha] * BT_ + t * B_ + b)) * (3 * EA_) + EA_ + h * HD_;
    float p = 0.f;
    for (int d = lane; d < HD_; d += 64) p = fmaf(qrow[d], krow[d], p);
    p = waveReduceSum(p);
    if (lane == 0) sc[t] = p * 0.031622776601683794f;
  }
  __syncthreads();
  float a[T_];
  float m = sc[0];
#pragma unroll
  for (int t = 1; t < T_; ++t) m = fmaxf(m, sc[t]);
  float sum = 0.f;
#pragma unroll
  for (int t = 0; t < T_; ++t) { a[t] = expf(sc[t] - m); sum += a[t]; }
  float inv = 1.f / sum;
#pragma unroll
  for (int t = 0; t < T_; ++t) a[t] *= inv;
  int orow = mha * BT_ + s_ * B_ + b;
  for (int d = threadIdx.x; d < HD_; d += 256) {
    float o = 0.f;
#pragma unroll
    for (int t = 0; t < T_; ++t)
      o = fmaf(a[t], P[((size_t)(pv[mha] * BT_ + t * B_ + b)) * (3 * EA_) + 2 * EA_ + h * HD_ + d], o);
    atao[(size_t)orow * KP3 + h * HD_ + d] = f2bf(o);
  }
  if (h == 0 && threadIdx.x < 8) atao[(size_t)orow * KP3 + EA_ + threadIdx.x] = 0;
}

__global__ void k_epiAO(const float* __restrict__ part, const float* __restrict__ aob,
                        unsigned short* __restrict__ atll, int ksplit) {
  int c = blockIdx.x * 256 + threadIdx.x;
  int row = blockIdx.y;
  if (c >= KP3) return;
  if (c >= EA_) { atll[(size_t)row * KP3 + c] = 0; return; }
  float s = 0.f;
  for (int ks = 0; ks < ksplit; ++ks) s += part[((size_t)(ks * R3_ + row)) * EA_ + c];
  atll[(size_t)row * KP3 + c] = f2bf(s + aob[c]);
}

__global__ void k_epiLL(const float* __restrict__ part, const float* __restrict__ llb,
                        float* __restrict__ o2p, int ksplit) {
  int n = blockIdx.x * 256 + threadIdx.x;
  int row = blockIdx.y;  // t*B+b
  if (n >= N_) return;
  float s = 0.f;
  for (int g = 0; g < 3; ++g)
    for (int ks = 0; ks < ksplit; ++ks)
      s += part[((size_t)(ks * R3_ + g * BT_ + row)) * N_ + n];
  int t = row / B_, b = row % B_;
  o2p[(size_t)b * (T_ * N_) + t * N_ + n] = BETA_ * (s + 3.f * llb[n]);
}

__global__ void k_proj(const float* __restrict__ out4, const float* __restrict__ pw,
                       const float* __restrict__ pb, float* __restrict__ outp) {
  int i = blockIdx.x * 256 + threadIdx.x;
  if (i >= BTN_) return;
  int b = i / (T_ * N_);
  int t = (i / N_) % T_;
  int n = i % N_;
  float acc = pb[t];
  for (int t2 = 0; t2 < T_; ++t2) {
    const float* o = out4 + ((size_t)(b * T_ + t2) * N_ + n) * D_;
#pragma unroll
    for (int d = 0; d < D_; ++d) acc = fmaf(o[d], pw[(t2 * D_ + d) * T_ + t], acc);
  }
  outp[i] = acc;
}

__global__ void k_p2(const float* __restrict__ o2p, const float* __restrict__ p2w,
                     const float* __restrict__ p2b, float* __restrict__ o2f) {
  int i = blockIdx.x * 256 + threadIdx.x;
  if (i >= BTN_) return;
  int b = i / (T_ * N_);
  int t = (i / N_) % T_;
  int n = i % N_;
  float acc = p2b[t];
  const float* src = o2p + (size_t)b * (T_ * N_) + (size_t)n * T_;
#pragma unroll
  for (int c = 0; c < T_; ++c) acc = fmaf(src[c], p2w[c * T_ + t], acc);
  o2f[i] = acc;
}

// fused: out3 write + f-normalization -> bf16 padded rows g1b/g2b [8000][32]
__global__ void k_fng(const float* __restrict__ outp, const float* __restrict__ o2f,
                      float* __restrict__ dout, unsigned short* __restrict__ g1b,
                      unsigned short* __restrict__ g2b) {
  int r = blockIdx.x * 256 + threadIdx.x;
  if (r >= B_ * N_) return;
  int b = r / N_, n = r % N_;
  float v1[T_], v2[T_];
  float s1 = 0.f, s2 = 0.f;
#pragma unroll
  for (int t = 0; t < T_; ++t) {
    size_t idx = (size_t)b * T_ * N_ + (size_t)t * N_ + n;
    v1[t] = outp[idx];
    v2[t] = o2f[idx];
    dout[idx] = v1[t] + v2[t];
    s1 = fmaf(v1[t], v1[t], s1);
    s2 = fmaf(v2[t], v2[t], s2);
  }
  float n1 = fmaxf(sqrtf(s1), 1e-12f), n2 = fmaxf(sqrtf(s2), 1e-12f);
  float i1 = 10.f / n1, i2 = 1.f / n2;
  unsigned short q[32], z[32];
#pragma unroll
  for (int t = 0; t < T_; ++t) { q[t] = f2bf(v1[t] * i1); z[t] = f2bf(v2[t] * i2); }
#pragma unroll
  for (int t = T_; t < 32; ++t) { q[t] = 0; z[t] = 0; }
  short8* qd = (short8*)(g1b + (size_t)r * 32);
  short8* zd = (short8*)(g2b + (size_t)r * 32);
#pragma unroll
  for (int c = 0; c < 4; ++c) {
    short8 pv, pz;
#pragma unroll
    for (int e = 0; e < 8; ++e) { pv[e] = (short)q[c * 8 + e]; pz[e] = (short)z[c * 8 + e]; }
    qd[c] = pv;
    zd[c] = pz;
  }
}

// MFMA logsumexp: per block 16 q-rows; 16 j-slices (4 waves x grid.y=4)
__global__ __launch_bounds__(256) void k_lsemf(const unsigned short* __restrict__ g1b,
                                               const unsigned short* __restrict__ g2b,
                                               float* __restrict__ psm,
                                               float* __restrict__ psd) {
  int lane = threadIdx.x & 63, w = threadIdx.x >> 6;
  int lr = lane & 15, lo = lane >> 4;
  int i0 = blockIdx.x * 16;
  int slice = blockIdx.y * 4 + w;     // 0..15
  short8 a = *(const short8*)(g1b + (size_t)(i0 + lr) * 32 + lo * 8);
  float sm[4] = {0.f, 0.f, 0.f, 0.f};
  float sd[4] = {0.f, 0.f, 0.f, 0.f};
  for (int t = slice; t < 500; t += 16) {
    int j0 = t * 16;
    short8 b = *(const short8*)(g2b + (size_t)(j0 + lr) * 32 + lo * 8);
    f32x4 acc = {0.f, 0.f, 0.f, 0.f};
    acc = __builtin_amdgcn_mfma_f32_16x16x32_bf16(a, b, acc, 0, 0, 0);
#pragma unroll
    for (int rg = 0; rg < 4; ++rg) {
      float s = acc[rg];                      // row=i0+lo*4+rg, col=j0+lr
      sm[rg] += __expf(s);
      if (j0 + lr == i0 + lo * 4 + rg) sd[rg] = s;
    }
  }
#pragma unroll
  for (int off = 1; off < 16; off <<= 1) {
#pragma unroll
    for (int rg = 0; rg < 4; ++rg) {
      sm[rg] += __shfl_xor(sm[rg], off);
      sd[rg] += __shfl_xor(sd[rg], off);
    }
  }
  __shared__ float lsm[4][16], lsd[4][16];
  if (lr == 0) {
#pragma unroll
    for (int rg = 0; rg < 4; ++rg) {
      lsm[w][lo * 4 + rg] = sm[rg];
      lsd[w][lo * 4 + rg] = sd[rg];
    }
  }
  __syncthreads();
  if (threadIdx.x < 16) {
    float m = lsm[0][threadIdx.x] + lsm[1][threadIdx.x] + lsm[2][threadIdx.x] + lsm[3][threadIdx.x];
    float d = lsd[0][threadIdx.x] + lsd[1][threadIdx.x] + lsd[2][threadIdx.x] + lsd[3][threadIdx.x];
    psm[(size_t)blockIdx.y * 8000 + i0 + threadIdx.x] = m;
    psd[(size_t)blockIdx.y * 8000 + i0 + threadIdx.x] = d;
  }
}

// fused: combine j-splits + mean + final scalars
__global__ __launch_bounds__(1024) void k_lsefin(const float* __restrict__ psm,
                                                 const float* __restrict__ psd,
                                                 const float* __restrict__ ws,
                                                 float* __restrict__ dout) {
  float acc = 0.f;
  for (int r = threadIdx.x; r < B_ * N_; r += 1024) {
    float sm = psm[r] + psm[8000 + r] + psm[16000 + r] + psm[24000 + r];
    float sd = psd[r] + psd[8000 + r] + psd[16000 + r] + psd[24000 + r];
    acc += sd - logf(sm);
  }
  __shared__ float red[16];
  acc = waveReduceSum(acc);
  if ((threadIdx.x & 63) == 0) red[threadIdx.x >> 6] = acc;
  __syncthreads();
  if (threadIdx.x == 0) {
    float s = 0.f;
    for (int i = 0; i < 16; ++i) s += red[i];
    float closs = -s * (1.f / (B_ * N_));
    dout[BTN_] = ws[OFF_BAL];
    dout[BTN_ + 1] = CW_ * closs;
  }
}

// ---------------------------------------------------------------------------
extern "C" void kernel_launch(void* const* d_in, const int* in_sizes, int n_in,
                              void* d_out, int out_size, void* d_ws, size_t ws_size,
                              hipStream_t stream) {
  const float* x    = (const float*)d_in[0];
  const float* velo = (const float*)d_in[1];
  const float* adj  = (const float*)d_in[2];
  const float* lapd = (const float*)d_in[3];
  const float* laph = (const float*)d_in[4];
  const float* sw   = (const float*)d_in[5];
  const float* sb   = (const float*)d_in[6];
  const float* gw   = (const float*)d_in[7];
  const float* ew1  = (const float*)d_in[8];
  const float* eb1  = (const float*)d_in[9];
  const float* ew2  = (const float*)d_in[10];
  const float* eb2  = (const float*)d_in[11];
  const float* pw   = (const float*)d_in[12];
  const float* pb   = (const float*)d_in[13];
  const float* ltw  = (const float*)d_in[14];
  const float* ltb  = (const float*)d_in[15];
  const float* qkvw = (const float*)d_in[16];
  const float* qkvb = (const float*)d_in[17];
  const float* aow  = (const float*)d_in[18];
  const float* aob  = (const float*)d_in[19];
  const float* llw  = (const float*)d_in[20];
  const float* llb  = (const float*)d_in[21];
  const float* p2w  = (const float*)d_in[22];
  const float* p2b  = (const float*)d_in[23];
  float* ws = (float*)d_ws;
  float* dout = (float*)d_out;
  const float* v0 = velo;  // velo[0,0,:]
  float* part = ws + OFF_PART;
  unsigned short* btQ  = (unsigned short*)(ws + OFF_BT_Q);
  unsigned short* btA  = (unsigned short*)(ws + OFF_BT_A);
  unsigned short* btL  = (unsigned short*)(ws + OFF_BT_L);
  unsigned short* btW  = (unsigned short*)(ws + OFF_BT_W);
  unsigned short* atLin = (unsigned short*)(ws + OFF_AT_LIN);
  unsigned short* atQ   = (unsigned short*)(ws + OFF_AT_Q);
  unsigned short* atAO  = (unsigned short*)(ws + OFF_AT_AO);
  unsigned short* atLL  = (unsigned short*)(ws + OFF_AT_LL);
  unsigned short* g1b   = (unsigned short*)(ws + OFF_G1B);
  unsigned short* g2b   = (unsigned short*)(ws + OFF_G2B);
  dim3 b256(256);

  k_init<<<dim3(1), dim3(64), 0, stream>>>(ws);

  // fused weight transposes to bf16 (vectorized: float4 reads, uint2 writes)
  k_wtrans4<<<dim3(W2_TOT), b256, 0, stream>>>(qkvw, aow, llw, ltw, btQ, btA, btL, btW);

  k_start<<<dim3((BTN_ * D_ + 255) / 256), b256, 0, stream>>>(x, sw, sb, ws + OFF_OUT4);

  for (int l = 0; l < L_; ++l) {
    k_feat<<<dim3(B_ * D_), b256, 0, stream>>>(ws + OFF_OUT4, ws + OFF_FEAT);
    k_gate<<<dim3(1), dim3(64), 0, stream>>>(ws + OFF_FEAT, gw, ws, l);
    k_expert<<<dim3((T_ * N_ + 255) / 256, B_), b256, 0, stream>>>(ws + OFF_OUT4, ew1, eb1, ew2, eb2, ws, l);
  }

  k_wavelet<<<dim3((BTN_ + 255) / 256), b256, 0, stream>>>(x, velo, ws + OFF_LOWT, ws + OFF_HVT);
  k_rowsum<<<dim3(2 * BT_), b256, 0, stream>>>(ws + OFF_LOWT, ws + OFF_HVT, ws);
  k_S<<<dim3(N_), b256, 0, stream>>>(adj, v0, ws + OFF_S);

  // fused stats (lapd, laph, NS) -> partials -> {mu, 1/std} x3
  k_stats3<<<dim3(512, 1, 3), b256, 0, stream>>>(lapd, laph, adj, v0, ws + OFF_S, ws + OFF_STP);
  k_stats2<<<dim3(3), b256, 0, stream>>>(ws + OFF_STP, ws + OFF_STAT);

  // fused r1/r2/r3 GEMMs (split-K 16 each, concurrent) + fused epilogue
  k_rgemm3<<<dim3(8, RKS_, 3), b256, 0, stream>>>(ws + OFF_LOWT, ws + OFF_HVT, lapd, laph,
                                                  adj, v0, ws + OFF_S, part);
  k_epiR3<<<dim3(8, 48, 3), b256, 0, stream>>>(part, ws, atLin);

  k_minmax<<<dim3(64, 3), b256, 0, stream>>>(ws + OFF_ALIN, ws + OFF_MMP);
  k_minmax2<<<dim3(3), dim3(64), 0, stream>>>(ws);
  k_colsum<<<dim3(12, 16), b256, 0, stream>>>(ltw, ws + OFF_CSP);
  k_colsum2<<<dim3(12), b256, 0, stream>>>(ws);

  // lin (MFMA)
  k_mfma<<<dim3(47, 9), b256, 0, stream>>>(atLin, btW, part, EA_, KP2, KP2 / 32, 7);
  k_epiLin<<<dim3(12, 144), b256, 0, stream>>>(part, ltb, ws, atQ, 9);

  // qkv (MFMA)
  k_mfma<<<dim3(141, 4), b256, 0, stream>>>(atQ, btQ, part, 3 * EA_, KP3, KP3 / 32, 24);
  k_epiQkv<<<dim3(36, 144), b256, 0, stream>>>(part, qkvb, ws + OFF_P, 4);

  // attention
  k_attn<<<dim3(T_ * B_ * H_, 3), b256, 0, stream>>>(ws + OFF_P, atAO);

  // attn-out (MFMA)
  k_mfma<<<dim3(47, 12), b256, 0, stream>>>(atAO, btA, part, EA_, KP3, KP3 / 32, 8);
  k_epiAO<<<dim3(12, 144), b256, 0, stream>>>(part, aob, atLL, 12);

  // ll (MFMA)
  k_mfma<<<dim3(32, 12), b256, 0, stream>>>(atLL, btL, part, N_, KP3, KP3 / 32, 8);
  k_epiLL<<<dim3(8, 48), b256, 0, stream>>>(part, llb, ws + OFF_O2P, 12);

  k_proj<<<dim3((BTN_ + 255) / 256), b256, 0, stream>>>(ws + OFF_OUT4, pw, pb, ws + OFF_OUTP);
  k_p2<<<dim3((BTN_ + 255) / 256), b256, 0, stream>>>(ws + OFF_O2P, p2w, p2b, ws + OFF_O2F);

  // fused out3 + fnorm (writes dout body + bf16 g1b/g2b)
  k_fng<<<dim3((B_ * N_ + 255) / 256), b256, 0, stream>>>(ws + OFF_OUTP, ws + OFF_O2F, dout, g1b, g2b);

  // MFMA logsumexp; psm/psd partials live in `part`
  k_lsemf<<<dim3(500, 4), b256, 0, stream>>>(g1b, g2b, part, part + 32000);
  k_lsefin<<<dim3(1), dim3(1024), 0, stream>>>(part, part + 32000, ws, dout);
}

// Round 13
// 586.829 us; speedup vs baseline: 1.7876x; 1.1208x over previous
//
#include <hip/hip_runtime.h>
#include <math.h>

// ---------------------------------------------------------------------------
// Model constants
// ---------------------------------------------------------------------------
namespace {
constexpr int B_ = 4, T_ = 12, N_ = 2000, D_ = 16, FF_ = 64, E_ = 4, L_ = 2;
constexpr int EA_ = 3000, H_ = 3, HD_ = EA_ / H_;   // 1000
constexpr int BT_ = B_ * T_;                         // 48
constexpr int R3_ = 3 * BT_;                         // 144
constexpr long long NN_ = (long long)N_ * N_;        // 4,000,000
constexpr int BTN_ = B_ * T_ * N_;                   // 96,000
constexpr float BETA_ = 0.01f, CW_ = 0.001f;
constexpr int RKS_ = 20;                             // r-GEMM split-K (fused x3)
constexpr int RKC_ = 100;                            // r-GEMM k-chunk
constexpr int KP3 = 3008;                            // K=3000 padded to 32
constexpr int KP2 = 2016;                            // K=2000 padded to 32

// transpose grid: 64K x 64N tiles, nTile fastest (page-friendly reads)
constexpr int W2_QN = 141, W2_QK = 47;    // qkvw: Nc=9000, Kp=3008
constexpr int W2_AN = 47,  W2_AK = 47;    // aow : Nc=3000, Kp=3008
constexpr int W2_LN = 32,  W2_LK = 47;    // llw : Nc=2000, Kp=3008
constexpr int W2_WN = 47,  W2_WK = 32;    // ltw : Nc=3000, Kp=2016
constexpr int W2_C0 = W2_QN * W2_QK;
constexpr int W2_C1 = W2_C0 + W2_AN * W2_AK;
constexpr int W2_C2 = W2_C1 + W2_LN * W2_LK;
constexpr int W2_TOT = W2_C2 + W2_WN * W2_WK;

// ---------------------------------------------------------------------------
// Workspace layout (float offsets)
// ---------------------------------------------------------------------------
constexpr size_t OFF_OUT4 = 0;                                   // [B,T,N,D]
constexpr size_t OFF_LOWT = OFF_OUT4 + (size_t)BTN_ * D_;        // lowT^T [N][48]
constexpr size_t OFF_HVT  = OFF_LOWT + BTN_;                     // highV^T [N][48]
constexpr size_t OFF_ALIN = OFF_HVT + BTN_;                      // r^T [N][144]
constexpr size_t OFF_RT   = OFF_ALIN + (size_t)N_ * R3_;         // (unused, kept)
constexpr size_t OFF_P    = OFF_RT + (size_t)EA_ * R3_;          // P [144][9000]
constexpr size_t OFF_AOT  = OFF_P + (size_t)R3_ * 3 * EA_;       // (unused, kept)
constexpr size_t OFF_OT   = OFF_AOT + (size_t)EA_ * R3_;         // (unused, kept)
constexpr size_t OFF_O2P  = OFF_OT + (size_t)EA_ * R3_;          // out2 pre-p2 [B][T*N]
constexpr size_t OFF_OUTP = OFF_O2P + BTN_;                      // outp [B,T,N]
constexpr size_t OFF_O2F  = OFF_OUTP + BTN_;                     // out2 final [B,T,N]
constexpr size_t OFF_LI   = OFF_O2F + BTN_;                      // (spare)
constexpr size_t OFF_S    = OFF_LI + 8000;                       // G row sums [2000]
constexpr size_t OFF_RSL  = OFF_S + 2000;
constexpr size_t OFF_RSH  = OFF_RSL + 48;
constexpr size_t OFF_STP  = OFF_RSH + 48;
constexpr size_t OFF_STAT = OFF_STP + 3072;
constexpr size_t OFF_MMP  = OFF_STAT + 8;
constexpr size_t OFF_AB   = OFF_MMP + 384;
constexpr size_t OFF_CSP  = OFF_AB + 8;
constexpr size_t OFF_CS   = OFF_CSP + 48000;
constexpr size_t OFF_FEAT = OFF_CS + 3000;
constexpr size_t OFF_GATE = OFF_FEAT + 64;
constexpr size_t OFF_BAL  = OFF_GATE + 16;
constexpr size_t OFF_PART = ((OFF_BAL + 1 + 255) & ~(size_t)255); // split-K partials
constexpr size_t PARTCAP  = 6000000;                              // cap (floats)
// bf16 regions (sizes in floats = ushorts/2)
constexpr size_t OFF_BT_Q  = OFF_PART + PARTCAP;                  // qkvw^T  [9000][KP3]
constexpr size_t OFF_BT_A  = OFF_BT_Q + (size_t)9000 * KP3 / 2;   // aow^T   [3000][KP3]
constexpr size_t OFF_BT_L  = OFF_BT_A + (size_t)3000 * KP3 / 2;   // llw^T   [2000][KP3]
constexpr size_t OFF_BT_W  = OFF_BT_L + (size_t)2000 * KP3 / 2;   // ltw^T   [3000][KP2]
constexpr size_t OFF_AT_LIN= OFF_BT_W + (size_t)3000 * KP2 / 2;   // ALIN^T  [144][KP2]
constexpr size_t OFF_AT_Q  = OFF_AT_LIN + (size_t)R3_ * KP2 / 2;  // RT^T    [144][KP3]
constexpr size_t OFF_AT_AO = OFF_AT_Q + (size_t)R3_ * KP3 / 2;    // Ao      [144][KP3]
constexpr size_t OFF_AT_LL = OFF_AT_AO + (size_t)R3_ * KP3 / 2;   // O       [144][KP3]
constexpr size_t OFF_G1B   = OFF_AT_LL + (size_t)R3_ * KP3 / 2;   // f1 bf16 [8000][32]
constexpr size_t OFF_G2B   = OFF_G1B + 128000;                    // f2 bf16 [8000][32]
} // namespace

typedef __attribute__((ext_vector_type(8))) short short8;
typedef __attribute__((ext_vector_type(4))) float f32x4;

// ---------------------------------------------------------------------------
// Helpers
// ---------------------------------------------------------------------------
__device__ __forceinline__ float waveReduceSum(float v) {
  for (int off = 32; off; off >>= 1) v += __shfl_down(v, off);
  return v;
}

__device__ __forceinline__ unsigned short f2bf(float x) {  // RNE fp32->bf16
  unsigned int u = __float_as_uint(x);
  unsigned int r = (u + 0x7FFFu + ((u >> 16) & 1u)) >> 16;
  return (unsigned short)r;
}

__device__ __forceinline__ void fma16(float* __restrict__ acc,
                                      const float4* __restrict__ a4, float bv) {
#pragma unroll
  for (int r4 = 0; r4 < 4; ++r4) {
    float4 av = a4[r4];
    acc[r4 * 4 + 0] = fmaf(av.x, bv, acc[r4 * 4 + 0]);
    acc[r4 * 4 + 1] = fmaf(av.y, bv, acc[r4 * 4 + 1]);
    acc[r4 * 4 + 2] = fmaf(av.z, bv, acc[r4 * 4 + 2]);
    acc[r4 * 4 + 3] = fmaf(av.w, bv, acc[r4 * 4 + 3]);
  }
}

// ---------------------------------------------------------------------------
__global__ void k_init(float* ws) {
  if (threadIdx.x == 0) ws[OFF_BAL] = 0.f;
}

__global__ void k_start(const float* __restrict__ x, const float* __restrict__ sw,
                        const float* __restrict__ sb, float* __restrict__ out4) {
  int i = blockIdx.x * 256 + threadIdx.x;
  if (i >= BTN_ * D_) return;
  int d = i & 15;
  out4[i] = fmaf(x[i >> 4], sw[d], sb[d]);
}

__global__ void k_feat(const float* __restrict__ out4, float* __restrict__ feat) {
  int b = blockIdx.x >> 4, d = blockIdx.x & 15;
  float s = 0.f;
  for (int tn = threadIdx.x; tn < T_ * N_; tn += 256)
    s += out4[((size_t)b * T_ * N_ + tn) * D_ + d];
  __shared__ float red[4];
  s = waveReduceSum(s);
  if ((threadIdx.x & 63) == 0) red[threadIdx.x >> 6] = s;
  __syncthreads();
  if (threadIdx.x == 0)
    feat[blockIdx.x] = (red[0] + red[1] + red[2] + red[3]) * (1.f / (T_ * N_));
}

__global__ void k_gate(const float* __restrict__ feat, const float* __restrict__ gw,
                       float* __restrict__ ws, int l) {
  __shared__ float lg[B_ * E_];
  int tid = threadIdx.x;
  if (tid < B_ * E_) {
    int b = tid >> 2, e = tid & 3;
    float s = 0.f;
    for (int d = 0; d < D_; ++d) s = fmaf(feat[b * D_ + d], gw[(l * D_ + d) * E_ + e], s);
    lg[tid] = s;
  }
  __syncthreads();
  if (tid == 0) {
    float* gates = ws + OFF_GATE;
    float imp[E_] = {0, 0, 0, 0}, load[E_] = {0, 0, 0, 0};
    for (int i = 0; i < B_ * E_; ++i) gates[i] = 0.f;
    for (int b = 0; b < B_; ++b) {
      const float* lb = lg + b * E_;
      int i1 = 0; float v1 = lb[0];
      for (int e = 1; e < E_; ++e) if (lb[e] > v1) { v1 = lb[e]; i1 = e; }
      int i2 = -1; float v2 = -1e30f;
      for (int e = 0; e < E_; ++e) { if (e == i1) continue; if (lb[e] > v2) { v2 = lb[e]; i2 = e; } }
      float e2 = expf(v2 - v1);
      float den = 1.f + e2;
      float g1 = 1.f / den, g2 = e2 / den;
      gates[b * E_ + i1] = g1; gates[b * E_ + i2] = g2;
      imp[i1] += g1; imp[i2] += g2; load[i1] += 1.f; load[i2] += 1.f;
    }
    float bal = 0.f;
    float m = 0.f; for (int e = 0; e < E_; ++e) m += imp[e]; m *= 0.25f;
    float v = 0.f; for (int e = 0; e < E_; ++e) { float d = imp[e] - m; v += d * d; } v *= 0.25f;
    bal += v / (m * m + 1e-10f);
    m = 0.f; for (int e = 0; e < E_; ++e) m += load[e]; m *= 0.25f;
    v = 0.f; for (int e = 0; e < E_; ++e) { float d = load[e] - m; v += d * d; } v *= 0.25f;
    bal += v / (m * m + 1e-10f);
    ws[OFF_BAL] += bal;
  }
}

// MoE expert apply; gelu via sigmoid identity
__global__ void k_expert(float* __restrict__ out4, const float* __restrict__ w1,
                         const float* __restrict__ b1, const float* __restrict__ w2,
                         const float* __restrict__ b2, const float* __restrict__ ws, int l) {
  int b = blockIdx.y;
  int tn = blockIdx.x * 256 + threadIdx.x;
  if (tn >= T_ * N_) return;
  float* row = out4 + ((size_t)b * T_ * N_ + tn) * D_;
  float r[D_], acc[D_];
#pragma unroll
  for (int d = 0; d < D_; ++d) { r[d] = row[d]; acc[d] = r[d]; }
  const float* gates = ws + OFF_GATE;
  for (int e = 0; e < E_; ++e) {
    float g = gates[b * E_ + e];
    if (g <= 0.f) continue;
    const float* W1 = w1 + (size_t)(l * E_ + e) * D_ * FF_;
    const float* B1 = b1 + (size_t)(l * E_ + e) * FF_;
    const float* W2 = w2 + (size_t)(l * E_ + e) * FF_ * D_;
    const float* B2 = b2 + (size_t)(l * E_ + e) * D_;
#pragma unroll 4
    for (int f = 0; f < FF_; ++f) {
      float p = B1[f];
#pragma unroll
      for (int d = 0; d < D_; ++d) p = fmaf(r[d], W1[d * FF_ + f], p);
      float c2 = 1.5957691216057308f * (p + 0.044715f * p * p * p);
      float e1 = __expf(-c2);
      float hv = p * __builtin_amdgcn_rcpf(1.f + e1);
      float gh = g * hv;
#pragma unroll
      for (int d = 0; d < D_; ++d) acc[d] = fmaf(gh, W2[f * D_ + d], acc[d]);
    }
#pragma unroll
    for (int d = 0; d < D_; ++d) acc[d] = fmaf(g, B2[d], acc[d]);
  }
#pragma unroll
  for (int d = 0; d < D_; ++d) row[d] = acc[d];
}

__global__ void k_wavelet(const float* __restrict__ x, const float* __restrict__ velo,
                          float* __restrict__ lowT, float* __restrict__ hvT) {
  int i = blockIdx.x * 256 + threadIdx.x;
  if (i >= BTN_) return;
  int b = i / (T_ * N_);
  int t = (i / N_) % T_;
  int n = i % N_;
  int ip = b * T_ * N_ + ((t + T_ - 1) % T_) * N_ + n;
  int row = t * B_ + b;
  lowT[(size_t)n * BT_ + row] = 0.5f * (x[i] + x[ip]);
  hvT[(size_t)n * BT_ + row] = 0.5f * (velo[i] - velo[ip]);
}

__global__ void k_rowsum(const float* __restrict__ lowT, const float* __restrict__ hvT,
                         float* __restrict__ ws) {
  int which = blockIdx.x / BT_;
  int row = blockIdx.x % BT_;
  const float* M = which ? hvT : lowT;
  float s = 0.f;
  for (int n = threadIdx.x; n < N_; n += 256) s += M[(size_t)n * BT_ + row];
  __shared__ float red[4];
  s = waveReduceSum(s);
  if ((threadIdx.x & 63) == 0) red[threadIdx.x >> 6] = s;
  __syncthreads();
  if (threadIdx.x == 0) ws[(which ? OFF_RSH : OFF_RSL) + row] = red[0] + red[1] + red[2] + red[3];
}

__global__ void k_S(const float* __restrict__ adj, const float* __restrict__ v0,
                    float* __restrict__ S) {
  int m = blockIdx.x;
  float vm = v0[m];
  const float* a = adj + (size_t)m * N_;
  float s = 0.f;
  for (int n = threadIdx.x; n < N_; n += 256) s += vm / a[n];
  __shared__ float red[4];
  s = waveReduceSum(s);
  if ((threadIdx.x & 63) == 0) red[threadIdx.x >> 6] = s;
  __syncthreads();
  if (threadIdx.x == 0) S[m] = red[0] + red[1] + red[2] + red[3];
}

// fused: sum/sumsq of lapd (z=0), laph (z=1), NS laplacian (z=2)
__global__ void k_stats3(const float* __restrict__ lapd, const float* __restrict__ laph,
                         const float* __restrict__ adj, const float* __restrict__ v0,
                         const float* __restrict__ S, float* __restrict__ stp) {
  int z = blockIdx.z;
  float s = 0.f, ss = 0.f;
  if (z < 2) {
    const float* M = z ? laph : lapd;
    for (long long i = blockIdx.x * 256 + threadIdx.x; i < NN_; i += 512 * 256) {
      float v = M[i];
      s += v; ss = fmaf(v, v, ss);
    }
  } else {
    for (long long i = blockIdx.x * 256 + threadIdx.x; i < NN_; i += 512 * 256) {
      int m = (int)(i / N_), n = (int)(i % N_);
      float e = -(v0[m] / adj[i]);
      if (m == n) e += S[m];
      s += e; ss = fmaf(e, e, ss);
    }
  }
  __shared__ float r1[4], r2[4];
  for (int off = 32; off; off >>= 1) { s += __shfl_down(s, off); ss += __shfl_down(ss, off); }
  if ((threadIdx.x & 63) == 0) { r1[threadIdx.x >> 6] = s; r2[threadIdx.x >> 6] = ss; }
  __syncthreads();
  if (threadIdx.x == 0) {
    float* p = stp + (size_t)z * 1024;
    p[blockIdx.x * 2] = r1[0] + r1[1] + r1[2] + r1[3];
    p[blockIdx.x * 2 + 1] = r2[0] + r2[1] + r2[2] + r2[3];
  }
}

__global__ void k_stats2(const float* __restrict__ stp, float* __restrict__ stat) {
  int z = blockIdx.x;
  const float* part = stp + (size_t)z * 1024;
  float s = 0.f, ss = 0.f;
  for (int i = threadIdx.x; i < 512; i += 256) { s += part[i * 2]; ss += part[i * 2 + 1]; }
  __shared__ float r1[4], r2[4];
  for (int off = 32; off; off >>= 1) { s += __shfl_down(s, off); ss += __shfl_down(ss, off); }
  if ((threadIdx.x & 63) == 0) { r1[threadIdx.x >> 6] = s; r2[threadIdx.x >> 6] = ss; }
  __syncthreads();
  if (threadIdx.x == 0) {
    float su = r1[0] + r1[1] + r1[2] + r1[3];
    float sq = r2[0] + r2[1] + r2[2] + r2[3];
    float mu = su * (1.f / (float)NN_);
    float var = sq * (1.f / (float)NN_) - mu * mu;
    stat[2 * z] = mu;
    stat[2 * z + 1] = 1.f / sqrtf(var);
  }
}

// ---------------------------------------------------------------------------
// Fused r-GEMMs, 16-row accumulators: blockIdx.z = z*3 + rg.
// z=0 lowT@lapd, z=1 hvT@NS(on the fly), z=2 lowT@laph.
// part[z][ks][48][N] (rg writes rows rg*16..rg*16+15). Grid (8, RKS_, 9).
// ---------------------------------------------------------------------------
__global__ __launch_bounds__(256) void k_rgemm3(
    const float* __restrict__ lowT, const float* __restrict__ hvT,
    const float* __restrict__ lapd, const float* __restrict__ laph,
    const float* __restrict__ adj, const float* __restrict__ v0,
    const float* __restrict__ S, float* __restrict__ part) {
  int zz = blockIdx.z;
  int z = zz / 3, rg = zz % 3;
  int col = blockIdx.x * 256 + threadIdx.x;
  int m0 = blockIdx.y * RKC_;
  int m1 = min(N_, m0 + RKC_);
  float acc[16];
#pragma unroll
  for (int r = 0; r < 16; ++r) acc[r] = 0.f;
  if (col < N_) {
    const float* Abase = (z == 1 ? hvT : lowT);
    const float* ap = Abase + (size_t)m0 * BT_ + rg * 16;
    if (z != 1) {
      const float* Bm = z ? laph : lapd;
      const float* bp = Bm + (size_t)m0 * N_ + col;
      int len = m1 - m0;
      int ng = len >> 3;
      float bc[8];
      if (ng > 0) {
#pragma unroll
        for (int u = 0; u < 8; ++u) bc[u] = bp[(size_t)u * N_];
      }
      for (int gi = 0; gi < ng; ++gi) {
        float bn[8];
        bool more = (gi + 1 < ng);
        if (more) {
#pragma unroll
          for (int u = 0; u < 8; ++u) bn[u] = bp[(size_t)(8 + u) * N_];
        }
#pragma unroll
        for (int u = 0; u < 8; ++u)
          fma16(acc, (const float4*)(ap + (size_t)u * BT_), bc[u]);
        ap += (size_t)8 * BT_;
        bp += (size_t)8 * N_;
        if (more) {
#pragma unroll
          for (int u = 0; u < 8; ++u) bc[u] = bn[u];
        }
      }
      for (int m = m0 + (ng << 3); m < m1; ++m) {
        fma16(acc, (const float4*)ap, *bp);
        ap += BT_;
        bp += N_;
      }
    } else {
      const float* jp = adj + (size_t)m0 * N_ + col;
      int len = m1 - m0;
      int ng = len >> 3;
      float jc[8];
      if (ng > 0) {
#pragma unroll
        for (int u = 0; u < 8; ++u) jc[u] = jp[(size_t)u * N_];
      }
      int m = m0;
      for (int gi = 0; gi < ng; ++gi) {
        float jn[8];
        bool more = (gi + 1 < ng);
        if (more) {
#pragma unroll
          for (int u = 0; u < 8; ++u) jn[u] = jp[(size_t)(8 + u) * N_];
        }
#pragma unroll
        for (int u = 0; u < 8; ++u) {
          float bv = -(v0[m + u] / jc[u]);
          if (m + u == col) bv += S[m + u];
          fma16(acc, (const float4*)(ap + (size_t)u * BT_), bv);
        }
        m += 8;
        ap += (size_t)8 * BT_;
        jp += (size_t)8 * N_;
        if (more) {
#pragma unroll
          for (int u = 0; u < 8; ++u) jc[u] = jn[u];
        }
      }
      for (; m < m1; ++m) {
        float bv = -(v0[m] / (*jp));
        if (m == col) bv += S[m];
        fma16(acc, (const float4*)ap, bv);
        ap += BT_;
        jp += N_;
      }
    }
    float* pp = part + (((size_t)z * RKS_ + blockIdx.y) * BT_ + rg * 16) * N_ + col;
#pragma unroll
    for (int r = 0; r < 16; ++r) pp[(size_t)r * N_] = acc[r];
  }
}

// fused r epilogue: z selects group / stats / rowsum; -> ALIN + At_lin bf16
__global__ void k_epiR3(const float* __restrict__ part, float* __restrict__ ws,
                        unsigned short* __restrict__ atl) {
  int z = blockIdx.z;
  int n = blockIdx.x * 256 + threadIdx.x;
  int row = blockIdx.y;
  if (n >= KP2) return;
  int arow = z * BT_ + row;
  if (n >= N_) { atl[(size_t)arow * KP2 + n] = 0; return; }
  const float* base = part + (size_t)z * RKS_ * BT_ * N_;
  float s = 0.f;
  for (int ks = 0; ks < RKS_; ++ks) s += base[((size_t)(ks * BT_ + row)) * N_ + n];
  int statIdx = (z == 0) ? 0 : (z == 1 ? 4 : 2);
  size_t rsOff = (z == 1) ? OFF_RSH : OFF_RSL;
  float mu = ws[OFF_STAT + statIdx], isd = ws[OFF_STAT + statIdx + 1];
  float val = (s - mu * ws[rsOff + row]) * isd;
  ws[OFF_ALIN + (size_t)n * R3_ + arow] = val;
  atl[(size_t)arow * KP2 + n] = f2bf(val);
}

// ---------------------------------------------------------------------------
// Weight transpose: fp32 [K][Nc] -> bf16 [Nc][Kp]; float4 reads, uint2 writes
// ---------------------------------------------------------------------------
__global__ __launch_bounds__(256) void k_wtrans4(
    const float* __restrict__ W0, const float* __restrict__ W1,
    const float* __restrict__ W2, const float* __restrict__ W3,
    unsigned short* __restrict__ T0, unsigned short* __restrict__ T1,
    unsigned short* __restrict__ T2, unsigned short* __restrict__ T3) {
  int bid = blockIdx.x;
  const float* W; unsigned short* Wt; int K, Nc, Kp, rel, NT;
  if (bid < W2_C0)      { W = W0; Wt = T0; K = EA_; Nc = 3 * EA_; Kp = KP3; rel = bid;         NT = W2_QN; }
  else if (bid < W2_C1) { W = W1; Wt = T1; K = EA_; Nc = EA_;     Kp = KP3; rel = bid - W2_C0; NT = W2_AN; }
  else if (bid < W2_C2) { W = W2; Wt = T2; K = EA_; Nc = N_;      Kp = KP3; rel = bid - W2_C1; NT = W2_LN; }
  else                  { W = W3; Wt = T3; K = N_;  Nc = EA_;     Kp = KP2; rel = bid - W2_C2; NT = W2_WN; }
  int kTile = rel / NT, nTile = rel % NT;   // nTile fastest
  int k0 = kTile * 64, n0 = nTile * 64;
  __shared__ float t[64][65];               // t[n_local][k_local]
  int nx = threadIdx.x & 15;                // n-group of 4
  int kk = threadIdx.x >> 4;                // k row base (16)
  bool fullN = (n0 + 64 <= Nc);
#pragma unroll
  for (int i = 0; i < 4; ++i) {
    int kl = kk + 16 * i;
    int k = k0 + kl;
    int n = n0 + 4 * nx;
    float4 v = {0.f, 0.f, 0.f, 0.f};
    if (k < K) {
      if (fullN) {
        v = *(const float4*)(W + (size_t)k * Nc + n);
      } else {
        if (n + 3 < Nc)      v = *(const float4*)(W + (size_t)k * Nc + n);
        else {
          if (n     < Nc) v.x = W[(size_t)k * Nc + n];
          if (n + 1 < Nc) v.y = W[(size_t)k * Nc + n + 1];
          if (n + 2 < Nc) v.z = W[(size_t)k * Nc + n + 2];
          if (n + 3 < Nc) v.w = W[(size_t)k * Nc + n + 3];
        }
      }
    }
    t[4 * nx + 0][kl] = v.x;
    t[4 * nx + 1][kl] = v.y;
    t[4 * nx + 2][kl] = v.z;
    t[4 * nx + 3][kl] = v.w;
  }
  __syncthreads();
  int kq = threadIdx.x & 15;                // k-quad
  int ny = threadIdx.x >> 4;                // n row base (16)
  int k = k0 + 4 * kq;
#pragma unroll
  for (int i = 0; i < 4; ++i) {
    int nl = ny + 16 * i;
    int n = n0 + nl;
    if (n < Nc && k + 3 < Kp) {
      unsigned int w0 = ((unsigned int)f2bf(t[nl][4 * kq + 1]) << 16) | f2bf(t[nl][4 * kq + 0]);
      unsigned int w1 = ((unsigned int)f2bf(t[nl][4 * kq + 3]) << 16) | f2bf(t[nl][4 * kq + 2]);
      uint2 u; u.x = w0; u.y = w1;
      *(uint2*)(Wt + (size_t)n * Kp + k) = u;
    }
  }
}

// ---------------------------------------------------------------------------
// MFMA GEMM: part[ks][144][Nc] = At(bf16 [144][Kp]) @ Bt(bf16 [Nc][Kp])^T
// ---------------------------------------------------------------------------
__global__ __launch_bounds__(256, 4) void k_mfma(
    const unsigned short* __restrict__ At, const unsigned short* __restrict__ Bt,
    float* __restrict__ part, int Nc, int Kp, int stepsTot, int stepChunk) {
  int lane = threadIdx.x & 63;
  int w = threadIdx.x >> 6;
  int lr = lane & 15, lo = lane >> 4;
  int gcol = blockIdx.x * 64 + w * 16 + lr;
  int bcol = min(gcol, Nc - 1);
  int s0 = blockIdx.y * stepChunk;
  int s1 = min(stepsTot, s0 + stepChunk);
  f32x4 acc[9];
#pragma unroll
  for (int mt = 0; mt < 9; ++mt) {
    acc[mt][0] = 0.f; acc[mt][1] = 0.f; acc[mt][2] = 0.f; acc[mt][3] = 0.f;
  }
  const unsigned short* bp = Bt + (size_t)bcol * Kp + (size_t)s0 * 32 + lo * 8;
  const unsigned short* ap = At + (size_t)lr * Kp + (size_t)s0 * 32 + lo * 8;
  for (int s = s0; s < s1; ++s) {
    short8 b = *(const short8*)bp;
#pragma unroll
    for (int mt = 0; mt < 9; ++mt) {
      short8 a = *(const short8*)(ap + (size_t)mt * 16 * Kp);
      acc[mt] = __builtin_amdgcn_mfma_f32_16x16x32_bf16(a, b, acc[mt], 0, 0, 0);
    }
    bp += 32;
    ap += 32;
  }
  if (gcol < Nc) {
#pragma unroll
    for (int mt = 0; mt < 9; ++mt) {
      int row = mt * 16 + lo * 4;
      float* pp = part + ((size_t)blockIdx.y * R3_ + row) * Nc + gcol;
      pp[0] = acc[mt][0];
      pp[(size_t)Nc] = acc[mt][1];
      pp[2 * (size_t)Nc] = acc[mt][2];
      pp[3 * (size_t)Nc] = acc[mt][3];
    }
  }
}

// ---------------------------------------------------------------------------
// Epilogues
// ---------------------------------------------------------------------------
__global__ void k_minmax(const float* __restrict__ alin, float* __restrict__ mmp) {
  int g = blockIdx.y;
  float mn = 3.4e38f, mx = -3.4e38f;
  for (int i = blockIdx.x * 256 + threadIdx.x; i < N_ * BT_; i += 64 * 256) {
    int n = i / BT_, r = i % BT_;
    float v = alin[(size_t)n * R3_ + g * BT_ + r];
    mn = fminf(mn, v); mx = fmaxf(mx, v);
  }
  __shared__ float rn[4], rx[4];
  for (int off = 32; off; off >>= 1) {
    mn = fminf(mn, __shfl_down(mn, off));
    mx = fmaxf(mx, __shfl_down(mx, off));
  }
  if ((threadIdx.x & 63) == 0) { rn[threadIdx.x >> 6] = mn; rx[threadIdx.x >> 6] = mx; }
  __syncthreads();
  if (threadIdx.x == 0) {
    mn = fminf(fminf(rn[0], rn[1]), fminf(rn[2], rn[3]));
    mx = fmaxf(fmaxf(rx[0], rx[1]), fmaxf(rx[2], rx[3]));
    mmp[(size_t)(g * 64 + blockIdx.x) * 2] = mn;
    mmp[(size_t)(g * 64 + blockIdx.x) * 2 + 1] = mx;
  }
}

__global__ void k_minmax2(float* __restrict__ ws) {
  int g = blockIdx.x;
  int i = threadIdx.x;
  float mn = ws[OFF_MMP + (size_t)(g * 64 + i) * 2];
  float mx = ws[OFF_MMP + (size_t)(g * 64 + i) * 2 + 1];
  for (int off = 32; off; off >>= 1) {
    mn = fminf(mn, __shfl_down(mn, off));
    mx = fmaxf(mx, __shfl_down(mx, off));
  }
  if (i == 0) {
    float denom = fmaxf(mx - mn, 1e-8f);
    float a = 1.f / denom;
    ws[OFF_AB + g * 2] = a;
    ws[OFF_AB + g * 2 + 1] = -mn * a;
  }
}

__global__ void k_colsum(const float* __restrict__ ltw, float* __restrict__ csp) {
  int e = blockIdx.x * 256 + threadIdx.x;
  int ks = blockIdx.y;
  if (e >= EA_) return;
  float s = 0.f;
  for (int n = ks * 125; n < (ks + 1) * 125; ++n) s += ltw[(size_t)n * EA_ + e];
  csp[(size_t)ks * EA_ + e] = s;
}
__global__ void k_colsum2(float* __restrict__ ws) {
  int e = blockIdx.x * 256 + threadIdx.x;
  if (e >= EA_) return;
  float s = 0.f;
  for (int ks = 0; ks < 16; ++ks) s += ws[OFF_CSP + (size_t)ks * EA_ + e];
  ws[OFF_CS + e] = s;
}

__global__ void k_epiLin(const float* __restrict__ part, const float* __restrict__ ltb,
                         float* __restrict__ ws, unsigned short* __restrict__ atq,
                         int ksplit) {
  int e = blockIdx.x * 256 + threadIdx.x;
  int row = blockIdx.y;
  if (e >= KP3) return;
  if (e >= EA_) { atq[(size_t)row * KP3 + e] = 0; return; }
  float s = 0.f;
  for (int ks = 0; ks < ksplit; ++ks) s += part[((size_t)(ks * R3_ + row)) * EA_ + e];
  int g = row / BT_;
  float a = ws[OFF_AB + g * 2], bb = ws[OFF_AB + g * 2 + 1];
  float val = fmaf(a, s, fmaf(bb, ws[OFF_CS + e], ltb[e]));
  atq[(size_t)row * KP3 + e] = f2bf(val);
}

__global__ void k_epiQkv(const float* __restrict__ part, const float* __restrict__ qkvb,
                         float* __restrict__ P, int ksplit) {
  int c = blockIdx.x * 256 + threadIdx.x;
  int row = blockIdx.y;
  if (c >= 3 * EA_) return;
  float s = 0.f;
  for (int ks = 0; ks < ksplit; ++ks) s += part[((size_t)(ks * R3_ + row)) * (3 * EA_) + c];
  P[(size_t)row * (3 * EA_) + c] = s + qkvb[c];
}

// attention: waves cover t in parallel (wave-local reductions, one barrier)
__global__ void k_attn(const float* __restrict__ P, unsigned short* __restrict__ atao) {
  int mha = blockIdx.y;
  int s_ = blockIdx.x / (B_ * H_);
  int rem = blockIdx.x % (B_ * H_);
  int b = rem / H_, h = rem % H_;
  const int pq[3] = {0, 1, 2}, pk[3] = {1, 2, 0}, pv[3] = {2, 0, 1};
  const float* qrow = P + ((size_t)(pq[mha] * BT_ + s_ * B_ + b)) * (3 * EA_) + h * HD_;
  __shared__ float sc[T_];
  int w = threadIdx.x >> 6, lane = threadIdx.x & 63;
  for (int t = w; t < T_; t += 4) {
    const float* krow = P + ((size_t)(pk[mha] * BT_ + t * B_ + b)) * (3 * EA_) + EA_ + h * HD_;
    float p = 0.f;
    for (int d = lane; d < HD_; d += 64) p = fmaf(qrow[d], krow[d], p);
    p = waveReduceSum(p);
    if (lane == 0) sc[t] = p * 0.031622776601683794f;
  }
  __syncthreads();
  float a[T_];
  float m = sc[0];
#pragma unroll
  for (int t = 1; t < T_; ++t) m = fmaxf(m, sc[t]);
  float sum = 0.f;
#pragma unroll
  for (int t = 0; t < T_; ++t) { a[t] = expf(sc[t] - m); sum += a[t]; }
  float inv = 1.f / sum;
#pragma unroll
  for (int t = 0; t < T_; ++t) a[t] *= inv;
  int orow = mha * BT_ + s_ * B_ + b;
  for (int d = threadIdx.x; d < HD_; d += 256) {
    float o = 0.f;
#pragma unroll
    for (int t = 0; t < T_; ++t)
      o = fmaf(a[t], P[((size_t)(pv[mha] * BT_ + t * B_ + b)) * (3 * EA_) + 2 * EA_ + h * HD_ + d], o);
    atao[(size_t)orow * KP3 + h * HD_ + d] = f2bf(o);
  }
  if (h == 0 && threadIdx.x < 8) atao[(size_t)orow * KP3 + EA_ + threadIdx.x] = 0;
}

__global__ void k_epiAO(const float* __restrict__ part, const float* __restrict__ aob,
                        unsigned short* __restrict__ atll, int ksplit) {
  int c = blockIdx.x * 256 + threadIdx.x;
  int row = blockIdx.y;
  if (c >= KP3) return;
  if (c >= EA_) { atll[(size_t)row * KP3 + c] = 0; return; }
  float s = 0.f;
  for (int ks = 0; ks < ksplit; ++ks) s += part[((size_t)(ks * R3_ + row)) * EA_ + c];
  atll[(size_t)row * KP3 + c] = f2bf(s + aob[c]);
}

__global__ void k_epiLL(const float* __restrict__ part, const float* __restrict__ llb,
                        float* __restrict__ o2p, int ksplit) {
  int n = blockIdx.x * 256 + threadIdx.x;
  int row = blockIdx.y;  // t*B+b
  if (n >= N_) return;
  float s = 0.f;
  for (int g = 0; g < 3; ++g)
    for (int ks = 0; ks < ksplit; ++ks)
      s += part[((size_t)(ks * R3_ + g * BT_ + row)) * N_ + n];
  int t = row / B_, b = row % B_;
  o2p[(size_t)b * (T_ * N_) + t * N_ + n] = BETA_ * (s + 3.f * llb[n]);
}

__global__ void k_proj(const float* __restrict__ out4, const float* __restrict__ pw,
                       const float* __restrict__ pb, float* __restrict__ outp) {
  int i = blockIdx.x * 256 + threadIdx.x;
  if (i >= BTN_) return;
  int b = i / (T_ * N_);
  int t = (i / N_) % T_;
  int n = i % N_;
  float acc = pb[t];
  for (int t2 = 0; t2 < T_; ++t2) {
    const float* o = out4 + ((size_t)(b * T_ + t2) * N_ + n) * D_;
#pragma unroll
    for (int d = 0; d < D_; ++d) acc = fmaf(o[d], pw[(t2 * D_ + d) * T_ + t], acc);
  }
  outp[i] = acc;
}

__global__ void k_p2(const float* __restrict__ o2p, const float* __restrict__ p2w,
                     const float* __restrict__ p2b, float* __restrict__ o2f) {
  int i = blockIdx.x * 256 + threadIdx.x;
  if (i >= BTN_) return;
  int b = i / (T_ * N_);
  int t = (i / N_) % T_;
  int n = i % N_;
  float acc = p2b[t];
  const float* src = o2p + (size_t)b * (T_ * N_) + (size_t)n * T_;
#pragma unroll
  for (int c = 0; c < T_; ++c) acc = fmaf(src[c], p2w[c * T_ + t], acc);
  o2f[i] = acc;
}

// fused: out3 write + f-normalization -> bf16 padded rows g1b/g2b [8000][32]
__global__ void k_fng(const float* __restrict__ outp, const float* __restrict__ o2f,
                      float* __restrict__ dout, unsigned short* __restrict__ g1b,
                      unsigned short* __restrict__ g2b) {
  int r = blockIdx.x * 256 + threadIdx.x;
  if (r >= B_ * N_) return;
  int b = r / N_, n = r % N_;
  float v1[T_], v2[T_];
  float s1 = 0.f, s2 = 0.f;
#pragma unroll
  for (int t = 0; t < T_; ++t) {
    size_t idx = (size_t)b * T_ * N_ + (size_t)t * N_ + n;
    v1[t] = outp[idx];
    v2[t] = o2f[idx];
    dout[idx] = v1[t] + v2[t];
    s1 = fmaf(v1[t], v1[t], s1);
    s2 = fmaf(v2[t], v2[t], s2);
  }
  float n1 = fmaxf(sqrtf(s1), 1e-12f), n2 = fmaxf(sqrtf(s2), 1e-12f);
  float i1 = 10.f / n1, i2 = 1.f / n2;
  unsigned short q[32], z[32];
#pragma unroll
  for (int t = 0; t < T_; ++t) { q[t] = f2bf(v1[t] * i1); z[t] = f2bf(v2[t] * i2); }
#pragma unroll
  for (int t = T_; t < 32; ++t) { q[t] = 0; z[t] = 0; }
  short8* qd = (short8*)(g1b + (size_t)r * 32);
  short8* zd = (short8*)(g2b + (size_t)r * 32);
#pragma unroll
  for (int c = 0; c < 4; ++c) {
    short8 pv, pz;
#pragma unroll
    for (int e = 0; e < 8; ++e) { pv[e] = (short)q[c * 8 + e]; pz[e] = (short)z[c * 8 + e]; }
    qd[c] = pv;
    zd[c] = pz;
  }
}

// MFMA logsumexp: per block 16 q-rows; 16 j-slices (4 waves x grid.y=4)
__global__ __launch_bounds__(256) void k_lsemf(const unsigned short* __restrict__ g1b,
                                               const unsigned short* __restrict__ g2b,
                                               float* __restrict__ psm,
                                               float* __restrict__ psd) {
  int lane = threadIdx.x & 63, w = threadIdx.x >> 6;
  int lr = lane & 15, lo = lane >> 4;
  int i0 = blockIdx.x * 16;
  int slice = blockIdx.y * 4 + w;     // 0..15
  short8 a = *(const short8*)(g1b + (size_t)(i0 + lr) * 32 + lo * 8);
  float sm[4] = {0.f, 0.f, 0.f, 0.f};
  float sd[4] = {0.f, 0.f, 0.f, 0.f};
  for (int t = slice; t < 500; t += 16) {
    int j0 = t * 16;
    short8 b = *(const short8*)(g2b + (size_t)(j0 + lr) * 32 + lo * 8);
    f32x4 acc = {0.f, 0.f, 0.f, 0.f};
    acc = __builtin_amdgcn_mfma_f32_16x16x32_bf16(a, b, acc, 0, 0, 0);
#pragma unroll
    for (int rg = 0; rg < 4; ++rg) {
      float s = acc[rg];                      // row=i0+lo*4+rg, col=j0+lr
      sm[rg] += __expf(s);
      if (j0 + lr == i0 + lo * 4 + rg) sd[rg] = s;
    }
  }
#pragma unroll
  for (int off = 1; off < 16; off <<= 1) {
#pragma unroll
    for (int rg = 0; rg < 4; ++rg) {
      sm[rg] += __shfl_xor(sm[rg], off);
      sd[rg] += __shfl_xor(sd[rg], off);
    }
  }
  __shared__ float lsm[4][16], lsd[4][16];
  if (lr == 0) {
#pragma unroll
    for (int rg = 0; rg < 4; ++rg) {
      lsm[w][lo * 4 + rg] = sm[rg];
      lsd[w][lo * 4 + rg] = sd[rg];
    }
  }
  __syncthreads();
  if (threadIdx.x < 16) {
    float m = lsm[0][threadIdx.x] + lsm[1][threadIdx.x] + lsm[2][threadIdx.x] + lsm[3][threadIdx.x];
    float d = lsd[0][threadIdx.x] + lsd[1][threadIdx.x] + lsd[2][threadIdx.x] + lsd[3][threadIdx.x];
    psm[(size_t)blockIdx.y * 8000 + i0 + threadIdx.x] = m;
    psd[(size_t)blockIdx.y * 8000 + i0 + threadIdx.x] = d;
  }
}

// fused: combine j-splits + mean + final scalars
__global__ __launch_bounds__(1024) void k_lsefin(const float* __restrict__ psm,
                                                 const float* __restrict__ psd,
                                                 const float* __restrict__ ws,
                                                 float* __restrict__ dout) {
  float acc = 0.f;
  for (int r = threadIdx.x; r < B_ * N_; r += 1024) {
    float sm = psm[r] + psm[8000 + r] + psm[16000 + r] + psm[24000 + r];
    float sd = psd[r] + psd[8000 + r] + psd[16000 + r] + psd[24000 + r];
    acc += sd - logf(sm);
  }
  __shared__ float red[16];
  acc = waveReduceSum(acc);
  if ((threadIdx.x & 63) == 0) red[threadIdx.x >> 6] = acc;
  __syncthreads();
  if (threadIdx.x == 0) {
    float s = 0.f;
    for (int i = 0; i < 16; ++i) s += red[i];
    float closs = -s * (1.f / (B_ * N_));
    dout[BTN_] = ws[OFF_BAL];
    dout[BTN_ + 1] = CW_ * closs;
  }
}

// ---------------------------------------------------------------------------
extern "C" void kernel_launch(void* const* d_in, const int* in_sizes, int n_in,
                              void* d_out, int out_size, void* d_ws, size_t ws_size,
                              hipStream_t stream) {
  const float* x    = (const float*)d_in[0];
  const float* velo = (const float*)d_in[1];
  const float* adj  = (const float*)d_in[2];
  const float* lapd = (const float*)d_in[3];
  const float* laph = (const float*)d_in[4];
  const float* sw   = (const float*)d_in[5];
  const float* sb   = (const float*)d_in[6];
  const float* gw   = (const float*)d_in[7];
  const float* ew1  = (const float*)d_in[8];
  const float* eb1  = (const float*)d_in[9];
  const float* ew2  = (const float*)d_in[10];
  const float* eb2  = (const float*)d_in[11];
  const float* pw   = (const float*)d_in[12];
  const float* pb   = (const float*)d_in[13];
  const float* ltw  = (const float*)d_in[14];
  const float* ltb  = (const float*)d_in[15];
  const float* qkvw = (const float*)d_in[16];
  const float* qkvb = (const float*)d_in[17];
  const float* aow  = (const float*)d_in[18];
  const float* aob  = (const float*)d_in[19];
  const float* llw  = (const float*)d_in[20];
  const float* llb  = (const float*)d_in[21];
  const float* p2w  = (const float*)d_in[22];
  const float* p2b  = (const float*)d_in[23];
  float* ws = (float*)d_ws;
  float* dout = (float*)d_out;
  const float* v0 = velo;  // velo[0,0,:]
  float* part = ws + OFF_PART;
  unsigned short* btQ  = (unsigned short*)(ws + OFF_BT_Q);
  unsigned short* btA  = (unsigned short*)(ws + OFF_BT_A);
  unsigned short* btL  = (unsigned short*)(ws + OFF_BT_L);
  unsigned short* btW  = (unsigned short*)(ws + OFF_BT_W);
  unsigned short* atLin = (unsigned short*)(ws + OFF_AT_LIN);
  unsigned short* atQ   = (unsigned short*)(ws + OFF_AT_Q);
  unsigned short* atAO  = (unsigned short*)(ws + OFF_AT_AO);
  unsigned short* atLL  = (unsigned short*)(ws + OFF_AT_LL);
  unsigned short* g1b   = (unsigned short*)(ws + OFF_G1B);
  unsigned short* g2b   = (unsigned short*)(ws + OFF_G2B);
  dim3 b256(256);

  k_init<<<dim3(1), dim3(64), 0, stream>>>(ws);

  // fused weight transposes to bf16 (vectorized: float4 reads, uint2 writes)
  k_wtrans4<<<dim3(W2_TOT), b256, 0, stream>>>(qkvw, aow, llw, ltw, btQ, btA, btL, btW);

  k_start<<<dim3((BTN_ * D_ + 255) / 256), b256, 0, stream>>>(x, sw, sb, ws + OFF_OUT4);

  for (int l = 0; l < L_; ++l) {
    k_feat<<<dim3(B_ * D_), b256, 0, stream>>>(ws + OFF_OUT4, ws + OFF_FEAT);
    k_gate<<<dim3(1), dim3(64), 0, stream>>>(ws + OFF_FEAT, gw, ws, l);
    k_expert<<<dim3((T_ * N_ + 255) / 256, B_), b256, 0, stream>>>(ws + OFF_OUT4, ew1, eb1, ew2, eb2, ws, l);
  }

  k_wavelet<<<dim3((BTN_ + 255) / 256), b256, 0, stream>>>(x, velo, ws + OFF_LOWT, ws + OFF_HVT);
  k_rowsum<<<dim3(2 * BT_), b256, 0, stream>>>(ws + OFF_LOWT, ws + OFF_HVT, ws);
  k_S<<<dim3(N_), b256, 0, stream>>>(adj, v0, ws + OFF_S);

  // fused stats (lapd, laph, NS) -> partials -> {mu, 1/std} x3
  k_stats3<<<dim3(512, 1, 3), b256, 0, stream>>>(lapd, laph, adj, v0, ws + OFF_S, ws + OFF_STP);
  k_stats2<<<dim3(3), b256, 0, stream>>>(ws + OFF_STP, ws + OFF_STAT);

  // fused r1/r2/r3 GEMMs: 16-row blocks, grid (8, 20, 9) = 1440 blocks
  k_rgemm3<<<dim3(8, RKS_, 9), b256, 0, stream>>>(ws + OFF_LOWT, ws + OFF_HVT, lapd, laph,
                                                  adj, v0, ws + OFF_S, part);
  k_epiR3<<<dim3(8, 48, 3), b256, 0, stream>>>(part, ws, atLin);

  k_minmax<<<dim3(64, 3), b256, 0, stream>>>(ws + OFF_ALIN, ws + OFF_MMP);
  k_minmax2<<<dim3(3), dim3(64), 0, stream>>>(ws);
  k_colsum<<<dim3(12, 16), b256, 0, stream>>>(ltw, ws + OFF_CSP);
  k_colsum2<<<dim3(12), b256, 0, stream>>>(ws);

  // lin (MFMA): 12 splits
  k_mfma<<<dim3(47, 12), b256, 0, stream>>>(atLin, btW, part, EA_, KP2, KP2 / 32, 6);
  k_epiLin<<<dim3(12, 144), b256, 0, stream>>>(part, ltb, ws, atQ, 12);

  // qkv (MFMA): 4 splits
  k_mfma<<<dim3(141, 4), b256, 0, stream>>>(atQ, btQ, part, 3 * EA_, KP3, KP3 / 32, 24);
  k_epiQkv<<<dim3(36, 144), b256, 0, stream>>>(part, qkvb, ws + OFF_P, 4);

  // attention
  k_attn<<<dim3(T_ * B_ * H_, 3), b256, 0, stream>>>(ws + OFF_P, atAO);

  // attn-out (MFMA): 12 splits
  k_mfma<<<dim3(47, 12), b256, 0, stream>>>(atAO, btA, part, EA_, KP3, KP3 / 32, 8);
  k_epiAO<<<dim3(12, 144), b256, 0, stream>>>(part, aob, atLL, 12);

  // ll (MFMA): 16 splits
  k_mfma<<<dim3(32, 16), b256, 0, stream>>>(atLL, btL, part, N_, KP3, KP3 / 32, 6);
  k_epiLL<<<dim3(8, 48), b256, 0, stream>>>(part, llb, ws + OFF_O2P, 16);

  k_proj<<<dim3((BTN_ + 255) / 256), b256, 0, stream>>>(ws + OFF_OUT4, pw, pb, ws + OFF_OUTP);
  k_p2<<<dim3((BTN_ + 255) / 256), b256, 0, stream>>>(ws + OFF_O2P, p2w, p2b, ws + OFF_O2F);

  // fused out3 + fnorm (writes dout body + bf16 g1b/g2b)
  k_fng<<<dim3((B_ * N_ + 255) / 256), b256, 0, stream>>>(ws + OFF_OUTP, ws + OFF_O2F, dout, g1b, g2b);

  // MFMA logsumexp; psm/psd partials live in `part`
  k_lsemf<<<dim3(500, 4), b256, 0, stream>>>(g1b, g2b, part, part + 32000);
  k_lsefin<<<dim3(1), dim3(1024), 0, stream>>>(part, part + 32000, ws, dout);
}

// Round 14
// 555.542 us; speedup vs baseline: 1.8883x; 1.0563x over previous
//
#include <hip/hip_runtime.h>
#include <math.h>

// ---------------------------------------------------------------------------
// Model constants
// ---------------------------------------------------------------------------
namespace {
constexpr int B_ = 4, T_ = 12, N_ = 2000, D_ = 16, FF_ = 64, E_ = 4, L_ = 2;
constexpr int EA_ = 3000, H_ = 3, HD_ = EA_ / H_;   // 1000
constexpr int BT_ = B_ * T_;                         // 48
constexpr int R3_ = 3 * BT_;                         // 144
constexpr long long NN_ = (long long)N_ * N_;        // 4,000,000
constexpr int BTN_ = B_ * T_ * N_;                   // 96,000
constexpr float BETA_ = 0.01f, CW_ = 0.001f;
constexpr int RKS_ = 20;                             // r-GEMM split-K (fused x3)
constexpr int RKC_ = 100;                            // r-GEMM k-chunk
constexpr int KP3 = 3008;                            // K=3000 padded to 32
constexpr int KP2 = 2016;                            // K=2000 padded to 32

// ---------------------------------------------------------------------------
// Workspace layout (float offsets)
// ---------------------------------------------------------------------------
constexpr size_t OFF_OUT4 = 0;                                   // [B,T,N,D]
constexpr size_t OFF_LOWT = OFF_OUT4 + (size_t)BTN_ * D_;        // lowT^T [N][48]
constexpr size_t OFF_HVT  = OFF_LOWT + BTN_;                     // highV^T [N][48]
constexpr size_t OFF_ALIN = OFF_HVT + BTN_;                      // r^T [N][144]
constexpr size_t OFF_RT   = OFF_ALIN + (size_t)N_ * R3_;         // (unused, kept)
constexpr size_t OFF_P    = OFF_RT + (size_t)EA_ * R3_;          // P [144][9000]
constexpr size_t OFF_AOT  = OFF_P + (size_t)R3_ * 3 * EA_;       // (unused, kept)
constexpr size_t OFF_OT   = OFF_AOT + (size_t)EA_ * R3_;         // (unused, kept)
constexpr size_t OFF_O2P  = OFF_OT + (size_t)EA_ * R3_;          // out2 pre-p2 [B][T*N]
constexpr size_t OFF_OUTP = OFF_O2P + BTN_;                      // outp [B,T,N]
constexpr size_t OFF_O2F  = OFF_OUTP + BTN_;                     // out2 final [B,T,N]
constexpr size_t OFF_LI   = OFF_O2F + BTN_;                      // (spare)
constexpr size_t OFF_S    = OFF_LI + 8000;                       // G row sums [2000]
constexpr size_t OFF_RSL  = OFF_S + 2000;
constexpr size_t OFF_RSH  = OFF_RSL + 48;
constexpr size_t OFF_STP  = OFF_RSH + 48;
constexpr size_t OFF_STAT = OFF_STP + 3072;
constexpr size_t OFF_MMP  = OFF_STAT + 8;
constexpr size_t OFF_AB   = OFF_MMP + 384;
constexpr size_t OFF_CSP  = OFF_AB + 8;
constexpr size_t OFF_CS   = OFF_CSP + 48000;
constexpr size_t OFF_FEAT = OFF_CS + 3000;
constexpr size_t OFF_GATE = OFF_FEAT + 64;
constexpr size_t OFF_BAL  = OFF_GATE + 16;
constexpr size_t OFF_PART = ((OFF_BAL + 1 + 255) & ~(size_t)255); // split-K partials
constexpr size_t PARTCAP  = 6000000;                              // cap (floats)
// bf16 A-operand regions (sizes in floats = ushorts/2)
constexpr size_t OFF_AT_LIN= OFF_PART + PARTCAP;                  // ALIN^T  [144][KP2]
constexpr size_t OFF_AT_Q  = OFF_AT_LIN + (size_t)R3_ * KP2 / 2;  // RT^T    [144][KP3]
constexpr size_t OFF_AT_AO = OFF_AT_Q + (size_t)R3_ * KP3 / 2;    // Ao      [144][KP3]
constexpr size_t OFF_AT_LL = OFF_AT_AO + (size_t)R3_ * KP3 / 2;   // O       [144][KP3]
constexpr size_t OFF_G1B   = OFF_AT_LL + (size_t)R3_ * KP3 / 2;   // f1 bf16 [8000][32]
constexpr size_t OFF_G2B   = OFF_G1B + 128000;                    // f2 bf16 [8000][32]
} // namespace

typedef __attribute__((ext_vector_type(8))) short short8;
typedef __attribute__((ext_vector_type(4))) float f32x4;

// ---------------------------------------------------------------------------
// Helpers
// ---------------------------------------------------------------------------
__device__ __forceinline__ float waveReduceSum(float v) {
  for (int off = 32; off; off >>= 1) v += __shfl_down(v, off);
  return v;
}

__device__ __forceinline__ unsigned short f2bf(float x) {  // RNE fp32->bf16
  unsigned int u = __float_as_uint(x);
  unsigned int r = (u + 0x7FFFu + ((u >> 16) & 1u)) >> 16;
  return (unsigned short)r;
}

__device__ __forceinline__ void fma16(float* __restrict__ acc,
                                      const float4* __restrict__ a4, float bv) {
#pragma unroll
  for (int r4 = 0; r4 < 4; ++r4) {
    float4 av = a4[r4];
    acc[r4 * 4 + 0] = fmaf(av.x, bv, acc[r4 * 4 + 0]);
    acc[r4 * 4 + 1] = fmaf(av.y, bv, acc[r4 * 4 + 1]);
    acc[r4 * 4 + 2] = fmaf(av.z, bv, acc[r4 * 4 + 2]);
    acc[r4 * 4 + 3] = fmaf(av.w, bv, acc[r4 * 4 + 3]);
  }
}

// ---------------------------------------------------------------------------
__global__ void k_init(float* ws) {
  if (threadIdx.x == 0) ws[OFF_BAL] = 0.f;
}

__global__ void k_start(const float* __restrict__ x, const float* __restrict__ sw,
                        const float* __restrict__ sb, float* __restrict__ out4) {
  int i = blockIdx.x * 256 + threadIdx.x;
  if (i >= BTN_ * D_) return;
  int d = i & 15;
  out4[i] = fmaf(x[i >> 4], sw[d], sb[d]);
}

__global__ void k_feat(const float* __restrict__ out4, float* __restrict__ feat) {
  int b = blockIdx.x >> 4, d = blockIdx.x & 15;
  float s = 0.f;
  for (int tn = threadIdx.x; tn < T_ * N_; tn += 256)
    s += out4[((size_t)b * T_ * N_ + tn) * D_ + d];
  __shared__ float red[4];
  s = waveReduceSum(s);
  if ((threadIdx.x & 63) == 0) red[threadIdx.x >> 6] = s;
  __syncthreads();
  if (threadIdx.x == 0)
    feat[blockIdx.x] = (red[0] + red[1] + red[2] + red[3]) * (1.f / (T_ * N_));
}

__global__ void k_gate(const float* __restrict__ feat, const float* __restrict__ gw,
                       float* __restrict__ ws, int l) {
  __shared__ float lg[B_ * E_];
  int tid = threadIdx.x;
  if (tid < B_ * E_) {
    int b = tid >> 2, e = tid & 3;
    float s = 0.f;
    for (int d = 0; d < D_; ++d) s = fmaf(feat[b * D_ + d], gw[(l * D_ + d) * E_ + e], s);
    lg[tid] = s;
  }
  __syncthreads();
  if (tid == 0) {
    float* gates = ws + OFF_GATE;
    float imp[E_] = {0, 0, 0, 0}, load[E_] = {0, 0, 0, 0};
    for (int i = 0; i < B_ * E_; ++i) gates[i] = 0.f;
    for (int b = 0; b < B_; ++b) {
      const float* lb = lg + b * E_;
      int i1 = 0; float v1 = lb[0];
      for (int e = 1; e < E_; ++e) if (lb[e] > v1) { v1 = lb[e]; i1 = e; }
      int i2 = -1; float v2 = -1e30f;
      for (int e = 0; e < E_; ++e) { if (e == i1) continue; if (lb[e] > v2) { v2 = lb[e]; i2 = e; } }
      float e2 = expf(v2 - v1);
      float den = 1.f + e2;
      float g1 = 1.f / den, g2 = e2 / den;
      gates[b * E_ + i1] = g1; gates[b * E_ + i2] = g2;
      imp[i1] += g1; imp[i2] += g2; load[i1] += 1.f; load[i2] += 1.f;
    }
    float bal = 0.f;
    float m = 0.f; for (int e = 0; e < E_; ++e) m += imp[e]; m *= 0.25f;
    float v = 0.f; for (int e = 0; e < E_; ++e) { float d = imp[e] - m; v += d * d; } v *= 0.25f;
    bal += v / (m * m + 1e-10f);
    m = 0.f; for (int e = 0; e < E_; ++e) m += load[e]; m *= 0.25f;
    v = 0.f; for (int e = 0; e < E_; ++e) { float d = load[e] - m; v += d * d; } v *= 0.25f;
    bal += v / (m * m + 1e-10f);
    ws[OFF_BAL] += bal;
  }
}

// MoE expert apply; gelu via sigmoid identity
__global__ void k_expert(float* __restrict__ out4, const float* __restrict__ w1,
                         const float* __restrict__ b1, const float* __restrict__ w2,
                         const float* __restrict__ b2, const float* __restrict__ ws, int l) {
  int b = blockIdx.y;
  int tn = blockIdx.x * 256 + threadIdx.x;
  if (tn >= T_ * N_) return;
  float* row = out4 + ((size_t)b * T_ * N_ + tn) * D_;
  float r[D_], acc[D_];
#pragma unroll
  for (int d = 0; d < D_; ++d) { r[d] = row[d]; acc[d] = r[d]; }
  const float* gates = ws + OFF_GATE;
  for (int e = 0; e < E_; ++e) {
    float g = gates[b * E_ + e];
    if (g <= 0.f) continue;
    const float* W1 = w1 + (size_t)(l * E_ + e) * D_ * FF_;
    const float* B1 = b1 + (size_t)(l * E_ + e) * FF_;
    const float* W2 = w2 + (size_t)(l * E_ + e) * FF_ * D_;
    const float* B2 = b2 + (size_t)(l * E_ + e) * D_;
#pragma unroll 4
    for (int f = 0; f < FF_; ++f) {
      float p = B1[f];
#pragma unroll
      for (int d = 0; d < D_; ++d) p = fmaf(r[d], W1[d * FF_ + f], p);
      float c2 = 1.5957691216057308f * (p + 0.044715f * p * p * p);
      float e1 = __expf(-c2);
      float hv = p * __builtin_amdgcn_rcpf(1.f + e1);
      float gh = g * hv;
#pragma unroll
      for (int d = 0; d < D_; ++d) acc[d] = fmaf(gh, W2[f * D_ + d], acc[d]);
    }
#pragma unroll
    for (int d = 0; d < D_; ++d) acc[d] = fmaf(g, B2[d], acc[d]);
  }
#pragma unroll
  for (int d = 0; d < D_; ++d) row[d] = acc[d];
}

__global__ void k_wavelet(const float* __restrict__ x, const float* __restrict__ velo,
                          float* __restrict__ lowT, float* __restrict__ hvT) {
  int i = blockIdx.x * 256 + threadIdx.x;
  if (i >= BTN_) return;
  int b = i / (T_ * N_);
  int t = (i / N_) % T_;
  int n = i % N_;
  int ip = b * T_ * N_ + ((t + T_ - 1) % T_) * N_ + n;
  int row = t * B_ + b;
  lowT[(size_t)n * BT_ + row] = 0.5f * (x[i] + x[ip]);
  hvT[(size_t)n * BT_ + row] = 0.5f * (velo[i] - velo[ip]);
}

__global__ void k_rowsum(const float* __restrict__ lowT, const float* __restrict__ hvT,
                         float* __restrict__ ws) {
  int which = blockIdx.x / BT_;
  int row = blockIdx.x % BT_;
  const float* M = which ? hvT : lowT;
  float s = 0.f;
  for (int n = threadIdx.x; n < N_; n += 256) s += M[(size_t)n * BT_ + row];
  __shared__ float red[4];
  s = waveReduceSum(s);
  if ((threadIdx.x & 63) == 0) red[threadIdx.x >> 6] = s;
  __syncthreads();
  if (threadIdx.x == 0) ws[(which ? OFF_RSH : OFF_RSL) + row] = red[0] + red[1] + red[2] + red[3];
}

__global__ void k_S(const float* __restrict__ adj, const float* __restrict__ v0,
                    float* __restrict__ S) {
  int m = blockIdx.x;
  float vm = v0[m];
  const float* a = adj + (size_t)m * N_;
  float s = 0.f;
  for (int n = threadIdx.x; n < N_; n += 256) s += vm / a[n];
  __shared__ float red[4];
  s = waveReduceSum(s);
  if ((threadIdx.x & 63) == 0) red[threadIdx.x >> 6] = s;
  __syncthreads();
  if (threadIdx.x == 0) S[m] = red[0] + red[1] + red[2] + red[3];
}

// fused: sum/sumsq of lapd (z=0), laph (z=1), NS laplacian (z=2)
__global__ void k_stats3(const float* __restrict__ lapd, const float* __restrict__ laph,
                         const float* __restrict__ adj, const float* __restrict__ v0,
                         const float* __restrict__ S, float* __restrict__ stp) {
  int z = blockIdx.z;
  float s = 0.f, ss = 0.f;
  if (z < 2) {
    const float* M = z ? laph : lapd;
    for (long long i = blockIdx.x * 256 + threadIdx.x; i < NN_; i += 512 * 256) {
      float v = M[i];
      s += v; ss = fmaf(v, v, ss);
    }
  } else {
    for (long long i = blockIdx.x * 256 + threadIdx.x; i < NN_; i += 512 * 256) {
      int m = (int)(i / N_), n = (int)(i % N_);
      float e = -(v0[m] / adj[i]);
      if (m == n) e += S[m];
      s += e; ss = fmaf(e, e, ss);
    }
  }
  __shared__ float r1[4], r2[4];
  for (int off = 32; off; off >>= 1) { s += __shfl_down(s, off); ss += __shfl_down(ss, off); }
  if ((threadIdx.x & 63) == 0) { r1[threadIdx.x >> 6] = s; r2[threadIdx.x >> 6] = ss; }
  __syncthreads();
  if (threadIdx.x == 0) {
    float* p = stp + (size_t)z * 1024;
    p[blockIdx.x * 2] = r1[0] + r1[1] + r1[2] + r1[3];
    p[blockIdx.x * 2 + 1] = r2[0] + r2[1] + r2[2] + r2[3];
  }
}

__global__ void k_stats2(const float* __restrict__ stp, float* __restrict__ stat) {
  int z = blockIdx.x;
  const float* part = stp + (size_t)z * 1024;
  float s = 0.f, ss = 0.f;
  for (int i = threadIdx.x; i < 512; i += 256) { s += part[i * 2]; ss += part[i * 2 + 1]; }
  __shared__ float r1[4], r2[4];
  for (int off = 32; off; off >>= 1) { s += __shfl_down(s, off); ss += __shfl_down(ss, off); }
  if ((threadIdx.x & 63) == 0) { r1[threadIdx.x >> 6] = s; r2[threadIdx.x >> 6] = ss; }
  __syncthreads();
  if (threadIdx.x == 0) {
    float su = r1[0] + r1[1] + r1[2] + r1[3];
    float sq = r2[0] + r2[1] + r2[2] + r2[3];
    float mu = su * (1.f / (float)NN_);
    float var = sq * (1.f / (float)NN_) - mu * mu;
    stat[2 * z] = mu;
    stat[2 * z + 1] = 1.f / sqrtf(var);
  }
}

// ---------------------------------------------------------------------------
// Fused r-GEMMs, 16-row accumulators: blockIdx.z = z*3 + rg. Grid (8, RKS_, 9).
// ---------------------------------------------------------------------------
__global__ __launch_bounds__(256) void k_rgemm3(
    const float* __restrict__ lowT, const float* __restrict__ hvT,
    const float* __restrict__ lapd, const float* __restrict__ laph,
    const float* __restrict__ adj, const float* __restrict__ v0,
    const float* __restrict__ S, float* __restrict__ part) {
  int zz = blockIdx.z;
  int z = zz / 3, rg = zz % 3;
  int col = blockIdx.x * 256 + threadIdx.x;
  int m0 = blockIdx.y * RKC_;
  int m1 = min(N_, m0 + RKC_);
  float acc[16];
#pragma unroll
  for (int r = 0; r < 16; ++r) acc[r] = 0.f;
  if (col < N_) {
    const float* Abase = (z == 1 ? hvT : lowT);
    const float* ap = Abase + (size_t)m0 * BT_ + rg * 16;
    if (z != 1) {
      const float* Bm = z ? laph : lapd;
      const float* bp = Bm + (size_t)m0 * N_ + col;
      int len = m1 - m0;
      int ng = len >> 3;
      float bc[8];
      if (ng > 0) {
#pragma unroll
        for (int u = 0; u < 8; ++u) bc[u] = bp[(size_t)u * N_];
      }
      for (int gi = 0; gi < ng; ++gi) {
        float bn[8];
        bool more = (gi + 1 < ng);
        if (more) {
#pragma unroll
          for (int u = 0; u < 8; ++u) bn[u] = bp[(size_t)(8 + u) * N_];
        }
#pragma unroll
        for (int u = 0; u < 8; ++u)
          fma16(acc, (const float4*)(ap + (size_t)u * BT_), bc[u]);
        ap += (size_t)8 * BT_;
        bp += (size_t)8 * N_;
        if (more) {
#pragma unroll
          for (int u = 0; u < 8; ++u) bc[u] = bn[u];
        }
      }
      for (int m = m0 + (ng << 3); m < m1; ++m) {
        fma16(acc, (const float4*)ap, *bp);
        ap += BT_;
        bp += N_;
      }
    } else {
      const float* jp = adj + (size_t)m0 * N_ + col;
      int len = m1 - m0;
      int ng = len >> 3;
      float jc[8];
      if (ng > 0) {
#pragma unroll
        for (int u = 0; u < 8; ++u) jc[u] = jp[(size_t)u * N_];
      }
      int m = m0;
      for (int gi = 0; gi < ng; ++gi) {
        float jn[8];
        bool more = (gi + 1 < ng);
        if (more) {
#pragma unroll
          for (int u = 0; u < 8; ++u) jn[u] = jp[(size_t)(8 + u) * N_];
        }
#pragma unroll
        for (int u = 0; u < 8; ++u) {
          float bv = -(v0[m + u] / jc[u]);
          if (m + u == col) bv += S[m + u];
          fma16(acc, (const float4*)(ap + (size_t)u * BT_), bv);
        }
        m += 8;
        ap += (size_t)8 * BT_;
        jp += (size_t)8 * N_;
        if (more) {
#pragma unroll
          for (int u = 0; u < 8; ++u) jc[u] = jn[u];
        }
      }
      for (; m < m1; ++m) {
        float bv = -(v0[m] / (*jp));
        if (m == col) bv += S[m];
        fma16(acc, (const float4*)ap, bv);
        ap += BT_;
        jp += N_;
      }
    }
    float* pp = part + (((size_t)z * RKS_ + blockIdx.y) * BT_ + rg * 16) * N_ + col;
#pragma unroll
    for (int r = 0; r < 16; ++r) pp[(size_t)r * N_] = acc[r];
  }
}

// fused r epilogue -> ALIN + At_lin bf16
__global__ void k_epiR3(const float* __restrict__ part, float* __restrict__ ws,
                        unsigned short* __restrict__ atl) {
  int z = blockIdx.z;
  int n = blockIdx.x * 256 + threadIdx.x;
  int row = blockIdx.y;
  if (n >= KP2) return;
  int arow = z * BT_ + row;
  if (n >= N_) { atl[(size_t)arow * KP2 + n] = 0; return; }
  const float* base = part + (size_t)z * RKS_ * BT_ * N_;
  float s = 0.f;
  for (int ks = 0; ks < RKS_; ++ks) s += base[((size_t)(ks * BT_ + row)) * N_ + n];
  int statIdx = (z == 0) ? 0 : (z == 1 ? 4 : 2);
  size_t rsOff = (z == 1) ? OFF_RSH : OFF_RSL;
  float mu = ws[OFF_STAT + statIdx], isd = ws[OFF_STAT + statIdx + 1];
  float val = (s - mu * ws[rsOff + row]) * isd;
  ws[OFF_ALIN + (size_t)n * R3_ + arow] = val;
  atl[(size_t)arow * KP2 + n] = f2bf(val);
}

// ---------------------------------------------------------------------------
// MFMA GEMM with fused B-transpose+bf16 conversion from original fp32 W[K][Nc].
// Per step: stage 32k x 64col tile (coalesced float4 reads) -> bf16-packed LDS
// (double-buffered) -> lane b-fragments via conflict-free LDS reads.
// part[ks][144][Nc]. A = bf16 [144][Kp] (k-contiguous).
// ---------------------------------------------------------------------------
__global__ __launch_bounds__(256) void k_mfmaW(
    const unsigned short* __restrict__ At, const float* __restrict__ W,
    float* __restrict__ part, int Nc, int Kp, int K, int stepChunk) {
  __shared__ unsigned int lds[2][64][21];
  int tid = threadIdx.x;
  int lane = tid & 63, w = tid >> 6;
  int lr = lane & 15, lo = lane >> 4;
  int colBase = blockIdx.x * 64;
  int gcol = colBase + w * 16 + lr;
  int stepsTot = Kp / 32;
  int s0 = blockIdx.y * stepChunk;
  int s1 = min(stepsTot, s0 + stepChunk);
  // staging role: kr2 = k-pair index (0..15), cg*4 = col group
  int cg = tid & 15, kr2 = tid >> 4;
  int c0l = 4 * cg;                      // local col 0..60
  bool fullC = (colBase + 64 <= Nc);

  f32x4 acc[9];
#pragma unroll
  for (int mt = 0; mt < 9; ++mt) {
    acc[mt][0] = 0.f; acc[mt][1] = 0.f; acc[mt][2] = 0.f; acc[mt][3] = 0.f;
  }

  auto stage = [&](int s, int buf) {
    int kA = s * 32 + 2 * kr2;
    int kB = kA + 1;
    float4 r0 = {0.f, 0.f, 0.f, 0.f}, r1 = {0.f, 0.f, 0.f, 0.f};
    int c0 = colBase + c0l;
    if (fullC) {
      if (kA < K) r0 = *(const float4*)(W + (size_t)kA * Nc + c0);
      if (kB < K) r1 = *(const float4*)(W + (size_t)kB * Nc + c0);
    } else {
      float rr0[4] = {0.f, 0.f, 0.f, 0.f}, rr1[4] = {0.f, 0.f, 0.f, 0.f};
#pragma unroll
      for (int e = 0; e < 4; ++e) {
        if (c0 + e < Nc) {
          if (kA < K) rr0[e] = W[(size_t)kA * Nc + c0 + e];
          if (kB < K) rr1[e] = W[(size_t)kB * Nc + c0 + e];
        }
      }
      r0.x = rr0[0]; r0.y = rr0[1]; r0.z = rr0[2]; r0.w = rr0[3];
      r1.x = rr1[0]; r1.y = rr1[1]; r1.z = rr1[2]; r1.w = rr1[3];
    }
    lds[buf][c0l + 0][kr2] = ((unsigned int)f2bf(r1.x) << 16) | f2bf(r0.x);
    lds[buf][c0l + 1][kr2] = ((unsigned int)f2bf(r1.y) << 16) | f2bf(r0.y);
    lds[buf][c0l + 2][kr2] = ((unsigned int)f2bf(r1.z) << 16) | f2bf(r0.z);
    lds[buf][c0l + 3][kr2] = ((unsigned int)f2bf(r1.w) << 16) | f2bf(r0.w);
  };

  if (s0 < s1) stage(s0, 0);
  __syncthreads();

  const unsigned short* ap = At + (size_t)lr * Kp + (size_t)s0 * 32 + lo * 8;
  int lcol = w * 16 + lr;
  for (int s = s0; s < s1; ++s) {
    int buf = (s - s0) & 1;
    union { unsigned int u[4]; short8 s8; } bu;
#pragma unroll
    for (int j = 0; j < 4; ++j) bu.u[j] = lds[buf][lcol][lo * 4 + j];
    short8 b = bu.s8;
#pragma unroll
    for (int mt = 0; mt < 9; ++mt) {
      short8 a = *(const short8*)(ap + (size_t)mt * 16 * Kp);
      acc[mt] = __builtin_amdgcn_mfma_f32_16x16x32_bf16(a, b, acc[mt], 0, 0, 0);
    }
    if (s + 1 < s1) stage(s + 1, buf ^ 1);
    __syncthreads();
    ap += 32;
  }

  if (gcol < Nc) {
#pragma unroll
    for (int mt = 0; mt < 9; ++mt) {
      int row = mt * 16 + lo * 4;
      float* pp = part + ((size_t)blockIdx.y * R3_ + row) * Nc + gcol;
      pp[0] = acc[mt][0];
      pp[(size_t)Nc] = acc[mt][1];
      pp[2 * (size_t)Nc] = acc[mt][2];
      pp[3 * (size_t)Nc] = acc[mt][3];
    }
  }
}

// ---------------------------------------------------------------------------
// Epilogues
// ---------------------------------------------------------------------------
__global__ void k_minmax(const float* __restrict__ alin, float* __restrict__ mmp) {
  int g = blockIdx.y;
  float mn = 3.4e38f, mx = -3.4e38f;
  for (int i = blockIdx.x * 256 + threadIdx.x; i < N_ * BT_; i += 64 * 256) {
    int n = i / BT_, r = i % BT_;
    float v = alin[(size_t)n * R3_ + g * BT_ + r];
    mn = fminf(mn, v); mx = fmaxf(mx, v);
  }
  __shared__ float rn[4], rx[4];
  for (int off = 32; off; off >>= 1) {
    mn = fminf(mn, __shfl_down(mn, off));
    mx = fmaxf(mx, __shfl_down(mx, off));
  }
  if ((threadIdx.x & 63) == 0) { rn[threadIdx.x >> 6] = mn; rx[threadIdx.x >> 6] = mx; }
  __syncthreads();
  if (threadIdx.x == 0) {
    mn = fminf(fminf(rn[0], rn[1]), fminf(rn[2], rn[3]));
    mx = fmaxf(fmaxf(rx[0], rx[1]), fmaxf(rx[2], rx[3]));
    mmp[(size_t)(g * 64 + blockIdx.x) * 2] = mn;
    mmp[(size_t)(g * 64 + blockIdx.x) * 2 + 1] = mx;
  }
}

__global__ void k_minmax2(float* __restrict__ ws) {
  int g = blockIdx.x;
  int i = threadIdx.x;
  float mn = ws[OFF_MMP + (size_t)(g * 64 + i) * 2];
  float mx = ws[OFF_MMP + (size_t)(g * 64 + i) * 2 + 1];
  for (int off = 32; off; off >>= 1) {
    mn = fminf(mn, __shfl_down(mn, off));
    mx = fmaxf(mx, __shfl_down(mx, off));
  }
  if (i == 0) {
    float denom = fmaxf(mx - mn, 1e-8f);
    float a = 1.f / denom;
    ws[OFF_AB + g * 2] = a;
    ws[OFF_AB + g * 2 + 1] = -mn * a;
  }
}

__global__ void k_colsum(const float* __restrict__ ltw, float* __restrict__ csp) {
  int e = blockIdx.x * 256 + threadIdx.x;
  int ks = blockIdx.y;
  if (e >= EA_) return;
  float s = 0.f;
  for (int n = ks * 125; n < (ks + 1) * 125; ++n) s += ltw[(size_t)n * EA_ + e];
  csp[(size_t)ks * EA_ + e] = s;
}
__global__ void k_colsum2(float* __restrict__ ws) {
  int e = blockIdx.x * 256 + threadIdx.x;
  if (e >= EA_) return;
  float s = 0.f;
  for (int ks = 0; ks < 16; ++ks) s += ws[OFF_CSP + (size_t)ks * EA_ + e];
  ws[OFF_CS + e] = s;
}

__global__ void k_epiLin(const float* __restrict__ part, const float* __restrict__ ltb,
                         float* __restrict__ ws, unsigned short* __restrict__ atq,
                         int ksplit) {
  int e = blockIdx.x * 256 + threadIdx.x;
  int row = blockIdx.y;
  if (e >= KP3) return;
  if (e >= EA_) { atq[(size_t)row * KP3 + e] = 0; return; }
  float s = 0.f;
  for (int ks = 0; ks < ksplit; ++ks) s += part[((size_t)(ks * R3_ + row)) * EA_ + e];
  int g = row / BT_;
  float a = ws[OFF_AB + g * 2], bb = ws[OFF_AB + g * 2 + 1];
  float val = fmaf(a, s, fmaf(bb, ws[OFF_CS + e], ltb[e]));
  atq[(size_t)row * KP3 + e] = f2bf(val);
}

__global__ void k_epiQkv(const float* __restrict__ part, const float* __restrict__ qkvb,
                         float* __restrict__ P, int ksplit) {
  int c = blockIdx.x * 256 + threadIdx.x;
  int row = blockIdx.y;
  if (c >= 3 * EA_) return;
  float s = 0.f;
  for (int ks = 0; ks < ksplit; ++ks) s += part[((size_t)(ks * R3_ + row)) * (3 * EA_) + c];
  P[(size_t)row * (3 * EA_) + c] = s + qkvb[c];
}

// attention: waves cover t in parallel (wave-local reductions, one barrier)
__global__ void k_attn(const float* __restrict__ P, unsigned short* __restrict__ atao) {
  int mha = blockIdx.y;
  int s_ = blockIdx.x / (B_ * H_);
  int rem = blockIdx.x % (B_ * H_);
  int b = rem / H_, h = rem % H_;
  const int pq[3] = {0, 1, 2}, pk[3] = {1, 2, 0}, pv[3] = {2, 0, 1};
  const float* qrow = P + ((size_t)(pq[mha] * BT_ + s_ * B_ + b)) * (3 * EA_) + h * HD_;
  __shared__ float sc[T_];
  int w = threadIdx.x >> 6, lane = threadIdx.x & 63;
  for (int t = w; t < T_; t += 4) {
    const float* krow = P + ((size_t)(pk[mha] * BT_ + t * B_ + b)) * (3 * EA_) + EA_ + h * HD_;
    float p = 0.f;
    for (int d = lane; d < HD_; d += 64) p = fmaf(qrow[d], krow[d], p);
    p = waveReduceSum(p);
    if (lane == 0) sc[t] = p * 0.031622776601683794f;
  }
  __syncthreads();
  float a[T_];
  float m = sc[0];
#pragma unroll
  for (int t = 1; t < T_; ++t) m = fmaxf(m, sc[t]);
  float sum = 0.f;
#pragma unroll
  for (int t = 0; t < T_; ++t) { a[t] = expf(sc[t] - m); sum += a[t]; }
  float inv = 1.f / sum;
#pragma unroll
  for (int t = 0; t < T_; ++t) a[t] *= inv;
  int orow = mha * BT_ + s_ * B_ + b;
  for (int d = threadIdx.x; d < HD_; d += 256) {
    float o = 0.f;
#pragma unroll
    for (int t = 0; t < T_; ++t)
      o = fmaf(a[t], P[((size_t)(pv[mha] * BT_ + t * B_ + b)) * (3 * EA_) + 2 * EA_ + h * HD_ + d], o);
    atao[(size_t)orow * KP3 + h * HD_ + d] = f2bf(o);
  }
  if (h == 0 && threadIdx.x < 8) atao[(size_t)orow * KP3 + EA_ + threadIdx.x] = 0;
}

__global__ void k_epiAO(const float* __restrict__ part, const float* __restrict__ aob,
                        unsigned short* __restrict__ atll, int ksplit) {
  int c = blockIdx.x * 256 + threadIdx.x;
  int row = blockIdx.y;
  if (c >= KP3) return;
  if (c >= EA_) { atll[(size_t)row * KP3 + c] = 0; return; }
  float s = 0.f;
  for (int ks = 0; ks < ksplit; ++ks) s += part[((size_t)(ks * R3_ + row)) * EA_ + c];
  atll[(size_t)row * KP3 + c] = f2bf(s + aob[c]);
}

__global__ void k_epiLL(const float* __restrict__ part, const float* __restrict__ llb,
                        float* __restrict__ o2p, int ksplit) {
  int n = blockIdx.x * 256 + threadIdx.x;
  int row = blockIdx.y;  // t*B+b
  if (n >= N_) return;
  float s = 0.f;
  for (int g = 0; g < 3; ++g)
    for (int ks = 0; ks < ksplit; ++ks)
      s += part[((size_t)(ks * R3_ + g * BT_ + row)) * N_ + n];
  int t = row / B_, b = row % B_;
  o2p[(size_t)b * (T_ * N_) + t * N_ + n] = BETA_ * (s + 3.f * llb[n]);
}

__global__ void k_proj(const float* __restrict__ out4, const float* __restrict__ pw,
                       const float* __restrict__ pb, float* __restrict__ outp) {
  int i = blockIdx.x * 256 + threadIdx.x;
  if (i >= BTN_) return;
  int b = i / (T_ * N_);
  int t = (i / N_) % T_;
  int n = i % N_;
  float acc = pb[t];
  for (int t2 = 0; t2 < T_; ++t2) {
    const float* o = out4 + ((size_t)(b * T_ + t2) * N_ + n) * D_;
#pragma unroll
    for (int d = 0; d < D_; ++d) acc = fmaf(o[d], pw[(t2 * D_ + d) * T_ + t], acc);
  }
  outp[i] = acc;
}

__global__ void k_p2(const float* __restrict__ o2p, const float* __restrict__ p2w,
                     const float* __restrict__ p2b, float* __restrict__ o2f) {
  int i = blockIdx.x * 256 + threadIdx.x;
  if (i >= BTN_) return;
  int b = i / (T_ * N_);
  int t = (i / N_) % T_;
  int n = i % N_;
  float acc = p2b[t];
  const float* src = o2p + (size_t)b * (T_ * N_) + (size_t)n * T_;
#pragma unroll
  for (int c = 0; c < T_; ++c) acc = fmaf(src[c], p2w[c * T_ + t], acc);
  o2f[i] = acc;
}

// fused: out3 write + f-normalization -> bf16 padded rows g1b/g2b [8000][32]
__global__ void k_fng(const float* __restrict__ outp, const float* __restrict__ o2f,
                      float* __restrict__ dout, unsigned short* __restrict__ g1b,
                      unsigned short* __restrict__ g2b) {
  int r = blockIdx.x * 256 + threadIdx.x;
  if (r >= B_ * N_) return;
  int b = r / N_, n = r % N_;
  float v1[T_], v2[T_];
  float s1 = 0.f, s2 = 0.f;
#pragma unroll
  for (int t = 0; t < T_; ++t) {
    size_t idx = (size_t)b * T_ * N_ + (size_t)t * N_ + n;
    v1[t] = outp[idx];
    v2[t] = o2f[idx];
    dout[idx] = v1[t] + v2[t];
    s1 = fmaf(v1[t], v1[t], s1);
    s2 = fmaf(v2[t], v2[t], s2);
  }
  float n1 = fmaxf(sqrtf(s1), 1e-12f), n2 = fmaxf(sqrtf(s2), 1e-12f);
  float i1 = 10.f / n1, i2 = 1.f / n2;
  unsigned short q[32], z[32];
#pragma unroll
  for (int t = 0; t < T_; ++t) { q[t] = f2bf(v1[t] * i1); z[t] = f2bf(v2[t] * i2); }
#pragma unroll
  for (int t = T_; t < 32; ++t) { q[t] = 0; z[t] = 0; }
  short8* qd = (short8*)(g1b + (size_t)r * 32);
  short8* zd = (short8*)(g2b + (size_t)r * 32);
#pragma unroll
  for (int c = 0; c < 4; ++c) {
    short8 pv, pz;
#pragma unroll
    for (int e = 0; e < 8; ++e) { pv[e] = (short)q[c * 8 + e]; pz[e] = (short)z[c * 8 + e]; }
    qd[c] = pv;
    zd[c] = pz;
  }
}

// MFMA logsumexp: per block 16 q-rows; 16 j-slices (4 waves x grid.y=4)
__global__ __launch_bounds__(256) void k_lsemf(const unsigned short* __restrict__ g1b,
                                               const unsigned short* __restrict__ g2b,
                                               float* __restrict__ psm,
                                               float* __restrict__ psd) {
  int lane = threadIdx.x & 63, w = threadIdx.x >> 6;
  int lr = lane & 15, lo = lane >> 4;
  int i0 = blockIdx.x * 16;
  int slice = blockIdx.y * 4 + w;     // 0..15
  short8 a = *(const short8*)(g1b + (size_t)(i0 + lr) * 32 + lo * 8);
  float sm[4] = {0.f, 0.f, 0.f, 0.f};
  float sd[4] = {0.f, 0.f, 0.f, 0.f};
  for (int t = slice; t < 500; t += 16) {
    int j0 = t * 16;
    short8 b = *(const short8*)(g2b + (size_t)(j0 + lr) * 32 + lo * 8);
    f32x4 acc = {0.f, 0.f, 0.f, 0.f};
    acc = __builtin_amdgcn_mfma_f32_16x16x32_bf16(a, b, acc, 0, 0, 0);
#pragma unroll
    for (int rg = 0; rg < 4; ++rg) {
      float s = acc[rg];
      sm[rg] += __expf(s);
      if (j0 + lr == i0 + lo * 4 + rg) sd[rg] = s;
    }
  }
#pragma unroll
  for (int off = 1; off < 16; off <<= 1) {
#pragma unroll
    for (int rg = 0; rg < 4; ++rg) {
      sm[rg] += __shfl_xor(sm[rg], off);
      sd[rg] += __shfl_xor(sd[rg], off);
    }
  }
  __shared__ float lsm[4][16], lsd[4][16];
  if (lr == 0) {
#pragma unroll
    for (int rg = 0; rg < 4; ++rg) {
      lsm[w][lo * 4 + rg] = sm[rg];
      lsd[w][lo * 4 + rg] = sd[rg];
    }
  }
  __syncthreads();
  if (threadIdx.x < 16) {
    float m = lsm[0][threadIdx.x] + lsm[1][threadIdx.x] + lsm[2][threadIdx.x] + lsm[3][threadIdx.x];
    float d = lsd[0][threadIdx.x] + lsd[1][threadIdx.x] + lsd[2][threadIdx.x] + lsd[3][threadIdx.x];
    psm[(size_t)blockIdx.y * 8000 + i0 + threadIdx.x] = m;
    psd[(size_t)blockIdx.y * 8000 + i0 + threadIdx.x] = d;
  }
}

// fused: combine j-splits + mean + final scalars
__global__ __launch_bounds__(1024) void k_lsefin(const float* __restrict__ psm,
                                                 const float* __restrict__ psd,
                                                 const float* __restrict__ ws,
                                                 float* __restrict__ dout) {
  float acc = 0.f;
  for (int r = threadIdx.x; r < B_ * N_; r += 1024) {
    float sm = psm[r] + psm[8000 + r] + psm[16000 + r] + psm[24000 + r];
    float sd = psd[r] + psd[8000 + r] + psd[16000 + r] + psd[24000 + r];
    acc += sd - logf(sm);
  }
  __shared__ float red[16];
  acc = waveReduceSum(acc);
  if ((threadIdx.x & 63) == 0) red[threadIdx.x >> 6] = acc;
  __syncthreads();
  if (threadIdx.x == 0) {
    float s = 0.f;
    for (int i = 0; i < 16; ++i) s += red[i];
    float closs = -s * (1.f / (B_ * N_));
    dout[BTN_] = ws[OFF_BAL];
    dout[BTN_ + 1] = CW_ * closs;
  }
}

// ---------------------------------------------------------------------------
extern "C" void kernel_launch(void* const* d_in, const int* in_sizes, int n_in,
                              void* d_out, int out_size, void* d_ws, size_t ws_size,
                              hipStream_t stream) {
  const float* x    = (const float*)d_in[0];
  const float* velo = (const float*)d_in[1];
  const float* adj  = (const float*)d_in[2];
  const float* lapd = (const float*)d_in[3];
  const float* laph = (const float*)d_in[4];
  const float* sw   = (const float*)d_in[5];
  const float* sb   = (const float*)d_in[6];
  const float* gw   = (const float*)d_in[7];
  const float* ew1  = (const float*)d_in[8];
  const float* eb1  = (const float*)d_in[9];
  const float* ew2  = (const float*)d_in[10];
  const float* eb2  = (const float*)d_in[11];
  const float* pw   = (const float*)d_in[12];
  const float* pb   = (const float*)d_in[13];
  const float* ltw  = (const float*)d_in[14];
  const float* ltb  = (const float*)d_in[15];
  const float* qkvw = (const float*)d_in[16];
  const float* qkvb = (const float*)d_in[17];
  const float* aow  = (const float*)d_in[18];
  const float* aob  = (const float*)d_in[19];
  const float* llw  = (const float*)d_in[20];
  const float* llb  = (const float*)d_in[21];
  const float* p2w  = (const float*)d_in[22];
  const float* p2b  = (const float*)d_in[23];
  float* ws = (float*)d_ws;
  float* dout = (float*)d_out;
  const float* v0 = velo;  // velo[0,0,:]
  float* part = ws + OFF_PART;
  unsigned short* atLin = (unsigned short*)(ws + OFF_AT_LIN);
  unsigned short* atQ   = (unsigned short*)(ws + OFF_AT_Q);
  unsigned short* atAO  = (unsigned short*)(ws + OFF_AT_AO);
  unsigned short* atLL  = (unsigned short*)(ws + OFF_AT_LL);
  unsigned short* g1b   = (unsigned short*)(ws + OFF_G1B);
  unsigned short* g2b   = (unsigned short*)(ws + OFF_G2B);
  dim3 b256(256);

  k_init<<<dim3(1), dim3(64), 0, stream>>>(ws);

  k_start<<<dim3((BTN_ * D_ + 255) / 256), b256, 0, stream>>>(x, sw, sb, ws + OFF_OUT4);

  for (int l = 0; l < L_; ++l) {
    k_feat<<<dim3(B_ * D_), b256, 0, stream>>>(ws + OFF_OUT4, ws + OFF_FEAT);
    k_gate<<<dim3(1), dim3(64), 0, stream>>>(ws + OFF_FEAT, gw, ws, l);
    k_expert<<<dim3((T_ * N_ + 255) / 256, B_), b256, 0, stream>>>(ws + OFF_OUT4, ew1, eb1, ew2, eb2, ws, l);
  }

  k_wavelet<<<dim3((BTN_ + 255) / 256), b256, 0, stream>>>(x, velo, ws + OFF_LOWT, ws + OFF_HVT);
  k_rowsum<<<dim3(2 * BT_), b256, 0, stream>>>(ws + OFF_LOWT, ws + OFF_HVT, ws);
  k_S<<<dim3(N_), b256, 0, stream>>>(adj, v0, ws + OFF_S);

  // fused stats (lapd, laph, NS)
  k_stats3<<<dim3(512, 1, 3), b256, 0, stream>>>(lapd, laph, adj, v0, ws + OFF_S, ws + OFF_STP);
  k_stats2<<<dim3(3), b256, 0, stream>>>(ws + OFF_STP, ws + OFF_STAT);

  // fused r1/r2/r3 GEMMs: 16-row blocks, grid (8, 20, 9)
  k_rgemm3<<<dim3(8, RKS_, 9), b256, 0, stream>>>(ws + OFF_LOWT, ws + OFF_HVT, lapd, laph,
                                                  adj, v0, ws + OFF_S, part);
  k_epiR3<<<dim3(8, 48, 3), b256, 0, stream>>>(part, ws, atLin);

  k_minmax<<<dim3(64, 3), b256, 0, stream>>>(ws + OFF_ALIN, ws + OFF_MMP);
  k_minmax2<<<dim3(3), dim3(64), 0, stream>>>(ws);
  k_colsum<<<dim3(12, 16), b256, 0, stream>>>(ltw, ws + OFF_CSP);
  k_colsum2<<<dim3(12), b256, 0, stream>>>(ws);

  // lin (MFMA, B=ltw fp32 [2000][3000]): 12 splits x 6 steps (KP2/32=63)
  k_mfmaW<<<dim3(47, 12), b256, 0, stream>>>(atLin, ltw, part, EA_, KP2, N_, 6);
  k_epiLin<<<dim3(12, 144), b256, 0, stream>>>(part, ltb, ws, atQ, 12);

  // qkv (MFMA, B=qkvw fp32 [3000][9000]): 4 splits x 24 steps (KP3/32=94)
  k_mfmaW<<<dim3(141, 4), b256, 0, stream>>>(atQ, qkvw, part, 3 * EA_, KP3, EA_, 24);
  k_epiQkv<<<dim3(36, 144), b256, 0, stream>>>(part, qkvb, ws + OFF_P, 4);

  // attention
  k_attn<<<dim3(T_ * B_ * H_, 3), b256, 0, stream>>>(ws + OFF_P, atAO);

  // attn-out (MFMA, B=aow fp32 [3000][3000]): 12 splits x 8 steps
  k_mfmaW<<<dim3(47, 12), b256, 0, stream>>>(atAO, aow, part, EA_, KP3, EA_, 8);
  k_epiAO<<<dim3(12, 144), b256, 0, stream>>>(part, aob, atLL, 12);

  // ll (MFMA, B=llw fp32 [3000][2000]): 16 splits x 6 steps
  k_mfmaW<<<dim3(32, 16), b256, 0, stream>>>(atLL, llw, part, N_, KP3, EA_, 6);
  k_epiLL<<<dim3(8, 48), b256, 0, stream>>>(part, llb, ws + OFF_O2P, 16);

  k_proj<<<dim3((BTN_ + 255) / 256), b256, 0, stream>>>(ws + OFF_OUT4, pw, pb, ws + OFF_OUTP);
  k_p2<<<dim3((BTN_ + 255) / 256), b256, 0, stream>>>(ws + OFF_O2P, p2w, p2b, ws + OFF_O2F);

  // fused out3 + fnorm (writes dout body + bf16 g1b/g2b)
  k_fng<<<dim3((B_ * N_ + 255) / 256), b256, 0, stream>>>(ws + OFF_OUTP, ws + OFF_O2F, dout, g1b, g2b);

  // MFMA logsumexp; psm/psd partials live in `part`
  k_lsemf<<<dim3(500, 4), b256, 0, stream>>>(g1b, g2b, part, part + 32000);
  k_lsefin<<<dim3(1), dim3(1024), 0, stream>>>(part, part + 32000, ws, dout);
}

// Round 15
// 492.686 us; speedup vs baseline: 2.1292x; 1.1276x over previous
//
#include <hip/hip_runtime.h>
#include <math.h>

// ---------------------------------------------------------------------------
// Model constants
// ---------------------------------------------------------------------------
namespace {
constexpr int B_ = 4, T_ = 12, N_ = 2000, D_ = 16, FF_ = 64, E_ = 4, L_ = 2;
constexpr int EA_ = 3000, H_ = 3, HD_ = EA_ / H_;   // 1000
constexpr int BT_ = B_ * T_;                         // 48
constexpr int R3_ = 3 * BT_;                         // 144
constexpr long long NN_ = (long long)N_ * N_;        // 4,000,000
constexpr int BTN_ = B_ * T_ * N_;                   // 96,000
constexpr float BETA_ = 0.01f, CW_ = 0.001f;
constexpr int RKS_ = 20;                             // r-GEMM split-K (fused x3)
constexpr int RKC_ = 100;                            // r-GEMM k-chunk
constexpr int KP3 = 3008;                            // K=3000 padded to 32
constexpr int KP2 = 2016;                            // K=2000 padded to 32

// ---------------------------------------------------------------------------
// Workspace layout (float offsets)
// ---------------------------------------------------------------------------
constexpr size_t OFF_OUT4 = 0;                                   // [B,T,N,D]
constexpr size_t OFF_LOWT = OFF_OUT4 + (size_t)BTN_ * D_;        // lowT^T [N][48]
constexpr size_t OFF_HVT  = OFF_LOWT + BTN_;                     // highV^T [N][48]
constexpr size_t OFF_ALIN = OFF_HVT + BTN_;                      // r^T [N][144]
constexpr size_t OFF_RT   = OFF_ALIN + (size_t)N_ * R3_;         // (unused, kept)
constexpr size_t OFF_P    = OFF_RT + (size_t)EA_ * R3_;          // P [144][9000]
constexpr size_t OFF_AOT  = OFF_P + (size_t)R3_ * 3 * EA_;       // (unused, kept)
constexpr size_t OFF_OT   = OFF_AOT + (size_t)EA_ * R3_;         // (unused, kept)
constexpr size_t OFF_O2P  = OFF_OT + (size_t)EA_ * R3_;          // out2 pre-p2 [B][T*N]
constexpr size_t OFF_OUTP = OFF_O2P + BTN_;                      // outp [B,T,N]
constexpr size_t OFF_O2F  = OFF_OUTP + BTN_;                     // out2 final [B,T,N]
constexpr size_t OFF_LI   = OFF_O2F + BTN_;                      // (spare)
constexpr size_t OFF_S    = OFF_LI + 8000;                       // G row sums [2000]
constexpr size_t OFF_RSL  = OFF_S + 2000;
constexpr size_t OFF_RSH  = OFF_RSL + 48;
constexpr size_t OFF_STP  = OFF_RSH + 48;
constexpr size_t OFF_STAT = OFF_STP + 3072;
constexpr size_t OFF_MMP  = OFF_STAT + 8;
constexpr size_t OFF_AB   = OFF_MMP + 384;
constexpr size_t OFF_CSP  = OFF_AB + 8;
constexpr size_t OFF_CS   = OFF_CSP + 48000;
constexpr size_t OFF_FEAT = OFF_CS + 3000;
constexpr size_t OFF_GATE = OFF_FEAT + 64;
constexpr size_t OFF_BAL  = OFF_GATE + 16;
constexpr size_t OFF_PART = ((OFF_BAL + 1 + 255) & ~(size_t)255); // split-K partials
constexpr size_t PARTCAP  = 13000000;                             // cap (floats)
// bf16 A-operand regions, k-octet-major [Kp/8][144][8] (sizes in floats)
constexpr size_t OFF_AT_LIN= OFF_PART + PARTCAP;                  // [KP2/8][144][8]
constexpr size_t OFF_AT_Q  = OFF_AT_LIN + (size_t)R3_ * KP2 / 2;
constexpr size_t OFF_AT_AO = OFF_AT_Q + (size_t)R3_ * KP3 / 2;
constexpr size_t OFF_AT_LL = OFF_AT_AO + (size_t)R3_ * KP3 / 2;
constexpr size_t OFF_G1B   = OFF_AT_LL + (size_t)R3_ * KP3 / 2;   // f1 bf16 [8000][32]
constexpr size_t OFF_G2B   = OFF_G1B + 128000;                    // f2 bf16 [8000][32]
} // namespace

typedef __attribute__((ext_vector_type(8))) short short8;
typedef __attribute__((ext_vector_type(4))) float f32x4;

// ---------------------------------------------------------------------------
// Helpers
// ---------------------------------------------------------------------------
__device__ __forceinline__ float waveReduceSum(float v) {
  for (int off = 32; off; off >>= 1) v += __shfl_down(v, off);
  return v;
}

__device__ __forceinline__ unsigned short f2bf(float x) {  // RNE fp32->bf16
  unsigned int u = __float_as_uint(x);
  unsigned int r = (u + 0x7FFFu + ((u >> 16) & 1u)) >> 16;
  return (unsigned short)r;
}

// k-octet-major A index: (row, k) -> [(k/8)][row][k%8]
__device__ __forceinline__ size_t aidx(int row, int k) {
  return ((size_t)(k >> 3) * R3_ + row) * 8 + (k & 7);
}

__device__ __forceinline__ void fma16(float* __restrict__ acc,
                                      const float4* __restrict__ a4, float bv) {
#pragma unroll
  for (int r4 = 0; r4 < 4; ++r4) {
    float4 av = a4[r4];
    acc[r4 * 4 + 0] = fmaf(av.x, bv, acc[r4 * 4 + 0]);
    acc[r4 * 4 + 1] = fmaf(av.y, bv, acc[r4 * 4 + 1]);
    acc[r4 * 4 + 2] = fmaf(av.z, bv, acc[r4 * 4 + 2]);
    acc[r4 * 4 + 3] = fmaf(av.w, bv, acc[r4 * 4 + 3]);
  }
}

// ---------------------------------------------------------------------------
__global__ void k_init(float* ws) {
  if (threadIdx.x == 0) ws[OFF_BAL] = 0.f;
}

__global__ void k_start(const float* __restrict__ x, const float* __restrict__ sw,
                        const float* __restrict__ sb, float* __restrict__ out4) {
  int i = blockIdx.x * 256 + threadIdx.x;
  if (i >= BTN_ * D_) return;
  int d = i & 15;
  out4[i] = fmaf(x[i >> 4], sw[d], sb[d]);
}

__global__ void k_feat(const float* __restrict__ out4, float* __restrict__ feat) {
  int b = blockIdx.x >> 4, d = blockIdx.x & 15;
  float s = 0.f;
  for (int tn = threadIdx.x; tn < T_ * N_; tn += 256)
    s += out4[((size_t)b * T_ * N_ + tn) * D_ + d];
  __shared__ float red[4];
  s = waveReduceSum(s);
  if ((threadIdx.x & 63) == 0) red[threadIdx.x >> 6] = s;
  __syncthreads();
  if (threadIdx.x == 0)
    feat[blockIdx.x] = (red[0] + red[1] + red[2] + red[3]) * (1.f / (T_ * N_));
}

__global__ void k_gate(const float* __restrict__ feat, const float* __restrict__ gw,
                       float* __restrict__ ws, int l) {
  __shared__ float lg[B_ * E_];
  int tid = threadIdx.x;
  if (tid < B_ * E_) {
    int b = tid >> 2, e = tid & 3;
    float s = 0.f;
    for (int d = 0; d < D_; ++d) s = fmaf(feat[b * D_ + d], gw[(l * D_ + d) * E_ + e], s);
    lg[tid] = s;
  }
  __syncthreads();
  if (tid == 0) {
    float* gates = ws + OFF_GATE;
    float imp[E_] = {0, 0, 0, 0}, load[E_] = {0, 0, 0, 0};
    for (int i = 0; i < B_ * E_; ++i) gates[i] = 0.f;
    for (int b = 0; b < B_; ++b) {
      const float* lb = lg + b * E_;
      int i1 = 0; float v1 = lb[0];
      for (int e = 1; e < E_; ++e) if (lb[e] > v1) { v1 = lb[e]; i1 = e; }
      int i2 = -1; float v2 = -1e30f;
      for (int e = 0; e < E_; ++e) { if (e == i1) continue; if (lb[e] > v2) { v2 = lb[e]; i2 = e; } }
      float e2 = expf(v2 - v1);
      float den = 1.f + e2;
      float g1 = 1.f / den, g2 = e2 / den;
      gates[b * E_ + i1] = g1; gates[b * E_ + i2] = g2;
      imp[i1] += g1; imp[i2] += g2; load[i1] += 1.f; load[i2] += 1.f;
    }
    float bal = 0.f;
    float m = 0.f; for (int e = 0; e < E_; ++e) m += imp[e]; m *= 0.25f;
    float v = 0.f; for (int e = 0; e < E_; ++e) { float d = imp[e] - m; v += d * d; } v *= 0.25f;
    bal += v / (m * m + 1e-10f);
    m = 0.f; for (int e = 0; e < E_; ++e) m += load[e]; m *= 0.25f;
    v = 0.f; for (int e = 0; e < E_; ++e) { float d = load[e] - m; v += d * d; } v *= 0.25f;
    bal += v / (m * m + 1e-10f);
    ws[OFF_BAL] += bal;
  }
}

// MoE expert apply; gelu via sigmoid identity
__global__ void k_expert(float* __restrict__ out4, const float* __restrict__ w1,
                         const float* __restrict__ b1, const float* __restrict__ w2,
                         const float* __restrict__ b2, const float* __restrict__ ws, int l) {
  int b = blockIdx.y;
  int tn = blockIdx.x * 256 + threadIdx.x;
  if (tn >= T_ * N_) return;
  float* row = out4 + ((size_t)b * T_ * N_ + tn) * D_;
  float r[D_], acc[D_];
#pragma unroll
  for (int d = 0; d < D_; ++d) { r[d] = row[d]; acc[d] = r[d]; }
  const float* gates = ws + OFF_GATE;
  for (int e = 0; e < E_; ++e) {
    float g = gates[b * E_ + e];
    if (g <= 0.f) continue;
    const float* W1 = w1 + (size_t)(l * E_ + e) * D_ * FF_;
    const float* B1 = b1 + (size_t)(l * E_ + e) * FF_;
    const float* W2 = w2 + (size_t)(l * E_ + e) * FF_ * D_;
    const float* B2 = b2 + (size_t)(l * E_ + e) * D_;
#pragma unroll 4
    for (int f = 0; f < FF_; ++f) {
      float p = B1[f];
#pragma unroll
      for (int d = 0; d < D_; ++d) p = fmaf(r[d], W1[d * FF_ + f], p);
      float c2 = 1.5957691216057308f * (p + 0.044715f * p * p * p);
      float e1 = __expf(-c2);
      float hv = p * __builtin_amdgcn_rcpf(1.f + e1);
      float gh = g * hv;
#pragma unroll
      for (int d = 0; d < D_; ++d) acc[d] = fmaf(gh, W2[f * D_ + d], acc[d]);
    }
#pragma unroll
    for (int d = 0; d < D_; ++d) acc[d] = fmaf(g, B2[d], acc[d]);
  }
#pragma unroll
  for (int d = 0; d < D_; ++d) row[d] = acc[d];
}

__global__ void k_wavelet(const float* __restrict__ x, const float* __restrict__ velo,
                          float* __restrict__ lowT, float* __restrict__ hvT) {
  int i = blockIdx.x * 256 + threadIdx.x;
  if (i >= BTN_) return;
  int b = i / (T_ * N_);
  int t = (i / N_) % T_;
  int n = i % N_;
  int ip = b * T_ * N_ + ((t + T_ - 1) % T_) * N_ + n;
  int row = t * B_ + b;
  lowT[(size_t)n * BT_ + row] = 0.5f * (x[i] + x[ip]);
  hvT[(size_t)n * BT_ + row] = 0.5f * (velo[i] - velo[ip]);
}

__global__ void k_rowsum(const float* __restrict__ lowT, const float* __restrict__ hvT,
                         float* __restrict__ ws) {
  int which = blockIdx.x / BT_;
  int row = blockIdx.x % BT_;
  const float* M = which ? hvT : lowT;
  float s = 0.f;
  for (int n = threadIdx.x; n < N_; n += 256) s += M[(size_t)n * BT_ + row];
  __shared__ float red[4];
  s = waveReduceSum(s);
  if ((threadIdx.x & 63) == 0) red[threadIdx.x >> 6] = s;
  __syncthreads();
  if (threadIdx.x == 0) ws[(which ? OFF_RSH : OFF_RSL) + row] = red[0] + red[1] + red[2] + red[3];
}

__global__ void k_S(const float* __restrict__ adj, const float* __restrict__ v0,
                    float* __restrict__ S) {
  int m = blockIdx.x;
  float vm = v0[m];
  const float* a = adj + (size_t)m * N_;
  float s = 0.f;
  for (int n = threadIdx.x; n < N_; n += 256) s += vm / a[n];
  __shared__ float red[4];
  s = waveReduceSum(s);
  if ((threadIdx.x & 63) == 0) red[threadIdx.x >> 6] = s;
  __syncthreads();
  if (threadIdx.x == 0) S[m] = red[0] + red[1] + red[2] + red[3];
}

// fused: sum/sumsq of lapd (z=0), laph (z=1), NS laplacian (z=2)
__global__ void k_stats3(const float* __restrict__ lapd, const float* __restrict__ laph,
                         const float* __restrict__ adj, const float* __restrict__ v0,
                         const float* __restrict__ S, float* __restrict__ stp) {
  int z = blockIdx.z;
  float s = 0.f, ss = 0.f;
  if (z < 2) {
    const float* M = z ? laph : lapd;
    for (long long i = blockIdx.x * 256 + threadIdx.x; i < NN_; i += 512 * 256) {
      float v = M[i];
      s += v; ss = fmaf(v, v, ss);
    }
  } else {
    for (long long i = blockIdx.x * 256 + threadIdx.x; i < NN_; i += 512 * 256) {
      int m = (int)(i / N_), n = (int)(i % N_);
      float e = -(v0[m] / adj[i]);
      if (m == n) e += S[m];
      s += e; ss = fmaf(e, e, ss);
    }
  }
  __shared__ float r1[4], r2[4];
  for (int off = 32; off; off >>= 1) { s += __shfl_down(s, off); ss += __shfl_down(ss, off); }
  if ((threadIdx.x & 63) == 0) { r1[threadIdx.x >> 6] = s; r2[threadIdx.x >> 6] = ss; }
  __syncthreads();
  if (threadIdx.x == 0) {
    float* p = stp + (size_t)z * 1024;
    p[blockIdx.x * 2] = r1[0] + r1[1] + r1[2] + r1[3];
    p[blockIdx.x * 2 + 1] = r2[0] + r2[1] + r2[2] + r2[3];
  }
}

__global__ void k_stats2(const float* __restrict__ stp, float* __restrict__ stat) {
  int z = blockIdx.x;
  const float* part = stp + (size_t)z * 1024;
  float s = 0.f, ss = 0.f;
  for (int i = threadIdx.x; i < 512; i += 256) { s += part[i * 2]; ss += part[i * 2 + 1]; }
  __shared__ float r1[4], r2[4];
  for (int off = 32; off; off >>= 1) { s += __shfl_down(s, off); ss += __shfl_down(ss, off); }
  if ((threadIdx.x & 63) == 0) { r1[threadIdx.x >> 6] = s; r2[threadIdx.x >> 6] = ss; }
  __syncthreads();
  if (threadIdx.x == 0) {
    float su = r1[0] + r1[1] + r1[2] + r1[3];
    float sq = r2[0] + r2[1] + r2[2] + r2[3];
    float mu = su * (1.f / (float)NN_);
    float var = sq * (1.f / (float)NN_) - mu * mu;
    stat[2 * z] = mu;
    stat[2 * z + 1] = 1.f / sqrtf(var);
  }
}

// ---------------------------------------------------------------------------
// Fused r-GEMMs, 16-row accumulators: blockIdx.z = z*3 + rg. Grid (8, RKS_, 9).
// ---------------------------------------------------------------------------
__global__ __launch_bounds__(256) void k_rgemm3(
    const float* __restrict__ lowT, const float* __restrict__ hvT,
    const float* __restrict__ lapd, const float* __restrict__ laph,
    const float* __restrict__ adj, const float* __restrict__ v0,
    const float* __restrict__ S, float* __restrict__ part) {
  int zz = blockIdx.z;
  int z = zz / 3, rg = zz % 3;
  int col = blockIdx.x * 256 + threadIdx.x;
  int m0 = blockIdx.y * RKC_;
  int m1 = min(N_, m0 + RKC_);
  float acc[16];
#pragma unroll
  for (int r = 0; r < 16; ++r) acc[r] = 0.f;
  if (col < N_) {
    const float* Abase = (z == 1 ? hvT : lowT);
    const float* ap = Abase + (size_t)m0 * BT_ + rg * 16;
    if (z != 1) {
      const float* Bm = z ? laph : lapd;
      const float* bp = Bm + (size_t)m0 * N_ + col;
      int len = m1 - m0;
      int ng = len >> 3;
      float bc[8];
      if (ng > 0) {
#pragma unroll
        for (int u = 0; u < 8; ++u) bc[u] = bp[(size_t)u * N_];
      }
      for (int gi = 0; gi < ng; ++gi) {
        float bn[8];
        bool more = (gi + 1 < ng);
        if (more) {
#pragma unroll
          for (int u = 0; u < 8; ++u) bn[u] = bp[(size_t)(8 + u) * N_];
        }
#pragma unroll
        for (int u = 0; u < 8; ++u)
          fma16(acc, (const float4*)(ap + (size_t)u * BT_), bc[u]);
        ap += (size_t)8 * BT_;
        bp += (size_t)8 * N_;
        if (more) {
#pragma unroll
          for (int u = 0; u < 8; ++u) bc[u] = bn[u];
        }
      }
      for (int m = m0 + (ng << 3); m < m1; ++m) {
        fma16(acc, (const float4*)ap, *bp);
        ap += BT_;
        bp += N_;
      }
    } else {
      const float* jp = adj + (size_t)m0 * N_ + col;
      int len = m1 - m0;
      int ng = len >> 3;
      float jc[8];
      if (ng > 0) {
#pragma unroll
        for (int u = 0; u < 8; ++u) jc[u] = jp[(size_t)u * N_];
      }
      int m = m0;
      for (int gi = 0; gi < ng; ++gi) {
        float jn[8];
        bool more = (gi + 1 < ng);
        if (more) {
#pragma unroll
          for (int u = 0; u < 8; ++u) jn[u] = jp[(size_t)(8 + u) * N_];
        }
#pragma unroll
        for (int u = 0; u < 8; ++u) {
          float bv = -(v0[m + u] / jc[u]);
          if (m + u == col) bv += S[m + u];
          fma16(acc, (const float4*)(ap + (size_t)u * BT_), bv);
        }
        m += 8;
        ap += (size_t)8 * BT_;
        jp += (size_t)8 * N_;
        if (more) {
#pragma unroll
          for (int u = 0; u < 8; ++u) jc[u] = jn[u];
        }
      }
      for (; m < m1; ++m) {
        float bv = -(v0[m] / (*jp));
        if (m == col) bv += S[m];
        fma16(acc, (const float4*)ap, bv);
        ap += BT_;
        jp += N_;
      }
    }
    float* pp = part + (((size_t)z * RKS_ + blockIdx.y) * BT_ + rg * 16) * N_ + col;
#pragma unroll
    for (int r = 0; r < 16; ++r) pp[(size_t)r * N_] = acc[r];
  }
}

// fused r epilogue -> ALIN + At_lin bf16 (k-octet-major)
__global__ void k_epiR3(const float* __restrict__ part, float* __restrict__ ws,
                        unsigned short* __restrict__ atl) {
  int z = blockIdx.z;
  int n = blockIdx.x * 256 + threadIdx.x;
  int row = blockIdx.y;
  if (n >= KP2) return;
  int arow = z * BT_ + row;
  if (n >= N_) { atl[aidx(arow, n)] = 0; return; }
  const float* base = part + (size_t)z * RKS_ * BT_ * N_;
  float s = 0.f;
  for (int ks = 0; ks < RKS_; ++ks) s += base[((size_t)(ks * BT_ + row)) * N_ + n];
  int statIdx = (z == 0) ? 0 : (z == 1 ? 4 : 2);
  size_t rsOff = (z == 1) ? OFF_RSH : OFF_RSL;
  float mu = ws[OFF_STAT + statIdx], isd = ws[OFF_STAT + statIdx + 1];
  float val = (s - mu * ws[rsOff + row]) * isd;
  ws[OFF_ALIN + (size_t)n * R3_ + arow] = val;
  atl[aidx(arow, n)] = f2bf(val);
}

// ---------------------------------------------------------------------------
// MFMA GEMM with fused B-transpose+bf16 from fp32 W[K][Nc]; A in k-octet-major
// bf16 [Kp/8][144][8] (fragment load = 4 x 256B contiguous segments).
// part[ks][144][Nc].
// ---------------------------------------------------------------------------
__global__ __launch_bounds__(256) void k_mfmaW(
    const unsigned short* __restrict__ At, const float* __restrict__ W,
    float* __restrict__ part, int Nc, int Kp, int K, int stepChunk) {
  __shared__ unsigned int lds[2][64][21];
  int tid = threadIdx.x;
  int lane = tid & 63, w = tid >> 6;
  int lr = lane & 15, lo = lane >> 4;
  int colBase = blockIdx.x * 64;
  int gcol = colBase + w * 16 + lr;
  int stepsTot = Kp / 32;
  int s0 = blockIdx.y * stepChunk;
  int s1 = min(stepsTot, s0 + stepChunk);
  int cg = tid & 15, kr2 = tid >> 4;
  int c0l = 4 * cg;
  bool fullC = (colBase + 64 <= Nc);

  f32x4 acc[9];
#pragma unroll
  for (int mt = 0; mt < 9; ++mt) {
    acc[mt][0] = 0.f; acc[mt][1] = 0.f; acc[mt][2] = 0.f; acc[mt][3] = 0.f;
  }

  auto stage = [&](int s, int buf) {
    int kA = s * 32 + 2 * kr2;
    int kB = kA + 1;
    float4 r0 = {0.f, 0.f, 0.f, 0.f}, r1 = {0.f, 0.f, 0.f, 0.f};
    int c0 = colBase + c0l;
    if (fullC) {
      if (kA < K) r0 = *(const float4*)(W + (size_t)kA * Nc + c0);
      if (kB < K) r1 = *(const float4*)(W + (size_t)kB * Nc + c0);
    } else {
      float rr0[4] = {0.f, 0.f, 0.f, 0.f}, rr1[4] = {0.f, 0.f, 0.f, 0.f};
#pragma unroll
      for (int e = 0; e < 4; ++e) {
        if (c0 + e < Nc) {
          if (kA < K) rr0[e] = W[(size_t)kA * Nc + c0 + e];
          if (kB < K) rr1[e] = W[(size_t)kB * Nc + c0 + e];
        }
      }
      r0.x = rr0[0]; r0.y = rr0[1]; r0.z = rr0[2]; r0.w = rr0[3];
      r1.x = rr1[0]; r1.y = rr1[1]; r1.z = rr1[2]; r1.w = rr1[3];
    }
    lds[buf][c0l + 0][kr2] = ((unsigned int)f2bf(r1.x) << 16) | f2bf(r0.x);
    lds[buf][c0l + 1][kr2] = ((unsigned int)f2bf(r1.y) << 16) | f2bf(r0.y);
    lds[buf][c0l + 2][kr2] = ((unsigned int)f2bf(r1.z) << 16) | f2bf(r0.z);
    lds[buf][c0l + 3][kr2] = ((unsigned int)f2bf(r1.w) << 16) | f2bf(r0.w);
  };

  if (s0 < s1) stage(s0, 0);
  __syncthreads();

  // A base: k-octet (s*4 + lo), row lr; advance 4*144*8 ushorts per step
  const unsigned short* ap = At + ((size_t)(s0 * 4 + lo) * R3_ + lr) * 8;
  int lcol = w * 16 + lr;
  for (int s = s0; s < s1; ++s) {
    int buf = (s - s0) & 1;
    union { unsigned int u[4]; short8 s8; } bu;
#pragma unroll
    for (int j = 0; j < 4; ++j) bu.u[j] = lds[buf][lcol][lo * 4 + j];
    short8 b = bu.s8;
#pragma unroll
    for (int mt = 0; mt < 9; ++mt) {
      short8 a = *(const short8*)(ap + (size_t)mt * 128);
      acc[mt] = __builtin_amdgcn_mfma_f32_16x16x32_bf16(a, b, acc[mt], 0, 0, 0);
    }
    if (s + 1 < s1) stage(s + 1, buf ^ 1);
    __syncthreads();
    ap += (size_t)4 * R3_ * 8;
  }

  if (gcol < Nc) {
#pragma unroll
    for (int mt = 0; mt < 9; ++mt) {
      int row = mt * 16 + lo * 4;
      float* pp = part + ((size_t)blockIdx.y * R3_ + row) * Nc + gcol;
      pp[0] = acc[mt][0];
      pp[(size_t)Nc] = acc[mt][1];
      pp[2 * (size_t)Nc] = acc[mt][2];
      pp[3 * (size_t)Nc] = acc[mt][3];
    }
  }
}

// ---------------------------------------------------------------------------
// Epilogues
// ---------------------------------------------------------------------------
__global__ void k_minmax(const float* __restrict__ alin, float* __restrict__ mmp) {
  int g = blockIdx.y;
  float mn = 3.4e38f, mx = -3.4e38f;
  for (int i = blockIdx.x * 256 + threadIdx.x; i < N_ * BT_; i += 64 * 256) {
    int n = i / BT_, r = i % BT_;
    float v = alin[(size_t)n * R3_ + g * BT_ + r];
    mn = fminf(mn, v); mx = fmaxf(mx, v);
  }
  __shared__ float rn[4], rx[4];
  for (int off = 32; off; off >>= 1) {
    mn = fminf(mn, __shfl_down(mn, off));
    mx = fmaxf(mx, __shfl_down(mx, off));
  }
  if ((threadIdx.x & 63) == 0) { rn[threadIdx.x >> 6] = mn; rx[threadIdx.x >> 6] = mx; }
  __syncthreads();
  if (threadIdx.x == 0) {
    mn = fminf(fminf(rn[0], rn[1]), fminf(rn[2], rn[3]));
    mx = fmaxf(fmaxf(rx[0], rx[1]), fmaxf(rx[2], rx[3]));
    mmp[(size_t)(g * 64 + blockIdx.x) * 2] = mn;
    mmp[(size_t)(g * 64 + blockIdx.x) * 2 + 1] = mx;
  }
}

__global__ void k_minmax2(float* __restrict__ ws) {
  int g = blockIdx.x;
  int i = threadIdx.x;
  float mn = ws[OFF_MMP + (size_t)(g * 64 + i) * 2];
  float mx = ws[OFF_MMP + (size_t)(g * 64 + i) * 2 + 1];
  for (int off = 32; off; off >>= 1) {
    mn = fminf(mn, __shfl_down(mn, off));
    mx = fmaxf(mx, __shfl_down(mx, off));
  }
  if (i == 0) {
    float denom = fmaxf(mx - mn, 1e-8f);
    float a = 1.f / denom;
    ws[OFF_AB + g * 2] = a;
    ws[OFF_AB + g * 2 + 1] = -mn * a;
  }
}

__global__ void k_colsum(const float* __restrict__ ltw, float* __restrict__ csp) {
  int e = blockIdx.x * 256 + threadIdx.x;
  int ks = blockIdx.y;
  if (e >= EA_) return;
  float s = 0.f;
  for (int n = ks * 125; n < (ks + 1) * 125; ++n) s += ltw[(size_t)n * EA_ + e];
  csp[(size_t)ks * EA_ + e] = s;
}
__global__ void k_colsum2(float* __restrict__ ws) {
  int e = blockIdx.x * 256 + threadIdx.x;
  if (e >= EA_) return;
  float s = 0.f;
  for (int ks = 0; ks < 16; ++ks) s += ws[OFF_CSP + (size_t)ks * EA_ + e];
  ws[OFF_CS + e] = s;
}

__global__ void k_epiLin(const float* __restrict__ part, const float* __restrict__ ltb,
                         float* __restrict__ ws, unsigned short* __restrict__ atq,
                         int ksplit) {
  int e = blockIdx.x * 256 + threadIdx.x;
  int row = blockIdx.y;
  if (e >= KP3) return;
  if (e >= EA_) { atq[aidx(row, e)] = 0; return; }
  float s = 0.f;
  for (int ks = 0; ks < ksplit; ++ks) s += part[((size_t)(ks * R3_ + row)) * EA_ + e];
  int g = row / BT_;
  float a = ws[OFF_AB + g * 2], bb = ws[OFF_AB + g * 2 + 1];
  float val = fmaf(a, s, fmaf(bb, ws[OFF_CS + e], ltb[e]));
  atq[aidx(row, e)] = f2bf(val);
}

__global__ void k_epiQkv(const float* __restrict__ part, const float* __restrict__ qkvb,
                         float* __restrict__ P, int ksplit) {
  int c = blockIdx.x * 256 + threadIdx.x;
  int row = blockIdx.y;
  if (c >= 3 * EA_) return;
  float s = 0.f;
  for (int ks = 0; ks < ksplit; ++ks) s += part[((size_t)(ks * R3_ + row)) * (3 * EA_) + c];
  P[(size_t)row * (3 * EA_) + c] = s + qkvb[c];
}

// attention: waves cover t in parallel (wave-local reductions, one barrier)
__global__ void k_attn(const float* __restrict__ P, unsigned short* __restrict__ atao) {
  int mha = blockIdx.y;
  int s_ = blockIdx.x / (B_ * H_);
  int rem = blockIdx.x % (B_ * H_);
  int b = rem / H_, h = rem % H_;
  const int pq[3] = {0, 1, 2}, pk[3] = {1, 2, 0}, pv[3] = {2, 0, 1};
  const float* qrow = P + ((size_t)(pq[mha] * BT_ + s_ * B_ + b)) * (3 * EA_) + h * HD_;
  __shared__ float sc[T_];
  int w = threadIdx.x >> 6, lane = threadIdx.x & 63;
  for (int t = w; t < T_; t += 4) {
    const float* krow = P + ((size_t)(pk[mha] * BT_ + t * B_ + b)) * (3 * EA_) + EA_ + h * HD_;
    float p = 0.f;
    for (int d = lane; d < HD_; d += 64) p = fmaf(qrow[d], krow[d], p);
    p = waveReduceSum(p);
    if (lane == 0) sc[t] = p * 0.031622776601683794f;
  }
  __syncthreads();
  float a[T_];
  float m = sc[0];
#pragma unroll
  for (int t = 1; t < T_; ++t) m = fmaxf(m, sc[t]);
  float sum = 0.f;
#pragma unroll
  for (int t = 0; t < T_; ++t) { a[t] = expf(sc[t] - m); sum += a[t]; }
  float inv = 1.f / sum;
#pragma unroll
  for (int t = 0; t < T_; ++t) a[t] *= inv;
  int orow = mha * BT_ + s_ * B_ + b;
  for (int d = threadIdx.x; d < HD_; d += 256) {
    float o = 0.f;
#pragma unroll
    for (int t = 0; t < T_; ++t)
      o = fmaf(a[t], P[((size_t)(pv[mha] * BT_ + t * B_ + b)) * (3 * EA_) + 2 * EA_ + h * HD_ + d], o);
    atao[aidx(orow, h * HD_ + d)] = f2bf(o);
  }
  if (h == 0 && threadIdx.x < 8) atao[aidx(orow, EA_ + threadIdx.x)] = 0;
}

__global__ void k_epiAO(const float* __restrict__ part, const float* __restrict__ aob,
                        unsigned short* __restrict__ atll, int ksplit) {
  int c = blockIdx.x * 256 + threadIdx.x;
  int row = blockIdx.y;
  if (c >= KP3) return;
  if (c >= EA_) { atll[aidx(row, c)] = 0; return; }
  float s = 0.f;
  for (int ks = 0; ks < ksplit; ++ks) s += part[((size_t)(ks * R3_ + row)) * EA_ + c];
  atll[aidx(row, c)] = f2bf(s + aob[c]);
}

__global__ void k_epiLL(const float* __restrict__ part, const float* __restrict__ llb,
                        float* __restrict__ o2p, int ksplit) {
  int n = blockIdx.x * 256 + threadIdx.x;
  int row = blockIdx.y;  // t*B+b
  if (n >= N_) return;
  float s = 0.f;
  for (int g = 0; g < 3; ++g)
    for (int ks = 0; ks < ksplit; ++ks)
      s += part[((size_t)(ks * R3_ + g * BT_ + row)) * N_ + n];
  int t = row / B_, b = row % B_;
  o2p[(size_t)b * (T_ * N_) + t * N_ + n] = BETA_ * (s + 3.f * llb[n]);
}

__global__ void k_proj(const float* __restrict__ out4, const float* __restrict__ pw,
                       const float* __restrict__ pb, float* __restrict__ outp) {
  int i = blockIdx.x * 256 + threadIdx.x;
  if (i >= BTN_) return;
  int b = i / (T_ * N_);
  int t = (i / N_) % T_;
  int n = i % N_;
  float acc = pb[t];
  for (int t2 = 0; t2 < T_; ++t2) {
    const float* o = out4 + ((size_t)(b * T_ + t2) * N_ + n) * D_;
#pragma unroll
    for (int d = 0; d < D_; ++d) acc = fmaf(o[d], pw[(t2 * D_ + d) * T_ + t], acc);
  }
  outp[i] = acc;
}

__global__ void k_p2(const float* __restrict__ o2p, const float* __restrict__ p2w,
                     const float* __restrict__ p2b, float* __restrict__ o2f) {
  int i = blockIdx.x * 256 + threadIdx.x;
  if (i >= BTN_) return;
  int b = i / (T_ * N_);
  int t = (i / N_) % T_;
  int n = i % N_;
  float acc = p2b[t];
  const float* src = o2p + (size_t)b * (T_ * N_) + (size_t)n * T_;
#pragma unroll
  for (int c = 0; c < T_; ++c) acc = fmaf(src[c], p2w[c * T_ + t], acc);
  o2f[i] = acc;
}

// fused: out3 write + f-normalization -> bf16 padded rows g1b/g2b [8000][32]
__global__ void k_fng(const float* __restrict__ outp, const float* __restrict__ o2f,
                      float* __restrict__ dout, unsigned short* __restrict__ g1b,
                      unsigned short* __restrict__ g2b) {
  int r = blockIdx.x * 256 + threadIdx.x;
  if (r >= B_ * N_) return;
  int b = r / N_, n = r % N_;
  float v1[T_], v2[T_];
  float s1 = 0.f, s2 = 0.f;
#pragma unroll
  for (int t = 0; t < T_; ++t) {
    size_t idx = (size_t)b * T_ * N_ + (size_t)t * N_ + n;
    v1[t] = outp[idx];
    v2[t] = o2f[idx];
    dout[idx] = v1[t] + v2[t];
    s1 = fmaf(v1[t], v1[t], s1);
    s2 = fmaf(v2[t], v2[t], s2);
  }
  float n1 = fmaxf(sqrtf(s1), 1e-12f), n2 = fmaxf(sqrtf(s2), 1e-12f);
  float i1 = 10.f / n1, i2 = 1.f / n2;
  unsigned short q[32], z[32];
#pragma unroll
  for (int t = 0; t < T_; ++t) { q[t] = f2bf(v1[t] * i1); z[t] = f2bf(v2[t] * i2); }
#pragma unroll
  for (int t = T_; t < 32; ++t) { q[t] = 0; z[t] = 0; }
  short8* qd = (short8*)(g1b + (size_t)r * 32);
  short8* zd = (short8*)(g2b + (size_t)r * 32);
#pragma unroll
  for (int c = 0; c < 4; ++c) {
    short8 pv, pz;
#pragma unroll
    for (int e = 0; e < 8; ++e) { pv[e] = (short)q[c * 8 + e]; pz[e] = (short)z[c * 8 + e]; }
    qd[c] = pv;
    zd[c] = pz;
  }
}

// MFMA logsumexp: per block 16 q-rows; 16 j-slices (4 waves x grid.y=4)
__global__ __launch_bounds__(256) void k_lsemf(const unsigned short* __restrict__ g1b,
                                               const unsigned short* __restrict__ g2b,
                                               float* __restrict__ psm,
                                               float* __restrict__ psd) {
  int lane = threadIdx.x & 63, w = threadIdx.x >> 6;
  int lr = lane & 15, lo = lane >> 4;
  int i0 = blockIdx.x * 16;
  int slice = blockIdx.y * 4 + w;     // 0..15
  short8 a = *(const short8*)(g1b + (size_t)(i0 + lr) * 32 + lo * 8);
  float sm[4] = {0.f, 0.f, 0.f, 0.f};
  float sd[4] = {0.f, 0.f, 0.f, 0.f};
  for (int t = slice; t < 500; t += 16) {
    int j0 = t * 16;
    short8 b = *(const short8*)(g2b + (size_t)(j0 + lr) * 32 + lo * 8);
    f32x4 acc = {0.f, 0.f, 0.f, 0.f};
    acc = __builtin_amdgcn_mfma_f32_16x16x32_bf16(a, b, acc, 0, 0, 0);
#pragma unroll
    for (int rg = 0; rg < 4; ++rg) {
      float s = acc[rg];
      sm[rg] += __expf(s);
      if (j0 + lr == i0 + lo * 4 + rg) sd[rg] = s;
    }
  }
#pragma unroll
  for (int off = 1; off < 16; off <<= 1) {
#pragma unroll
    for (int rg = 0; rg < 4; ++rg) {
      sm[rg] += __shfl_xor(sm[rg], off);
      sd[rg] += __shfl_xor(sd[rg], off);
    }
  }
  __shared__ float lsm[4][16], lsd[4][16];
  if (lr == 0) {
#pragma unroll
    for (int rg = 0; rg < 4; ++rg) {
      lsm[w][lo * 4 + rg] = sm[rg];
      lsd[w][lo * 4 + rg] = sd[rg];
    }
  }
  __syncthreads();
  if (threadIdx.x < 16) {
    float m = lsm[0][threadIdx.x] + lsm[1][threadIdx.x] + lsm[2][threadIdx.x] + lsm[3][threadIdx.x];
    float d = lsd[0][threadIdx.x] + lsd[1][threadIdx.x] + lsd[2][threadIdx.x] + lsd[3][threadIdx.x];
    psm[(size_t)blockIdx.y * 8000 + i0 + threadIdx.x] = m;
    psd[(size_t)blockIdx.y * 8000 + i0 + threadIdx.x] = d;
  }
}

// fused: combine j-splits + mean + final scalars
__global__ __launch_bounds__(1024) void k_lsefin(const float* __restrict__ psm,
                                                 const float* __restrict__ psd,
                                                 const float* __restrict__ ws,
                                                 float* __restrict__ dout) {
  float acc = 0.f;
  for (int r = threadIdx.x; r < B_ * N_; r += 1024) {
    float sm = psm[r] + psm[8000 + r] + psm[16000 + r] + psm[24000 + r];
    float sd = psd[r] + psd[8000 + r] + psd[16000 + r] + psd[24000 + r];
    acc += sd - logf(sm);
  }
  __shared__ float red[16];
  acc = waveReduceSum(acc);
  if ((threadIdx.x & 63) == 0) red[threadIdx.x >> 6] = acc;
  __syncthreads();
  if (threadIdx.x == 0) {
    float s = 0.f;
    for (int i = 0; i < 16; ++i) s += red[i];
    float closs = -s * (1.f / (B_ * N_));
    dout[BTN_] = ws[OFF_BAL];
    dout[BTN_ + 1] = CW_ * closs;
  }
}

// ---------------------------------------------------------------------------
extern "C" void kernel_launch(void* const* d_in, const int* in_sizes, int n_in,
                              void* d_out, int out_size, void* d_ws, size_t ws_size,
                              hipStream_t stream) {
  const float* x    = (const float*)d_in[0];
  const float* velo = (const float*)d_in[1];
  const float* adj  = (const float*)d_in[2];
  const float* lapd = (const float*)d_in[3];
  const float* laph = (const float*)d_in[4];
  const float* sw   = (const float*)d_in[5];
  const float* sb   = (const float*)d_in[6];
  const float* gw   = (const float*)d_in[7];
  const float* ew1  = (const float*)d_in[8];
  const float* eb1  = (const float*)d_in[9];
  const float* ew2  = (const float*)d_in[10];
  const float* eb2  = (const float*)d_in[11];
  const float* pw   = (const float*)d_in[12];
  const float* pb   = (const float*)d_in[13];
  const float* ltw  = (const float*)d_in[14];
  const float* ltb  = (const float*)d_in[15];
  const float* qkvw = (const float*)d_in[16];
  const float* qkvb = (const float*)d_in[17];
  const float* aow  = (const float*)d_in[18];
  const float* aob  = (const float*)d_in[19];
  const float* llw  = (const float*)d_in[20];
  const float* llb  = (const float*)d_in[21];
  const float* p2w  = (const float*)d_in[22];
  const float* p2b  = (const float*)d_in[23];
  float* ws = (float*)d_ws;
  float* dout = (float*)d_out;
  const float* v0 = velo;  // velo[0,0,:]
  float* part = ws + OFF_PART;
  unsigned short* atLin = (unsigned short*)(ws + OFF_AT_LIN);
  unsigned short* atQ   = (unsigned short*)(ws + OFF_AT_Q);
  unsigned short* atAO  = (unsigned short*)(ws + OFF_AT_AO);
  unsigned short* atLL  = (unsigned short*)(ws + OFF_AT_LL);
  unsigned short* g1b   = (unsigned short*)(ws + OFF_G1B);
  unsigned short* g2b   = (unsigned short*)(ws + OFF_G2B);
  dim3 b256(256);

  k_init<<<dim3(1), dim3(64), 0, stream>>>(ws);

  k_start<<<dim3((BTN_ * D_ + 255) / 256), b256, 0, stream>>>(x, sw, sb, ws + OFF_OUT4);

  for (int l = 0; l < L_; ++l) {
    k_feat<<<dim3(B_ * D_), b256, 0, stream>>>(ws + OFF_OUT4, ws + OFF_FEAT);
    k_gate<<<dim3(1), dim3(64), 0, stream>>>(ws + OFF_FEAT, gw, ws, l);
    k_expert<<<dim3((T_ * N_ + 255) / 256, B_), b256, 0, stream>>>(ws + OFF_OUT4, ew1, eb1, ew2, eb2, ws, l);
  }

  k_wavelet<<<dim3((BTN_ + 255) / 256), b256, 0, stream>>>(x, velo, ws + OFF_LOWT, ws + OFF_HVT);
  k_rowsum<<<dim3(2 * BT_), b256, 0, stream>>>(ws + OFF_LOWT, ws + OFF_HVT, ws);
  k_S<<<dim3(N_), b256, 0, stream>>>(adj, v0, ws + OFF_S);

  // fused stats (lapd, laph, NS)
  k_stats3<<<dim3(512, 1, 3), b256, 0, stream>>>(lapd, laph, adj, v0, ws + OFF_S, ws + OFF_STP);
  k_stats2<<<dim3(3), b256, 0, stream>>>(ws + OFF_STP, ws + OFF_STAT);

  // fused r1/r2/r3 GEMMs: 16-row blocks, grid (8, 20, 9)
  k_rgemm3<<<dim3(8, RKS_, 9), b256, 0, stream>>>(ws + OFF_LOWT, ws + OFF_HVT, lapd, laph,
                                                  adj, v0, ws + OFF_S, part);
  k_epiR3<<<dim3(8, 48, 3), b256, 0, stream>>>(part, ws, atLin);

  k_minmax<<<dim3(64, 3), b256, 0, stream>>>(ws + OFF_ALIN, ws + OFF_MMP);
  k_minmax2<<<dim3(3), dim3(64), 0, stream>>>(ws);
  k_colsum<<<dim3(12, 16), b256, 0, stream>>>(ltw, ws + OFF_CSP);
  k_colsum2<<<dim3(12), b256, 0, stream>>>(ws);

  // lin (MFMA, B=ltw fp32 [2000][3000]): 16 splits x 4 steps (63 steps)
  k_mfmaW<<<dim3(47, 16), b256, 0, stream>>>(atLin, ltw, part, EA_, KP2, N_, 4);
  k_epiLin<<<dim3(12, 144), b256, 0, stream>>>(part, ltb, ws, atQ, 16);

  // qkv (MFMA, B=qkvw fp32 [3000][9000]): 8 splits x 12 steps (94 steps)
  k_mfmaW<<<dim3(141, 8), b256, 0, stream>>>(atQ, qkvw, part, 3 * EA_, KP3, EA_, 12);
  k_epiQkv<<<dim3(36, 144), b256, 0, stream>>>(part, qkvb, ws + OFF_P, 8);

  // attention
  k_attn<<<dim3(T_ * B_ * H_, 3), b256, 0, stream>>>(ws + OFF_P, atAO);

  // attn-out (MFMA, B=aow fp32 [3000][3000]): 16 splits x 6 steps
  k_mfmaW<<<dim3(47, 16), b256, 0, stream>>>(atAO, aow, part, EA_, KP3, EA_, 6);
  k_epiAO<<<dim3(12, 144), b256, 0, stream>>>(part, aob, atLL, 16);

  // ll (MFMA, B=llw fp32 [3000][2000]): 20 splits x 5 steps
  k_mfmaW<<<dim3(32, 20), b256, 0, stream>>>(atLL, llw, part, N_, KP3, EA_, 5);
  k_epiLL<<<dim3(8, 48), b256, 0, stream>>>(part, llb, ws + OFF_O2P, 20);

  k_proj<<<dim3((BTN_ + 255) / 256), b256, 0, stream>>>(ws + OFF_OUT4, pw, pb, ws + OFF_OUTP);
  k_p2<<<dim3((BTN_ + 255) / 256), b256, 0, stream>>>(ws + OFF_O2P, p2w, p2b, ws + OFF_O2F);

  // fused out3 + fnorm (writes dout body + bf16 g1b/g2b)
  k_fng<<<dim3((B_ * N_ + 255) / 256), b256, 0, stream>>>(ws + OFF_OUTP, ws + OFF_O2F, dout, g1b, g2b);

  // MFMA logsumexp; psm/psd partials live in `part`
  k_lsemf<<<dim3(500, 4), b256, 0, stream>>>(g1b, g2b, part, part + 32000);
  k_lsefin<<<dim3(1), dim3(1024), 0, stream>>>(part, part + 32000, ws, dout);
}